// Round 2
// baseline (1448.392 us; speedup 1.0000x reference)
//
#include <hip/hip_runtime.h>
#include <math.h>

#define NE 160000
#define NN 10000

#define DEV __device__ __forceinline__

typedef float v2f __attribute__((ext_vector_type(2)));
typedef __attribute__((ext_vector_type(8))) short bf16x8;   // 8 bf16 (4 VGPRs)
typedef __attribute__((ext_vector_type(4))) float f32x4;

DEV float fsilu(float x) { return x / (1.0f + __expf(-x)); }
DEV float fsig(float x)  { return 1.0f / (1.0f + __expf(-x)); }

// ---- bf16 pack/unpack helpers (RNE) ----
DEV unsigned pack2(float a, float b) {
  unsigned ua = __float_as_uint(a); ua += 0x7FFFu + ((ua >> 16) & 1u);
  unsigned ub = __float_as_uint(b); ub += 0x7FFFu + ((ub >> 16) & 1u);
  return (ua >> 16) | (ub & 0xFFFF0000u);
}
DEV float unlo(unsigned u) { return __uint_as_float(u << 16); }
DEV float unhi(unsigned u) { return __uint_as_float(u & 0xFFFF0000u); }

// ---- fp8 e4m3 (OCP, HW-converted) ----
DEV unsigned packf8_4(float a, float b, float c, float d) {
  int r = __builtin_amdgcn_cvt_pk_fp8_f32(a, b, 0, false);
  r = __builtin_amdgcn_cvt_pk_fp8_f32(c, d, r, true);
  return (unsigned)r;
}
template<bool HI>
DEV v2f up2(unsigned u) { return __builtin_amdgcn_cvt_pk_f32_fp8((int)u, HI); }

// dot of 16 fp8 values (one uint4) against q[0..16)
DEV float dot16(uint4 u, const float* q, float d) {
  v2f f;
  f = up2<false>(u.x); d = fmaf(f.x, q[0],  d); d = fmaf(f.y, q[1],  d);
  f = up2<true >(u.x); d = fmaf(f.x, q[2],  d); d = fmaf(f.y, q[3],  d);
  f = up2<false>(u.y); d = fmaf(f.x, q[4],  d); d = fmaf(f.y, q[5],  d);
  f = up2<true >(u.y); d = fmaf(f.x, q[6],  d); d = fmaf(f.y, q[7],  d);
  f = up2<false>(u.z); d = fmaf(f.x, q[8],  d); d = fmaf(f.y, q[9],  d);
  f = up2<true >(u.z); d = fmaf(f.x, q[10], d); d = fmaf(f.y, q[11], d);
  f = up2<false>(u.w); d = fmaf(f.x, q[12], d); d = fmaf(f.y, q[13], d);
  f = up2<true >(u.w); d = fmaf(f.x, q[14], d); d = fmaf(f.y, q[15], d);
  return d;
}
// o[0..16) += pk * fp8x16(u)
DEV void acc16(uint4 u, float pk, float* o) {
  v2f f;
  f = up2<false>(u.x); o[0]  = fmaf(pk, f.x, o[0]);  o[1]  = fmaf(pk, f.y, o[1]);
  f = up2<true >(u.x); o[2]  = fmaf(pk, f.x, o[2]);  o[3]  = fmaf(pk, f.y, o[3]);
  f = up2<false>(u.y); o[4]  = fmaf(pk, f.x, o[4]);  o[5]  = fmaf(pk, f.y, o[5]);
  f = up2<true >(u.y); o[6]  = fmaf(pk, f.x, o[6]);  o[7]  = fmaf(pk, f.y, o[7]);
  f = up2<false>(u.z); o[8]  = fmaf(pk, f.x, o[8]);  o[9]  = fmaf(pk, f.y, o[9]);
  f = up2<true >(u.z); o[10] = fmaf(pk, f.x, o[10]); o[11] = fmaf(pk, f.y, o[11]);
  f = up2<false>(u.w); o[12] = fmaf(pk, f.x, o[12]); o[13] = fmaf(pk, f.y, o[13]);
  f = up2<true >(u.w); o[14] = fmaf(pk, f.x, o[14]); o[15] = fmaf(pk, f.y, o[15]);
}

// 2-edge, 32-out GEMM chunk (w block-uniform -> s_load broadcast)
template<int K>
DEV void g2(const float* __restrict__ x0, const float* __restrict__ x1,
            const float* __restrict__ w, float (&a0)[32], float (&a1)[32]) {
#pragma unroll 4
  for (int k = 0; k < K; k += 4) {
    const float4 u = *(const float4*)(x0 + k);
    const float4 v = *(const float4*)(x1 + k);
    const float* wr = w + (size_t)k * 64;
#pragma unroll
    for (int j = 0; j < 32; ++j) { float ww = wr[j];       a0[j] = fmaf(u.x, ww, a0[j]); a1[j] = fmaf(v.x, ww, a1[j]); }
#pragma unroll
    for (int j = 0; j < 32; ++j) { float ww = wr[64 + j];  a0[j] = fmaf(u.y, ww, a0[j]); a1[j] = fmaf(v.y, ww, a1[j]); }
#pragma unroll
    for (int j = 0; j < 32; ++j) { float ww = wr[128 + j]; a0[j] = fmaf(u.z, ww, a0[j]); a1[j] = fmaf(v.z, ww, a1[j]); }
#pragma unroll
    for (int j = 0; j < 32; ++j) { float ww = wr[192 + j]; a0[j] = fmaf(u.w, ww, a0[j]); a1[j] = fmaf(v.w, ww, a1[j]); }
  }
}

// 1-edge, 32-out GEMM chunk
template<int K>
DEV void g1(const float* __restrict__ x, const float* __restrict__ w,
            float (&a)[32]) {
#pragma unroll 4
  for (int k = 0; k < K; k += 4) {
    const float4 u = *(const float4*)(x + k);
    const float* wr = w + (size_t)k * 64;
#pragma unroll
    for (int j = 0; j < 32; ++j) a[j] = fmaf(u.x, wr[j], a[j]);
#pragma unroll
    for (int j = 0; j < 32; ++j) a[j] = fmaf(u.y, wr[64 + j], a[j]);
#pragma unroll
    for (int j = 0; j < 32; ++j) a[j] = fmaf(u.z, wr[128 + j], a[j]);
#pragma unroll
    for (int j = 0; j < 32; ++j) a[j] = fmaf(u.w, wr[192 + j], a[j]);
  }
}

// 1-edge, 16-out GEMV chunk (for quad-split kernels)
template<int K>
DEV void g16(const float* __restrict__ x, const float* __restrict__ w,
             float (&a)[16]) {
#pragma unroll 4
  for (int k = 0; k < K; k += 4) {
    const float4 u = *(const float4*)(x + k);
    const float* wr = w + (size_t)k * 64;
#pragma unroll
    for (int j = 0; j < 16; ++j) a[j] = fmaf(u.x, wr[j], a[j]);
#pragma unroll
    for (int j = 0; j < 16; ++j) a[j] = fmaf(u.y, wr[64 + j], a[j]);
#pragma unroll
    for (int j = 0; j < 16; ++j) a[j] = fmaf(u.z, wr[128 + j], a[j]);
#pragma unroll
    for (int j = 0; j < 16; ++j) a[j] = fmaf(u.w, wr[192 + j], a[j]);
  }
}

// sum across a lane quad (lanes 4e..4e+3)
DEV float qsum(float v) { v += __shfl_xor(v, 1); v += __shfl_xor(v, 2); return v; }

DEV void ldrow16(const unsigned* __restrict__ p, unsigned (&r)[16]) {
#pragma unroll
  for (int t = 0; t < 4; ++t) {
    uint4 u = ((const uint4*)p)[t];
    r[4*t] = u.x; r[4*t+1] = u.y; r[4*t+2] = u.z; r[4*t+3] = u.w;
  }
}
DEV void storef8_64(unsigned* dst, const float (&a)[64]) {  // 16 uints (fp8)
#pragma unroll
  for (int t = 0; t < 4; ++t)
    ((uint4*)dst)[t] = make_uint4(
        packf8_4(a[16*t+0],  a[16*t+1],  a[16*t+2],  a[16*t+3]),
        packf8_4(a[16*t+4],  a[16*t+5],  a[16*t+6],  a[16*t+7]),
        packf8_4(a[16*t+8],  a[16*t+9],  a[16*t+10], a[16*t+11]),
        packf8_4(a[16*t+12], a[16*t+13], a[16*t+14], a[16*t+15]));
}
DEV void unpackf8(const unsigned (&p)[16], float (&o)[64]) {
#pragma unroll
  for (int t = 0; t < 16; ++t) {
    v2f f0 = up2<false>(p[t]);
    v2f f1 = up2<true >(p[t]);
    o[4*t+0] = f0.x; o[4*t+1] = f0.y; o[4*t+2] = f1.x; o[4*t+3] = f1.y;
  }
}
DEV void store32(float* dst, const float (&a)[32]) {
#pragma unroll
  for (int j = 0; j < 32; j += 4)
    *(float4*)(dst + j) = make_float4(a[j], a[j+1], a[j+2], a[j+3]);
}

// ---------- CSR build over edges[0] (rows) ----------
__global__ void __launch_bounds__(256)
k_count(const int* __restrict__ edges, int* __restrict__ icnt) {
  int e = blockIdx.x * 256 + threadIdx.x;
  if (e < NE) atomicAdd(&icnt[edges[e]], 1);
}

__global__ void __launch_bounds__(256)
k_scan(const int* __restrict__ icnt, int* __restrict__ ioffs) {
  __shared__ int part[256];
  const int t = threadIdx.x;
  const int base = t * 40;
  int loc[40];
  int s = 0;
#pragma unroll
  for (int i = 0; i < 40; ++i) {
    int idx = base + i;
    int v = (idx < NN) ? icnt[idx] : 0;
    loc[i] = v; s += v;
  }
  part[t] = s;
  __syncthreads();
  for (int off = 1; off < 256; off <<= 1) {
    int v = (t >= off) ? part[t - off] : 0;
    __syncthreads();
    part[t] += v;
    __syncthreads();
  }
  int run = (t == 0) ? 0 : part[t - 1];
#pragma unroll
  for (int i = 0; i < 40; ++i) {
    int idx = base + i;
    if (idx < NN) { ioffs[idx] = run; run += loc[i]; }
  }
  if (t == 255) ioffs[NN] = NE;
}

__global__ void __launch_bounds__(256)
k_fill(const int* __restrict__ edges, const int* __restrict__ ioffs,
       int* __restrict__ icur, int* __restrict__ eidx) {
  int e = blockIdx.x * 256 + threadIdx.x;
  if (e >= NE) return;
  int r = edges[e];
  int p = atomicAdd(&icur[r], 1);
  eidx[ioffs[r] + p] = e;
}

// ---------- chem layer 1: 272 -> 64 silu (2 edges/thread, y-split) ----------
__global__ void __launch_bounds__(128)
k_chem1(const float* __restrict__ h, const float* __restrict__ na,
        const float* __restrict__ ea, const int* __restrict__ edges,
        const float* __restrict__ w1, const float* __restrict__ b1,
        float* __restrict__ act1c) {
  const int tid = threadIdx.x;
  const int e0 = blockIdx.x * 256 + tid, e1 = e0 + 128;
  const int co = blockIdx.y * 32;
  const int r0 = edges[e0], c0 = edges[NE + e0];
  const int r1 = edges[e1], c1 = edges[NE + e1];
  float a0[32], a1[32];
#pragma unroll
  for (int j = 0; j < 32; ++j) { a0[j] = b1[co + j]; a1[j] = a0[j]; }
  g2<64>(h  + (size_t)r0 * 64, h  + (size_t)r1 * 64, w1 + co,            a0, a1);
  g2<64>(h  + (size_t)c0 * 64, h  + (size_t)c1 * 64, w1 +  64 * 64 + co, a0, a1);
  g2<64>(na + (size_t)r0 * 64, na + (size_t)r1 * 64, w1 + 128 * 64 + co, a0, a1);
  g2<64>(na + (size_t)c0 * 64, na + (size_t)c1 * 64, w1 + 192 * 64 + co, a0, a1);
  g2<16>(ea + (size_t)e0 * 16, ea + (size_t)e1 * 16, w1 + 256 * 64 + co, a0, a1);
#pragma unroll
  for (int j = 0; j < 32; ++j) { a0[j] = fsilu(a0[j]); a1[j] = fsilu(a1[j]); }
  store32(act1c + (size_t)e0 * 64 + co, a0);
  store32(act1c + (size_t)e1 * 64 + co, a1);
}

// ---------- pos layer 1: 36 -> 64 silu ----------
__global__ void __launch_bounds__(256)
k_pos1(const float* __restrict__ coord, const float* __restrict__ nv,
       const float* __restrict__ ea, const int* __restrict__ edges,
       const float* __restrict__ w1, const float* __restrict__ b1,
       float* __restrict__ act1p) {
  const int e = blockIdx.x * 256 + threadIdx.x;
  const int co = blockIdx.y * 32;
  const int r = edges[e], c = edges[NE + e];

  float dx = coord[r * 3 + 0] - coord[c * 3 + 0];
  float dy = coord[r * 3 + 1] - coord[c * 3 + 1];
  float dz = coord[r * 3 + 2] - coord[c * 3 + 2];
  float nrm = sqrtf(dx * dx + dy * dy + dz * dz);
  float inv = 1.0f / (nrm + 1e-8f);
  dx *= inv; dy *= inv; dz *= inv;
  float ir = dx * dx + dy * dy + dz * dz;

  float in[36];
#pragma unroll
  for (int v = 0; v < 5; ++v) {
    float s = 0.f;
#pragma unroll
    for (int d = 0; d < 3; ++d)
      s += nv[(size_t)r * 15 + v * 3 + d] * nv[(size_t)c * 15 + v * 3 + d];
    in[v] = s;
  }
  {
    float cexp = -0.5f;
#pragma unroll
    for (int k = 0; k < 15; ++k) { in[5 + k] = __expf(ir * cexp); cexp *= (1.0f / 2.25f); }
  }
#pragma unroll
  for (int k = 0; k < 16; k += 4) {
    float4 e4 = *(const float4*)(ea + (size_t)e * 16 + k);
    in[20 + k] = e4.x; in[21 + k] = e4.y; in[22 + k] = e4.z; in[23 + k] = e4.w;
  }

  float acc[32];
#pragma unroll
  for (int j = 0; j < 32; ++j) acc[j] = b1[co + j];
#pragma unroll
  for (int k = 0; k < 36; ++k) {
    const float x = in[k];
    const float* wr = w1 + (size_t)k * 64 + co;
#pragma unroll
    for (int j = 0; j < 32; ++j) acc[j] = fmaf(x, wr[j], acc[j]);
  }
#pragma unroll
  for (int j = 0; j < 32; ++j) acc[j] = fsilu(acc[j]);
  store32(act1p + (size_t)e * 64 + co, acc);
}

// ---------- layer 2 of both MLPs (2 edges/thread, y-split) ----------
__global__ void __launch_bounds__(128)
k_l2(const float* __restrict__ act1c, const float* __restrict__ act1p,
     const float* __restrict__ w2c, const float* __restrict__ b2c,
     const float* __restrict__ w2p, const float* __restrict__ b2p,
     float* __restrict__ chem, float* __restrict__ pos) {
  const int tid = threadIdx.x;
  const int e0 = blockIdx.x * 256 + tid, e1 = e0 + 128;
  const int co = blockIdx.y * 32;
  float a0[32], a1[32];
#pragma unroll
  for (int j = 0; j < 32; ++j) { a0[j] = b2c[co + j]; a1[j] = a0[j]; }
  g2<64>(act1c + (size_t)e0 * 64, act1c + (size_t)e1 * 64, w2c + co, a0, a1);
#pragma unroll
  for (int j = 0; j < 32; ++j) { a0[j] = fsilu(a0[j]); a1[j] = fsilu(a1[j]); }
  store32(chem + (size_t)e0 * 64 + co, a0);
  store32(chem + (size_t)e1 * 64 + co, a1);
#pragma unroll
  for (int j = 0; j < 32; ++j) { a0[j] = b2p[co + j]; a1[j] = a0[j]; }
  g2<64>(act1p + (size_t)e0 * 64, act1p + (size_t)e1 * 64, w2p + co, a0, a1);
#pragma unroll
  for (int j = 0; j < 32; ++j) { a0[j] = fsilu(a0[j]); a1[j] = fsilu(a1[j]); }
  store32(pos + (size_t)e0 * 64 + co, a0);
  store32(pos + (size_t)e1 * 64 + co, a1);
}

// ---------- fused scalars: quad-split (4 threads/edge, 16 cols each) ----------
// z = silu(chem@Wsh+b)*pos, att-gated -> zb bf16; be[4]; u/x heads; coord atomics.
// Quad reductions via __shfl_xor(1/2). Grid: NE/64 blocks of 256 (10000 waves).
__global__ void __launch_bounds__(256)
k_scalars(const float* __restrict__ coord, const int* __restrict__ edges,
          const float* __restrict__ chem, const float* __restrict__ pos,
          const float* __restrict__ wsh, const float* __restrict__ bsh,
          const float* __restrict__ watt, const float* __restrict__ batt,
          const float* __restrict__ wu1, const float* __restrict__ bu1,
          const float* __restrict__ wu2, const float* __restrict__ bu2,
          const float* __restrict__ wx1, const float* __restrict__ bx1,
          const float* __restrict__ wx2, const float* __restrict__ bx2,
          const float* __restrict__ wb,
          unsigned* __restrict__ zb, float* __restrict__ be,
          float* __restrict__ x_sum, float* __restrict__ cntf) {
  const int tid = threadIdx.x;
  const int e   = blockIdx.x * 64 + (tid >> 2);
  const int sub = tid & 3;
  const int co  = sub * 16;
  const float* crow = chem + (size_t)e * 64;
  const float* prow = pos  + (size_t)e * 64;

  // z chunk [co, co+16)
  float z[16];
  {
    float acc[16];
#pragma unroll
    for (int j = 0; j < 16; ++j) acc[j] = bsh[co + j];
    g16<64>(crow, wsh + co, acc);
#pragma unroll
    for (int j = 0; j < 16; j += 4) {
      float4 p4 = *(const float4*)(prow + co + j);
      z[j+0] = fsilu(acc[j+0]) * p4.x; z[j+1] = fsilu(acc[j+1]) * p4.y;
      z[j+2] = fsilu(acc[j+2]) * p4.z; z[j+3] = fsilu(acc[j+3]) * p4.w;
    }
  }
  // att gate: quad-reduced full-row dot
  float ap = 0.f;
#pragma unroll
  for (int k = 0; k < 16; ++k) ap = fmaf(z[k], watt[co + k], ap);
  const float sg = fsig(qsum(ap) + batt[0]);
#pragma unroll
  for (int j = 0; j < 16; ++j) z[j] *= sg;

  // zb: 8 uints per sub (contiguous 32B per lane -> fully coalesced)
  {
    unsigned* zrow = zb + (size_t)e * 32 + sub * 8;
#pragma unroll
    for (int t = 0; t < 2; ++t)
      ((uint4*)zrow)[t] = make_uint4(pack2(z[8*t],   z[8*t+1]), pack2(z[8*t+2], z[8*t+3]),
                                     pack2(z[8*t+4], z[8*t+5]), pack2(z[8*t+6], z[8*t+7]));
  }
  // per-head b scalars (quad partials)
  {
    float b0 = 0.f, b1 = 0.f, b2 = 0.f, b3 = 0.f;
#pragma unroll
    for (int k = 0; k < 16; ++k) {
      const float zk = z[k];
      b0 = fmaf(zk, wb[0 * 64 + co + k], b0);
      b1 = fmaf(zk, wb[1 * 64 + co + k], b1);
      b2 = fmaf(zk, wb[2 * 64 + co + k], b2);
      b3 = fmaf(zk, wb[3 * 64 + co + k], b3);
    }
    b0 = qsum(b0); b1 = qsum(b1); b2 = qsum(b2); b3 = qsum(b3);
    if (sub == 0) *(float4*)(be + (size_t)e * 4) = make_float4(b0, b1, b2, b3);
  }
  // u = silu(chem@wu1+bu1)@wu2 + bu2   (quad partial over 16 cols)
  float u;
  {
    float acc[16];
#pragma unroll
    for (int j = 0; j < 16; ++j) acc[j] = bu1[co + j];
    g16<64>(crow, wu1 + co, acc);
    float up = 0.f;
#pragma unroll
    for (int j = 0; j < 16; ++j) up = fmaf(fsilu(acc[j]), wu2[co + j], up);
    u = qsum(up) + bu2[0];
  }
  // xs = silu(pos@wx1+bx1)@wx2 + bx2
  float xs;
  {
    float acc[16];
#pragma unroll
    for (int j = 0; j < 16; ++j) acc[j] = bx1[co + j];
    g16<64>(prow, wx1 + co, acc);
    float xp = 0.f;
#pragma unroll
    for (int j = 0; j < 16; ++j) xp = fmaf(fsilu(acc[j]), wx2[co + j], xp);
    xs = qsum(xp) + bx2[0];
  }

  if (sub == 0) {
    const int r = edges[e], c = edges[NE + e];
    float dx = coord[r * 3 + 0] - coord[c * 3 + 0];
    float dy = coord[r * 3 + 1] - coord[c * 3 + 1];
    float dz = coord[r * 3 + 2] - coord[c * 3 + 2];
    float nrm = sqrtf(dx * dx + dy * dy + dz * dz);
    float inv = 1.0f / (nrm + 1e-8f);
    float t = u * xs;
    atomicAdd(&x_sum[r * 3 + 0], dx * inv * t);
    atomicAdd(&x_sum[r * 3 + 1], dy * inv * t);
    atomicAdd(&x_sum[r * 3 + 2], dz * inv * t);
    atomicAdd(&cntf[r], 1.0f);
  }
}

// ---------- weight prep: wtb[m][n][k] = W_m[k][n] in bf16 (A-operand layout) ----------
// m = hd*4 + which, which: 0=k, 1=v, 2=q, 3=g
__global__ void __launch_bounds__(256)
k_wprep(const float* __restrict__ wk, const float* __restrict__ wv,
        const float* __restrict__ wq, const float* __restrict__ wg,
        unsigned short* __restrict__ wtb) {
  const int m = blockIdx.x;          // 0..15
  const int hd = m >> 2, which = m & 3;
  const float* src = (which == 0) ? wk : (which == 1) ? wv : (which == 2) ? wq : wg;
  src += (size_t)hd * 4096;
  const int t = threadIdx.x;
#pragma unroll
  for (int i = 0; i < 16; ++i) {
    int idx = t * 16 + i;
    int n = idx >> 6, kk = idx & 63;
    unsigned u = __float_as_uint(src[kk * 64 + n]);
    u += 0x7FFFu + ((u >> 16) & 1u);
    wtb[(size_t)m * 4096 + idx] = (unsigned short)(u >> 16);
  }
}

// ---------- MFMA projections: z[NE,64]bf16 @ 16x W[64,64]bf16 -> kvh/qho/gf8 fp8 ----------
// D[n][e] = W^T * z^T per mfma_f32_16x16x32_bf16. C/D layout (m89-verified):
// col=lane&15 (edge), row=(lane>>4)*4+reg (4 consecutive n) -> one packf8_4 per frag.
// Each wave: 64 edges (4 e-tiles), loops 16 matrices; A-frags L2-resident (128KB).
__global__ void __launch_bounds__(256)
k_projm(const unsigned* __restrict__ zb, const unsigned short* __restrict__ wtb,
        const float* __restrict__ bg,
        unsigned* __restrict__ kvh, unsigned* __restrict__ qho,
        unsigned* __restrict__ gf8) {
  const int lane = threadIdx.x & 63;
  const int wid  = threadIdx.x >> 6;        // wave 0..3
  const int er   = lane & 15;               // edge-in-tile (D col / B col / A row)
  const int q    = lane >> 4;               // k-block (A/B), row-quad (D)
  const int e0   = blockIdx.x * 256 + wid * 64 + er;

  // B frags: z^T, col=e, k=(lane>>4)*8 + i (+32 for half 1)
  bf16x8 zf[4][2];
#pragma unroll
  for (int et = 0; et < 4; ++et) {
    const unsigned* zrow = zb + (size_t)(e0 + et * 16) * 32;   // 64 bf16
    zf[et][0] = __builtin_bit_cast(bf16x8, *(const uint4*)(zrow + q * 4));
    zf[et][1] = __builtin_bit_cast(bf16x8, *(const uint4*)(zrow + 16 + q * 4));
  }

  const f32x4 zero = {0.f, 0.f, 0.f, 0.f};
#pragma unroll 1
  for (int m = 0; m < 16; ++m) {
    const unsigned short* wm = wtb + (size_t)m * 4096;
    f32x4 acc[4][4];
#pragma unroll
    for (int et = 0; et < 4; ++et)
#pragma unroll
      for (int nf = 0; nf < 4; ++nf) acc[et][nf] = zero;
#pragma unroll
    for (int nf = 0; nf < 4; ++nf) {
      // A frag: row n = nf*16 + er, k = q*8..q*8+7 (half 0), +32 (half 1)
      const unsigned short* ar = wm + (size_t)(nf * 16 + er) * 64 + q * 8;
      const bf16x8 a0 = *(const bf16x8*)ar;
      const bf16x8 a1 = *(const bf16x8*)(ar + 32);
#pragma unroll
      for (int et = 0; et < 4; ++et) {
        acc[et][nf] = __builtin_amdgcn_mfma_f32_16x16x32_bf16(a0, zf[et][0], acc[et][nf], 0, 0, 0);
        acc[et][nf] = __builtin_amdgcn_mfma_f32_16x16x32_bf16(a1, zf[et][1], acc[et][nf], 0, 0, 0);
      }
    }
    const int hd = m >> 2, which = m & 3;    // wave-uniform
#pragma unroll
    for (int et = 0; et < 4; ++et) {
      const size_t rec = (size_t)(e0 + et * 16) * 4 + hd;
      unsigned* dst = (which == 0) ? (kvh + rec * 32)
                    : (which == 1) ? (kvh + rec * 32 + 16)
                    : (which == 2) ? (qho + rec * 16)
                                   : (gf8 + rec * 16);
      if (which == 3) {
#pragma unroll
        for (int nf = 0; nf < 4; ++nf) {
          const float4 b4 = *(const float4*)(bg + hd * 64 + nf * 16 + q * 4);
          dst[nf * 4 + q] = packf8_4(fsig(acc[et][nf].x + b4.x), fsig(acc[et][nf].y + b4.y),
                                     fsig(acc[et][nf].z + b4.z), fsig(acc[et][nf].w + b4.w));
        }
      } else {
#pragma unroll
        for (int nf = 0; nf < 4; ++nf)
          dst[nf * 4 + q] = packf8_4(acc[et][nf].x, acc[et][nf].y,
                                     acc[et][nf].z, acc[et][nf].w);
      }
    }
  }
}

// ---------- attention: flat grid, lane quad = 4 heads of one edge ----------
// gathers at [i2*4+hd] -> 4 lanes read 512B contiguous; ho fp8 overwrites q slot
__global__ void __launch_bounds__(256)
k_attn(unsigned* __restrict__ qho, const unsigned* __restrict__ gf8,
       const unsigned* __restrict__ kvh, const float* __restrict__ be,
       const int* __restrict__ klist) {
  const int t = blockIdx.x * 256 + threadIdx.x;
  const int e = t >> 2, hd = t & 3;

  // q (fp8 -> fp32, unscaled)
  float q[64];
  {
    unsigned qp[16];
    ldrow16(qho + (size_t)t * 16, qp);
    unpackf8(qp, q);
  }

  int i2[8], j2[8];
#pragma unroll
  for (int kn = 0; kn < 8; ++kn) {
    i2[kn] = klist[(size_t)e * 16 + kn];
    j2[kn] = klist[(size_t)e * 16 + 8 + kn];
  }
  float bv[8];
#pragma unroll
  for (int kn = 0; kn < 8; ++kn)
    bv[kn] = be[(size_t)((i2[kn] < 0) ? 0 : j2[kn]) * 4 + hd];

  const uint4* kv4 = (const uint4*)kvh;   // 8 uint4 per record
  float alpha[8];
#pragma unroll 2
  for (int kn = 0; kn < 8; ++kn) {
    if (i2[kn] < 0) { alpha[kn] = -10000.0f; continue; }
    const uint4* kr = kv4 + ((size_t)i2[kn] * 4 + hd) * 8;
    uint4 u0 = kr[0], u1 = kr[1], u2 = kr[2], u3 = kr[3];
    float d = 0.f;
    d = dot16(u0, q,      d);
    d = dot16(u1, q + 16, d);
    d = dot16(u2, q + 32, d);
    d = dot16(u3, q + 48, d);
    alpha[kn] = d * 0.125f + bv[kn];
  }
  float mx = alpha[0];
#pragma unroll
  for (int kn = 1; kn < 8; ++kn) mx = fmaxf(mx, alpha[kn]);
  float p[8], s = 0.f;
#pragma unroll
  for (int kn = 0; kn < 8; ++kn) { p[kn] = __expf(alpha[kn] - mx); s += p[kn]; }
  float is = 1.0f / s;
#pragma unroll
  for (int kn = 0; kn < 8; ++kn) p[kn] *= is;

  float ov[64];
#pragma unroll
  for (int j = 0; j < 64; ++j) ov[j] = 0.f;
#pragma unroll 2
  for (int kn = 0; kn < 8; ++kn) {
    int vi = (i2[kn] < 0) ? (NE - 1) : i2[kn];   // jax v[-1] wraps
    const uint4* vr = kv4 + ((size_t)vi * 4 + hd) * 8 + 4;
    uint4 u0 = vr[0], u1 = vr[1], u2 = vr[2], u3 = vr[3];
    const float pk = p[kn];
    acc16(u0, pk, ov +  0);
    acc16(u1, pk, ov + 16);
    acc16(u2, pk, ov + 32);
    acc16(u3, pk, ov + 48);
  }
  // gate (precomputed sigmoid, fp8)
  {
    unsigned gp[16];
    ldrow16(gf8 + (size_t)t * 16, gp);
    float g[64];
    unpackf8(gp, g);
#pragma unroll
    for (int j = 0; j < 64; ++j) ov[j] *= g[j];
  }
  // ho fp8 -> same slot as q (thread-private)
  storef8_64(qho + (size_t)t * 16, ov);
}

// ---------- output projection (all heads), per-edge m row (non-atomic) ----------
__global__ void __launch_bounds__(256)
k_mout(const unsigned* __restrict__ qho, const float* __restrict__ wout,
       float* __restrict__ medge) {
  const int e = blockIdx.x * 256 + threadIdx.x;
  float mm[64];
#pragma unroll
  for (int j = 0; j < 64; ++j) mm[j] = 0.f;
#pragma unroll 1
  for (int hd = 0; hd < 4; ++hd) {
    unsigned hp[16];
    ldrow16(qho + ((size_t)e * 4 + hd) * 16, hp);
    const float* wo = wout + (size_t)hd * 4096;
#pragma unroll 4
    for (int t = 0; t < 16; ++t) {
      v2f f0 = up2<false>(hp[t]);
      v2f f1 = up2<true >(hp[t]);
      const float* wr = wo + (size_t)(4 * t) * 64;
#pragma unroll
      for (int j = 0; j < 64; ++j) mm[j] = fmaf(f0.x, wr[j], mm[j]);
#pragma unroll
      for (int j = 0; j < 64; ++j) mm[j] = fmaf(f0.y, wr[64 + j], mm[j]);
#pragma unroll
      for (int j = 0; j < 64; ++j) mm[j] = fmaf(f1.x, wr[128 + j], mm[j]);
#pragma unroll
      for (int j = 0; j < 64; ++j) mm[j] = fmaf(f1.y, wr[192 + j], mm[j]);
    }
  }
  float* mr = medge + (size_t)e * 64;
#pragma unroll
  for (int j = 0; j < 64; j += 4)
    *(float4*)(mr + j) = make_float4(mm[j], mm[j+1], mm[j+2], mm[j+3]);
}

// ---------- CSR gather: per-node segment sum of medge ----------
__global__ void __launch_bounds__(256)
k_nodesum(const float* __restrict__ medge, const int* __restrict__ ioffs,
          const int* __restrict__ eidx, float* __restrict__ m_sum) {
  const int wid = threadIdx.x >> 6, lane = threadIdx.x & 63;
  const int n = blockIdx.x * 4 + wid;
  if (n >= NN) return;
  const int beg = ioffs[n], end = ioffs[n + 1];
  float acc = 0.f;
  for (int i = beg; i < end; ++i) {
    int e = eidx[i];
    acc += medge[(size_t)e * 64 + lane];
  }
  m_sum[(size_t)n * 64 + lane] = acc;
}

// ---------- final node update ----------
__global__ void __launch_bounds__(256)
k_final(const float* __restrict__ h, const float* __restrict__ na,
        const float* __restrict__ coord, const float* __restrict__ icoord,
        const float* __restrict__ m_sum, const float* __restrict__ x_sum,
        const float* __restrict__ cntf, const float* __restrict__ bout,
        const float* __restrict__ wh1, const float* __restrict__ bh1,
        const float* __restrict__ wh2, const float* __restrict__ bh2,
        float* __restrict__ scr, float* __restrict__ out) {
  int n = blockIdx.x * 256 + threadIdx.x;
  if (n >= NN) return;
  float cn = cntf[n];
  float invc = 1.0f / fmaxf(cn, 1.0f);
  float bsc = (cn > 0.f) ? 1.0f : 0.0f;   // empty segment => m_agg = 0 (no bout)

#pragma unroll
  for (int d = 0; d < 3; ++d)
    out[(size_t)NN * 64 + n * 3 + d] =
        0.2f * icoord[n * 3 + d] + 0.8f * coord[n * 3 + d] + x_sum[n * 3 + d] * invc;

  const float* hr = h  + (size_t)n * 64;
  const float* nr = na + (size_t)n * 64;
  const float* mr = m_sum + (size_t)n * 64;
  float* srow = scr + (size_t)n * 64;

#pragma unroll 1
  for (int cc = 0; cc < 64; cc += 32) {
    float acc[32];
#pragma unroll
    for (int j = 0; j < 32; ++j) acc[j] = bh1[cc + j];
    g1<64>(hr, wh1 + cc, acc);
    g1<64>(nr, wh1 + 64 * 64 + cc, acc);
#pragma unroll 4
    for (int k = 0; k < 64; k += 4) {
      float4 m4 = *(const float4*)(mr + k);
      float xv[4] = { fmaf(m4.x, invc, bout[k] * bsc), fmaf(m4.y, invc, bout[k+1] * bsc),
                      fmaf(m4.z, invc, bout[k+2] * bsc), fmaf(m4.w, invc, bout[k+3] * bsc) };
#pragma unroll
      for (int q = 0; q < 4; ++q) {
        const float* wr = wh1 + (size_t)(128 + k + q) * 64 + cc;
        const float x = xv[q];
#pragma unroll
        for (int j = 0; j < 32; ++j) acc[j] = fmaf(x, wr[j], acc[j]);
      }
    }
#pragma unroll
    for (int j = 0; j < 32; ++j) acc[j] = fsilu(acc[j]);
    store32(srow + cc, acc);
  }
#pragma unroll 1
  for (int cc = 0; cc < 64; cc += 32) {
    float acc[32];
#pragma unroll
    for (int j = 0; j < 32; ++j) acc[j] = bh2[cc + j];
    g1<64>(srow, wh2 + cc, acc);
#pragma unroll
    for (int j = 0; j < 32; j += 4) {
      float4 h4 = *(const float4*)(hr + cc + j);
      *(float4*)(out + (size_t)n * 64 + cc + j) =
          make_float4(acc[j] + h4.x, acc[j+1] + h4.y, acc[j+2] + h4.z, acc[j+3] + h4.w);
    }
  }
}

extern "C" void kernel_launch(void* const* d_in, const int* in_sizes, int n_in,
                              void* d_out, int out_size, void* d_ws, size_t ws_size,
                              hipStream_t stream) {
  (void)in_sizes; (void)n_in; (void)out_size; (void)ws_size;
  const float* h      = (const float*)d_in[0];
  const float* coord  = (const float*)d_in[1];
  const int*   edges  = (const int*)  d_in[2];
  const float* nvecs  = (const float*)d_in[3];
  const float* ea     = (const float*)d_in[4];
  const float* na     = (const float*)d_in[5];
  const float* icoord = (const float*)d_in[6];
  const int*   klist  = (const int*)  d_in[7];
  const float* w_chem1 = (const float*)d_in[8];
  const float* b_chem1 = (const float*)d_in[9];
  const float* w_chem2 = (const float*)d_in[10];
  const float* b_chem2 = (const float*)d_in[11];
  const float* w_pos1  = (const float*)d_in[12];
  const float* b_pos1  = (const float*)d_in[13];
  const float* w_pos2  = (const float*)d_in[14];
  const float* b_pos2  = (const float*)d_in[15];
  const float* w_sh    = (const float*)d_in[16];
  const float* b_sh    = (const float*)d_in[17];
  const float* w_att   = (const float*)d_in[18];
  const float* b_att   = (const float*)d_in[19];
  const float* wq      = (const float*)d_in[20];
  const float* wk      = (const float*)d_in[21];
  const float* wv      = (const float*)d_in[22];
  const float* wb      = (const float*)d_in[23];
  const float* wg      = (const float*)d_in[24];
  const float* bg      = (const float*)d_in[25];
  const float* w_out   = (const float*)d_in[26];
  const float* b_out   = (const float*)d_in[27];
  const float* wu1     = (const float*)d_in[28];
  const float* bu1     = (const float*)d_in[29];
  const float* wu2     = (const float*)d_in[30];
  const float* bu2     = (const float*)d_in[31];
  const float* wx1     = (const float*)d_in[32];
  const float* bx1     = (const float*)d_in[33];
  const float* wx2     = (const float*)d_in[34];
  const float* bx2     = (const float*)d_in[35];
  const float* wh1     = (const float*)d_in[36];
  const float* bh1     = (const float*)d_in[37];
  const float* wh2     = (const float*)d_in[38];
  const float* bh2     = (const float*)d_in[39];

  float* out = (float*)d_out;
  float* ws  = (float*)d_ws;
  // Phase-reused regions (NE*64 floats each):
  //  R1+R2: act1c/act1p -> kvh [e*4+hd] fp8 (82MB) -> medge in R1 after attn
  //  R3:    chem        -> qho [e*4+hd] fp8 q, then ho in-place
  //  R4:    pos         -> gf8 [e*4+hd] fp8 sigmoid-gate
  float* R1 = ws;
  float* R2 = R1 + (size_t)NE * 64;
  float* R3 = R2 + (size_t)NE * 64;
  float* R4 = R3 + (size_t)NE * 64;
  float* zbf   = R4 + (size_t)NE * 64;      // NE*32 floats (bf16 gated z)
  float* x_sum = zbf + (size_t)NE * 32;     // NN*3 (zeroed)
  float* cntf  = x_sum + (size_t)NN * 3;    // NN (zeroed)
  int*   icnt  = (int*)(cntf + NN);         // NN (zeroed)
  int*   icur  = icnt + NN;                 // NN (zeroed)
  float* m_sum = (float*)(icur + NN);       // NN*64
  float* be    = m_sum + (size_t)NN * 64;   // 4*NE  ([e*4+hd] layout)
  float* nscr  = be + (size_t)4 * NE;       // NN*64
  unsigned short* wtb = (unsigned short*)(nscr + (size_t)NN * 64);  // 16*64*64 bf16 (128KB, 16B-aligned)
  int*   ioffs = (int*)(wtb + 16 * 4096);   // NN+1
  int*   eidx  = ioffs + (NN + 1);          // NE

  unsigned* kvh = (unsigned*)R1;   // [NE*4][32] interleaved fp8 (spans R1+R2)
  unsigned* qho = (unsigned*)R3;   // [NE*4][16] fp8 q -> ho
  unsigned* gf8 = (unsigned*)R4;   // [NE*4][16] fp8 gate
  unsigned* zb  = (unsigned*)zbf;
  float* medge = R1;               // after attention (kvh dead)

  (void)hipMemsetAsync(x_sum, 0, ((size_t)NN * 3 + NN + NN + NN) * sizeof(float), stream);

  dim3 b128(128), b256(256);
  dim3 gs2(NE / 256, 2);
  dim3 gflat(NE / 256);

  // weight prep + CSR build (independent of the MLP pipeline)
  k_wprep<<<dim3(16), b256, 0, stream>>>(wk, wv, wq, wg, wtb);
  k_count<<<gflat, b256, 0, stream>>>(edges, icnt);
  k_scan <<<dim3(1), b256, 0, stream>>>(icnt, ioffs);
  k_fill <<<gflat, b256, 0, stream>>>(edges, ioffs, icur, eidx);

  k_chem1<<<gs2, b128, 0, stream>>>(h, na, ea, edges, w_chem1, b_chem1, R1);
  k_pos1 <<<gs2, b256, 0, stream>>>(coord, nvecs, ea, edges, w_pos1, b_pos1, R2);
  k_l2   <<<gs2, b128, 0, stream>>>(R1, R2, w_chem2, b_chem2, w_pos2, b_pos2, R3, R4);
  k_scalars<<<dim3(NE / 64), b256, 0, stream>>>(coord, edges, R3, R4, w_sh, b_sh, w_att, b_att,
                                                wu1, bu1, wu2, bu2, wx1, bx1, wx2, bx2, wb,
                                                zb, be, x_sum, cntf);
  k_projm<<<dim3(NE / 256), b256, 0, stream>>>(zb, wtb, bg, kvh, qho, gf8);
  k_attn <<<dim3(NE * 4 / 256), b256, 0, stream>>>(qho, gf8, kvh, be, klist);
  k_mout <<<gflat, b256, 0, stream>>>(qho, w_out, medge);
  k_nodesum<<<dim3((NN + 3) / 4), b256, 0, stream>>>(medge, ioffs, eidx, m_sum);
  k_final<<<dim3((NN + 255) / 256), b256, 0, stream>>>(h, na, coord, icoord, m_sum, x_sum,
                                                       cntf, b_out, wh1, bh1, wh2, bh2,
                                                       nscr, out);
}

// Round 3
// 1048.226 us; speedup vs baseline: 1.3818x; 1.3818x over previous
//
#include <hip/hip_runtime.h>
#include <math.h>

#define NE 160000
#define NN 10000

#define DEV __device__ __forceinline__

typedef float v2f __attribute__((ext_vector_type(2)));
typedef __attribute__((ext_vector_type(8))) short bf16x8;   // 8 bf16 (4 VGPRs)
typedef __attribute__((ext_vector_type(4))) float f32x4;

DEV float fsilu(float x) { return x / (1.0f + __expf(-x)); }
DEV float fsig(float x)  { return 1.0f / (1.0f + __expf(-x)); }

// ---- bf16 pack/unpack helpers (RNE) ----
DEV unsigned pack2(float a, float b) {
  unsigned ua = __float_as_uint(a); ua += 0x7FFFu + ((ua >> 16) & 1u);
  unsigned ub = __float_as_uint(b); ub += 0x7FFFu + ((ub >> 16) & 1u);
  return (ua >> 16) | (ub & 0xFFFF0000u);
}

// ---- fp8 e4m3 (OCP, HW-converted) ----
DEV unsigned packf8_4(float a, float b, float c, float d) {
  int r = __builtin_amdgcn_cvt_pk_fp8_f32(a, b, 0, false);
  r = __builtin_amdgcn_cvt_pk_fp8_f32(c, d, r, true);
  return (unsigned)r;
}
template<bool HI>
DEV v2f up2(unsigned u) { return __builtin_amdgcn_cvt_pk_f32_fp8((int)u, HI); }

// dot of 16 fp8 values (one uint4) against q[0..16)
DEV float dot16(uint4 u, const float* q, float d) {
  v2f f;
  f = up2<false>(u.x); d = fmaf(f.x, q[0],  d); d = fmaf(f.y, q[1],  d);
  f = up2<true >(u.x); d = fmaf(f.x, q[2],  d); d = fmaf(f.y, q[3],  d);
  f = up2<false>(u.y); d = fmaf(f.x, q[4],  d); d = fmaf(f.y, q[5],  d);
  f = up2<true >(u.y); d = fmaf(f.x, q[6],  d); d = fmaf(f.y, q[7],  d);
  f = up2<false>(u.z); d = fmaf(f.x, q[8],  d); d = fmaf(f.y, q[9],  d);
  f = up2<true >(u.z); d = fmaf(f.x, q[10], d); d = fmaf(f.y, q[11], d);
  f = up2<false>(u.w); d = fmaf(f.x, q[12], d); d = fmaf(f.y, q[13], d);
  f = up2<true >(u.w); d = fmaf(f.x, q[14], d); d = fmaf(f.y, q[15], d);
  return d;
}
// o[0..16) += pk * fp8x16(u)
DEV void acc16(uint4 u, float pk, float* o) {
  v2f f;
  f = up2<false>(u.x); o[0]  = fmaf(pk, f.x, o[0]);  o[1]  = fmaf(pk, f.y, o[1]);
  f = up2<true >(u.x); o[2]  = fmaf(pk, f.x, o[2]);  o[3]  = fmaf(pk, f.y, o[3]);
  f = up2<false>(u.y); o[4]  = fmaf(pk, f.x, o[4]);  o[5]  = fmaf(pk, f.y, o[5]);
  f = up2<true >(u.y); o[6]  = fmaf(pk, f.x, o[6]);  o[7]  = fmaf(pk, f.y, o[7]);
  f = up2<false>(u.z); o[8]  = fmaf(pk, f.x, o[8]);  o[9]  = fmaf(pk, f.y, o[9]);
  f = up2<true >(u.z); o[10] = fmaf(pk, f.x, o[10]); o[11] = fmaf(pk, f.y, o[11]);
  f = up2<false>(u.w); o[12] = fmaf(pk, f.x, o[12]); o[13] = fmaf(pk, f.y, o[13]);
  f = up2<true >(u.w); o[14] = fmaf(pk, f.x, o[14]); o[15] = fmaf(pk, f.y, o[15]);
}

// 2-edge, 32-out GEMM chunk (w block-uniform -> s_load broadcast)
template<int K>
DEV void g2(const float* __restrict__ x0, const float* __restrict__ x1,
            const float* __restrict__ w, float (&a0)[32], float (&a1)[32]) {
#pragma unroll 4
  for (int k = 0; k < K; k += 4) {
    const float4 u = *(const float4*)(x0 + k);
    const float4 v = *(const float4*)(x1 + k);
    const float* wr = w + (size_t)k * 64;
#pragma unroll
    for (int j = 0; j < 32; ++j) { float ww = wr[j];       a0[j] = fmaf(u.x, ww, a0[j]); a1[j] = fmaf(v.x, ww, a1[j]); }
#pragma unroll
    for (int j = 0; j < 32; ++j) { float ww = wr[64 + j];  a0[j] = fmaf(u.y, ww, a0[j]); a1[j] = fmaf(v.y, ww, a1[j]); }
#pragma unroll
    for (int j = 0; j < 32; ++j) { float ww = wr[128 + j]; a0[j] = fmaf(u.z, ww, a0[j]); a1[j] = fmaf(v.z, ww, a1[j]); }
#pragma unroll
    for (int j = 0; j < 32; ++j) { float ww = wr[192 + j]; a0[j] = fmaf(u.w, ww, a0[j]); a1[j] = fmaf(v.w, ww, a1[j]); }
  }
}

// 1-edge, 32-out GEMM chunk
template<int K>
DEV void g1(const float* __restrict__ x, const float* __restrict__ w,
            float (&a)[32]) {
#pragma unroll 4
  for (int k = 0; k < K; k += 4) {
    const float4 u = *(const float4*)(x + k);
    const float* wr = w + (size_t)k * 64;
#pragma unroll
    for (int j = 0; j < 32; ++j) a[j] = fmaf(u.x, wr[j], a[j]);
#pragma unroll
    for (int j = 0; j < 32; ++j) a[j] = fmaf(u.y, wr[64 + j], a[j]);
#pragma unroll
    for (int j = 0; j < 32; ++j) a[j] = fmaf(u.z, wr[128 + j], a[j]);
#pragma unroll
    for (int j = 0; j < 32; ++j) a[j] = fmaf(u.w, wr[192 + j], a[j]);
  }
}

DEV void ldrow16(const unsigned* __restrict__ p, unsigned (&r)[16]) {
#pragma unroll
  for (int t = 0; t < 4; ++t) {
    uint4 u = ((const uint4*)p)[t];
    r[4*t] = u.x; r[4*t+1] = u.y; r[4*t+2] = u.z; r[4*t+3] = u.w;
  }
}
DEV void storef8_64(unsigned* dst, const float (&a)[64]) {  // 16 uints (fp8)
#pragma unroll
  for (int t = 0; t < 4; ++t)
    ((uint4*)dst)[t] = make_uint4(
        packf8_4(a[16*t+0],  a[16*t+1],  a[16*t+2],  a[16*t+3]),
        packf8_4(a[16*t+4],  a[16*t+5],  a[16*t+6],  a[16*t+7]),
        packf8_4(a[16*t+8],  a[16*t+9],  a[16*t+10], a[16*t+11]),
        packf8_4(a[16*t+12], a[16*t+13], a[16*t+14], a[16*t+15]));
}
DEV void unpackf8(const unsigned (&p)[16], float (&o)[64]) {
#pragma unroll
  for (int t = 0; t < 16; ++t) {
    v2f f0 = up2<false>(p[t]);
    v2f f1 = up2<true >(p[t]);
    o[4*t+0] = f0.x; o[4*t+1] = f0.y; o[4*t+2] = f1.x; o[4*t+3] = f1.y;
  }
}
DEV void store32(float* dst, const float (&a)[32]) {
#pragma unroll
  for (int j = 0; j < 32; j += 4)
    *(float4*)(dst + j) = make_float4(a[j], a[j+1], a[j+2], a[j+3]);
}

// pack 8 consecutive fp32 -> bf16x8 (B-fragment k-slice)
DEV bf16x8 packrow8(const float* __restrict__ p) {
  float4 a = *(const float4*)p;
  float4 b = *(const float4*)(p + 4);
  uint4 u = make_uint4(pack2(a.x, a.y), pack2(a.z, a.w),
                       pack2(b.x, b.y), pack2(b.z, b.w));
  return __builtin_bit_cast(bf16x8, u);
}

// 16x16x32 GEMM over K=64: acc[nf] (n = nf*16 + q*4 + reg), A from wtb matrix wm
DEV void mm4(const unsigned short* __restrict__ wm, int er, int q,
             const bf16x8 (&bfr)[2], f32x4 (&acc)[4]) {
#pragma unroll
  for (int nf = 0; nf < 4; ++nf) {
    const unsigned short* ar = wm + (size_t)(nf * 16 + er) * 64 + q * 8;
    const bf16x8 a0 = *(const bf16x8*)ar;
    const bf16x8 a1 = *(const bf16x8*)(ar + 32);
    acc[nf] = __builtin_amdgcn_mfma_f32_16x16x32_bf16(a0, bfr[0], acc[nf], 0, 0, 0);
    acc[nf] = __builtin_amdgcn_mfma_f32_16x16x32_bf16(a1, bfr[1], acc[nf], 0, 0, 0);
  }
}

// ---------- CSR build over edges[0] (rows) ----------
__global__ void __launch_bounds__(256)
k_count(const int* __restrict__ edges, int* __restrict__ icnt) {
  int e = blockIdx.x * 256 + threadIdx.x;
  if (e < NE) atomicAdd(&icnt[edges[e]], 1);
}

__global__ void __launch_bounds__(256)
k_scan(const int* __restrict__ icnt, int* __restrict__ ioffs) {
  __shared__ int part[256];
  const int t = threadIdx.x;
  const int base = t * 40;
  int loc[40];
  int s = 0;
#pragma unroll
  for (int i = 0; i < 40; ++i) {
    int idx = base + i;
    int v = (idx < NN) ? icnt[idx] : 0;
    loc[i] = v; s += v;
  }
  part[t] = s;
  __syncthreads();
  for (int off = 1; off < 256; off <<= 1) {
    int v = (t >= off) ? part[t - off] : 0;
    __syncthreads();
    part[t] += v;
    __syncthreads();
  }
  int run = (t == 0) ? 0 : part[t - 1];
#pragma unroll
  for (int i = 0; i < 40; ++i) {
    int idx = base + i;
    if (idx < NN) { ioffs[idx] = run; run += loc[i]; }
  }
  if (t == 255) ioffs[NN] = NE;
}

__global__ void __launch_bounds__(256)
k_fill(const int* __restrict__ edges, const int* __restrict__ ioffs,
       int* __restrict__ icur, int* __restrict__ eidx) {
  int e = blockIdx.x * 256 + threadIdx.x;
  if (e >= NE) return;
  int r = edges[e];
  int p = atomicAdd(&icur[r], 1);
  eidx[ioffs[r] + p] = e;
}

// ---------- chem layer 1: 272 -> 64 silu (2 edges/thread, y-split) ----------
__global__ void __launch_bounds__(128)
k_chem1(const float* __restrict__ h, const float* __restrict__ na,
        const float* __restrict__ ea, const int* __restrict__ edges,
        const float* __restrict__ w1, const float* __restrict__ b1,
        float* __restrict__ act1c) {
  const int tid = threadIdx.x;
  const int e0 = blockIdx.x * 256 + tid, e1 = e0 + 128;
  const int co = blockIdx.y * 32;
  const int r0 = edges[e0], c0 = edges[NE + e0];
  const int r1 = edges[e1], c1 = edges[NE + e1];
  float a0[32], a1[32];
#pragma unroll
  for (int j = 0; j < 32; ++j) { a0[j] = b1[co + j]; a1[j] = a0[j]; }
  g2<64>(h  + (size_t)r0 * 64, h  + (size_t)r1 * 64, w1 + co,            a0, a1);
  g2<64>(h  + (size_t)c0 * 64, h  + (size_t)c1 * 64, w1 +  64 * 64 + co, a0, a1);
  g2<64>(na + (size_t)r0 * 64, na + (size_t)r1 * 64, w1 + 128 * 64 + co, a0, a1);
  g2<64>(na + (size_t)c0 * 64, na + (size_t)c1 * 64, w1 + 192 * 64 + co, a0, a1);
  g2<16>(ea + (size_t)e0 * 16, ea + (size_t)e1 * 16, w1 + 256 * 64 + co, a0, a1);
#pragma unroll
  for (int j = 0; j < 32; ++j) { a0[j] = fsilu(a0[j]); a1[j] = fsilu(a1[j]); }
  store32(act1c + (size_t)e0 * 64 + co, a0);
  store32(act1c + (size_t)e1 * 64 + co, a1);
}

// ---------- pos layer 1: 36 -> 64 silu ----------
__global__ void __launch_bounds__(256)
k_pos1(const float* __restrict__ coord, const float* __restrict__ nv,
       const float* __restrict__ ea, const int* __restrict__ edges,
       const float* __restrict__ w1, const float* __restrict__ b1,
       float* __restrict__ act1p) {
  const int e = blockIdx.x * 256 + threadIdx.x;
  const int co = blockIdx.y * 32;
  const int r = edges[e], c = edges[NE + e];

  float dx = coord[r * 3 + 0] - coord[c * 3 + 0];
  float dy = coord[r * 3 + 1] - coord[c * 3 + 1];
  float dz = coord[r * 3 + 2] - coord[c * 3 + 2];
  float nrm = sqrtf(dx * dx + dy * dy + dz * dz);
  float inv = 1.0f / (nrm + 1e-8f);
  dx *= inv; dy *= inv; dz *= inv;
  float ir = dx * dx + dy * dy + dz * dz;

  float in[36];
#pragma unroll
  for (int v = 0; v < 5; ++v) {
    float s = 0.f;
#pragma unroll
    for (int d = 0; d < 3; ++d)
      s += nv[(size_t)r * 15 + v * 3 + d] * nv[(size_t)c * 15 + v * 3 + d];
    in[v] = s;
  }
  {
    float cexp = -0.5f;
#pragma unroll
    for (int k = 0; k < 15; ++k) { in[5 + k] = __expf(ir * cexp); cexp *= (1.0f / 2.25f); }
  }
#pragma unroll
  for (int k = 0; k < 16; k += 4) {
    float4 e4 = *(const float4*)(ea + (size_t)e * 16 + k);
    in[20 + k] = e4.x; in[21 + k] = e4.y; in[22 + k] = e4.z; in[23 + k] = e4.w;
  }

  float acc[32];
#pragma unroll
  for (int j = 0; j < 32; ++j) acc[j] = b1[co + j];
#pragma unroll
  for (int k = 0; k < 36; ++k) {
    const float x = in[k];
    const float* wr = w1 + (size_t)k * 64 + co;
#pragma unroll
    for (int j = 0; j < 32; ++j) acc[j] = fmaf(x, wr[j], acc[j]);
  }
#pragma unroll
  for (int j = 0; j < 32; ++j) acc[j] = fsilu(acc[j]);
  store32(act1p + (size_t)e * 64 + co, acc);
}

// ---------- layer 2 of both MLPs (2 edges/thread, y-split) ----------
__global__ void __launch_bounds__(128)
k_l2(const float* __restrict__ act1c, const float* __restrict__ act1p,
     const float* __restrict__ w2c, const float* __restrict__ b2c,
     const float* __restrict__ w2p, const float* __restrict__ b2p,
     float* __restrict__ chem, float* __restrict__ pos) {
  const int tid = threadIdx.x;
  const int e0 = blockIdx.x * 256 + tid, e1 = e0 + 128;
  const int co = blockIdx.y * 32;
  float a0[32], a1[32];
#pragma unroll
  for (int j = 0; j < 32; ++j) { a0[j] = b2c[co + j]; a1[j] = a0[j]; }
  g2<64>(act1c + (size_t)e0 * 64, act1c + (size_t)e1 * 64, w2c + co, a0, a1);
#pragma unroll
  for (int j = 0; j < 32; ++j) { a0[j] = fsilu(a0[j]); a1[j] = fsilu(a1[j]); }
  store32(chem + (size_t)e0 * 64 + co, a0);
  store32(chem + (size_t)e1 * 64 + co, a1);
#pragma unroll
  for (int j = 0; j < 32; ++j) { a0[j] = b2p[co + j]; a1[j] = a0[j]; }
  g2<64>(act1p + (size_t)e0 * 64, act1p + (size_t)e1 * 64, w2p + co, a0, a1);
#pragma unroll
  for (int j = 0; j < 32; ++j) { a0[j] = fsilu(a0[j]); a1[j] = fsilu(a1[j]); }
  store32(pos + (size_t)e0 * 64 + co, a0);
  store32(pos + (size_t)e1 * 64 + co, a1);
}

// ---------- weight prep: wtb[m][n][k] = W_m[k][n] in bf16 (A-operand layout) ----------
// m<16: hd*4+which (0=k,1=v,2=q,3=g); m=16: wsh, 17: wu1, 18: wx1
__global__ void __launch_bounds__(256)
k_wprep(const float* __restrict__ wk, const float* __restrict__ wv,
        const float* __restrict__ wq, const float* __restrict__ wg,
        const float* __restrict__ wsh, const float* __restrict__ wu1,
        const float* __restrict__ wx1,
        unsigned short* __restrict__ wtb) {
  const int m = blockIdx.x;          // 0..18
  const float* src;
  if (m < 16) {
    const int hd = m >> 2, which = m & 3;
    src = ((which == 0) ? wk : (which == 1) ? wv : (which == 2) ? wq : wg)
          + (size_t)hd * 4096;
  } else {
    src = (m == 16) ? wsh : (m == 17) ? wu1 : wx1;
  }
  const int t = threadIdx.x;
#pragma unroll
  for (int i = 0; i < 16; ++i) {
    int idx = t * 16 + i;
    int n = idx >> 6, kk = idx & 63;
    unsigned u = __float_as_uint(src[kk * 64 + n]);
    u += 0x7FFFu + ((u >> 16) & 1u);
    wtb[(size_t)m * 4096 + idx] = (unsigned short)(u >> 16);
  }
}

// ---------- MFMA fused scalars: z/att-gate/be/u/x via matrix cores ----------
// Wave = 16 edges (er = lane&15), q = lane>>4 selects k-slice (inputs) and
// n-quad (outputs, n = nf*16 + q*4 + reg). Row-reductions: __shfl_xor 16/32.
// Weights from wtb (L2-resident, 16B A-frag loads) -> no per-lane weight GEMV.
__global__ void __launch_bounds__(256)
k_scal_m(const float* __restrict__ coord, const int* __restrict__ edges,
         const float* __restrict__ chem, const float* __restrict__ pos,
         const unsigned short* __restrict__ wtb,
         const float* __restrict__ bsh,
         const float* __restrict__ watt, const float* __restrict__ batt,
         const float* __restrict__ bu1, const float* __restrict__ wu2,
         const float* __restrict__ bu2,
         const float* __restrict__ bx1, const float* __restrict__ wx2,
         const float* __restrict__ bx2,
         const float* __restrict__ wb,
         unsigned* __restrict__ zb, float* __restrict__ be,
         float* __restrict__ x_sum, float* __restrict__ cntf) {
  const int lane = threadIdx.x & 63;
  const int wid  = threadIdx.x >> 6;
  const int er   = lane & 15;
  const int q    = lane >> 4;
  const int e    = blockIdx.x * 64 + wid * 16 + er;
  const float* crow = chem + (size_t)e * 64;
  const float* prow = pos  + (size_t)e * 64;

  // B-frags: bf16-packed k-slices of this edge's chem/pos rows
  bf16x8 cf[2], pf[2];
  cf[0] = packrow8(crow + q * 8); cf[1] = packrow8(crow + 32 + q * 8);
  pf[0] = packrow8(prow + q * 8); pf[1] = packrow8(prow + 32 + q * 8);

  const f32x4 zero = {0.f, 0.f, 0.f, 0.f};

  // z = silu(chem @ wsh + bsh) * pos   (n per lane: nf*16 + q*4 + reg)
  float z[16];
  {
    f32x4 acc[4] = {zero, zero, zero, zero};
    mm4(wtb + (size_t)16 * 4096, er, q, cf, acc);
#pragma unroll
    for (int nf = 0; nf < 4; ++nf) {
      const float4 b4 = *(const float4*)(bsh + nf * 16 + q * 4);
      const float4 p4 = *(const float4*)(prow + nf * 16 + q * 4);
      z[4*nf+0] = fsilu(acc[nf].x + b4.x) * p4.x;
      z[4*nf+1] = fsilu(acc[nf].y + b4.y) * p4.y;
      z[4*nf+2] = fsilu(acc[nf].z + b4.z) * p4.z;
      z[4*nf+3] = fsilu(acc[nf].w + b4.w) * p4.w;
    }
  }
  // att gate: full-row dot reduced across q-groups
  {
    float ap = 0.f;
#pragma unroll
    for (int nf = 0; nf < 4; ++nf)
#pragma unroll
      for (int r = 0; r < 4; ++r)
        ap = fmaf(z[4*nf+r], watt[nf * 16 + q * 4 + r], ap);
    ap += __shfl_xor(ap, 16);
    ap += __shfl_xor(ap, 32);
    const float sg = fsig(ap + batt[0]);
#pragma unroll
    for (int j = 0; j < 16; ++j) z[j] *= sg;
  }
  // zb bf16 row (layout identical to original): uint idx = nf*8 + q*2
  {
    unsigned* zrow = zb + (size_t)e * 32 + q * 2;
#pragma unroll
    for (int nf = 0; nf < 4; ++nf) {
      uint2 w = make_uint2(pack2(z[4*nf+0], z[4*nf+1]), pack2(z[4*nf+2], z[4*nf+3]));
      *(uint2*)(zrow + nf * 8) = w;
    }
  }
  // per-head b scalars
  {
    float bb[4];
#pragma unroll
    for (int hd = 0; hd < 4; ++hd) {
      float b = 0.f;
#pragma unroll
      for (int nf = 0; nf < 4; ++nf)
#pragma unroll
        for (int r = 0; r < 4; ++r)
          b = fmaf(z[4*nf+r], wb[hd * 64 + nf * 16 + q * 4 + r], b);
      b += __shfl_xor(b, 16);
      b += __shfl_xor(b, 32);
      bb[hd] = b;
    }
    if (q == 0)
      *(float4*)(be + (size_t)e * 4) = make_float4(bb[0], bb[1], bb[2], bb[3]);
  }
  // u = silu(chem@wu1+bu1)@wu2 + bu2
  float u;
  {
    f32x4 acc[4] = {zero, zero, zero, zero};
    mm4(wtb + (size_t)17 * 4096, er, q, cf, acc);
    float up = 0.f;
#pragma unroll
    for (int nf = 0; nf < 4; ++nf) {
      const float4 b4 = *(const float4*)(bu1 + nf * 16 + q * 4);
      const float4 w4 = *(const float4*)(wu2 + nf * 16 + q * 4);
      up = fmaf(fsilu(acc[nf].x + b4.x), w4.x, up);
      up = fmaf(fsilu(acc[nf].y + b4.y), w4.y, up);
      up = fmaf(fsilu(acc[nf].z + b4.z), w4.z, up);
      up = fmaf(fsilu(acc[nf].w + b4.w), w4.w, up);
    }
    up += __shfl_xor(up, 16);
    up += __shfl_xor(up, 32);
    u = up + bu2[0];
  }
  // xs = silu(pos@wx1+bx1)@wx2 + bx2
  float xs;
  {
    f32x4 acc[4] = {zero, zero, zero, zero};
    mm4(wtb + (size_t)18 * 4096, er, q, pf, acc);
    float xp = 0.f;
#pragma unroll
    for (int nf = 0; nf < 4; ++nf) {
      const float4 b4 = *(const float4*)(bx1 + nf * 16 + q * 4);
      const float4 w4 = *(const float4*)(wx2 + nf * 16 + q * 4);
      xp = fmaf(fsilu(acc[nf].x + b4.x), w4.x, xp);
      xp = fmaf(fsilu(acc[nf].y + b4.y), w4.y, xp);
      xp = fmaf(fsilu(acc[nf].z + b4.z), w4.z, xp);
      xp = fmaf(fsilu(acc[nf].w + b4.w), w4.w, xp);
    }
    xp += __shfl_xor(xp, 16);
    xp += __shfl_xor(xp, 32);
    xs = xp + bx2[0];
  }

  if (q == 0) {
    const int r = edges[e], c = edges[NE + e];
    float dx = coord[r * 3 + 0] - coord[c * 3 + 0];
    float dy = coord[r * 3 + 1] - coord[c * 3 + 1];
    float dz = coord[r * 3 + 2] - coord[c * 3 + 2];
    float nrm = sqrtf(dx * dx + dy * dy + dz * dz);
    float inv = 1.0f / (nrm + 1e-8f);
    float t = u * xs;
    atomicAdd(&x_sum[r * 3 + 0], dx * inv * t);
    atomicAdd(&x_sum[r * 3 + 1], dy * inv * t);
    atomicAdd(&x_sum[r * 3 + 2], dz * inv * t);
    atomicAdd(&cntf[r], 1.0f);
  }
}

// ---------- MFMA projections: z[NE,64]bf16 @ 16x W[64,64]bf16 -> kvh/qho/gf8 fp8 ----------
// D[n][e] = W^T * z^T per mfma_f32_16x16x32_bf16. C/D layout (m89-verified):
// col=lane&15 (edge), row=(lane>>4)*4+reg (4 consecutive n) -> one packf8_4 per frag.
// Each wave: 64 edges (4 e-tiles), loops 16 matrices; A-frags L2-resident (128KB).
__global__ void __launch_bounds__(256)
k_projm(const unsigned* __restrict__ zb, const unsigned short* __restrict__ wtb,
        const float* __restrict__ bg,
        unsigned* __restrict__ kvh, unsigned* __restrict__ qho,
        unsigned* __restrict__ gf8) {
  const int lane = threadIdx.x & 63;
  const int wid  = threadIdx.x >> 6;        // wave 0..3
  const int er   = lane & 15;               // edge-in-tile (D col / B col / A row)
  const int q    = lane >> 4;               // k-block (A/B), row-quad (D)
  const int e0   = blockIdx.x * 256 + wid * 64 + er;

  // B frags: z^T, col=e, k=(lane>>4)*8 + i (+32 for half 1)
  bf16x8 zf[4][2];
#pragma unroll
  for (int et = 0; et < 4; ++et) {
    const unsigned* zrow = zb + (size_t)(e0 + et * 16) * 32;   // 64 bf16
    zf[et][0] = __builtin_bit_cast(bf16x8, *(const uint4*)(zrow + q * 4));
    zf[et][1] = __builtin_bit_cast(bf16x8, *(const uint4*)(zrow + 16 + q * 4));
  }

  const f32x4 zero = {0.f, 0.f, 0.f, 0.f};
#pragma unroll 1
  for (int m = 0; m < 16; ++m) {
    const unsigned short* wm = wtb + (size_t)m * 4096;
    f32x4 acc[4][4];
#pragma unroll
    for (int et = 0; et < 4; ++et)
#pragma unroll
      for (int nf = 0; nf < 4; ++nf) acc[et][nf] = zero;
#pragma unroll
    for (int nf = 0; nf < 4; ++nf) {
      // A frag: row n = nf*16 + er, k = q*8..q*8+7 (half 0), +32 (half 1)
      const unsigned short* ar = wm + (size_t)(nf * 16 + er) * 64 + q * 8;
      const bf16x8 a0 = *(const bf16x8*)ar;
      const bf16x8 a1 = *(const bf16x8*)(ar + 32);
#pragma unroll
      for (int et = 0; et < 4; ++et) {
        acc[et][nf] = __builtin_amdgcn_mfma_f32_16x16x32_bf16(a0, zf[et][0], acc[et][nf], 0, 0, 0);
        acc[et][nf] = __builtin_amdgcn_mfma_f32_16x16x32_bf16(a1, zf[et][1], acc[et][nf], 0, 0, 0);
      }
    }
    const int hd = m >> 2, which = m & 3;    // wave-uniform
#pragma unroll
    for (int et = 0; et < 4; ++et) {
      const size_t rec = (size_t)(e0 + et * 16) * 4 + hd;
      unsigned* dst = (which == 0) ? (kvh + rec * 32)
                    : (which == 1) ? (kvh + rec * 32 + 16)
                    : (which == 2) ? (qho + rec * 16)
                                   : (gf8 + rec * 16);
      if (which == 3) {
#pragma unroll
        for (int nf = 0; nf < 4; ++nf) {
          const float4 b4 = *(const float4*)(bg + hd * 64 + nf * 16 + q * 4);
          dst[nf * 4 + q] = packf8_4(fsig(acc[et][nf].x + b4.x), fsig(acc[et][nf].y + b4.y),
                                     fsig(acc[et][nf].z + b4.z), fsig(acc[et][nf].w + b4.w));
        }
      } else {
#pragma unroll
        for (int nf = 0; nf < 4; ++nf)
          dst[nf * 4 + q] = packf8_4(acc[et][nf].x, acc[et][nf].y,
                                     acc[et][nf].z, acc[et][nf].w);
      }
    }
  }
}

// ---------- attention: flat grid, lane quad = 4 heads of one edge ----------
// gathers at [i2*4+hd] -> 4 lanes read 512B contiguous; ho fp8 overwrites q slot
__global__ void __launch_bounds__(256)
k_attn(unsigned* __restrict__ qho, const unsigned* __restrict__ gf8,
       const unsigned* __restrict__ kvh, const float* __restrict__ be,
       const int* __restrict__ klist) {
  const int t = blockIdx.x * 256 + threadIdx.x;
  const int e = t >> 2, hd = t & 3;

  // q (fp8 -> fp32, unscaled)
  float q[64];
  {
    unsigned qp[16];
    ldrow16(qho + (size_t)t * 16, qp);
    unpackf8(qp, q);
  }

  int i2[8], j2[8];
#pragma unroll
  for (int kn = 0; kn < 8; ++kn) {
    i2[kn] = klist[(size_t)e * 16 + kn];
    j2[kn] = klist[(size_t)e * 16 + 8 + kn];
  }
  float bv[8];
#pragma unroll
  for (int kn = 0; kn < 8; ++kn)
    bv[kn] = be[(size_t)((i2[kn] < 0) ? 0 : j2[kn]) * 4 + hd];

  const uint4* kv4 = (const uint4*)kvh;   // 8 uint4 per record
  float alpha[8];
#pragma unroll 2
  for (int kn = 0; kn < 8; ++kn) {
    if (i2[kn] < 0) { alpha[kn] = -10000.0f; continue; }
    const uint4* kr = kv4 + ((size_t)i2[kn] * 4 + hd) * 8;
    uint4 u0 = kr[0], u1 = kr[1], u2 = kr[2], u3 = kr[3];
    float d = 0.f;
    d = dot16(u0, q,      d);
    d = dot16(u1, q + 16, d);
    d = dot16(u2, q + 32, d);
    d = dot16(u3, q + 48, d);
    alpha[kn] = d * 0.125f + bv[kn];
  }
  float mx = alpha[0];
#pragma unroll
  for (int kn = 1; kn < 8; ++kn) mx = fmaxf(mx, alpha[kn]);
  float p[8], s = 0.f;
#pragma unroll
  for (int kn = 0; kn < 8; ++kn) { p[kn] = __expf(alpha[kn] - mx); s += p[kn]; }
  float is = 1.0f / s;
#pragma unroll
  for (int kn = 0; kn < 8; ++kn) p[kn] *= is;

  float ov[64];
#pragma unroll
  for (int j = 0; j < 64; ++j) ov[j] = 0.f;
#pragma unroll 2
  for (int kn = 0; kn < 8; ++kn) {
    int vi = (i2[kn] < 0) ? (NE - 1) : i2[kn];   // jax v[-1] wraps
    const uint4* vr = kv4 + ((size_t)vi * 4 + hd) * 8 + 4;
    uint4 u0 = vr[0], u1 = vr[1], u2 = vr[2], u3 = vr[3];
    const float pk = p[kn];
    acc16(u0, pk, ov +  0);
    acc16(u1, pk, ov + 16);
    acc16(u2, pk, ov + 32);
    acc16(u3, pk, ov + 48);
  }
  // gate (precomputed sigmoid, fp8)
  {
    unsigned gp[16];
    ldrow16(gf8 + (size_t)t * 16, gp);
    float g[64];
    unpackf8(gp, g);
#pragma unroll
    for (int j = 0; j < 64; ++j) ov[j] *= g[j];
  }
  // ho fp8 -> same slot as q (thread-private)
  storef8_64(qho + (size_t)t * 16, ov);
}

// ---------- output projection (all heads), per-edge m row (non-atomic) ----------
__global__ void __launch_bounds__(256)
k_mout(const unsigned* __restrict__ qho, const float* __restrict__ wout,
       float* __restrict__ medge) {
  const int e = blockIdx.x * 256 + threadIdx.x;
  float mm[64];
#pragma unroll
  for (int j = 0; j < 64; ++j) mm[j] = 0.f;
#pragma unroll 1
  for (int hd = 0; hd < 4; ++hd) {
    unsigned hp[16];
    ldrow16(qho + ((size_t)e * 4 + hd) * 16, hp);
    const float* wo = wout + (size_t)hd * 4096;
#pragma unroll 4
    for (int t = 0; t < 16; ++t) {
      v2f f0 = up2<false>(hp[t]);
      v2f f1 = up2<true >(hp[t]);
      const float* wr = wo + (size_t)(4 * t) * 64;
#pragma unroll
      for (int j = 0; j < 64; ++j) mm[j] = fmaf(f0.x, wr[j], mm[j]);
#pragma unroll
      for (int j = 0; j < 64; ++j) mm[j] = fmaf(f0.y, wr[64 + j], mm[j]);
#pragma unroll
      for (int j = 0; j < 64; ++j) mm[j] = fmaf(f1.x, wr[128 + j], mm[j]);
#pragma unroll
      for (int j = 0; j < 64; ++j) mm[j] = fmaf(f1.y, wr[192 + j], mm[j]);
    }
  }
  float* mr = medge + (size_t)e * 64;
#pragma unroll
  for (int j = 0; j < 64; j += 4)
    *(float4*)(mr + j) = make_float4(mm[j], mm[j+1], mm[j+2], mm[j+3]);
}

// ---------- CSR gather: per-node segment sum of medge ----------
__global__ void __launch_bounds__(256)
k_nodesum(const float* __restrict__ medge, const int* __restrict__ ioffs,
          const int* __restrict__ eidx, float* __restrict__ m_sum) {
  const int wid = threadIdx.x >> 6, lane = threadIdx.x & 63;
  const int n = blockIdx.x * 4 + wid;
  if (n >= NN) return;
  const int beg = ioffs[n], end = ioffs[n + 1];
  float acc = 0.f;
  for (int i = beg; i < end; ++i) {
    int e = eidx[i];
    acc += medge[(size_t)e * 64 + lane];
  }
  m_sum[(size_t)n * 64 + lane] = acc;
}

// ---------- final node update ----------
__global__ void __launch_bounds__(256)
k_final(const float* __restrict__ h, const float* __restrict__ na,
        const float* __restrict__ coord, const float* __restrict__ icoord,
        const float* __restrict__ m_sum, const float* __restrict__ x_sum,
        const float* __restrict__ cntf, const float* __restrict__ bout,
        const float* __restrict__ wh1, const float* __restrict__ bh1,
        const float* __restrict__ wh2, const float* __restrict__ bh2,
        float* __restrict__ scr, float* __restrict__ out) {
  int n = blockIdx.x * 256 + threadIdx.x;
  if (n >= NN) return;
  float cn = cntf[n];
  float invc = 1.0f / fmaxf(cn, 1.0f);
  float bsc = (cn > 0.f) ? 1.0f : 0.0f;   // empty segment => m_agg = 0 (no bout)

#pragma unroll
  for (int d = 0; d < 3; ++d)
    out[(size_t)NN * 64 + n * 3 + d] =
        0.2f * icoord[n * 3 + d] + 0.8f * coord[n * 3 + d] + x_sum[n * 3 + d] * invc;

  const float* hr = h  + (size_t)n * 64;
  const float* nr = na + (size_t)n * 64;
  const float* mr = m_sum + (size_t)n * 64;
  float* srow = scr + (size_t)n * 64;

#pragma unroll 1
  for (int cc = 0; cc < 64; cc += 32) {
    float acc[32];
#pragma unroll
    for (int j = 0; j < 32; ++j) acc[j] = bh1[cc + j];
    g1<64>(hr, wh1 + cc, acc);
    g1<64>(nr, wh1 + 64 * 64 + cc, acc);
#pragma unroll 4
    for (int k = 0; k < 64; k += 4) {
      float4 m4 = *(const float4*)(mr + k);
      float xv[4] = { fmaf(m4.x, invc, bout[k] * bsc), fmaf(m4.y, invc, bout[k+1] * bsc),
                      fmaf(m4.z, invc, bout[k+2] * bsc), fmaf(m4.w, invc, bout[k+3] * bsc) };
#pragma unroll
      for (int q = 0; q < 4; ++q) {
        const float* wr = wh1 + (size_t)(128 + k + q) * 64 + cc;
        const float x = xv[q];
#pragma unroll
        for (int j = 0; j < 32; ++j) acc[j] = fmaf(x, wr[j], acc[j]);
      }
    }
#pragma unroll
    for (int j = 0; j < 32; ++j) acc[j] = fsilu(acc[j]);
    store32(srow + cc, acc);
  }
#pragma unroll 1
  for (int cc = 0; cc < 64; cc += 32) {
    float acc[32];
#pragma unroll
    for (int j = 0; j < 32; ++j) acc[j] = bh2[cc + j];
    g1<64>(srow, wh2 + cc, acc);
#pragma unroll
    for (int j = 0; j < 32; j += 4) {
      float4 h4 = *(const float4*)(hr + cc + j);
      *(float4*)(out + (size_t)n * 64 + cc + j) =
          make_float4(acc[j] + h4.x, acc[j+1] + h4.y, acc[j+2] + h4.z, acc[j+3] + h4.w);
    }
  }
}

extern "C" void kernel_launch(void* const* d_in, const int* in_sizes, int n_in,
                              void* d_out, int out_size, void* d_ws, size_t ws_size,
                              hipStream_t stream) {
  (void)in_sizes; (void)n_in; (void)out_size; (void)ws_size;
  const float* h      = (const float*)d_in[0];
  const float* coord  = (const float*)d_in[1];
  const int*   edges  = (const int*)  d_in[2];
  const float* nvecs  = (const float*)d_in[3];
  const float* ea     = (const float*)d_in[4];
  const float* na     = (const float*)d_in[5];
  const float* icoord = (const float*)d_in[6];
  const int*   klist  = (const int*)  d_in[7];
  const float* w_chem1 = (const float*)d_in[8];
  const float* b_chem1 = (const float*)d_in[9];
  const float* w_chem2 = (const float*)d_in[10];
  const float* b_chem2 = (const float*)d_in[11];
  const float* w_pos1  = (const float*)d_in[12];
  const float* b_pos1  = (const float*)d_in[13];
  const float* w_pos2  = (const float*)d_in[14];
  const float* b_pos2  = (const float*)d_in[15];
  const float* w_sh    = (const float*)d_in[16];
  const float* b_sh    = (const float*)d_in[17];
  const float* w_att   = (const float*)d_in[18];
  const float* b_att   = (const float*)d_in[19];
  const float* wq      = (const float*)d_in[20];
  const float* wk      = (const float*)d_in[21];
  const float* wv      = (const float*)d_in[22];
  const float* wb      = (const float*)d_in[23];
  const float* wg      = (const float*)d_in[24];
  const float* bg      = (const float*)d_in[25];
  const float* w_out   = (const float*)d_in[26];
  const float* b_out   = (const float*)d_in[27];
  const float* wu1     = (const float*)d_in[28];
  const float* bu1     = (const float*)d_in[29];
  const float* wu2     = (const float*)d_in[30];
  const float* bu2     = (const float*)d_in[31];
  const float* wx1     = (const float*)d_in[32];
  const float* bx1     = (const float*)d_in[33];
  const float* wx2     = (const float*)d_in[34];
  const float* bx2     = (const float*)d_in[35];
  const float* wh1     = (const float*)d_in[36];
  const float* bh1     = (const float*)d_in[37];
  const float* wh2     = (const float*)d_in[38];
  const float* bh2     = (const float*)d_in[39];

  float* out = (float*)d_out;
  float* ws  = (float*)d_ws;
  // Phase-reused regions (NE*64 floats each):
  //  R1+R2: act1c/act1p -> kvh [e*4+hd] fp8 (82MB) -> medge in R1 after attn
  //  R3:    chem        -> qho [e*4+hd] fp8 q, then ho in-place
  //  R4:    pos         -> gf8 [e*4+hd] fp8 sigmoid-gate
  float* R1 = ws;
  float* R2 = R1 + (size_t)NE * 64;
  float* R3 = R2 + (size_t)NE * 64;
  float* R4 = R3 + (size_t)NE * 64;
  float* zbf   = R4 + (size_t)NE * 64;      // NE*32 floats (bf16 gated z)
  float* x_sum = zbf + (size_t)NE * 32;     // NN*3 (zeroed)
  float* cntf  = x_sum + (size_t)NN * 3;    // NN (zeroed)
  int*   icnt  = (int*)(cntf + NN);         // NN (zeroed)
  int*   icur  = icnt + NN;                 // NN (zeroed)
  float* m_sum = (float*)(icur + NN);       // NN*64
  float* be    = m_sum + (size_t)NN * 64;   // 4*NE  ([e*4+hd] layout)
  float* nscr  = be + (size_t)4 * NE;       // NN*64
  unsigned short* wtb = (unsigned short*)(nscr + (size_t)NN * 64);  // 19*64*64 bf16 (152KB, 16B-aligned)
  int*   ioffs = (int*)(wtb + 19 * 4096);   // NN+1
  int*   eidx  = ioffs + (NN + 1);          // NE

  unsigned* kvh = (unsigned*)R1;   // [NE*4][32] interleaved fp8 (spans R1+R2)
  unsigned* qho = (unsigned*)R3;   // [NE*4][16] fp8 q -> ho
  unsigned* gf8 = (unsigned*)R4;   // [NE*4][16] fp8 gate
  unsigned* zb  = (unsigned*)zbf;
  float* medge = R1;               // after attention (kvh dead)

  (void)hipMemsetAsync(x_sum, 0, ((size_t)NN * 3 + NN + NN + NN) * sizeof(float), stream);

  dim3 b128(128), b256(256);
  dim3 gs2(NE / 256, 2);
  dim3 gflat(NE / 256);

  // weight prep + CSR build (independent of the MLP pipeline)
  k_wprep<<<dim3(19), b256, 0, stream>>>(wk, wv, wq, wg, w_sh, wu1, wx1, wtb);
  k_count<<<gflat, b256, 0, stream>>>(edges, icnt);
  k_scan <<<dim3(1), b256, 0, stream>>>(icnt, ioffs);
  k_fill <<<gflat, b256, 0, stream>>>(edges, ioffs, icur, eidx);

  k_chem1<<<gs2, b128, 0, stream>>>(h, na, ea, edges, w_chem1, b_chem1, R1);
  k_pos1 <<<gs2, b256, 0, stream>>>(coord, nvecs, ea, edges, w_pos1, b_pos1, R2);
  k_l2   <<<gs2, b128, 0, stream>>>(R1, R2, w_chem2, b_chem2, w_pos2, b_pos2, R3, R4);
  k_scal_m<<<dim3(NE / 64), b256, 0, stream>>>(coord, edges, R3, R4, wtb,
                                               b_sh, w_att, b_att,
                                               bu1, wu2, bu2, bx1, wx2, bx2, wb,
                                               zb, be, x_sum, cntf);
  k_projm<<<dim3(NE / 256), b256, 0, stream>>>(zb, wtb, bg, kvh, qho, gf8);
  k_attn <<<dim3(NE * 4 / 256), b256, 0, stream>>>(qho, gf8, kvh, be, klist);
  k_mout <<<gflat, b256, 0, stream>>>(qho, w_out, medge);
  k_nodesum<<<dim3((NN + 3) / 4), b256, 0, stream>>>(medge, ioffs, eidx, m_sum);
  k_final<<<dim3((NN + 255) / 256), b256, 0, stream>>>(h, na, coord, icoord, m_sum, x_sum,
                                                       cntf, b_out, wh1, bh1, wh2, bh2,
                                                       nscr, out);
}

// Round 5
// 909.238 us; speedup vs baseline: 1.5930x; 1.1529x over previous
//
#include <hip/hip_runtime.h>
#include <math.h>

#define NE 160000
#define NN 10000

#define DEV __device__ __forceinline__

typedef float v2f __attribute__((ext_vector_type(2)));
typedef __attribute__((ext_vector_type(8))) short bf16x8;   // 8 bf16 (4 VGPRs)
typedef __attribute__((ext_vector_type(4))) float f32x4;

DEV float fsilu(float x) { return x / (1.0f + __expf(-x)); }
DEV float fsig(float x)  { return 1.0f / (1.0f + __expf(-x)); }

// ---- bf16 pack/unpack helpers (RNE) ----
DEV unsigned pack2(float a, float b) {
  unsigned ua = __float_as_uint(a); ua += 0x7FFFu + ((ua >> 16) & 1u);
  unsigned ub = __float_as_uint(b); ub += 0x7FFFu + ((ub >> 16) & 1u);
  return (ua >> 16) | (ub & 0xFFFF0000u);
}

// ---- fp8 e4m3 (OCP, HW-converted) ----
DEV unsigned packf8_4(float a, float b, float c, float d) {
  int r = __builtin_amdgcn_cvt_pk_fp8_f32(a, b, 0, false);
  r = __builtin_amdgcn_cvt_pk_fp8_f32(c, d, r, true);
  return (unsigned)r;
}
template<bool HI>
DEV v2f up2(unsigned u) { return __builtin_amdgcn_cvt_pk_f32_fp8((int)u, HI); }

// dot of 16 fp8 values (one uint4) against q[0..16)
DEV float dot16(uint4 u, const float* q, float d) {
  v2f f;
  f = up2<false>(u.x); d = fmaf(f.x, q[0],  d); d = fmaf(f.y, q[1],  d);
  f = up2<true >(u.x); d = fmaf(f.x, q[2],  d); d = fmaf(f.y, q[3],  d);
  f = up2<false>(u.y); d = fmaf(f.x, q[4],  d); d = fmaf(f.y, q[5],  d);
  f = up2<true >(u.y); d = fmaf(f.x, q[6],  d); d = fmaf(f.y, q[7],  d);
  f = up2<false>(u.z); d = fmaf(f.x, q[8],  d); d = fmaf(f.y, q[9],  d);
  f = up2<true >(u.z); d = fmaf(f.x, q[10], d); d = fmaf(f.y, q[11], d);
  f = up2<false>(u.w); d = fmaf(f.x, q[12], d); d = fmaf(f.y, q[13], d);
  f = up2<true >(u.w); d = fmaf(f.x, q[14], d); d = fmaf(f.y, q[15], d);
  return d;
}
// o[0..16) += pk * fp8x16(u)
DEV void acc16(uint4 u, float pk, float* o) {
  v2f f;
  f = up2<false>(u.x); o[0]  = fmaf(pk, f.x, o[0]);  o[1]  = fmaf(pk, f.y, o[1]);
  f = up2<true >(u.x); o[2]  = fmaf(pk, f.x, o[2]);  o[3]  = fmaf(pk, f.y, o[3]);
  f = up2<false>(u.y); o[4]  = fmaf(pk, f.x, o[4]);  o[5]  = fmaf(pk, f.y, o[5]);
  f = up2<true >(u.y); o[6]  = fmaf(pk, f.x, o[6]);  o[7]  = fmaf(pk, f.y, o[7]);
  f = up2<false>(u.z); o[8]  = fmaf(pk, f.x, o[8]);  o[9]  = fmaf(pk, f.y, o[9]);
  f = up2<true >(u.z); o[10] = fmaf(pk, f.x, o[10]); o[11] = fmaf(pk, f.y, o[11]);
  f = up2<false>(u.w); o[12] = fmaf(pk, f.x, o[12]); o[13] = fmaf(pk, f.y, o[13]);
  f = up2<true >(u.w); o[14] = fmaf(pk, f.x, o[14]); o[15] = fmaf(pk, f.y, o[15]);
}

// 2-edge, 32-out GEMM chunk (w block-uniform -> s_load broadcast)
template<int K>
DEV void g2(const float* __restrict__ x0, const float* __restrict__ x1,
            const float* __restrict__ w, float (&a0)[32], float (&a1)[32]) {
#pragma unroll 4
  for (int k = 0; k < K; k += 4) {
    const float4 u = *(const float4*)(x0 + k);
    const float4 v = *(const float4*)(x1 + k);
    const float* wr = w + (size_t)k * 64;
#pragma unroll
    for (int j = 0; j < 32; ++j) { float ww = wr[j];       a0[j] = fmaf(u.x, ww, a0[j]); a1[j] = fmaf(v.x, ww, a1[j]); }
#pragma unroll
    for (int j = 0; j < 32; ++j) { float ww = wr[64 + j];  a0[j] = fmaf(u.y, ww, a0[j]); a1[j] = fmaf(v.y, ww, a1[j]); }
#pragma unroll
    for (int j = 0; j < 32; ++j) { float ww = wr[128 + j]; a0[j] = fmaf(u.z, ww, a0[j]); a1[j] = fmaf(v.z, ww, a1[j]); }
#pragma unroll
    for (int j = 0; j < 32; ++j) { float ww = wr[192 + j]; a0[j] = fmaf(u.w, ww, a0[j]); a1[j] = fmaf(v.w, ww, a1[j]); }
  }
}

// 1-edge, 32-out GEMM chunk
template<int K>
DEV void g1(const float* __restrict__ x, const float* __restrict__ w,
            float (&a)[32]) {
#pragma unroll 4
  for (int k = 0; k < K; k += 4) {
    const float4 u = *(const float4*)(x + k);
    const float* wr = w + (size_t)k * 64;
#pragma unroll
    for (int j = 0; j < 32; ++j) a[j] = fmaf(u.x, wr[j], a[j]);
#pragma unroll
    for (int j = 0; j < 32; ++j) a[j] = fmaf(u.y, wr[64 + j], a[j]);
#pragma unroll
    for (int j = 0; j < 32; ++j) a[j] = fmaf(u.z, wr[128 + j], a[j]);
#pragma unroll
    for (int j = 0; j < 32; ++j) a[j] = fmaf(u.w, wr[192 + j], a[j]);
  }
}

DEV void ldrow16(const unsigned* __restrict__ p, unsigned (&r)[16]) {
#pragma unroll
  for (int t = 0; t < 4; ++t) {
    uint4 u = ((const uint4*)p)[t];
    r[4*t] = u.x; r[4*t+1] = u.y; r[4*t+2] = u.z; r[4*t+3] = u.w;
  }
}
DEV void unpackf8(const unsigned (&p)[16], float (&o)[64]) {
#pragma unroll
  for (int t = 0; t < 16; ++t) {
    v2f f0 = up2<false>(p[t]);
    v2f f1 = up2<true >(p[t]);
    o[4*t+0] = f0.x; o[4*t+1] = f0.y; o[4*t+2] = f1.x; o[4*t+3] = f1.y;
  }
}
DEV void store32(float* dst, const float (&a)[32]) {
#pragma unroll
  for (int j = 0; j < 32; j += 4)
    *(float4*)(dst + j) = make_float4(a[j], a[j+1], a[j+2], a[j+3]);
}

// pack 8 consecutive fp32 -> bf16x8 (B-fragment k-slice)
DEV bf16x8 packrow8(const float* __restrict__ p) {
  float4 a = *(const float4*)p;
  float4 b = *(const float4*)(p + 4);
  uint4 u = make_uint4(pack2(a.x, a.y), pack2(a.z, a.w),
                       pack2(b.x, b.y), pack2(b.z, b.w));
  return __builtin_bit_cast(bf16x8, u);
}

// 16x16x32 GEMM over K=64: acc[nf] (n = nf*16 + q*4 + reg), A from wtb matrix wm
DEV void mm4(const unsigned short* __restrict__ wm, int er, int q,
             const bf16x8 (&bfr)[2], f32x4 (&acc)[4]) {
#pragma unroll
  for (int nf = 0; nf < 4; ++nf) {
    const unsigned short* ar = wm + (size_t)(nf * 16 + er) * 64 + q * 8;
    const bf16x8 a0 = *(const bf16x8*)ar;
    const bf16x8 a1 = *(const bf16x8*)(ar + 32);
    acc[nf] = __builtin_amdgcn_mfma_f32_16x16x32_bf16(a0, bfr[0], acc[nf], 0, 0, 0);
    acc[nf] = __builtin_amdgcn_mfma_f32_16x16x32_bf16(a1, bfr[1], acc[nf], 0, 0, 0);
  }
}

// ---------- CSR build over edges[0] (rows) ----------
__global__ void __launch_bounds__(256)
k_count(const int* __restrict__ edges, int* __restrict__ icnt) {
  int e = blockIdx.x * 256 + threadIdx.x;
  if (e < NE) atomicAdd(&icnt[edges[e]], 1);
}

__global__ void __launch_bounds__(256)
k_scan(const int* __restrict__ icnt, int* __restrict__ ioffs) {
  __shared__ int part[256];
  const int t = threadIdx.x;
  const int base = t * 40;
  int loc[40];
  int s = 0;
#pragma unroll
  for (int i = 0; i < 40; ++i) {
    int idx = base + i;
    int v = (idx < NN) ? icnt[idx] : 0;
    loc[i] = v; s += v;
  }
  part[t] = s;
  __syncthreads();
  for (int off = 1; off < 256; off <<= 1) {
    int v = (t >= off) ? part[t - off] : 0;
    __syncthreads();
    part[t] += v;
    __syncthreads();
  }
  int run = (t == 0) ? 0 : part[t - 1];
#pragma unroll
  for (int i = 0; i < 40; ++i) {
    int idx = base + i;
    if (idx < NN) { ioffs[idx] = run; run += loc[i]; }
  }
  if (t == 255) ioffs[NN] = NE;
}

__global__ void __launch_bounds__(256)
k_fill(const int* __restrict__ edges, const int* __restrict__ ioffs,
       int* __restrict__ icur, int* __restrict__ eidx) {
  int e = blockIdx.x * 256 + threadIdx.x;
  if (e >= NE) return;
  int r = edges[e];
  int p = atomicAdd(&icur[r], 1);
  eidx[ioffs[r] + p] = e;
}

// ---------- chem layer 1: 272 -> 64 silu (2 edges/thread, y-split) ----------
__global__ void __launch_bounds__(128)
k_chem1(const float* __restrict__ h, const float* __restrict__ na,
        const float* __restrict__ ea, const int* __restrict__ edges,
        const float* __restrict__ w1, const float* __restrict__ b1,
        float* __restrict__ act1c) {
  const int tid = threadIdx.x;
  const int e0 = blockIdx.x * 256 + tid, e1 = e0 + 128;
  const int co = blockIdx.y * 32;
  const int r0 = edges[e0], c0 = edges[NE + e0];
  const int r1 = edges[e1], c1 = edges[NE + e1];
  float a0[32], a1[32];
#pragma unroll
  for (int j = 0; j < 32; ++j) { a0[j] = b1[co + j]; a1[j] = a0[j]; }
  g2<64>(h  + (size_t)r0 * 64, h  + (size_t)r1 * 64, w1 + co,            a0, a1);
  g2<64>(h  + (size_t)c0 * 64, h  + (size_t)c1 * 64, w1 +  64 * 64 + co, a0, a1);
  g2<64>(na + (size_t)r0 * 64, na + (size_t)r1 * 64, w1 + 128 * 64 + co, a0, a1);
  g2<64>(na + (size_t)c0 * 64, na + (size_t)c1 * 64, w1 + 192 * 64 + co, a0, a1);
  g2<16>(ea + (size_t)e0 * 16, ea + (size_t)e1 * 16, w1 + 256 * 64 + co, a0, a1);
#pragma unroll
  for (int j = 0; j < 32; ++j) { a0[j] = fsilu(a0[j]); a1[j] = fsilu(a1[j]); }
  store32(act1c + (size_t)e0 * 64 + co, a0);
  store32(act1c + (size_t)e1 * 64 + co, a1);
}

// ---------- pos layer 1: 36 -> 64 silu ----------
__global__ void __launch_bounds__(256)
k_pos1(const float* __restrict__ coord, const float* __restrict__ nv,
       const float* __restrict__ ea, const int* __restrict__ edges,
       const float* __restrict__ w1, const float* __restrict__ b1,
       float* __restrict__ act1p) {
  const int e = blockIdx.x * 256 + threadIdx.x;
  const int co = blockIdx.y * 32;
  const int r = edges[e], c = edges[NE + e];

  float dx = coord[r * 3 + 0] - coord[c * 3 + 0];
  float dy = coord[r * 3 + 1] - coord[c * 3 + 1];
  float dz = coord[r * 3 + 2] - coord[c * 3 + 2];
  float nrm = sqrtf(dx * dx + dy * dy + dz * dz);
  float inv = 1.0f / (nrm + 1e-8f);
  dx *= inv; dy *= inv; dz *= inv;
  float ir = dx * dx + dy * dy + dz * dz;

  float in[36];
#pragma unroll
  for (int v = 0; v < 5; ++v) {
    float s = 0.f;
#pragma unroll
    for (int d = 0; d < 3; ++d)
      s += nv[(size_t)r * 15 + v * 3 + d] * nv[(size_t)c * 15 + v * 3 + d];
    in[v] = s;
  }
  {
    float cexp = -0.5f;
#pragma unroll
    for (int k = 0; k < 15; ++k) { in[5 + k] = __expf(ir * cexp); cexp *= (1.0f / 2.25f); }
  }
#pragma unroll
  for (int k = 0; k < 16; k += 4) {
    float4 e4 = *(const float4*)(ea + (size_t)e * 16 + k);
    in[20 + k] = e4.x; in[21 + k] = e4.y; in[22 + k] = e4.z; in[23 + k] = e4.w;
  }

  float acc[32];
#pragma unroll
  for (int j = 0; j < 32; ++j) acc[j] = b1[co + j];
#pragma unroll
  for (int k = 0; k < 36; ++k) {
    const float x = in[k];
    const float* wr = w1 + (size_t)k * 64 + co;
#pragma unroll
    for (int j = 0; j < 32; ++j) acc[j] = fmaf(x, wr[j], acc[j]);
  }
#pragma unroll
  for (int j = 0; j < 32; ++j) acc[j] = fsilu(acc[j]);
  store32(act1p + (size_t)e * 64 + co, acc);
}

// ---------- layer 2 of both MLPs (2 edges/thread, y-split) ----------
__global__ void __launch_bounds__(128)
k_l2(const float* __restrict__ act1c, const float* __restrict__ act1p,
     const float* __restrict__ w2c, const float* __restrict__ b2c,
     const float* __restrict__ w2p, const float* __restrict__ b2p,
     float* __restrict__ chem, float* __restrict__ pos) {
  const int tid = threadIdx.x;
  const int e0 = blockIdx.x * 256 + tid, e1 = e0 + 128;
  const int co = blockIdx.y * 32;
  float a0[32], a1[32];
#pragma unroll
  for (int j = 0; j < 32; ++j) { a0[j] = b2c[co + j]; a1[j] = a0[j]; }
  g2<64>(act1c + (size_t)e0 * 64, act1c + (size_t)e1 * 64, w2c + co, a0, a1);
#pragma unroll
  for (int j = 0; j < 32; ++j) { a0[j] = fsilu(a0[j]); a1[j] = fsilu(a1[j]); }
  store32(chem + (size_t)e0 * 64 + co, a0);
  store32(chem + (size_t)e1 * 64 + co, a1);
#pragma unroll
  for (int j = 0; j < 32; ++j) { a0[j] = b2p[co + j]; a1[j] = a0[j]; }
  g2<64>(act1p + (size_t)e0 * 64, act1p + (size_t)e1 * 64, w2p + co, a0, a1);
#pragma unroll
  for (int j = 0; j < 32; ++j) { a0[j] = fsilu(a0[j]); a1[j] = fsilu(a1[j]); }
  store32(pos + (size_t)e0 * 64 + co, a0);
  store32(pos + (size_t)e1 * 64 + co, a1);
}

// ---------- weight prep: wtb[m][n][k] = W_m[k][n] in bf16 (A-operand layout) ----------
// m<16: hd*4+which (0=k,1=v,2=q,3=g); 16: wsh, 17: wu1, 18: wx1, 19..22: w_out per head
__global__ void __launch_bounds__(256)
k_wprep(const float* __restrict__ wk, const float* __restrict__ wv,
        const float* __restrict__ wq, const float* __restrict__ wg,
        const float* __restrict__ wsh, const float* __restrict__ wu1,
        const float* __restrict__ wx1, const float* __restrict__ wout,
        unsigned short* __restrict__ wtb) {
  const int m = blockIdx.x;          // 0..22
  const float* src;
  if (m < 16) {
    const int hd = m >> 2, which = m & 3;
    src = ((which == 0) ? wk : (which == 1) ? wv : (which == 2) ? wq : wg)
          + (size_t)hd * 4096;
  } else if (m < 19) {
    src = (m == 16) ? wsh : (m == 17) ? wu1 : wx1;
  } else {
    src = wout + (size_t)(m - 19) * 4096;   // w_out rows hd*64..hd*64+63
  }
  const int t = threadIdx.x;
#pragma unroll
  for (int i = 0; i < 16; ++i) {
    int idx = t * 16 + i;
    int n = idx >> 6, kk = idx & 63;
    unsigned u = __float_as_uint(src[kk * 64 + n]);
    u += 0x7FFFu + ((u >> 16) & 1u);
    wtb[(size_t)m * 4096 + idx] = (unsigned short)(u >> 16);
  }
}

// ---------- MFMA fused scalars: z/att-gate/be/u/x via matrix cores ----------
__global__ void __launch_bounds__(256)
k_scal_m(const float* __restrict__ coord, const int* __restrict__ edges,
         const float* __restrict__ chem, const float* __restrict__ pos,
         const unsigned short* __restrict__ wtb,
         const float* __restrict__ bsh,
         const float* __restrict__ watt, const float* __restrict__ batt,
         const float* __restrict__ bu1, const float* __restrict__ wu2,
         const float* __restrict__ bu2,
         const float* __restrict__ bx1, const float* __restrict__ wx2,
         const float* __restrict__ bx2,
         const float* __restrict__ wb,
         unsigned* __restrict__ zb, float* __restrict__ be,
         float* __restrict__ x_sum, float* __restrict__ cntf) {
  const int lane = threadIdx.x & 63;
  const int wid  = threadIdx.x >> 6;
  const int er   = lane & 15;
  const int q    = lane >> 4;
  const int e    = blockIdx.x * 64 + wid * 16 + er;
  const float* crow = chem + (size_t)e * 64;
  const float* prow = pos  + (size_t)e * 64;

  // B-frags: bf16-packed k-slices of this edge's chem/pos rows
  bf16x8 cf[2], pf[2];
  cf[0] = packrow8(crow + q * 8); cf[1] = packrow8(crow + 32 + q * 8);
  pf[0] = packrow8(prow + q * 8); pf[1] = packrow8(prow + 32 + q * 8);

  const f32x4 zero = {0.f, 0.f, 0.f, 0.f};

  // z = silu(chem @ wsh + bsh) * pos   (n per lane: nf*16 + q*4 + reg)
  float z[16];
  {
    f32x4 acc[4] = {zero, zero, zero, zero};
    mm4(wtb + (size_t)16 * 4096, er, q, cf, acc);
#pragma unroll
    for (int nf = 0; nf < 4; ++nf) {
      const float4 b4 = *(const float4*)(bsh + nf * 16 + q * 4);
      const float4 p4 = *(const float4*)(prow + nf * 16 + q * 4);
      z[4*nf+0] = fsilu(acc[nf].x + b4.x) * p4.x;
      z[4*nf+1] = fsilu(acc[nf].y + b4.y) * p4.y;
      z[4*nf+2] = fsilu(acc[nf].z + b4.z) * p4.z;
      z[4*nf+3] = fsilu(acc[nf].w + b4.w) * p4.w;
    }
  }
  // att gate: full-row dot reduced across q-groups
  {
    float ap = 0.f;
#pragma unroll
    for (int nf = 0; nf < 4; ++nf)
#pragma unroll
      for (int r = 0; r < 4; ++r)
        ap = fmaf(z[4*nf+r], watt[nf * 16 + q * 4 + r], ap);
    ap += __shfl_xor(ap, 16);
    ap += __shfl_xor(ap, 32);
    const float sg = fsig(ap + batt[0]);
#pragma unroll
    for (int j = 0; j < 16; ++j) z[j] *= sg;
  }
  // zb bf16 row (layout identical to original): uint idx = nf*8 + q*2
  {
    unsigned* zrow = zb + (size_t)e * 32 + q * 2;
#pragma unroll
    for (int nf = 0; nf < 4; ++nf) {
      uint2 w = make_uint2(pack2(z[4*nf+0], z[4*nf+1]), pack2(z[4*nf+2], z[4*nf+3]));
      *(uint2*)(zrow + nf * 8) = w;
    }
  }
  // per-head b scalars
  {
    float bb[4];
#pragma unroll
    for (int hd = 0; hd < 4; ++hd) {
      float b = 0.f;
#pragma unroll
      for (int nf = 0; nf < 4; ++nf)
#pragma unroll
        for (int r = 0; r < 4; ++r)
          b = fmaf(z[4*nf+r], wb[hd * 64 + nf * 16 + q * 4 + r], b);
      b += __shfl_xor(b, 16);
      b += __shfl_xor(b, 32);
      bb[hd] = b;
    }
    if (q == 0)
      *(float4*)(be + (size_t)e * 4) = make_float4(bb[0], bb[1], bb[2], bb[3]);
  }
  // u = silu(chem@wu1+bu1)@wu2 + bu2
  float u;
  {
    f32x4 acc[4] = {zero, zero, zero, zero};
    mm4(wtb + (size_t)17 * 4096, er, q, cf, acc);
    float up = 0.f;
#pragma unroll
    for (int nf = 0; nf < 4; ++nf) {
      const float4 b4 = *(const float4*)(bu1 + nf * 16 + q * 4);
      const float4 w4 = *(const float4*)(wu2 + nf * 16 + q * 4);
      up = fmaf(fsilu(acc[nf].x + b4.x), w4.x, up);
      up = fmaf(fsilu(acc[nf].y + b4.y), w4.y, up);
      up = fmaf(fsilu(acc[nf].z + b4.z), w4.z, up);
      up = fmaf(fsilu(acc[nf].w + b4.w), w4.w, up);
    }
    up += __shfl_xor(up, 16);
    up += __shfl_xor(up, 32);
    u = up + bu2[0];
  }
  // xs = silu(pos@wx1+bx1)@wx2 + bx2
  float xs;
  {
    f32x4 acc[4] = {zero, zero, zero, zero};
    mm4(wtb + (size_t)18 * 4096, er, q, pf, acc);
    float xp = 0.f;
#pragma unroll
    for (int nf = 0; nf < 4; ++nf) {
      const float4 b4 = *(const float4*)(bx1 + nf * 16 + q * 4);
      const float4 w4 = *(const float4*)(wx2 + nf * 16 + q * 4);
      xp = fmaf(fsilu(acc[nf].x + b4.x), w4.x, xp);
      xp = fmaf(fsilu(acc[nf].y + b4.y), w4.y, xp);
      xp = fmaf(fsilu(acc[nf].z + b4.z), w4.z, xp);
      xp = fmaf(fsilu(acc[nf].w + b4.w), w4.w, xp);
    }
    xp += __shfl_xor(xp, 16);
    xp += __shfl_xor(xp, 32);
    xs = xp + bx2[0];
  }

  if (q == 0) {
    const int r = edges[e], c = edges[NE + e];
    float dx = coord[r * 3 + 0] - coord[c * 3 + 0];
    float dy = coord[r * 3 + 1] - coord[c * 3 + 1];
    float dz = coord[r * 3 + 2] - coord[c * 3 + 2];
    float nrm = sqrtf(dx * dx + dy * dy + dz * dz);
    float inv = 1.0f / (nrm + 1e-8f);
    float t = u * xs;
    atomicAdd(&x_sum[r * 3 + 0], dx * inv * t);
    atomicAdd(&x_sum[r * 3 + 1], dy * inv * t);
    atomicAdd(&x_sum[r * 3 + 2], dz * inv * t);
    atomicAdd(&cntf[r], 1.0f);
  }
}

// ---------- MFMA projections -> ksep/vsep (deinterleaved fp8), qho fp8, gf8 fp8 ----------
// K and V in SEPARATE arrays so attention gathers touch fully-used 256B spans.
__global__ void __launch_bounds__(256)
k_projm(const unsigned* __restrict__ zb, const unsigned short* __restrict__ wtb,
        const float* __restrict__ bg,
        unsigned* __restrict__ ksep, unsigned* __restrict__ vsep,
        unsigned* __restrict__ qho, unsigned* __restrict__ gf8) {
  const int lane = threadIdx.x & 63;
  const int wid  = threadIdx.x >> 6;        // wave 0..3
  const int er   = lane & 15;               // edge-in-tile (D col / B col / A row)
  const int q    = lane >> 4;               // k-block (A/B), row-quad (D)
  const int e0   = blockIdx.x * 256 + wid * 64 + er;

  // B frags: z^T, col=e, k=(lane>>4)*8 + i (+32 for half 1)
  bf16x8 zf[4][2];
#pragma unroll
  for (int et = 0; et < 4; ++et) {
    const unsigned* zrow = zb + (size_t)(e0 + et * 16) * 32;   // 64 bf16
    zf[et][0] = __builtin_bit_cast(bf16x8, *(const uint4*)(zrow + q * 4));
    zf[et][1] = __builtin_bit_cast(bf16x8, *(const uint4*)(zrow + 16 + q * 4));
  }

  const f32x4 zero = {0.f, 0.f, 0.f, 0.f};
#pragma unroll 1
  for (int m = 0; m < 16; ++m) {
    const unsigned short* wm = wtb + (size_t)m * 4096;
    f32x4 acc[4][4];
#pragma unroll
    for (int et = 0; et < 4; ++et)
#pragma unroll
      for (int nf = 0; nf < 4; ++nf) acc[et][nf] = zero;
#pragma unroll
    for (int nf = 0; nf < 4; ++nf) {
      const unsigned short* ar = wm + (size_t)(nf * 16 + er) * 64 + q * 8;
      const bf16x8 a0 = *(const bf16x8*)ar;
      const bf16x8 a1 = *(const bf16x8*)(ar + 32);
#pragma unroll
      for (int et = 0; et < 4; ++et) {
        acc[et][nf] = __builtin_amdgcn_mfma_f32_16x16x32_bf16(a0, zf[et][0], acc[et][nf], 0, 0, 0);
        acc[et][nf] = __builtin_amdgcn_mfma_f32_16x16x32_bf16(a1, zf[et][1], acc[et][nf], 0, 0, 0);
      }
    }
    const int hd = m >> 2, which = m & 3;    // wave-uniform
#pragma unroll
    for (int et = 0; et < 4; ++et) {
      const size_t rec = (size_t)(e0 + et * 16) * 4 + hd;
      unsigned* dst = (which == 0) ? (ksep + rec * 16)
                    : (which == 1) ? (vsep + rec * 16)
                    : (which == 2) ? (qho + rec * 16)
                                   : (gf8 + rec * 16);
      if (which == 3) {
#pragma unroll
        for (int nf = 0; nf < 4; ++nf) {
          const float4 b4 = *(const float4*)(bg + hd * 64 + nf * 16 + q * 4);
          dst[nf * 4 + q] = packf8_4(fsig(acc[et][nf].x + b4.x), fsig(acc[et][nf].y + b4.y),
                                     fsig(acc[et][nf].z + b4.z), fsig(acc[et][nf].w + b4.w));
        }
      } else {
#pragma unroll
        for (int nf = 0; nf < 4; ++nf)
          dst[nf * 4 + q] = packf8_4(acc[et][nf].x, acc[et][nf].y,
                                     acc[et][nf].z, acc[et][nf].w);
      }
    }
  }
}

// ---------- attention: flat grid, lane quad = 4 heads of one edge ----------
// K/V deinterleaved: quad gather = 256B fully-used contiguous.
// ho stored BF16 split across qho (k 0..31) + gf8 (k 32..63) records (both dead).
__global__ void __launch_bounds__(256)
k_attn(unsigned* __restrict__ qho, unsigned* __restrict__ gf8,
       const unsigned* __restrict__ ksep, const unsigned* __restrict__ vsep,
       const float* __restrict__ be, const int* __restrict__ klist) {
  const int t = blockIdx.x * 256 + threadIdx.x;
  const int e = t >> 2, hd = t & 3;

  // q (fp8 -> fp32, unscaled)
  float q[64];
  {
    unsigned qp[16];
    ldrow16(qho + (size_t)t * 16, qp);
    unpackf8(qp, q);
  }

  int i2[8], j2[8];
#pragma unroll
  for (int kn = 0; kn < 8; ++kn) {
    i2[kn] = klist[(size_t)e * 16 + kn];
    j2[kn] = klist[(size_t)e * 16 + 8 + kn];
  }
  float bv[8];
#pragma unroll
  for (int kn = 0; kn < 8; ++kn)
    bv[kn] = be[(size_t)((i2[kn] < 0) ? 0 : j2[kn]) * 4 + hd];

  const uint4* k4 = (const uint4*)ksep;   // 4 uint4 per record
  float alpha[8];
#pragma unroll 2
  for (int kn = 0; kn < 8; ++kn) {
    if (i2[kn] < 0) { alpha[kn] = -10000.0f; continue; }
    const uint4* kr = k4 + ((size_t)i2[kn] * 4 + hd) * 4;
    uint4 u0 = kr[0], u1 = kr[1], u2 = kr[2], u3 = kr[3];
    float d = 0.f;
    d = dot16(u0, q,      d);
    d = dot16(u1, q + 16, d);
    d = dot16(u2, q + 32, d);
    d = dot16(u3, q + 48, d);
    alpha[kn] = d * 0.125f + bv[kn];
  }
  float mx = alpha[0];
#pragma unroll
  for (int kn = 1; kn < 8; ++kn) mx = fmaxf(mx, alpha[kn]);
  float p[8], s = 0.f;
#pragma unroll
  for (int kn = 0; kn < 8; ++kn) { p[kn] = __expf(alpha[kn] - mx); s += p[kn]; }
  float is = 1.0f / s;
#pragma unroll
  for (int kn = 0; kn < 8; ++kn) p[kn] *= is;

  float ov[64];
#pragma unroll
  for (int j = 0; j < 64; ++j) ov[j] = 0.f;
  const uint4* v4 = (const uint4*)vsep;
#pragma unroll 2
  for (int kn = 0; kn < 8; ++kn) {
    int vi = (i2[kn] < 0) ? (NE - 1) : i2[kn];   // jax v[-1] wraps
    const uint4* vr = v4 + ((size_t)vi * 4 + hd) * 4;
    uint4 u0 = vr[0], u1 = vr[1], u2 = vr[2], u3 = vr[3];
    const float pk = p[kn];
    acc16(u0, pk, ov +  0);
    acc16(u1, pk, ov + 16);
    acc16(u2, pk, ov + 32);
    acc16(u3, pk, ov + 48);
  }
  // gate (precomputed sigmoid, fp8)
  {
    unsigned gp[16];
    ldrow16(gf8 + (size_t)t * 16, gp);
    float g[64];
    unpackf8(gp, g);
#pragma unroll
    for (int j = 0; j < 64; ++j) ov[j] *= g[j];
  }
  // ho bf16: low 32 vals -> qho rec, high 32 -> gf8 rec (thread-private slots)
  {
    unsigned* qr = qho + (size_t)t * 16;
    unsigned* gr = gf8 + (size_t)t * 16;
#pragma unroll
    for (int t2 = 0; t2 < 2; ++t2) {
      ((uint4*)qr)[t2] = make_uint4(pack2(ov[8*t2+0],  ov[8*t2+1]),  pack2(ov[8*t2+2],  ov[8*t2+3]),
                                    pack2(ov[8*t2+4],  ov[8*t2+5]),  pack2(ov[8*t2+6],  ov[8*t2+7]));
      ((uint4*)qr)[2+t2] = make_uint4(pack2(ov[16+8*t2+0], ov[16+8*t2+1]), pack2(ov[16+8*t2+2], ov[16+8*t2+3]),
                                      pack2(ov[16+8*t2+4], ov[16+8*t2+5]), pack2(ov[16+8*t2+6], ov[16+8*t2+7]));
      ((uint4*)gr)[t2] = make_uint4(pack2(ov[32+8*t2+0], ov[32+8*t2+1]), pack2(ov[32+8*t2+2], ov[32+8*t2+3]),
                                    pack2(ov[32+8*t2+4], ov[32+8*t2+5]), pack2(ov[32+8*t2+6], ov[32+8*t2+7]));
      ((uint4*)gr)[2+t2] = make_uint4(pack2(ov[48+8*t2+0], ov[48+8*t2+1]), pack2(ov[48+8*t2+2], ov[48+8*t2+3]),
                                      pack2(ov[48+8*t2+4], ov[48+8*t2+5]), pack2(ov[48+8*t2+6], ov[48+8*t2+7]));
    }
  }
}

// ---------- output projection via MFMA: m[e] = sum_hd ho_hd @ Wout_hd ----------
// ho bf16 from qho(k 0..31)+gf8(k 32..63); Wout^T bf16 at wtb[19+hd]. C chained over heads.
__global__ void __launch_bounds__(256)
k_mout(const unsigned* __restrict__ qho, const unsigned* __restrict__ gf8,
       const unsigned short* __restrict__ wtb, float* __restrict__ medge) {
  const int lane = threadIdx.x & 63;
  const int wid  = threadIdx.x >> 6;
  const int er   = lane & 15;
  const int q    = lane >> 4;
  const int e0   = blockIdx.x * 256 + wid * 64 + er;

  const f32x4 zero = {0.f, 0.f, 0.f, 0.f};
  f32x4 acc[4][4];
#pragma unroll
  for (int et = 0; et < 4; ++et)
#pragma unroll
    for (int nf = 0; nf < 4; ++nf) acc[et][nf] = zero;

#pragma unroll 1
  for (int hd = 0; hd < 4; ++hd) {
    const unsigned short* wm = wtb + (size_t)(19 + hd) * 4096;
    bf16x8 hf[4][2];
#pragma unroll
    for (int et = 0; et < 4; ++et) {
      const size_t rec = (size_t)(e0 + et * 16) * 4 + hd;
      hf[et][0] = __builtin_bit_cast(bf16x8, *(const uint4*)(qho + rec * 16 + q * 4));
      hf[et][1] = __builtin_bit_cast(bf16x8, *(const uint4*)(gf8 + rec * 16 + q * 4));
    }
#pragma unroll
    for (int nf = 0; nf < 4; ++nf) {
      const unsigned short* ar = wm + (size_t)(nf * 16 + er) * 64 + q * 8;
      const bf16x8 a0 = *(const bf16x8*)ar;
      const bf16x8 a1 = *(const bf16x8*)(ar + 32);
#pragma unroll
      for (int et = 0; et < 4; ++et) {
        acc[et][nf] = __builtin_amdgcn_mfma_f32_16x16x32_bf16(a0, hf[et][0], acc[et][nf], 0, 0, 0);
        acc[et][nf] = __builtin_amdgcn_mfma_f32_16x16x32_bf16(a1, hf[et][1], acc[et][nf], 0, 0, 0);
      }
    }
  }
#pragma unroll
  for (int et = 0; et < 4; ++et)
#pragma unroll
    for (int nf = 0; nf < 4; ++nf)
      *(float4*)(medge + (size_t)(e0 + et * 16) * 64 + nf * 16 + q * 4) =
          make_float4(acc[et][nf].x, acc[et][nf].y, acc[et][nf].z, acc[et][nf].w);
}

// ---------- CSR gather: per-node segment sum of medge ----------
__global__ void __launch_bounds__(256)
k_nodesum(const float* __restrict__ medge, const int* __restrict__ ioffs,
          const int* __restrict__ eidx, float* __restrict__ m_sum) {
  const int wid = threadIdx.x >> 6, lane = threadIdx.x & 63;
  const int n = blockIdx.x * 4 + wid;
  if (n >= NN) return;
  const int beg = ioffs[n], end = ioffs[n + 1];
  float acc = 0.f;
  for (int i = beg; i < end; ++i) {
    int e = eidx[i];
    acc += medge[(size_t)e * 64 + lane];
  }
  m_sum[(size_t)n * 64 + lane] = acc;
}

// ---------- final node update ----------
__global__ void __launch_bounds__(256)
k_final(const float* __restrict__ h, const float* __restrict__ na,
        const float* __restrict__ coord, const float* __restrict__ icoord,
        const float* __restrict__ m_sum, const float* __restrict__ x_sum,
        const float* __restrict__ cntf, const float* __restrict__ bout,
        const float* __restrict__ wh1, const float* __restrict__ bh1,
        const float* __restrict__ wh2, const float* __restrict__ bh2,
        float* __restrict__ scr, float* __restrict__ out) {
  int n = blockIdx.x * 256 + threadIdx.x;
  if (n >= NN) return;
  float cn = cntf[n];
  float invc = 1.0f / fmaxf(cn, 1.0f);
  float bsc = (cn > 0.f) ? 1.0f : 0.0f;   // empty segment => m_agg = 0 (no bout)

#pragma unroll
  for (int d = 0; d < 3; ++d)
    out[(size_t)NN * 64 + n * 3 + d] =
        0.2f * icoord[n * 3 + d] + 0.8f * coord[n * 3 + d] + x_sum[n * 3 + d] * invc;

  const float* hr = h  + (size_t)n * 64;
  const float* nr = na + (size_t)n * 64;
  const float* mr = m_sum + (size_t)n * 64;
  float* srow = scr + (size_t)n * 64;

#pragma unroll 1
  for (int cc = 0; cc < 64; cc += 32) {
    float acc[32];
#pragma unroll
    for (int j = 0; j < 32; ++j) acc[j] = bh1[cc + j];
    g1<64>(hr, wh1 + cc, acc);
    g1<64>(nr, wh1 + 64 * 64 + cc, acc);
#pragma unroll 4
    for (int k = 0; k < 64; k += 4) {
      float4 m4 = *(const float4*)(mr + k);
      float xv[4] = { fmaf(m4.x, invc, bout[k] * bsc), fmaf(m4.y, invc, bout[k+1] * bsc),
                      fmaf(m4.z, invc, bout[k+2] * bsc), fmaf(m4.w, invc, bout[k+3] * bsc) };
#pragma unroll
      for (int q = 0; q < 4; ++q) {
        const float* wr = wh1 + (size_t)(128 + k + q) * 64 + cc;
        const float x = xv[q];
#pragma unroll
        for (int j = 0; j < 32; ++j) acc[j] = fmaf(x, wr[j], acc[j]);
      }
    }
#pragma unroll
    for (int j = 0; j < 32; ++j) acc[j] = fsilu(acc[j]);
    store32(srow + cc, acc);
  }
#pragma unroll 1
  for (int cc = 0; cc < 64; cc += 32) {
    float acc[32];
#pragma unroll
    for (int j = 0; j < 32; ++j) acc[j] = bh2[cc + j];
    g1<64>(srow, wh2 + cc, acc);
#pragma unroll
    for (int j = 0; j < 32; j += 4) {
      float4 h4 = *(const float4*)(hr + cc + j);
      *(float4*)(out + (size_t)n * 64 + cc + j) =
          make_float4(acc[j] + h4.x, acc[j+1] + h4.y, acc[j+2] + h4.z, acc[j+3] + h4.w);
    }
  }
}

extern "C" void kernel_launch(void* const* d_in, const int* in_sizes, int n_in,
                              void* d_out, int out_size, void* d_ws, size_t ws_size,
                              hipStream_t stream) {
  (void)in_sizes; (void)n_in; (void)out_size; (void)ws_size;
  const float* h      = (const float*)d_in[0];
  const float* coord  = (const float*)d_in[1];
  const int*   edges  = (const int*)  d_in[2];
  const float* nvecs  = (const float*)d_in[3];
  const float* ea     = (const float*)d_in[4];
  const float* na     = (const float*)d_in[5];
  const float* icoord = (const float*)d_in[6];
  const int*   klist  = (const int*)  d_in[7];
  const float* w_chem1 = (const float*)d_in[8];
  const float* b_chem1 = (const float*)d_in[9];
  const float* w_chem2 = (const float*)d_in[10];
  const float* b_chem2 = (const float*)d_in[11];
  const float* w_pos1  = (const float*)d_in[12];
  const float* b_pos1  = (const float*)d_in[13];
  const float* w_pos2  = (const float*)d_in[14];
  const float* b_pos2  = (const float*)d_in[15];
  const float* w_sh    = (const float*)d_in[16];
  const float* b_sh    = (const float*)d_in[17];
  const float* w_att   = (const float*)d_in[18];
  const float* b_att   = (const float*)d_in[19];
  const float* wq      = (const float*)d_in[20];
  const float* wk      = (const float*)d_in[21];
  const float* wv      = (const float*)d_in[22];
  const float* wb      = (const float*)d_in[23];
  const float* wg      = (const float*)d_in[24];
  const float* bg      = (const float*)d_in[25];
  const float* w_out   = (const float*)d_in[26];
  const float* b_out   = (const float*)d_in[27];
  const float* wu1     = (const float*)d_in[28];
  const float* bu1     = (const float*)d_in[29];
  const float* wu2     = (const float*)d_in[30];
  const float* bu2     = (const float*)d_in[31];
  const float* wx1     = (const float*)d_in[32];
  const float* bx1     = (const float*)d_in[33];
  const float* wx2     = (const float*)d_in[34];
  const float* bx2     = (const float*)d_in[35];
  const float* wh1     = (const float*)d_in[36];
  const float* bh1     = (const float*)d_in[37];
  const float* wh2     = (const float*)d_in[38];
  const float* bh2     = (const float*)d_in[39];

  float* out = (float*)d_out;
  float* ws  = (float*)d_ws;
  // Phase-reused regions (NE*64 floats each):
  //  R1: act1c -> ksep [NE*4][64B] fp8 K -> medge after attn
  //  R2: act1p -> vsep [NE*4][64B] fp8 V
  //  R3: chem  -> qho  [NE*4][16u] fp8 q -> ho bf16 low-half after attn
  //  R4: pos   -> gf8  [NE*4][16u] fp8 gate -> ho bf16 high-half after attn
  float* R1 = ws;
  float* R2 = R1 + (size_t)NE * 64;
  float* R3 = R2 + (size_t)NE * 64;
  float* R4 = R3 + (size_t)NE * 64;
  float* zbf   = R4 + (size_t)NE * 64;      // NE*32 floats (bf16 gated z)
  float* x_sum = zbf + (size_t)NE * 32;     // NN*3 (zeroed)
  float* cntf  = x_sum + (size_t)NN * 3;    // NN (zeroed)
  int*   icnt  = (int*)(cntf + NN);         // NN (zeroed)
  int*   icur  = icnt + NN;                 // NN (zeroed)
  float* m_sum = (float*)(icur + NN);       // NN*64
  float* be    = m_sum + (size_t)NN * 64;   // 4*NE  ([e*4+hd] layout)
  float* nscr  = be + (size_t)4 * NE;       // NN*64
  unsigned short* wtb = (unsigned short*)(nscr + (size_t)NN * 64);  // 23*64*64 bf16 (184KB)
  int*   ioffs = (int*)(wtb + 23 * 4096);   // NN+1
  int*   eidx  = ioffs + (NN + 1);          // NE

  unsigned* ksep = (unsigned*)R1;  // [NE*4][16u] fp8 K (deinterleaved)
  unsigned* vsep = (unsigned*)R2;  // [NE*4][16u] fp8 V
  unsigned* qho  = (unsigned*)R3;  // [NE*4][16u] fp8 q -> bf16 ho lo
  unsigned* gf8  = (unsigned*)R4;  // [NE*4][16u] fp8 gate -> bf16 ho hi
  unsigned* zb   = (unsigned*)zbf;
  float* medge = R1;               // after attention (ksep dead)

  (void)hipMemsetAsync(x_sum, 0, ((size_t)NN * 3 + NN + NN + NN) * sizeof(float), stream);

  dim3 b128(128), b256(256);
  dim3 gs2(NE / 256, 2);
  dim3 gflat(NE / 256);

  // weight prep + CSR build (independent of the MLP pipeline)
  k_wprep<<<dim3(23), b256, 0, stream>>>(wk, wv, wq, wg, w_sh, wu1, wx1, w_out, wtb);
  k_count<<<gflat, b256, 0, stream>>>(edges, icnt);
  k_scan <<<dim3(1), b256, 0, stream>>>(icnt, ioffs);
  k_fill <<<gflat, b256, 0, stream>>>(edges, ioffs, icur, eidx);

  k_chem1<<<gs2, b128, 0, stream>>>(h, na, ea, edges, w_chem1, b_chem1, R1);
  k_pos1 <<<gs2, b256, 0, stream>>>(coord, nvecs, ea, edges, w_pos1, b_pos1, R2);
  k_l2   <<<gs2, b128, 0, stream>>>(R1, R2, w_chem2, b_chem2, w_pos2, b_pos2, R3, R4);
  k_scal_m<<<dim3(NE / 64), b256, 0, stream>>>(coord, edges, R3, R4, wtb,
                                               b_sh, w_att, b_att,
                                               bu1, wu2, bu2, bx1, wx2, bx2, wb,
                                               zb, be, x_sum, cntf);
  k_projm<<<dim3(NE / 256), b256, 0, stream>>>(zb, wtb, bg, ksep, vsep, qho, gf8);
  k_attn <<<dim3(NE * 4 / 256), b256, 0, stream>>>(qho, gf8, ksep, vsep, be, klist);
  k_mout <<<dim3(NE / 256), b256, 0, stream>>>(qho, gf8, wtb, medge);
  k_nodesum<<<dim3((NN + 3) / 4), b256, 0, stream>>>(medge, ioffs, eidx, m_sum);
  k_final<<<dim3((NN + 255) / 256), b256, 0, stream>>>(h, na, coord, icoord, m_sum, x_sum,
                                                       cntf, b_out, wh1, bh1, wh2, bh2,
                                                       nscr, out);
}

// Round 6
// 896.692 us; speedup vs baseline: 1.6153x; 1.0140x over previous
//
#include <hip/hip_runtime.h>
#include <math.h>

#define NE 160000
#define NN 10000

#define DEV __device__ __forceinline__

typedef float v2f __attribute__((ext_vector_type(2)));
typedef __attribute__((ext_vector_type(8))) short bf16x8;   // 8 bf16 (4 VGPRs)
typedef __attribute__((ext_vector_type(4))) float f32x4;

DEV float fsilu(float x) { return x / (1.0f + __expf(-x)); }
DEV float fsig(float x)  { return 1.0f / (1.0f + __expf(-x)); }

// ---- bf16 pack/unpack helpers (RNE) ----
DEV unsigned pack2(float a, float b) {
  unsigned ua = __float_as_uint(a); ua += 0x7FFFu + ((ua >> 16) & 1u);
  unsigned ub = __float_as_uint(b); ub += 0x7FFFu + ((ub >> 16) & 1u);
  return (ua >> 16) | (ub & 0xFFFF0000u);
}

// ---- fp8 e4m3 (OCP, HW-converted) ----
DEV unsigned packf8_4(float a, float b, float c, float d) {
  int r = __builtin_amdgcn_cvt_pk_fp8_f32(a, b, 0, false);
  r = __builtin_amdgcn_cvt_pk_fp8_f32(c, d, r, true);
  return (unsigned)r;
}
template<bool HI>
DEV v2f up2(unsigned u) { return __builtin_amdgcn_cvt_pk_f32_fp8((int)u, HI); }

// dot of 16 fp8 values (one uint4) against q[0..16)
DEV float dot16(uint4 u, const float* q, float d) {
  v2f f;
  f = up2<false>(u.x); d = fmaf(f.x, q[0],  d); d = fmaf(f.y, q[1],  d);
  f = up2<true >(u.x); d = fmaf(f.x, q[2],  d); d = fmaf(f.y, q[3],  d);
  f = up2<false>(u.y); d = fmaf(f.x, q[4],  d); d = fmaf(f.y, q[5],  d);
  f = up2<true >(u.y); d = fmaf(f.x, q[6],  d); d = fmaf(f.y, q[7],  d);
  f = up2<false>(u.z); d = fmaf(f.x, q[8],  d); d = fmaf(f.y, q[9],  d);
  f = up2<true >(u.z); d = fmaf(f.x, q[10], d); d = fmaf(f.y, q[11], d);
  f = up2<false>(u.w); d = fmaf(f.x, q[12], d); d = fmaf(f.y, q[13], d);
  f = up2<true >(u.w); d = fmaf(f.x, q[14], d); d = fmaf(f.y, q[15], d);
  return d;
}
// o[0..16) += pk * fp8x16(u)
DEV void acc16(uint4 u, float pk, float* o) {
  v2f f;
  f = up2<false>(u.x); o[0]  = fmaf(pk, f.x, o[0]);  o[1]  = fmaf(pk, f.y, o[1]);
  f = up2<true >(u.x); o[2]  = fmaf(pk, f.x, o[2]);  o[3]  = fmaf(pk, f.y, o[3]);
  f = up2<false>(u.y); o[4]  = fmaf(pk, f.x, o[4]);  o[5]  = fmaf(pk, f.y, o[5]);
  f = up2<true >(u.y); o[6]  = fmaf(pk, f.x, o[6]);  o[7]  = fmaf(pk, f.y, o[7]);
  f = up2<false>(u.z); o[8]  = fmaf(pk, f.x, o[8]);  o[9]  = fmaf(pk, f.y, o[9]);
  f = up2<true >(u.z); o[10] = fmaf(pk, f.x, o[10]); o[11] = fmaf(pk, f.y, o[11]);
  f = up2<false>(u.w); o[12] = fmaf(pk, f.x, o[12]); o[13] = fmaf(pk, f.y, o[13]);
  f = up2<true >(u.w); o[14] = fmaf(pk, f.x, o[14]); o[15] = fmaf(pk, f.y, o[15]);
}

// 2-edge, 32-out GEMM chunk (w block-uniform -> s_load broadcast)
template<int K>
DEV void g2(const float* __restrict__ x0, const float* __restrict__ x1,
            const float* __restrict__ w, float (&a0)[32], float (&a1)[32]) {
#pragma unroll 4
  for (int k = 0; k < K; k += 4) {
    const float4 u = *(const float4*)(x0 + k);
    const float4 v = *(const float4*)(x1 + k);
    const float* wr = w + (size_t)k * 64;
#pragma unroll
    for (int j = 0; j < 32; ++j) { float ww = wr[j];       a0[j] = fmaf(u.x, ww, a0[j]); a1[j] = fmaf(v.x, ww, a1[j]); }
#pragma unroll
    for (int j = 0; j < 32; ++j) { float ww = wr[64 + j];  a0[j] = fmaf(u.y, ww, a0[j]); a1[j] = fmaf(v.y, ww, a1[j]); }
#pragma unroll
    for (int j = 0; j < 32; ++j) { float ww = wr[128 + j]; a0[j] = fmaf(u.z, ww, a0[j]); a1[j] = fmaf(v.z, ww, a1[j]); }
#pragma unroll
    for (int j = 0; j < 32; ++j) { float ww = wr[192 + j]; a0[j] = fmaf(u.w, ww, a0[j]); a1[j] = fmaf(v.w, ww, a1[j]); }
  }
}

DEV void ldrow16(const unsigned* __restrict__ p, unsigned (&r)[16]) {
#pragma unroll
  for (int t = 0; t < 4; ++t) {
    uint4 u = ((const uint4*)p)[t];
    r[4*t] = u.x; r[4*t+1] = u.y; r[4*t+2] = u.z; r[4*t+3] = u.w;
  }
}
DEV void unpackf8(const unsigned (&p)[16], float (&o)[64]) {
#pragma unroll
  for (int t = 0; t < 16; ++t) {
    v2f f0 = up2<false>(p[t]);
    v2f f1 = up2<true >(p[t]);
    o[4*t+0] = f0.x; o[4*t+1] = f0.y; o[4*t+2] = f1.x; o[4*t+3] = f1.y;
  }
}
DEV void store32(float* dst, const float (&a)[32]) {
#pragma unroll
  for (int j = 0; j < 32; j += 4)
    *(float4*)(dst + j) = make_float4(a[j], a[j+1], a[j+2], a[j+3]);
}

// pack 8 consecutive fp32 -> bf16x8 (B-fragment k-slice)
DEV bf16x8 packrow8(const float* __restrict__ p) {
  float4 a = *(const float4*)p;
  float4 b = *(const float4*)(p + 4);
  uint4 u = make_uint4(pack2(a.x, a.y), pack2(a.z, a.w),
                       pack2(b.x, b.y), pack2(b.z, b.w));
  return __builtin_bit_cast(bf16x8, u);
}

// 16x16x32 GEMM over K=64: acc[nf] (n = nf*16 + q*4 + reg), A from wtb matrix wm
DEV void mm4(const unsigned short* __restrict__ wm, int er, int q,
             const bf16x8 (&bfr)[2], f32x4 (&acc)[4]) {
#pragma unroll
  for (int nf = 0; nf < 4; ++nf) {
    const unsigned short* ar = wm + (size_t)(nf * 16 + er) * 64 + q * 8;
    const bf16x8 a0 = *(const bf16x8*)ar;
    const bf16x8 a1 = *(const bf16x8*)(ar + 32);
    acc[nf] = __builtin_amdgcn_mfma_f32_16x16x32_bf16(a0, bfr[0], acc[nf], 0, 0, 0);
    acc[nf] = __builtin_amdgcn_mfma_f32_16x16x32_bf16(a1, bfr[1], acc[nf], 0, 0, 0);
  }
}

// ---------- CSR build over edges[0] (rows) ----------
__global__ void __launch_bounds__(256)
k_count(const int* __restrict__ edges, int* __restrict__ icnt) {
  int e = blockIdx.x * 256 + threadIdx.x;
  if (e < NE) atomicAdd(&icnt[edges[e]], 1);
}

__global__ void __launch_bounds__(256)
k_scan(const int* __restrict__ icnt, int* __restrict__ ioffs) {
  __shared__ int part[256];
  const int t = threadIdx.x;
  const int base = t * 40;
  int loc[40];
  int s = 0;
#pragma unroll
  for (int i = 0; i < 40; ++i) {
    int idx = base + i;
    int v = (idx < NN) ? icnt[idx] : 0;
    loc[i] = v; s += v;
  }
  part[t] = s;
  __syncthreads();
  for (int off = 1; off < 256; off <<= 1) {
    int v = (t >= off) ? part[t - off] : 0;
    __syncthreads();
    part[t] += v;
    __syncthreads();
  }
  int run = (t == 0) ? 0 : part[t - 1];
#pragma unroll
  for (int i = 0; i < 40; ++i) {
    int idx = base + i;
    if (idx < NN) { ioffs[idx] = run; run += loc[i]; }
  }
  if (t == 255) ioffs[NN] = NE;
}

__global__ void __launch_bounds__(256)
k_fill(const int* __restrict__ edges, const int* __restrict__ ioffs,
       int* __restrict__ icur, int* __restrict__ eidx) {
  int e = blockIdx.x * 256 + threadIdx.x;
  if (e >= NE) return;
  int r = edges[e];
  int p = atomicAdd(&icur[r], 1);
  eidx[ioffs[r] + p] = e;
}

// ---------- chem layer 1: 272 -> 64 silu (2 edges/thread, y-split) ----------
__global__ void __launch_bounds__(128)
k_chem1(const float* __restrict__ h, const float* __restrict__ na,
        const float* __restrict__ ea, const int* __restrict__ edges,
        const float* __restrict__ w1, const float* __restrict__ b1,
        float* __restrict__ act1c) {
  const int tid = threadIdx.x;
  const int e0 = blockIdx.x * 256 + tid, e1 = e0 + 128;
  const int co = blockIdx.y * 32;
  const int r0 = edges[e0], c0 = edges[NE + e0];
  const int r1 = edges[e1], c1 = edges[NE + e1];
  float a0[32], a1[32];
#pragma unroll
  for (int j = 0; j < 32; ++j) { a0[j] = b1[co + j]; a1[j] = a0[j]; }
  g2<64>(h  + (size_t)r0 * 64, h  + (size_t)r1 * 64, w1 + co,            a0, a1);
  g2<64>(h  + (size_t)c0 * 64, h  + (size_t)c1 * 64, w1 +  64 * 64 + co, a0, a1);
  g2<64>(na + (size_t)r0 * 64, na + (size_t)r1 * 64, w1 + 128 * 64 + co, a0, a1);
  g2<64>(na + (size_t)c0 * 64, na + (size_t)c1 * 64, w1 + 192 * 64 + co, a0, a1);
  g2<16>(ea + (size_t)e0 * 16, ea + (size_t)e1 * 16, w1 + 256 * 64 + co, a0, a1);
#pragma unroll
  for (int j = 0; j < 32; ++j) { a0[j] = fsilu(a0[j]); a1[j] = fsilu(a1[j]); }
  store32(act1c + (size_t)e0 * 64 + co, a0);
  store32(act1c + (size_t)e1 * 64 + co, a1);
}

// ---------- pos layer 1: 36 -> 64 silu ----------
__global__ void __launch_bounds__(256)
k_pos1(const float* __restrict__ coord, const float* __restrict__ nv,
       const float* __restrict__ ea, const int* __restrict__ edges,
       const float* __restrict__ w1, const float* __restrict__ b1,
       float* __restrict__ act1p) {
  const int e = blockIdx.x * 256 + threadIdx.x;
  const int co = blockIdx.y * 32;
  const int r = edges[e], c = edges[NE + e];

  float dx = coord[r * 3 + 0] - coord[c * 3 + 0];
  float dy = coord[r * 3 + 1] - coord[c * 3 + 1];
  float dz = coord[r * 3 + 2] - coord[c * 3 + 2];
  float nrm = sqrtf(dx * dx + dy * dy + dz * dz);
  float inv = 1.0f / (nrm + 1e-8f);
  dx *= inv; dy *= inv; dz *= inv;
  float ir = dx * dx + dy * dy + dz * dz;

  float in[36];
#pragma unroll
  for (int v = 0; v < 5; ++v) {
    float s = 0.f;
#pragma unroll
    for (int d = 0; d < 3; ++d)
      s += nv[(size_t)r * 15 + v * 3 + d] * nv[(size_t)c * 15 + v * 3 + d];
    in[v] = s;
  }
  {
    float cexp = -0.5f;
#pragma unroll
    for (int k = 0; k < 15; ++k) { in[5 + k] = __expf(ir * cexp); cexp *= (1.0f / 2.25f); }
  }
#pragma unroll
  for (int k = 0; k < 16; k += 4) {
    float4 e4 = *(const float4*)(ea + (size_t)e * 16 + k);
    in[20 + k] = e4.x; in[21 + k] = e4.y; in[22 + k] = e4.z; in[23 + k] = e4.w;
  }

  float acc[32];
#pragma unroll
  for (int j = 0; j < 32; ++j) acc[j] = b1[co + j];
#pragma unroll
  for (int k = 0; k < 36; ++k) {
    const float x = in[k];
    const float* wr = w1 + (size_t)k * 64 + co;
#pragma unroll
    for (int j = 0; j < 32; ++j) acc[j] = fmaf(x, wr[j], acc[j]);
  }
#pragma unroll
  for (int j = 0; j < 32; ++j) acc[j] = fsilu(acc[j]);
  store32(act1p + (size_t)e * 64 + co, acc);
}

// ---------- layer 2 of both MLPs (2 edges/thread, y-split) ----------
__global__ void __launch_bounds__(128)
k_l2(const float* __restrict__ act1c, const float* __restrict__ act1p,
     const float* __restrict__ w2c, const float* __restrict__ b2c,
     const float* __restrict__ w2p, const float* __restrict__ b2p,
     float* __restrict__ chem, float* __restrict__ pos) {
  const int tid = threadIdx.x;
  const int e0 = blockIdx.x * 256 + tid, e1 = e0 + 128;
  const int co = blockIdx.y * 32;
  float a0[32], a1[32];
#pragma unroll
  for (int j = 0; j < 32; ++j) { a0[j] = b2c[co + j]; a1[j] = a0[j]; }
  g2<64>(act1c + (size_t)e0 * 64, act1c + (size_t)e1 * 64, w2c + co, a0, a1);
#pragma unroll
  for (int j = 0; j < 32; ++j) { a0[j] = fsilu(a0[j]); a1[j] = fsilu(a1[j]); }
  store32(chem + (size_t)e0 * 64 + co, a0);
  store32(chem + (size_t)e1 * 64 + co, a1);
#pragma unroll
  for (int j = 0; j < 32; ++j) { a0[j] = b2p[co + j]; a1[j] = a0[j]; }
  g2<64>(act1p + (size_t)e0 * 64, act1p + (size_t)e1 * 64, w2p + co, a0, a1);
#pragma unroll
  for (int j = 0; j < 32; ++j) { a0[j] = fsilu(a0[j]); a1[j] = fsilu(a1[j]); }
  store32(pos + (size_t)e0 * 64 + co, a0);
  store32(pos + (size_t)e1 * 64 + co, a1);
}

// ---------- weight prep: wtb[m][n][k] = W_m[k][n] in bf16 (A-operand layout) ----------
// m<16: hd*4+which (0=k,1=v,2=q,3=g); 16: wsh, 17: wu1, 18: wx1, 19..22: w_out per head,
// 23..25: wh1 k-slices (h / na / m_agg), 26: wh2
__global__ void __launch_bounds__(256)
k_wprep(const float* __restrict__ wk, const float* __restrict__ wv,
        const float* __restrict__ wq, const float* __restrict__ wg,
        const float* __restrict__ wsh, const float* __restrict__ wu1,
        const float* __restrict__ wx1, const float* __restrict__ wout,
        const float* __restrict__ wh1, const float* __restrict__ wh2,
        unsigned short* __restrict__ wtb) {
  const int m = blockIdx.x;          // 0..26
  const float* src;
  if (m < 16) {
    const int hd = m >> 2, which = m & 3;
    src = ((which == 0) ? wk : (which == 1) ? wv : (which == 2) ? wq : wg)
          + (size_t)hd * 4096;
  } else if (m < 19) {
    src = (m == 16) ? wsh : (m == 17) ? wu1 : wx1;
  } else if (m < 23) {
    src = wout + (size_t)(m - 19) * 4096;   // w_out rows hd*64..hd*64+63
  } else if (m < 26) {
    src = wh1 + (size_t)(m - 23) * 4096;    // wh1 rows: h / na / m_agg slices
  } else {
    src = wh2;
  }
  const int t = threadIdx.x;
#pragma unroll
  for (int i = 0; i < 16; ++i) {
    int idx = t * 16 + i;
    int n = idx >> 6, kk = idx & 63;
    unsigned u = __float_as_uint(src[kk * 64 + n]);
    u += 0x7FFFu + ((u >> 16) & 1u);
    wtb[(size_t)m * 4096 + idx] = (unsigned short)(u >> 16);
  }
}

// ---------- MFMA fused scalars: z/att-gate/be/u/x via matrix cores ----------
__global__ void __launch_bounds__(256)
k_scal_m(const float* __restrict__ coord, const int* __restrict__ edges,
         const float* __restrict__ chem, const float* __restrict__ pos,
         const unsigned short* __restrict__ wtb,
         const float* __restrict__ bsh,
         const float* __restrict__ watt, const float* __restrict__ batt,
         const float* __restrict__ bu1, const float* __restrict__ wu2,
         const float* __restrict__ bu2,
         const float* __restrict__ bx1, const float* __restrict__ wx2,
         const float* __restrict__ bx2,
         const float* __restrict__ wb,
         unsigned* __restrict__ zb, float* __restrict__ be,
         float* __restrict__ x_sum, float* __restrict__ cntf) {
  const int lane = threadIdx.x & 63;
  const int wid  = threadIdx.x >> 6;
  const int er   = lane & 15;
  const int q    = lane >> 4;
  const int e    = blockIdx.x * 64 + wid * 16 + er;
  const float* crow = chem + (size_t)e * 64;
  const float* prow = pos  + (size_t)e * 64;

  // B-frags: bf16-packed k-slices of this edge's chem/pos rows
  bf16x8 cf[2], pf[2];
  cf[0] = packrow8(crow + q * 8); cf[1] = packrow8(crow + 32 + q * 8);
  pf[0] = packrow8(prow + q * 8); pf[1] = packrow8(prow + 32 + q * 8);

  const f32x4 zero = {0.f, 0.f, 0.f, 0.f};

  // z = silu(chem @ wsh + bsh) * pos   (n per lane: nf*16 + q*4 + reg)
  float z[16];
  {
    f32x4 acc[4] = {zero, zero, zero, zero};
    mm4(wtb + (size_t)16 * 4096, er, q, cf, acc);
#pragma unroll
    for (int nf = 0; nf < 4; ++nf) {
      const float4 b4 = *(const float4*)(bsh + nf * 16 + q * 4);
      const float4 p4 = *(const float4*)(prow + nf * 16 + q * 4);
      z[4*nf+0] = fsilu(acc[nf].x + b4.x) * p4.x;
      z[4*nf+1] = fsilu(acc[nf].y + b4.y) * p4.y;
      z[4*nf+2] = fsilu(acc[nf].z + b4.z) * p4.z;
      z[4*nf+3] = fsilu(acc[nf].w + b4.w) * p4.w;
    }
  }
  // att gate: full-row dot reduced across q-groups
  {
    float ap = 0.f;
#pragma unroll
    for (int nf = 0; nf < 4; ++nf)
#pragma unroll
      for (int r = 0; r < 4; ++r)
        ap = fmaf(z[4*nf+r], watt[nf * 16 + q * 4 + r], ap);
    ap += __shfl_xor(ap, 16);
    ap += __shfl_xor(ap, 32);
    const float sg = fsig(ap + batt[0]);
#pragma unroll
    for (int j = 0; j < 16; ++j) z[j] *= sg;
  }
  // zb bf16 row (layout identical to original): uint idx = nf*8 + q*2
  {
    unsigned* zrow = zb + (size_t)e * 32 + q * 2;
#pragma unroll
    for (int nf = 0; nf < 4; ++nf) {
      uint2 w = make_uint2(pack2(z[4*nf+0], z[4*nf+1]), pack2(z[4*nf+2], z[4*nf+3]));
      *(uint2*)(zrow + nf * 8) = w;
    }
  }
  // per-head b scalars
  {
    float bb[4];
#pragma unroll
    for (int hd = 0; hd < 4; ++hd) {
      float b = 0.f;
#pragma unroll
      for (int nf = 0; nf < 4; ++nf)
#pragma unroll
        for (int r = 0; r < 4; ++r)
          b = fmaf(z[4*nf+r], wb[hd * 64 + nf * 16 + q * 4 + r], b);
      b += __shfl_xor(b, 16);
      b += __shfl_xor(b, 32);
      bb[hd] = b;
    }
    if (q == 0)
      *(float4*)(be + (size_t)e * 4) = make_float4(bb[0], bb[1], bb[2], bb[3]);
  }
  // u = silu(chem@wu1+bu1)@wu2 + bu2
  float u;
  {
    f32x4 acc[4] = {zero, zero, zero, zero};
    mm4(wtb + (size_t)17 * 4096, er, q, cf, acc);
    float up = 0.f;
#pragma unroll
    for (int nf = 0; nf < 4; ++nf) {
      const float4 b4 = *(const float4*)(bu1 + nf * 16 + q * 4);
      const float4 w4 = *(const float4*)(wu2 + nf * 16 + q * 4);
      up = fmaf(fsilu(acc[nf].x + b4.x), w4.x, up);
      up = fmaf(fsilu(acc[nf].y + b4.y), w4.y, up);
      up = fmaf(fsilu(acc[nf].z + b4.z), w4.z, up);
      up = fmaf(fsilu(acc[nf].w + b4.w), w4.w, up);
    }
    up += __shfl_xor(up, 16);
    up += __shfl_xor(up, 32);
    u = up + bu2[0];
  }
  // xs = silu(pos@wx1+bx1)@wx2 + bx2
  float xs;
  {
    f32x4 acc[4] = {zero, zero, zero, zero};
    mm4(wtb + (size_t)18 * 4096, er, q, pf, acc);
    float xp = 0.f;
#pragma unroll
    for (int nf = 0; nf < 4; ++nf) {
      const float4 b4 = *(const float4*)(bx1 + nf * 16 + q * 4);
      const float4 w4 = *(const float4*)(wx2 + nf * 16 + q * 4);
      xp = fmaf(fsilu(acc[nf].x + b4.x), w4.x, xp);
      xp = fmaf(fsilu(acc[nf].y + b4.y), w4.y, xp);
      xp = fmaf(fsilu(acc[nf].z + b4.z), w4.z, xp);
      xp = fmaf(fsilu(acc[nf].w + b4.w), w4.w, xp);
    }
    xp += __shfl_xor(xp, 16);
    xp += __shfl_xor(xp, 32);
    xs = xp + bx2[0];
  }

  if (q == 0) {
    const int r = edges[e], c = edges[NE + e];
    float dx = coord[r * 3 + 0] - coord[c * 3 + 0];
    float dy = coord[r * 3 + 1] - coord[c * 3 + 1];
    float dz = coord[r * 3 + 2] - coord[c * 3 + 2];
    float nrm = sqrtf(dx * dx + dy * dy + dz * dz);
    float inv = 1.0f / (nrm + 1e-8f);
    float t = u * xs;
    atomicAdd(&x_sum[r * 3 + 0], dx * inv * t);
    atomicAdd(&x_sum[r * 3 + 1], dy * inv * t);
    atomicAdd(&x_sum[r * 3 + 2], dz * inv * t);
    atomicAdd(&cntf[r], 1.0f);
  }
}

// ---------- MFMA projections -> ksep/vsep (deinterleaved fp8), qho fp8, gf8 fp8 ----------
// K and V in SEPARATE arrays so attention gathers touch fully-used 256B spans.
__global__ void __launch_bounds__(256)
k_projm(const unsigned* __restrict__ zb, const unsigned short* __restrict__ wtb,
        const float* __restrict__ bg,
        unsigned* __restrict__ ksep, unsigned* __restrict__ vsep,
        unsigned* __restrict__ qho, unsigned* __restrict__ gf8) {
  const int lane = threadIdx.x & 63;
  const int wid  = threadIdx.x >> 6;        // wave 0..3
  const int er   = lane & 15;               // edge-in-tile (D col / B col / A row)
  const int q    = lane >> 4;               // k-block (A/B), row-quad (D)
  const int e0   = blockIdx.x * 256 + wid * 64 + er;

  // B frags: z^T, col=e, k=(lane>>4)*8 + i (+32 for half 1)
  bf16x8 zf[4][2];
#pragma unroll
  for (int et = 0; et < 4; ++et) {
    const unsigned* zrow = zb + (size_t)(e0 + et * 16) * 32;   // 64 bf16
    zf[et][0] = __builtin_bit_cast(bf16x8, *(const uint4*)(zrow + q * 4));
    zf[et][1] = __builtin_bit_cast(bf16x8, *(const uint4*)(zrow + 16 + q * 4));
  }

  const f32x4 zero = {0.f, 0.f, 0.f, 0.f};
#pragma unroll 1
  for (int m = 0; m < 16; ++m) {
    const unsigned short* wm = wtb + (size_t)m * 4096;
    f32x4 acc[4][4];
#pragma unroll
    for (int et = 0; et < 4; ++et)
#pragma unroll
      for (int nf = 0; nf < 4; ++nf) acc[et][nf] = zero;
#pragma unroll
    for (int nf = 0; nf < 4; ++nf) {
      const unsigned short* ar = wm + (size_t)(nf * 16 + er) * 64 + q * 8;
      const bf16x8 a0 = *(const bf16x8*)ar;
      const bf16x8 a1 = *(const bf16x8*)(ar + 32);
#pragma unroll
      for (int et = 0; et < 4; ++et) {
        acc[et][nf] = __builtin_amdgcn_mfma_f32_16x16x32_bf16(a0, zf[et][0], acc[et][nf], 0, 0, 0);
        acc[et][nf] = __builtin_amdgcn_mfma_f32_16x16x32_bf16(a1, zf[et][1], acc[et][nf], 0, 0, 0);
      }
    }
    const int hd = m >> 2, which = m & 3;    // wave-uniform
#pragma unroll
    for (int et = 0; et < 4; ++et) {
      const size_t rec = (size_t)(e0 + et * 16) * 4 + hd;
      unsigned* dst = (which == 0) ? (ksep + rec * 16)
                    : (which == 1) ? (vsep + rec * 16)
                    : (which == 2) ? (qho + rec * 16)
                                   : (gf8 + rec * 16);
      if (which == 3) {
#pragma unroll
        for (int nf = 0; nf < 4; ++nf) {
          const float4 b4 = *(const float4*)(bg + hd * 64 + nf * 16 + q * 4);
          dst[nf * 4 + q] = packf8_4(fsig(acc[et][nf].x + b4.x), fsig(acc[et][nf].y + b4.y),
                                     fsig(acc[et][nf].z + b4.z), fsig(acc[et][nf].w + b4.w));
        }
      } else {
#pragma unroll
        for (int nf = 0; nf < 4; ++nf)
          dst[nf * 4 + q] = packf8_4(acc[et][nf].x, acc[et][nf].y,
                                     acc[et][nf].z, acc[et][nf].w);
      }
    }
  }
}

// ---------- attention: flat grid, lane quad = 4 heads of one edge ----------
// K/V deinterleaved: quad gather = 256B fully-used contiguous.
// ho stored BF16 split across qho (k 0..31) + gf8 (k 32..63) records (both dead).
__global__ void __launch_bounds__(256)
k_attn(unsigned* __restrict__ qho, unsigned* __restrict__ gf8,
       const unsigned* __restrict__ ksep, const unsigned* __restrict__ vsep,
       const float* __restrict__ be, const int* __restrict__ klist) {
  const int t = blockIdx.x * 256 + threadIdx.x;
  const int e = t >> 2, hd = t & 3;

  // q (fp8 -> fp32, unscaled)
  float q[64];
  {
    unsigned qp[16];
    ldrow16(qho + (size_t)t * 16, qp);
    unpackf8(qp, q);
  }

  int i2[8], j2[8];
#pragma unroll
  for (int kn = 0; kn < 8; ++kn) {
    i2[kn] = klist[(size_t)e * 16 + kn];
    j2[kn] = klist[(size_t)e * 16 + 8 + kn];
  }
  float bv[8];
#pragma unroll
  for (int kn = 0; kn < 8; ++kn)
    bv[kn] = be[(size_t)((i2[kn] < 0) ? 0 : j2[kn]) * 4 + hd];

  const uint4* k4 = (const uint4*)ksep;   // 4 uint4 per record
  float alpha[8];
#pragma unroll 2
  for (int kn = 0; kn < 8; ++kn) {
    if (i2[kn] < 0) { alpha[kn] = -10000.0f; continue; }
    const uint4* kr = k4 + ((size_t)i2[kn] * 4 + hd) * 4;
    uint4 u0 = kr[0], u1 = kr[1], u2 = kr[2], u3 = kr[3];
    float d = 0.f;
    d = dot16(u0, q,      d);
    d = dot16(u1, q + 16, d);
    d = dot16(u2, q + 32, d);
    d = dot16(u3, q + 48, d);
    alpha[kn] = d * 0.125f + bv[kn];
  }
  float mx = alpha[0];
#pragma unroll
  for (int kn = 1; kn < 8; ++kn) mx = fmaxf(mx, alpha[kn]);
  float p[8], s = 0.f;
#pragma unroll
  for (int kn = 0; kn < 8; ++kn) { p[kn] = __expf(alpha[kn] - mx); s += p[kn]; }
  float is = 1.0f / s;
#pragma unroll
  for (int kn = 0; kn < 8; ++kn) p[kn] *= is;

  float ov[64];
#pragma unroll
  for (int j = 0; j < 64; ++j) ov[j] = 0.f;
  const uint4* v4 = (const uint4*)vsep;
#pragma unroll 2
  for (int kn = 0; kn < 8; ++kn) {
    int vi = (i2[kn] < 0) ? (NE - 1) : i2[kn];   // jax v[-1] wraps
    const uint4* vr = v4 + ((size_t)vi * 4 + hd) * 4;
    uint4 u0 = vr[0], u1 = vr[1], u2 = vr[2], u3 = vr[3];
    const float pk = p[kn];
    acc16(u0, pk, ov +  0);
    acc16(u1, pk, ov + 16);
    acc16(u2, pk, ov + 32);
    acc16(u3, pk, ov + 48);
  }
  // gate (precomputed sigmoid, fp8)
  {
    unsigned gp[16];
    ldrow16(gf8 + (size_t)t * 16, gp);
    float g[64];
    unpackf8(gp, g);
#pragma unroll
    for (int j = 0; j < 64; ++j) ov[j] *= g[j];
  }
  // ho bf16: low 32 vals -> qho rec, high 32 -> gf8 rec (thread-private slots)
  {
    unsigned* qr = qho + (size_t)t * 16;
    unsigned* gr = gf8 + (size_t)t * 16;
#pragma unroll
    for (int t2 = 0; t2 < 2; ++t2) {
      ((uint4*)qr)[t2] = make_uint4(pack2(ov[8*t2+0],  ov[8*t2+1]),  pack2(ov[8*t2+2],  ov[8*t2+3]),
                                    pack2(ov[8*t2+4],  ov[8*t2+5]),  pack2(ov[8*t2+6],  ov[8*t2+7]));
      ((uint4*)qr)[2+t2] = make_uint4(pack2(ov[16+8*t2+0], ov[16+8*t2+1]), pack2(ov[16+8*t2+2], ov[16+8*t2+3]),
                                      pack2(ov[16+8*t2+4], ov[16+8*t2+5]), pack2(ov[16+8*t2+6], ov[16+8*t2+7]));
      ((uint4*)gr)[t2] = make_uint4(pack2(ov[32+8*t2+0], ov[32+8*t2+1]), pack2(ov[32+8*t2+2], ov[32+8*t2+3]),
                                    pack2(ov[32+8*t2+4], ov[32+8*t2+5]), pack2(ov[32+8*t2+6], ov[32+8*t2+7]));
      ((uint4*)gr)[2+t2] = make_uint4(pack2(ov[48+8*t2+0], ov[48+8*t2+1]), pack2(ov[48+8*t2+2], ov[48+8*t2+3]),
                                      pack2(ov[48+8*t2+4], ov[48+8*t2+5]), pack2(ov[48+8*t2+6], ov[48+8*t2+7]));
    }
  }
}

// ---------- output projection via MFMA: m[e] = sum_hd ho_hd @ Wout_hd ----------
// ho bf16 from qho(k 0..31)+gf8(k 32..63); Wout^T bf16 at wtb[19+hd]. C chained over heads.
__global__ void __launch_bounds__(256)
k_mout(const unsigned* __restrict__ qho, const unsigned* __restrict__ gf8,
       const unsigned short* __restrict__ wtb, float* __restrict__ medge) {
  const int lane = threadIdx.x & 63;
  const int wid  = threadIdx.x >> 6;
  const int er   = lane & 15;
  const int q    = lane >> 4;
  const int e0   = blockIdx.x * 256 + wid * 64 + er;

  const f32x4 zero = {0.f, 0.f, 0.f, 0.f};
  f32x4 acc[4][4];
#pragma unroll
  for (int et = 0; et < 4; ++et)
#pragma unroll
    for (int nf = 0; nf < 4; ++nf) acc[et][nf] = zero;

#pragma unroll 1
  for (int hd = 0; hd < 4; ++hd) {
    const unsigned short* wm = wtb + (size_t)(19 + hd) * 4096;
    bf16x8 hf[4][2];
#pragma unroll
    for (int et = 0; et < 4; ++et) {
      const size_t rec = (size_t)(e0 + et * 16) * 4 + hd;
      hf[et][0] = __builtin_bit_cast(bf16x8, *(const uint4*)(qho + rec * 16 + q * 4));
      hf[et][1] = __builtin_bit_cast(bf16x8, *(const uint4*)(gf8 + rec * 16 + q * 4));
    }
#pragma unroll
    for (int nf = 0; nf < 4; ++nf) {
      const unsigned short* ar = wm + (size_t)(nf * 16 + er) * 64 + q * 8;
      const bf16x8 a0 = *(const bf16x8*)ar;
      const bf16x8 a1 = *(const bf16x8*)(ar + 32);
#pragma unroll
      for (int et = 0; et < 4; ++et) {
        acc[et][nf] = __builtin_amdgcn_mfma_f32_16x16x32_bf16(a0, hf[et][0], acc[et][nf], 0, 0, 0);
        acc[et][nf] = __builtin_amdgcn_mfma_f32_16x16x32_bf16(a1, hf[et][1], acc[et][nf], 0, 0, 0);
      }
    }
  }
#pragma unroll
  for (int et = 0; et < 4; ++et)
#pragma unroll
    for (int nf = 0; nf < 4; ++nf)
      *(float4*)(medge + (size_t)(e0 + et * 16) * 64 + nf * 16 + q * 4) =
          make_float4(acc[et][nf].x, acc[et][nf].y, acc[et][nf].z, acc[et][nf].w);
}

// ---------- CSR gather: per-node segment sum of medge ----------
__global__ void __launch_bounds__(256)
k_nodesum(const float* __restrict__ medge, const int* __restrict__ ioffs,
          const int* __restrict__ eidx, float* __restrict__ m_sum) {
  const int wid = threadIdx.x >> 6, lane = threadIdx.x & 63;
  const int n = blockIdx.x * 4 + wid;
  if (n >= NN) return;
  const int beg = ioffs[n], end = ioffs[n + 1];
  float acc = 0.f;
  for (int i = beg; i < end; ++i) {
    int e = eidx[i];
    acc += medge[(size_t)e * 64 + lane];
  }
  m_sum[(size_t)n * 64 + lane] = acc;
}

// ---------- final node update via MFMA: wave = 16 nodes ----------
// concat(h,na,m_agg)@wh1 -> silu -> LDS re-layout -> @wh2 + bh2 + h (residual fp32)
__global__ void __launch_bounds__(256)
k_finm(const float* __restrict__ h, const float* __restrict__ na,
       const float* __restrict__ coord, const float* __restrict__ icoord,
       const float* __restrict__ m_sum, const float* __restrict__ x_sum,
       const float* __restrict__ cntf, const float* __restrict__ bout,
       const unsigned short* __restrict__ wtb,
       const float* __restrict__ bh1, const float* __restrict__ bh2,
       float* __restrict__ out) {
  __shared__ float lt[4][16][68];   // +4 pad breaks er*64 bank alias
  const int lane = threadIdx.x & 63;
  const int wid  = threadIdx.x >> 6;
  const int er   = lane & 15;
  const int q    = lane >> 4;
  const int e    = blockIdx.x * 64 + wid * 16 + er;
  const bool valid = e < NN;
  const int el = valid ? e : 0;

  const float* hr = h + (size_t)el * 64;
  const float* nr = na + (size_t)el * 64;
  const float* mr = m_sum + (size_t)el * 64;
  const float cn = cntf[el];
  const float invc = 1.0f / fmaxf(cn, 1.0f);
  const float bsc = (cn > 0.f) ? 1.0f : 0.0f;   // empty segment => m_agg = 0

  // B-frags: h, na, m_agg k-slices (bf16)
  bf16x8 hf[2], naf[2], mf[2];
  hf[0]  = packrow8(hr + q * 8); hf[1]  = packrow8(hr + 32 + q * 8);
  naf[0] = packrow8(nr + q * 8); naf[1] = packrow8(nr + 32 + q * 8);
#pragma unroll
  for (int half = 0; half < 2; ++half) {
    const int o = half * 32 + q * 8;
    const float4 m0 = *(const float4*)(mr + o);
    const float4 m1 = *(const float4*)(mr + o + 4);
    const float4 b0 = *(const float4*)(bout + o);
    const float4 b1 = *(const float4*)(bout + o + 4);
    float ma[8];
    ma[0] = fmaf(m0.x, invc, b0.x * bsc); ma[1] = fmaf(m0.y, invc, b0.y * bsc);
    ma[2] = fmaf(m0.z, invc, b0.z * bsc); ma[3] = fmaf(m0.w, invc, b0.w * bsc);
    ma[4] = fmaf(m1.x, invc, b1.x * bsc); ma[5] = fmaf(m1.y, invc, b1.y * bsc);
    ma[6] = fmaf(m1.z, invc, b1.z * bsc); ma[7] = fmaf(m1.w, invc, b1.w * bsc);
    uint4 u = make_uint4(pack2(ma[0], ma[1]), pack2(ma[2], ma[3]),
                         pack2(ma[4], ma[5]), pack2(ma[6], ma[7]));
    mf[half] = __builtin_bit_cast(bf16x8, u);
  }

  const f32x4 zero = {0.f, 0.f, 0.f, 0.f};
  f32x4 acc[4] = {zero, zero, zero, zero};
  mm4(wtb + (size_t)23 * 4096, er, q, hf,  acc);
  mm4(wtb + (size_t)24 * 4096, er, q, naf, acc);
  mm4(wtb + (size_t)25 * 4096, er, q, mf,  acc);
#pragma unroll
  for (int nf = 0; nf < 4; ++nf) {
    const float4 b4 = *(const float4*)(bh1 + nf * 16 + q * 4);
    float* d = &lt[wid][er][nf * 16 + q * 4];
    d[0] = fsilu(acc[nf].x + b4.x); d[1] = fsilu(acc[nf].y + b4.y);
    d[2] = fsilu(acc[nf].z + b4.z); d[3] = fsilu(acc[nf].w + b4.w);
  }
  __syncthreads();
  bf16x8 sf[2];
  sf[0] = packrow8(&lt[wid][er][q * 8]);
  sf[1] = packrow8(&lt[wid][er][32 + q * 8]);
  f32x4 a2[4] = {zero, zero, zero, zero};
  mm4(wtb + (size_t)26 * 4096, er, q, sf, a2);
  if (valid) {
#pragma unroll
    for (int nf = 0; nf < 4; ++nf) {
      const float4 b4 = *(const float4*)(bh2 + nf * 16 + q * 4);
      const float4 h4 = *(const float4*)(hr + nf * 16 + q * 4);
      *(float4*)(out + (size_t)e * 64 + nf * 16 + q * 4) =
          make_float4(a2[nf].x + b4.x + h4.x, a2[nf].y + b4.y + h4.y,
                      a2[nf].z + b4.z + h4.z, a2[nf].w + b4.w + h4.w);
    }
    if (q == 0) {
#pragma unroll
      for (int d = 0; d < 3; ++d)
        out[(size_t)NN * 64 + e * 3 + d] =
            0.2f * icoord[e * 3 + d] + 0.8f * coord[e * 3 + d] + x_sum[e * 3 + d] * invc;
    }
  }
}

extern "C" void kernel_launch(void* const* d_in, const int* in_sizes, int n_in,
                              void* d_out, int out_size, void* d_ws, size_t ws_size,
                              hipStream_t stream) {
  (void)in_sizes; (void)n_in; (void)out_size; (void)ws_size;
  const float* h      = (const float*)d_in[0];
  const float* coord  = (const float*)d_in[1];
  const int*   edges  = (const int*)  d_in[2];
  const float* nvecs  = (const float*)d_in[3];
  const float* ea     = (const float*)d_in[4];
  const float* na     = (const float*)d_in[5];
  const float* icoord = (const float*)d_in[6];
  const int*   klist  = (const int*)  d_in[7];
  const float* w_chem1 = (const float*)d_in[8];
  const float* b_chem1 = (const float*)d_in[9];
  const float* w_chem2 = (const float*)d_in[10];
  const float* b_chem2 = (const float*)d_in[11];
  const float* w_pos1  = (const float*)d_in[12];
  const float* b_pos1  = (const float*)d_in[13];
  const float* w_pos2  = (const float*)d_in[14];
  const float* b_pos2  = (const float*)d_in[15];
  const float* w_sh    = (const float*)d_in[16];
  const float* b_sh    = (const float*)d_in[17];
  const float* w_att   = (const float*)d_in[18];
  const float* b_att   = (const float*)d_in[19];
  const float* wq      = (const float*)d_in[20];
  const float* wk      = (const float*)d_in[21];
  const float* wv      = (const float*)d_in[22];
  const float* wb      = (const float*)d_in[23];
  const float* wg      = (const float*)d_in[24];
  const float* bg      = (const float*)d_in[25];
  const float* w_out   = (const float*)d_in[26];
  const float* b_out   = (const float*)d_in[27];
  const float* wu1     = (const float*)d_in[28];
  const float* bu1     = (const float*)d_in[29];
  const float* wu2     = (const float*)d_in[30];
  const float* bu2     = (const float*)d_in[31];
  const float* wx1     = (const float*)d_in[32];
  const float* bx1     = (const float*)d_in[33];
  const float* wx2     = (const float*)d_in[34];
  const float* bx2     = (const float*)d_in[35];
  const float* wh1     = (const float*)d_in[36];
  const float* bh1     = (const float*)d_in[37];
  const float* wh2     = (const float*)d_in[38];
  const float* bh2     = (const float*)d_in[39];

  float* out = (float*)d_out;
  float* ws  = (float*)d_ws;
  // Phase-reused regions (NE*64 floats each):
  //  R1: act1c -> ksep [NE*4][64B] fp8 K -> medge after attn
  //  R2: act1p -> vsep [NE*4][64B] fp8 V
  //  R3: chem  -> qho  [NE*4][16u] fp8 q -> ho bf16 low-half after attn
  //  R4: pos   -> gf8  [NE*4][16u] fp8 gate -> ho bf16 high-half after attn
  float* R1 = ws;
  float* R2 = R1 + (size_t)NE * 64;
  float* R3 = R2 + (size_t)NE * 64;
  float* R4 = R3 + (size_t)NE * 64;
  float* zbf   = R4 + (size_t)NE * 64;      // NE*32 floats (bf16 gated z)
  float* x_sum = zbf + (size_t)NE * 32;     // NN*3 (zeroed)
  float* cntf  = x_sum + (size_t)NN * 3;    // NN (zeroed)
  int*   icnt  = (int*)(cntf + NN);         // NN (zeroed)
  int*   icur  = icnt + NN;                 // NN (zeroed)
  float* m_sum = (float*)(icur + NN);       // NN*64
  float* be    = m_sum + (size_t)NN * 64;   // 4*NE  ([e*4+hd] layout)
  unsigned short* wtb = (unsigned short*)(be + (size_t)4 * NE);  // 27*64*64 bf16 (216KB)
  int*   ioffs = (int*)(wtb + 27 * 4096);   // NN+1
  int*   eidx  = ioffs + (NN + 1);          // NE

  unsigned* ksep = (unsigned*)R1;  // [NE*4][16u] fp8 K (deinterleaved)
  unsigned* vsep = (unsigned*)R2;  // [NE*4][16u] fp8 V
  unsigned* qho  = (unsigned*)R3;  // [NE*4][16u] fp8 q -> bf16 ho lo
  unsigned* gf8  = (unsigned*)R4;  // [NE*4][16u] fp8 gate -> bf16 ho hi
  unsigned* zb   = (unsigned*)zbf;
  float* medge = R1;               // after attention (ksep dead)

  (void)hipMemsetAsync(x_sum, 0, ((size_t)NN * 3 + NN + NN + NN) * sizeof(float), stream);

  dim3 b128(128), b256(256);
  dim3 gs2(NE / 256, 2);
  dim3 gflat(NE / 256);

  // weight prep + CSR build (independent of the MLP pipeline)
  k_wprep<<<dim3(27), b256, 0, stream>>>(wk, wv, wq, wg, w_sh, wu1, wx1, w_out,
                                         wh1, wh2, wtb);
  k_count<<<gflat, b256, 0, stream>>>(edges, icnt);
  k_scan <<<dim3(1), b256, 0, stream>>>(icnt, ioffs);
  k_fill <<<gflat, b256, 0, stream>>>(edges, ioffs, icur, eidx);

  k_chem1<<<gs2, b128, 0, stream>>>(h, na, ea, edges, w_chem1, b_chem1, R1);
  k_pos1 <<<gs2, b256, 0, stream>>>(coord, nvecs, ea, edges, w_pos1, b_pos1, R2);
  k_l2   <<<gs2, b128, 0, stream>>>(R1, R2, w_chem2, b_chem2, w_pos2, b_pos2, R3, R4);
  k_scal_m<<<dim3(NE / 64), b256, 0, stream>>>(coord, edges, R3, R4, wtb,
                                               b_sh, w_att, b_att,
                                               bu1, wu2, bu2, bx1, wx2, bx2, wb,
                                               zb, be, x_sum, cntf);
  k_projm<<<dim3(NE / 256), b256, 0, stream>>>(zb, wtb, bg, ksep, vsep, qho, gf8);
  k_attn <<<dim3(NE * 4 / 256), b256, 0, stream>>>(qho, gf8, ksep, vsep, be, klist);
  k_mout <<<dim3(NE / 256), b256, 0, stream>>>(qho, gf8, wtb, medge);
  k_nodesum<<<dim3((NN + 3) / 4), b256, 0, stream>>>(medge, ioffs, eidx, m_sum);
  k_finm<<<dim3((NN + 63) / 64), b256, 0, stream>>>(h, na, coord, icoord, m_sum, x_sum,
                                                    cntf, b_out, wtb, bh1, bh2, out);
}

// Round 7
// 666.445 us; speedup vs baseline: 2.1733x; 1.3455x over previous
//
#include <hip/hip_runtime.h>
#include <math.h>

#define NE 160000
#define NN 10000

#define DEV __device__ __forceinline__

typedef float v2f __attribute__((ext_vector_type(2)));
typedef __attribute__((ext_vector_type(8))) short bf16x8;   // 8 bf16 (4 VGPRs)
typedef __attribute__((ext_vector_type(4))) float f32x4;

DEV float fsilu(float x) { return x / (1.0f + __expf(-x)); }
DEV float fsig(float x)  { return 1.0f / (1.0f + __expf(-x)); }

// ---- bf16 pack/unpack helpers (RNE) ----
DEV unsigned pack2(float a, float b) {
  unsigned ua = __float_as_uint(a); ua += 0x7FFFu + ((ua >> 16) & 1u);
  unsigned ub = __float_as_uint(b); ub += 0x7FFFu + ((ub >> 16) & 1u);
  return (ua >> 16) | (ub & 0xFFFF0000u);
}

// ---- fp8 e4m3 (OCP, HW-converted) ----
DEV unsigned packf8_4(float a, float b, float c, float d) {
  int r = __builtin_amdgcn_cvt_pk_fp8_f32(a, b, 0, false);
  r = __builtin_amdgcn_cvt_pk_fp8_f32(c, d, r, true);
  return (unsigned)r;
}
template<bool HI>
DEV v2f up2(unsigned u) { return __builtin_amdgcn_cvt_pk_f32_fp8((int)u, HI); }

// dot of 16 fp8 values (one uint4) against q[0..16)
DEV float dot16(uint4 u, const float* q, float d) {
  v2f f;
  f = up2<false>(u.x); d = fmaf(f.x, q[0],  d); d = fmaf(f.y, q[1],  d);
  f = up2<true >(u.x); d = fmaf(f.x, q[2],  d); d = fmaf(f.y, q[3],  d);
  f = up2<false>(u.y); d = fmaf(f.x, q[4],  d); d = fmaf(f.y, q[5],  d);
  f = up2<true >(u.y); d = fmaf(f.x, q[6],  d); d = fmaf(f.y, q[7],  d);
  f = up2<false>(u.z); d = fmaf(f.x, q[8],  d); d = fmaf(f.y, q[9],  d);
  f = up2<true >(u.z); d = fmaf(f.x, q[10], d); d = fmaf(f.y, q[11], d);
  f = up2<false>(u.w); d = fmaf(f.x, q[12], d); d = fmaf(f.y, q[13], d);
  f = up2<true >(u.w); d = fmaf(f.x, q[14], d); d = fmaf(f.y, q[15], d);
  return d;
}
// o[0..16) += pk * fp8x16(u)
DEV void acc16(uint4 u, float pk, float* o) {
  v2f f;
  f = up2<false>(u.x); o[0]  = fmaf(pk, f.x, o[0]);  o[1]  = fmaf(pk, f.y, o[1]);
  f = up2<true >(u.x); o[2]  = fmaf(pk, f.x, o[2]);  o[3]  = fmaf(pk, f.y, o[3]);
  f = up2<false>(u.y); o[4]  = fmaf(pk, f.x, o[4]);  o[5]  = fmaf(pk, f.y, o[5]);
  f = up2<true >(u.y); o[6]  = fmaf(pk, f.x, o[6]);  o[7]  = fmaf(pk, f.y, o[7]);
  f = up2<false>(u.z); o[8]  = fmaf(pk, f.x, o[8]);  o[9]  = fmaf(pk, f.y, o[9]);
  f = up2<true >(u.z); o[10] = fmaf(pk, f.x, o[10]); o[11] = fmaf(pk, f.y, o[11]);
  f = up2<false>(u.w); o[12] = fmaf(pk, f.x, o[12]); o[13] = fmaf(pk, f.y, o[13]);
  f = up2<true >(u.w); o[14] = fmaf(pk, f.x, o[14]); o[15] = fmaf(pk, f.y, o[15]);
}

DEV void ldrow16(const unsigned* __restrict__ p, unsigned (&r)[16]) {
#pragma unroll
  for (int t = 0; t < 4; ++t) {
    uint4 u = ((const uint4*)p)[t];
    r[4*t] = u.x; r[4*t+1] = u.y; r[4*t+2] = u.z; r[4*t+3] = u.w;
  }
}
DEV void unpackf8(const unsigned (&p)[16], float (&o)[64]) {
#pragma unroll
  for (int t = 0; t < 16; ++t) {
    v2f f0 = up2<false>(p[t]);
    v2f f1 = up2<true >(p[t]);
    o[4*t+0] = f0.x; o[4*t+1] = f0.y; o[4*t+2] = f1.x; o[4*t+3] = f1.y;
  }
}
DEV void store32(float* dst, const float (&a)[32]) {
#pragma unroll
  for (int j = 0; j < 32; j += 4)
    *(float4*)(dst + j) = make_float4(a[j], a[j+1], a[j+2], a[j+3]);
}

// pack 8 consecutive fp32 -> bf16x8 (B-fragment k-slice)
DEV bf16x8 packrow8(const float* __restrict__ p) {
  float4 a = *(const float4*)p;
  float4 b = *(const float4*)(p + 4);
  uint4 u = make_uint4(pack2(a.x, a.y), pack2(a.z, a.w),
                       pack2(b.x, b.y), pack2(b.z, b.w));
  return __builtin_bit_cast(bf16x8, u);
}

// 16x16x32 GEMM over K=64: acc[nf] (n = nf*16 + q*4 + reg), A from wtb matrix wm
DEV void mm4(const unsigned short* __restrict__ wm, int er, int q,
             const bf16x8 (&bfr)[2], f32x4 (&acc)[4]) {
#pragma unroll
  for (int nf = 0; nf < 4; ++nf) {
    const unsigned short* ar = wm + (size_t)(nf * 16 + er) * 64 + q * 8;
    const bf16x8 a0 = *(const bf16x8*)ar;
    const bf16x8 a1 = *(const bf16x8*)(ar + 32);
    acc[nf] = __builtin_amdgcn_mfma_f32_16x16x32_bf16(a0, bfr[0], acc[nf], 0, 0, 0);
    acc[nf] = __builtin_amdgcn_mfma_f32_16x16x32_bf16(a1, bfr[1], acc[nf], 0, 0, 0);
  }
}

// ---------- CSR build over edges[0] (rows) ----------
__global__ void __launch_bounds__(256)
k_count(const int* __restrict__ edges, int* __restrict__ icnt) {
  int e = blockIdx.x * 256 + threadIdx.x;
  if (e < NE) atomicAdd(&icnt[edges[e]], 1);
}

__global__ void __launch_bounds__(256)
k_scan(const int* __restrict__ icnt, int* __restrict__ ioffs) {
  __shared__ int part[256];
  const int t = threadIdx.x;
  const int base = t * 40;
  int loc[40];
  int s = 0;
#pragma unroll
  for (int i = 0; i < 40; ++i) {
    int idx = base + i;
    int v = (idx < NN) ? icnt[idx] : 0;
    loc[i] = v; s += v;
  }
  part[t] = s;
  __syncthreads();
  for (int off = 1; off < 256; off <<= 1) {
    int v = (t >= off) ? part[t - off] : 0;
    __syncthreads();
    part[t] += v;
    __syncthreads();
  }
  int run = (t == 0) ? 0 : part[t - 1];
#pragma unroll
  for (int i = 0; i < 40; ++i) {
    int idx = base + i;
    if (idx < NN) { ioffs[idx] = run; run += loc[i]; }
  }
  if (t == 255) ioffs[NN] = NE;
}

__global__ void __launch_bounds__(256)
k_fill(const int* __restrict__ edges, const int* __restrict__ ioffs,
       int* __restrict__ icur, int* __restrict__ eidx) {
  int e = blockIdx.x * 256 + threadIdx.x;
  if (e >= NE) return;
  int r = edges[e];
  int p = atomicAdd(&icur[r], 1);
  eidx[ioffs[r] + p] = e;
}

// ---------- chem layer 1 via MFMA: 272 -> 64 silu; wave = 16 edges ----------
// 4 full K=64 slices (h[r],h[c],na[r],na[c]) + zero-padded K=16 edge-attr slice.
__global__ void __launch_bounds__(256)
k_chem1m(const float* __restrict__ h, const float* __restrict__ na,
         const float* __restrict__ ea, const int* __restrict__ edges,
         const unsigned short* __restrict__ wtb, const float* __restrict__ b1,
         float* __restrict__ act1c) {
  const int lane = threadIdx.x & 63;
  const int wid  = threadIdx.x >> 6;
  const int er   = lane & 15;
  const int q    = lane >> 4;
  const int e    = blockIdx.x * 64 + wid * 16 + er;
  const int r = edges[e], c = edges[NE + e];

  const f32x4 zero = {0.f, 0.f, 0.f, 0.f};
  f32x4 acc[4] = {zero, zero, zero, zero};
  bf16x8 f[2];
  const float* xr;
  xr = h  + (size_t)r * 64; f[0] = packrow8(xr + q * 8); f[1] = packrow8(xr + 32 + q * 8);
  mm4(wtb + (size_t)29 * 4096, er, q, f, acc);
  xr = h  + (size_t)c * 64; f[0] = packrow8(xr + q * 8); f[1] = packrow8(xr + 32 + q * 8);
  mm4(wtb + (size_t)30 * 4096, er, q, f, acc);
  xr = na + (size_t)r * 64; f[0] = packrow8(xr + q * 8); f[1] = packrow8(xr + 32 + q * 8);
  mm4(wtb + (size_t)31 * 4096, er, q, f, acc);
  xr = na + (size_t)c * 64; f[0] = packrow8(xr + q * 8); f[1] = packrow8(xr + 32 + q * 8);
  mm4(wtb + (size_t)32 * 4096, er, q, f, acc);
  // edge-attr slice: real B for k<16 (q=0,1), zero B elsewhere; half-2 skipped.
  {
    bf16x8 ef;
    if (q < 2) ef = packrow8(ea + (size_t)e * 16 + q * 8);
    else { uint4 z4 = make_uint4(0, 0, 0, 0); ef = __builtin_bit_cast(bf16x8, z4); }
    const unsigned short* wm = wtb + (size_t)33 * 4096;
#pragma unroll
    for (int nf = 0; nf < 4; ++nf) {
      const bf16x8 a0 = *(const bf16x8*)(wm + (size_t)(nf * 16 + er) * 64 + q * 8);
      acc[nf] = __builtin_amdgcn_mfma_f32_16x16x32_bf16(a0, ef, acc[nf], 0, 0, 0);
    }
  }
#pragma unroll
  for (int nf = 0; nf < 4; ++nf) {
    const float4 b4 = *(const float4*)(b1 + nf * 16 + q * 4);
    *(float4*)(act1c + (size_t)e * 64 + nf * 16 + q * 4) =
        make_float4(fsilu(acc[nf].x + b4.x), fsilu(acc[nf].y + b4.y),
                    fsilu(acc[nf].z + b4.z), fsilu(acc[nf].w + b4.w));
  }
}

// ---------- pos layer 1: 36 -> 64 silu ----------
__global__ void __launch_bounds__(256)
k_pos1(const float* __restrict__ coord, const float* __restrict__ nv,
       const float* __restrict__ ea, const int* __restrict__ edges,
       const float* __restrict__ w1, const float* __restrict__ b1,
       float* __restrict__ act1p) {
  const int e = blockIdx.x * 256 + threadIdx.x;
  const int co = blockIdx.y * 32;
  const int r = edges[e], c = edges[NE + e];

  float dx = coord[r * 3 + 0] - coord[c * 3 + 0];
  float dy = coord[r * 3 + 1] - coord[c * 3 + 1];
  float dz = coord[r * 3 + 2] - coord[c * 3 + 2];
  float nrm = sqrtf(dx * dx + dy * dy + dz * dz);
  float inv = 1.0f / (nrm + 1e-8f);
  dx *= inv; dy *= inv; dz *= inv;
  float ir = dx * dx + dy * dy + dz * dz;

  float in[36];
#pragma unroll
  for (int v = 0; v < 5; ++v) {
    float s = 0.f;
#pragma unroll
    for (int d = 0; d < 3; ++d)
      s += nv[(size_t)r * 15 + v * 3 + d] * nv[(size_t)c * 15 + v * 3 + d];
    in[v] = s;
  }
  {
    float cexp = -0.5f;
#pragma unroll
    for (int k = 0; k < 15; ++k) { in[5 + k] = __expf(ir * cexp); cexp *= (1.0f / 2.25f); }
  }
#pragma unroll
  for (int k = 0; k < 16; k += 4) {
    float4 e4 = *(const float4*)(ea + (size_t)e * 16 + k);
    in[20 + k] = e4.x; in[21 + k] = e4.y; in[22 + k] = e4.z; in[23 + k] = e4.w;
  }

  float acc[32];
#pragma unroll
  for (int j = 0; j < 32; ++j) acc[j] = b1[co + j];
#pragma unroll
  for (int k = 0; k < 36; ++k) {
    const float x = in[k];
    const float* wr = w1 + (size_t)k * 64 + co;
#pragma unroll
    for (int j = 0; j < 32; ++j) acc[j] = fmaf(x, wr[j], acc[j]);
  }
#pragma unroll
  for (int j = 0; j < 32; ++j) acc[j] = fsilu(acc[j]);
  store32(act1p + (size_t)e * 64 + co, acc);
}

// ---------- weight prep: wtb[m][n][k] = W_m[k][n] in bf16 (A-operand layout) ----------
// 0..15: hd*4+which (k,v,q,g); 16..18: wsh,wu1,wx1; 19..22: w_out/hd; 23..25: wh1 slices;
// 26: wh2; 27: w_chem2; 28: w_pos2; 29..32: w_chem1 K-slices; 33: w_chem1 ea-slice (pad16)
__global__ void __launch_bounds__(256)
k_wprep(const float* __restrict__ wk, const float* __restrict__ wv,
        const float* __restrict__ wq, const float* __restrict__ wg,
        const float* __restrict__ wsh, const float* __restrict__ wu1,
        const float* __restrict__ wx1, const float* __restrict__ wout,
        const float* __restrict__ wh1, const float* __restrict__ wh2,
        const float* __restrict__ w2c, const float* __restrict__ w2p,
        const float* __restrict__ wc1,
        unsigned short* __restrict__ wtb) {
  const int m = blockIdx.x;          // 0..33
  const float* src;
  bool pad16 = false;
  if (m < 16) {
    const int hd = m >> 2, which = m & 3;
    src = ((which == 0) ? wk : (which == 1) ? wv : (which == 2) ? wq : wg)
          + (size_t)hd * 4096;
  } else if (m < 19) {
    src = (m == 16) ? wsh : (m == 17) ? wu1 : wx1;
  } else if (m < 23) {
    src = wout + (size_t)(m - 19) * 4096;
  } else if (m < 26) {
    src = wh1 + (size_t)(m - 23) * 4096;
  } else if (m == 26) {
    src = wh2;
  } else if (m == 27) {
    src = w2c;
  } else if (m == 28) {
    src = w2p;
  } else if (m < 33) {
    src = wc1 + (size_t)(m - 29) * 4096;
  } else {
    src = wc1 + (size_t)4 * 4096;   // rows 256..271
    pad16 = true;
  }
  const int t = threadIdx.x;
#pragma unroll
  for (int i = 0; i < 16; ++i) {
    int idx = t * 16 + i;
    int n = idx >> 6, kk = idx & 63;
    float v = (pad16 && kk >= 16) ? 0.f : src[kk * 64 + n];
    unsigned u = __float_as_uint(v);
    u += 0x7FFFu + ((u >> 16) & 1u);
    wtb[(size_t)m * 4096 + idx] = (unsigned short)(u >> 16);
  }
}

// ---------- fused layer-2 + scalars (MFMA): act1c/act1p -> zb/be/u/x ----------
// Wave = 16 edges. Layer-2 D-frags re-laid to k-slices via per-wave LDS tiles
// (same-wave ds ordering -> no barrier). posD is already in z's elementwise layout.
__global__ void __launch_bounds__(256)
k_l2s(const float* __restrict__ coord, const int* __restrict__ edges,
      const float* __restrict__ act1c, const float* __restrict__ act1p,
      const unsigned short* __restrict__ wtb,
      const float* __restrict__ b2c, const float* __restrict__ b2p,
      const float* __restrict__ bsh,
      const float* __restrict__ watt, const float* __restrict__ batt,
      const float* __restrict__ bu1, const float* __restrict__ wu2,
      const float* __restrict__ bu2,
      const float* __restrict__ bx1, const float* __restrict__ wx2,
      const float* __restrict__ bx2,
      const float* __restrict__ wb,
      unsigned* __restrict__ zb, float* __restrict__ be,
      float* __restrict__ x_sum, float* __restrict__ cntf) {
  __shared__ float ltc[4][16][68];   // +4 pad breaks er*64 bank alias
  __shared__ float ltp[4][16][68];
  const int lane = threadIdx.x & 63;
  const int wid  = threadIdx.x >> 6;
  const int er   = lane & 15;
  const int q    = lane >> 4;
  const int e    = blockIdx.x * 64 + wid * 16 + er;

  const f32x4 zero = {0.f, 0.f, 0.f, 0.f};
  bf16x8 f[2];

  // layer-2 chem: chemD = silu(act1c @ w2c + b2c)
  {
    const float* xr = act1c + (size_t)e * 64;
    f[0] = packrow8(xr + q * 8); f[1] = packrow8(xr + 32 + q * 8);
  }
  f32x4 cD[4] = {zero, zero, zero, zero};
  mm4(wtb + (size_t)27 * 4096, er, q, f, cD);
#pragma unroll
  for (int nf = 0; nf < 4; ++nf) {
    const float4 bc = *(const float4*)(b2c + nf * 16 + q * 4);
    *(float4*)&ltc[wid][er][nf * 16 + q * 4] =
        make_float4(fsilu(cD[nf].x + bc.x), fsilu(cD[nf].y + bc.y),
                    fsilu(cD[nf].z + bc.z), fsilu(cD[nf].w + bc.w));
  }
  // layer-2 pos: posD = silu(act1p @ w2p + b2p)  (kept in regs: z's elementwise layout)
  {
    const float* xr = act1p + (size_t)e * 64;
    f[0] = packrow8(xr + q * 8); f[1] = packrow8(xr + 32 + q * 8);
  }
  f32x4 pD[4] = {zero, zero, zero, zero};
  mm4(wtb + (size_t)28 * 4096, er, q, f, pD);
  float pv[16];
#pragma unroll
  for (int nf = 0; nf < 4; ++nf) {
    const float4 bp = *(const float4*)(b2p + nf * 16 + q * 4);
    pv[4*nf+0] = fsilu(pD[nf].x + bp.x); pv[4*nf+1] = fsilu(pD[nf].y + bp.y);
    pv[4*nf+2] = fsilu(pD[nf].z + bp.z); pv[4*nf+3] = fsilu(pD[nf].w + bp.w);
    *(float4*)&ltp[wid][er][nf * 16 + q * 4] =
        make_float4(pv[4*nf+0], pv[4*nf+1], pv[4*nf+2], pv[4*nf+3]);
  }
  // re-read as k-slice B-frags (per-wave-private tiles; same-wave ds order)
  bf16x8 cf[2], pf[2];
  cf[0] = packrow8(&ltc[wid][er][q * 8]); cf[1] = packrow8(&ltc[wid][er][32 + q * 8]);
  pf[0] = packrow8(&ltp[wid][er][q * 8]); pf[1] = packrow8(&ltp[wid][er][32 + q * 8]);

  // z = silu(chem @ wsh + bsh) * pos
  float z[16];
  {
    f32x4 acc[4] = {zero, zero, zero, zero};
    mm4(wtb + (size_t)16 * 4096, er, q, cf, acc);
#pragma unroll
    for (int nf = 0; nf < 4; ++nf) {
      const float4 b4 = *(const float4*)(bsh + nf * 16 + q * 4);
      z[4*nf+0] = fsilu(acc[nf].x + b4.x) * pv[4*nf+0];
      z[4*nf+1] = fsilu(acc[nf].y + b4.y) * pv[4*nf+1];
      z[4*nf+2] = fsilu(acc[nf].z + b4.z) * pv[4*nf+2];
      z[4*nf+3] = fsilu(acc[nf].w + b4.w) * pv[4*nf+3];
    }
  }
  // att gate
  {
    float ap = 0.f;
#pragma unroll
    for (int nf = 0; nf < 4; ++nf)
#pragma unroll
      for (int r = 0; r < 4; ++r)
        ap = fmaf(z[4*nf+r], watt[nf * 16 + q * 4 + r], ap);
    ap += __shfl_xor(ap, 16);
    ap += __shfl_xor(ap, 32);
    const float sg = fsig(ap + batt[0]);
#pragma unroll
    for (int j = 0; j < 16; ++j) z[j] *= sg;
  }
  // zb bf16 row (layout identical to original): uint idx = nf*8 + q*2
  {
    unsigned* zrow = zb + (size_t)e * 32 + q * 2;
#pragma unroll
    for (int nf = 0; nf < 4; ++nf) {
      uint2 w = make_uint2(pack2(z[4*nf+0], z[4*nf+1]), pack2(z[4*nf+2], z[4*nf+3]));
      *(uint2*)(zrow + nf * 8) = w;
    }
  }
  // per-head b scalars
  {
    float bb[4];
#pragma unroll
    for (int hd = 0; hd < 4; ++hd) {
      float b = 0.f;
#pragma unroll
      for (int nf = 0; nf < 4; ++nf)
#pragma unroll
        for (int r = 0; r < 4; ++r)
          b = fmaf(z[4*nf+r], wb[hd * 64 + nf * 16 + q * 4 + r], b);
      b += __shfl_xor(b, 16);
      b += __shfl_xor(b, 32);
      bb[hd] = b;
    }
    if (q == 0)
      *(float4*)(be + (size_t)e * 4) = make_float4(bb[0], bb[1], bb[2], bb[3]);
  }
  // u = silu(chem@wu1+bu1)@wu2 + bu2
  float u;
  {
    f32x4 acc[4] = {zero, zero, zero, zero};
    mm4(wtb + (size_t)17 * 4096, er, q, cf, acc);
    float up = 0.f;
#pragma unroll
    for (int nf = 0; nf < 4; ++nf) {
      const float4 b4 = *(const float4*)(bu1 + nf * 16 + q * 4);
      const float4 w4 = *(const float4*)(wu2 + nf * 16 + q * 4);
      up = fmaf(fsilu(acc[nf].x + b4.x), w4.x, up);
      up = fmaf(fsilu(acc[nf].y + b4.y), w4.y, up);
      up = fmaf(fsilu(acc[nf].z + b4.z), w4.z, up);
      up = fmaf(fsilu(acc[nf].w + b4.w), w4.w, up);
    }
    up += __shfl_xor(up, 16);
    up += __shfl_xor(up, 32);
    u = up + bu2[0];
  }
  // xs = silu(pos@wx1+bx1)@wx2 + bx2
  float xs;
  {
    f32x4 acc[4] = {zero, zero, zero, zero};
    mm4(wtb + (size_t)18 * 4096, er, q, pf, acc);
    float xp = 0.f;
#pragma unroll
    for (int nf = 0; nf < 4; ++nf) {
      const float4 b4 = *(const float4*)(bx1 + nf * 16 + q * 4);
      const float4 w4 = *(const float4*)(wx2 + nf * 16 + q * 4);
      xp = fmaf(fsilu(acc[nf].x + b4.x), w4.x, xp);
      xp = fmaf(fsilu(acc[nf].y + b4.y), w4.y, xp);
      xp = fmaf(fsilu(acc[nf].z + b4.z), w4.z, xp);
      xp = fmaf(fsilu(acc[nf].w + b4.w), w4.w, xp);
    }
    xp += __shfl_xor(xp, 16);
    xp += __shfl_xor(xp, 32);
    xs = xp + bx2[0];
  }

  if (q == 0) {
    const int r = edges[e], c = edges[NE + e];
    float dx = coord[r * 3 + 0] - coord[c * 3 + 0];
    float dy = coord[r * 3 + 1] - coord[c * 3 + 1];
    float dz = coord[r * 3 + 2] - coord[c * 3 + 2];
    float nrm = sqrtf(dx * dx + dy * dy + dz * dz);
    float inv = 1.0f / (nrm + 1e-8f);
    float t = u * xs;
    atomicAdd(&x_sum[r * 3 + 0], dx * inv * t);
    atomicAdd(&x_sum[r * 3 + 1], dy * inv * t);
    atomicAdd(&x_sum[r * 3 + 2], dz * inv * t);
    atomicAdd(&cntf[r], 1.0f);
  }
}

// ---------- MFMA projections -> ksep/vsep (deinterleaved fp8), qho fp8, gf8 fp8 ----------
__global__ void __launch_bounds__(256)
k_projm(const unsigned* __restrict__ zb, const unsigned short* __restrict__ wtb,
        const float* __restrict__ bg,
        unsigned* __restrict__ ksep, unsigned* __restrict__ vsep,
        unsigned* __restrict__ qho, unsigned* __restrict__ gf8) {
  const int lane = threadIdx.x & 63;
  const int wid  = threadIdx.x >> 6;        // wave 0..3
  const int er   = lane & 15;               // edge-in-tile (D col / B col / A row)
  const int q    = lane >> 4;               // k-block (A/B), row-quad (D)
  const int e0   = blockIdx.x * 256 + wid * 64 + er;

  // B frags: z^T, col=e, k=(lane>>4)*8 + i (+32 for half 1)
  bf16x8 zf[4][2];
#pragma unroll
  for (int et = 0; et < 4; ++et) {
    const unsigned* zrow = zb + (size_t)(e0 + et * 16) * 32;   // 64 bf16
    zf[et][0] = __builtin_bit_cast(bf16x8, *(const uint4*)(zrow + q * 4));
    zf[et][1] = __builtin_bit_cast(bf16x8, *(const uint4*)(zrow + 16 + q * 4));
  }

  const f32x4 zero = {0.f, 0.f, 0.f, 0.f};
#pragma unroll 1
  for (int m = 0; m < 16; ++m) {
    const unsigned short* wm = wtb + (size_t)m * 4096;
    f32x4 acc[4][4];
#pragma unroll
    for (int et = 0; et < 4; ++et)
#pragma unroll
      for (int nf = 0; nf < 4; ++nf) acc[et][nf] = zero;
#pragma unroll
    for (int nf = 0; nf < 4; ++nf) {
      const unsigned short* ar = wm + (size_t)(nf * 16 + er) * 64 + q * 8;
      const bf16x8 a0 = *(const bf16x8*)ar;
      const bf16x8 a1 = *(const bf16x8*)(ar + 32);
#pragma unroll
      for (int et = 0; et < 4; ++et) {
        acc[et][nf] = __builtin_amdgcn_mfma_f32_16x16x32_bf16(a0, zf[et][0], acc[et][nf], 0, 0, 0);
        acc[et][nf] = __builtin_amdgcn_mfma_f32_16x16x32_bf16(a1, zf[et][1], acc[et][nf], 0, 0, 0);
      }
    }
    const int hd = m >> 2, which = m & 3;    // wave-uniform
#pragma unroll
    for (int et = 0; et < 4; ++et) {
      const size_t rec = (size_t)(e0 + et * 16) * 4 + hd;
      unsigned* dst = (which == 0) ? (ksep + rec * 16)
                    : (which == 1) ? (vsep + rec * 16)
                    : (which == 2) ? (qho + rec * 16)
                                   : (gf8 + rec * 16);
      if (which == 3) {
#pragma unroll
        for (int nf = 0; nf < 4; ++nf) {
          const float4 b4 = *(const float4*)(bg + hd * 64 + nf * 16 + q * 4);
          dst[nf * 4 + q] = packf8_4(fsig(acc[et][nf].x + b4.x), fsig(acc[et][nf].y + b4.y),
                                     fsig(acc[et][nf].z + b4.z), fsig(acc[et][nf].w + b4.w));
        }
      } else {
#pragma unroll
        for (int nf = 0; nf < 4; ++nf)
          dst[nf * 4 + q] = packf8_4(acc[et][nf].x, acc[et][nf].y,
                                     acc[et][nf].z, acc[et][nf].w);
      }
    }
  }
}

// ---------- attention: flat grid, lane quad = 4 heads of one edge ----------
// K/V deinterleaved: quad gather = 256B fully-used contiguous.
// ho stored BF16 split across qho (k 0..31) + gf8 (k 32..63) records (both dead).
__global__ void __launch_bounds__(256)
k_attn(unsigned* __restrict__ qho, unsigned* __restrict__ gf8,
       const unsigned* __restrict__ ksep, const unsigned* __restrict__ vsep,
       const float* __restrict__ be, const int* __restrict__ klist) {
  const int t = blockIdx.x * 256 + threadIdx.x;
  const int e = t >> 2, hd = t & 3;

  // q (fp8 -> fp32, unscaled)
  float q[64];
  {
    unsigned qp[16];
    ldrow16(qho + (size_t)t * 16, qp);
    unpackf8(qp, q);
  }

  int i2[8], j2[8];
#pragma unroll
  for (int kn = 0; kn < 8; ++kn) {
    i2[kn] = klist[(size_t)e * 16 + kn];
    j2[kn] = klist[(size_t)e * 16 + 8 + kn];
  }
  float bv[8];
#pragma unroll
  for (int kn = 0; kn < 8; ++kn)
    bv[kn] = be[(size_t)((i2[kn] < 0) ? 0 : j2[kn]) * 4 + hd];

  const uint4* k4 = (const uint4*)ksep;   // 4 uint4 per record
  float alpha[8];
#pragma unroll 2
  for (int kn = 0; kn < 8; ++kn) {
    if (i2[kn] < 0) { alpha[kn] = -10000.0f; continue; }
    const uint4* kr = k4 + ((size_t)i2[kn] * 4 + hd) * 4;
    uint4 u0 = kr[0], u1 = kr[1], u2 = kr[2], u3 = kr[3];
    float d = 0.f;
    d = dot16(u0, q,      d);
    d = dot16(u1, q + 16, d);
    d = dot16(u2, q + 32, d);
    d = dot16(u3, q + 48, d);
    alpha[kn] = d * 0.125f + bv[kn];
  }
  float mx = alpha[0];
#pragma unroll
  for (int kn = 1; kn < 8; ++kn) mx = fmaxf(mx, alpha[kn]);
  float p[8], s = 0.f;
#pragma unroll
  for (int kn = 0; kn < 8; ++kn) { p[kn] = __expf(alpha[kn] - mx); s += p[kn]; }
  float is = 1.0f / s;
#pragma unroll
  for (int kn = 0; kn < 8; ++kn) p[kn] *= is;

  float ov[64];
#pragma unroll
  for (int j = 0; j < 64; ++j) ov[j] = 0.f;
  const uint4* v4 = (const uint4*)vsep;
#pragma unroll 2
  for (int kn = 0; kn < 8; ++kn) {
    int vi = (i2[kn] < 0) ? (NE - 1) : i2[kn];   // jax v[-1] wraps
    const uint4* vr = v4 + ((size_t)vi * 4 + hd) * 4;
    uint4 u0 = vr[0], u1 = vr[1], u2 = vr[2], u3 = vr[3];
    const float pk = p[kn];
    acc16(u0, pk, ov +  0);
    acc16(u1, pk, ov + 16);
    acc16(u2, pk, ov + 32);
    acc16(u3, pk, ov + 48);
  }
  // gate (precomputed sigmoid, fp8)
  {
    unsigned gp[16];
    ldrow16(gf8 + (size_t)t * 16, gp);
    float g[64];
    unpackf8(gp, g);
#pragma unroll
    for (int j = 0; j < 64; ++j) ov[j] *= g[j];
  }
  // ho bf16: low 32 vals -> qho rec, high 32 -> gf8 rec (thread-private slots)
  {
    unsigned* qr = qho + (size_t)t * 16;
    unsigned* gr = gf8 + (size_t)t * 16;
#pragma unroll
    for (int t2 = 0; t2 < 2; ++t2) {
      ((uint4*)qr)[t2] = make_uint4(pack2(ov[8*t2+0],  ov[8*t2+1]),  pack2(ov[8*t2+2],  ov[8*t2+3]),
                                    pack2(ov[8*t2+4],  ov[8*t2+5]),  pack2(ov[8*t2+6],  ov[8*t2+7]));
      ((uint4*)qr)[2+t2] = make_uint4(pack2(ov[16+8*t2+0], ov[16+8*t2+1]), pack2(ov[16+8*t2+2], ov[16+8*t2+3]),
                                      pack2(ov[16+8*t2+4], ov[16+8*t2+5]), pack2(ov[16+8*t2+6], ov[16+8*t2+7]));
      ((uint4*)gr)[t2] = make_uint4(pack2(ov[32+8*t2+0], ov[32+8*t2+1]), pack2(ov[32+8*t2+2], ov[32+8*t2+3]),
                                    pack2(ov[32+8*t2+4], ov[32+8*t2+5]), pack2(ov[32+8*t2+6], ov[32+8*t2+7]));
      ((uint4*)gr)[2+t2] = make_uint4(pack2(ov[48+8*t2+0], ov[48+8*t2+1]), pack2(ov[48+8*t2+2], ov[48+8*t2+3]),
                                      pack2(ov[48+8*t2+4], ov[48+8*t2+5]), pack2(ov[48+8*t2+6], ov[48+8*t2+7]));
    }
  }
}

// ---------- output projection via MFMA: m[e] = sum_hd ho_hd @ Wout_hd ----------
__global__ void __launch_bounds__(256)
k_mout(const unsigned* __restrict__ qho, const unsigned* __restrict__ gf8,
       const unsigned short* __restrict__ wtb, float* __restrict__ medge) {
  const int lane = threadIdx.x & 63;
  const int wid  = threadIdx.x >> 6;
  const int er   = lane & 15;
  const int q    = lane >> 4;
  const int e0   = blockIdx.x * 256 + wid * 64 + er;

  const f32x4 zero = {0.f, 0.f, 0.f, 0.f};
  f32x4 acc[4][4];
#pragma unroll
  for (int et = 0; et < 4; ++et)
#pragma unroll
    for (int nf = 0; nf < 4; ++nf) acc[et][nf] = zero;

#pragma unroll 1
  for (int hd = 0; hd < 4; ++hd) {
    const unsigned short* wm = wtb + (size_t)(19 + hd) * 4096;
    bf16x8 hf[4][2];
#pragma unroll
    for (int et = 0; et < 4; ++et) {
      const size_t rec = (size_t)(e0 + et * 16) * 4 + hd;
      hf[et][0] = __builtin_bit_cast(bf16x8, *(const uint4*)(qho + rec * 16 + q * 4));
      hf[et][1] = __builtin_bit_cast(bf16x8, *(const uint4*)(gf8 + rec * 16 + q * 4));
    }
#pragma unroll
    for (int nf = 0; nf < 4; ++nf) {
      const unsigned short* ar = wm + (size_t)(nf * 16 + er) * 64 + q * 8;
      const bf16x8 a0 = *(const bf16x8*)ar;
      const bf16x8 a1 = *(const bf16x8*)(ar + 32);
#pragma unroll
      for (int et = 0; et < 4; ++et) {
        acc[et][nf] = __builtin_amdgcn_mfma_f32_16x16x32_bf16(a0, hf[et][0], acc[et][nf], 0, 0, 0);
        acc[et][nf] = __builtin_amdgcn_mfma_f32_16x16x32_bf16(a1, hf[et][1], acc[et][nf], 0, 0, 0);
      }
    }
  }
#pragma unroll
  for (int et = 0; et < 4; ++et)
#pragma unroll
    for (int nf = 0; nf < 4; ++nf)
      *(float4*)(medge + (size_t)(e0 + et * 16) * 64 + nf * 16 + q * 4) =
          make_float4(acc[et][nf].x, acc[et][nf].y, acc[et][nf].z, acc[et][nf].w);
}

// ---------- CSR gather: per-node segment sum of medge ----------
__global__ void __launch_bounds__(256)
k_nodesum(const float* __restrict__ medge, const int* __restrict__ ioffs,
          const int* __restrict__ eidx, float* __restrict__ m_sum) {
  const int wid = threadIdx.x >> 6, lane = threadIdx.x & 63;
  const int n = blockIdx.x * 4 + wid;
  if (n >= NN) return;
  const int beg = ioffs[n], end = ioffs[n + 1];
  float acc = 0.f;
  for (int i = beg; i < end; ++i) {
    int e = eidx[i];
    acc += medge[(size_t)e * 64 + lane];
  }
  m_sum[(size_t)n * 64 + lane] = acc;
}

// ---------- final node update via MFMA: wave = 16 nodes ----------
__global__ void __launch_bounds__(256)
k_finm(const float* __restrict__ h, const float* __restrict__ na,
       const float* __restrict__ coord, const float* __restrict__ icoord,
       const float* __restrict__ m_sum, const float* __restrict__ x_sum,
       const float* __restrict__ cntf, const float* __restrict__ bout,
       const unsigned short* __restrict__ wtb,
       const float* __restrict__ bh1, const float* __restrict__ bh2,
       float* __restrict__ out) {
  __shared__ float lt[4][16][68];   // +4 pad breaks er*64 bank alias
  const int lane = threadIdx.x & 63;
  const int wid  = threadIdx.x >> 6;
  const int er   = lane & 15;
  const int q    = lane >> 4;
  const int e    = blockIdx.x * 64 + wid * 16 + er;
  const bool valid = e < NN;
  const int el = valid ? e : 0;

  const float* hr = h + (size_t)el * 64;
  const float* nr = na + (size_t)el * 64;
  const float* mr = m_sum + (size_t)el * 64;
  const float cn = cntf[el];
  const float invc = 1.0f / fmaxf(cn, 1.0f);
  const float bsc = (cn > 0.f) ? 1.0f : 0.0f;   // empty segment => m_agg = 0

  // B-frags: h, na, m_agg k-slices (bf16)
  bf16x8 hf[2], naf[2], mf[2];
  hf[0]  = packrow8(hr + q * 8); hf[1]  = packrow8(hr + 32 + q * 8);
  naf[0] = packrow8(nr + q * 8); naf[1] = packrow8(nr + 32 + q * 8);
#pragma unroll
  for (int half = 0; half < 2; ++half) {
    const int o = half * 32 + q * 8;
    const float4 m0 = *(const float4*)(mr + o);
    const float4 m1 = *(const float4*)(mr + o + 4);
    const float4 b0 = *(const float4*)(bout + o);
    const float4 b1 = *(const float4*)(bout + o + 4);
    float ma[8];
    ma[0] = fmaf(m0.x, invc, b0.x * bsc); ma[1] = fmaf(m0.y, invc, b0.y * bsc);
    ma[2] = fmaf(m0.z, invc, b0.z * bsc); ma[3] = fmaf(m0.w, invc, b0.w * bsc);
    ma[4] = fmaf(m1.x, invc, b1.x * bsc); ma[5] = fmaf(m1.y, invc, b1.y * bsc);
    ma[6] = fmaf(m1.z, invc, b1.z * bsc); ma[7] = fmaf(m1.w, invc, b1.w * bsc);
    uint4 u = make_uint4(pack2(ma[0], ma[1]), pack2(ma[2], ma[3]),
                         pack2(ma[4], ma[5]), pack2(ma[6], ma[7]));
    mf[half] = __builtin_bit_cast(bf16x8, u);
  }

  const f32x4 zero = {0.f, 0.f, 0.f, 0.f};
  f32x4 acc[4] = {zero, zero, zero, zero};
  mm4(wtb + (size_t)23 * 4096, er, q, hf,  acc);
  mm4(wtb + (size_t)24 * 4096, er, q, naf, acc);
  mm4(wtb + (size_t)25 * 4096, er, q, mf,  acc);
#pragma unroll
  for (int nf = 0; nf < 4; ++nf) {
    const float4 b4 = *(const float4*)(bh1 + nf * 16 + q * 4);
    float* d = &lt[wid][er][nf * 16 + q * 4];
    d[0] = fsilu(acc[nf].x + b4.x); d[1] = fsilu(acc[nf].y + b4.y);
    d[2] = fsilu(acc[nf].z + b4.z); d[3] = fsilu(acc[nf].w + b4.w);
  }
  __syncthreads();
  bf16x8 sf[2];
  sf[0] = packrow8(&lt[wid][er][q * 8]);
  sf[1] = packrow8(&lt[wid][er][32 + q * 8]);
  f32x4 a2[4] = {zero, zero, zero, zero};
  mm4(wtb + (size_t)26 * 4096, er, q, sf, a2);
  if (valid) {
#pragma unroll
    for (int nf = 0; nf < 4; ++nf) {
      const float4 b4 = *(const float4*)(bh2 + nf * 16 + q * 4);
      const float4 h4 = *(const float4*)(hr + nf * 16 + q * 4);
      *(float4*)(out + (size_t)e * 64 + nf * 16 + q * 4) =
          make_float4(a2[nf].x + b4.x + h4.x, a2[nf].y + b4.y + h4.y,
                      a2[nf].z + b4.z + h4.z, a2[nf].w + b4.w + h4.w);
    }
    if (q == 0) {
#pragma unroll
      for (int d = 0; d < 3; ++d)
        out[(size_t)NN * 64 + e * 3 + d] =
            0.2f * icoord[e * 3 + d] + 0.8f * coord[e * 3 + d] + x_sum[e * 3 + d] * invc;
    }
  }
}

extern "C" void kernel_launch(void* const* d_in, const int* in_sizes, int n_in,
                              void* d_out, int out_size, void* d_ws, size_t ws_size,
                              hipStream_t stream) {
  (void)in_sizes; (void)n_in; (void)out_size; (void)ws_size;
  const float* h      = (const float*)d_in[0];
  const float* coord  = (const float*)d_in[1];
  const int*   edges  = (const int*)  d_in[2];
  const float* nvecs  = (const float*)d_in[3];
  const float* ea     = (const float*)d_in[4];
  const float* na     = (const float*)d_in[5];
  const float* icoord = (const float*)d_in[6];
  const int*   klist  = (const int*)  d_in[7];
  const float* w_chem1 = (const float*)d_in[8];
  const float* b_chem1 = (const float*)d_in[9];
  const float* w_chem2 = (const float*)d_in[10];
  const float* b_chem2 = (const float*)d_in[11];
  const float* w_pos1  = (const float*)d_in[12];
  const float* b_pos1  = (const float*)d_in[13];
  const float* w_pos2  = (const float*)d_in[14];
  const float* b_pos2  = (const float*)d_in[15];
  const float* w_sh    = (const float*)d_in[16];
  const float* b_sh    = (const float*)d_in[17];
  const float* w_att   = (const float*)d_in[18];
  const float* b_att   = (const float*)d_in[19];
  const float* wq      = (const float*)d_in[20];
  const float* wk      = (const float*)d_in[21];
  const float* wv      = (const float*)d_in[22];
  const float* wb      = (const float*)d_in[23];
  const float* wg      = (const float*)d_in[24];
  const float* bg      = (const float*)d_in[25];
  const float* w_out   = (const float*)d_in[26];
  const float* b_out   = (const float*)d_in[27];
  const float* wu1     = (const float*)d_in[28];
  const float* bu1     = (const float*)d_in[29];
  const float* wu2     = (const float*)d_in[30];
  const float* bu2     = (const float*)d_in[31];
  const float* wx1     = (const float*)d_in[32];
  const float* bx1     = (const float*)d_in[33];
  const float* wx2     = (const float*)d_in[34];
  const float* bx2     = (const float*)d_in[35];
  const float* wh1     = (const float*)d_in[36];
  const float* bh1     = (const float*)d_in[37];
  const float* wh2     = (const float*)d_in[38];
  const float* bh2     = (const float*)d_in[39];

  float* out = (float*)d_out;
  float* ws  = (float*)d_ws;
  // Phase-reused regions (NE*64 floats each):
  //  R1: act1c -> ksep [NE*4][64B] fp8 K -> medge after attn
  //  R2: act1p -> vsep [NE*4][64B] fp8 V
  //  R3: qho  [NE*4][16u] fp8 q -> ho bf16 low-half after attn
  //  R4: gf8  [NE*4][16u] fp8 gate -> ho bf16 high-half after attn
  float* R1 = ws;
  float* R2 = R1 + (size_t)NE * 64;
  float* R3 = R2 + (size_t)NE * 64;
  float* R4 = R3 + (size_t)NE * 64;
  float* zbf   = R4 + (size_t)NE * 64;      // NE*32 floats (bf16 gated z)
  float* x_sum = zbf + (size_t)NE * 32;     // NN*3 (zeroed)
  float* cntf  = x_sum + (size_t)NN * 3;    // NN (zeroed)
  int*   icnt  = (int*)(cntf + NN);         // NN (zeroed)
  int*   icur  = icnt + NN;                 // NN (zeroed)
  float* m_sum = (float*)(icur + NN);       // NN*64
  float* be    = m_sum + (size_t)NN * 64;   // 4*NE  ([e*4+hd] layout)
  unsigned short* wtb = (unsigned short*)(be + (size_t)4 * NE);  // 34*64*64 bf16 (278KB)
  int*   ioffs = (int*)(wtb + 34 * 4096);   // NN+1
  int*   eidx  = ioffs + (NN + 1);          // NE

  unsigned* ksep = (unsigned*)R1;  // [NE*4][16u] fp8 K (deinterleaved)
  unsigned* vsep = (unsigned*)R2;  // [NE*4][16u] fp8 V
  unsigned* qho  = (unsigned*)R3;  // [NE*4][16u] fp8 q -> bf16 ho lo
  unsigned* gf8  = (unsigned*)R4;  // [NE*4][16u] fp8 gate -> bf16 ho hi
  unsigned* zb   = (unsigned*)zbf;
  float* medge = R1;               // after attention (ksep dead)

  (void)hipMemsetAsync(x_sum, 0, ((size_t)NN * 3 + NN + NN + NN) * sizeof(float), stream);

  dim3 b256(256);
  dim3 gflat(NE / 256);

  // weight prep + CSR build (independent of the MLP pipeline)
  k_wprep<<<dim3(34), b256, 0, stream>>>(wk, wv, wq, wg, w_sh, wu1, wx1, w_out,
                                         wh1, wh2, w_chem2, w_pos2, w_chem1, wtb);
  k_count<<<gflat, b256, 0, stream>>>(edges, icnt);
  k_scan <<<dim3(1), b256, 0, stream>>>(icnt, ioffs);
  k_fill <<<gflat, b256, 0, stream>>>(edges, ioffs, icur, eidx);

  k_chem1m<<<dim3(NE / 64), b256, 0, stream>>>(h, na, ea, edges, wtb, b_chem1, R1);
  k_pos1  <<<dim3(NE / 256, 2), b256, 0, stream>>>(coord, nvecs, ea, edges, w_pos1, b_pos1, R2);
  k_l2s   <<<dim3(NE / 64), b256, 0, stream>>>(coord, edges, R1, R2, wtb,
                                               b_chem2, b_pos2, b_sh, w_att, b_att,
                                               bu1, wu2, bu2, bx1, wx2, bx2, wb,
                                               zb, be, x_sum, cntf);
  k_projm<<<dim3(NE / 256), b256, 0, stream>>>(zb, wtb, bg, ksep, vsep, qho, gf8);
  k_attn <<<dim3(NE * 4 / 256), b256, 0, stream>>>(qho, gf8, ksep, vsep, be, klist);
  k_mout <<<dim3(NE / 256), b256, 0, stream>>>(qho, gf8, wtb, medge);
  k_nodesum<<<dim3((NN + 3) / 4), b256, 0, stream>>>(medge, ioffs, eidx, m_sum);
  k_finm<<<dim3((NN + 63) / 64), b256, 0, stream>>>(h, na, coord, icoord, m_sum, x_sum,
                                                    cntf, b_out, wtb, bh1, bh2, out);
}

// Round 8
// 641.795 us; speedup vs baseline: 2.2568x; 1.0384x over previous
//
#include <hip/hip_runtime.h>
#include <math.h>

#define NE 160000
#define NN 10000

#define DEV __device__ __forceinline__

typedef float v2f __attribute__((ext_vector_type(2)));
typedef __attribute__((ext_vector_type(8))) short bf16x8;   // 8 bf16 (4 VGPRs)
typedef __attribute__((ext_vector_type(4))) float f32x4;

DEV float fsilu(float x) { return x / (1.0f + __expf(-x)); }
DEV float fsig(float x)  { return 1.0f / (1.0f + __expf(-x)); }

// ---- bf16 pack/unpack helpers (RNE) ----
DEV unsigned pack2(float a, float b) {
  unsigned ua = __float_as_uint(a); ua += 0x7FFFu + ((ua >> 16) & 1u);
  unsigned ub = __float_as_uint(b); ub += 0x7FFFu + ((ub >> 16) & 1u);
  return (ua >> 16) | (ub & 0xFFFF0000u);
}

// ---- fp8 e4m3 (OCP, HW-converted) ----
DEV unsigned packf8_4(float a, float b, float c, float d) {
  int r = __builtin_amdgcn_cvt_pk_fp8_f32(a, b, 0, false);
  r = __builtin_amdgcn_cvt_pk_fp8_f32(c, d, r, true);
  return (unsigned)r;
}
template<bool HI>
DEV v2f up2(unsigned u) { return __builtin_amdgcn_cvt_pk_f32_fp8((int)u, HI); }

// dot of 16 fp8 values (one uint4) against q[0..16)
DEV float dot16(uint4 u, const float* q, float d) {
  v2f f;
  f = up2<false>(u.x); d = fmaf(f.x, q[0],  d); d = fmaf(f.y, q[1],  d);
  f = up2<true >(u.x); d = fmaf(f.x, q[2],  d); d = fmaf(f.y, q[3],  d);
  f = up2<false>(u.y); d = fmaf(f.x, q[4],  d); d = fmaf(f.y, q[5],  d);
  f = up2<true >(u.y); d = fmaf(f.x, q[6],  d); d = fmaf(f.y, q[7],  d);
  f = up2<false>(u.z); d = fmaf(f.x, q[8],  d); d = fmaf(f.y, q[9],  d);
  f = up2<true >(u.z); d = fmaf(f.x, q[10], d); d = fmaf(f.y, q[11], d);
  f = up2<false>(u.w); d = fmaf(f.x, q[12], d); d = fmaf(f.y, q[13], d);
  f = up2<true >(u.w); d = fmaf(f.x, q[14], d); d = fmaf(f.y, q[15], d);
  return d;
}
// o[0..16) += pk * fp8x16(u)
DEV void acc16(uint4 u, float pk, float* o) {
  v2f f;
  f = up2<false>(u.x); o[0]  = fmaf(pk, f.x, o[0]);  o[1]  = fmaf(pk, f.y, o[1]);
  f = up2<true >(u.x); o[2]  = fmaf(pk, f.x, o[2]);  o[3]  = fmaf(pk, f.y, o[3]);
  f = up2<false>(u.y); o[4]  = fmaf(pk, f.x, o[4]);  o[5]  = fmaf(pk, f.y, o[5]);
  f = up2<true >(u.y); o[6]  = fmaf(pk, f.x, o[6]);  o[7]  = fmaf(pk, f.y, o[7]);
  f = up2<false>(u.z); o[8]  = fmaf(pk, f.x, o[8]);  o[9]  = fmaf(pk, f.y, o[9]);
  f = up2<true >(u.z); o[10] = fmaf(pk, f.x, o[10]); o[11] = fmaf(pk, f.y, o[11]);
  f = up2<false>(u.w); o[12] = fmaf(pk, f.x, o[12]); o[13] = fmaf(pk, f.y, o[13]);
  f = up2<true >(u.w); o[14] = fmaf(pk, f.x, o[14]); o[15] = fmaf(pk, f.y, o[15]);
}

DEV void ldrow16(const unsigned* __restrict__ p, unsigned (&r)[16]) {
#pragma unroll
  for (int t = 0; t < 4; ++t) {
    uint4 u = ((const uint4*)p)[t];
    r[4*t] = u.x; r[4*t+1] = u.y; r[4*t+2] = u.z; r[4*t+3] = u.w;
  }
}
DEV void unpackf8(const unsigned (&p)[16], float (&o)[64]) {
#pragma unroll
  for (int t = 0; t < 16; ++t) {
    v2f f0 = up2<false>(p[t]);
    v2f f1 = up2<true >(p[t]);
    o[4*t+0] = f0.x; o[4*t+1] = f0.y; o[4*t+2] = f1.x; o[4*t+3] = f1.y;
  }
}
DEV void store32(float* dst, const float (&a)[32]) {
#pragma unroll
  for (int j = 0; j < 32; j += 4)
    *(float4*)(dst + j) = make_float4(a[j], a[j+1], a[j+2], a[j+3]);
}

// pack 8 consecutive fp32 -> bf16x8 (B-fragment k-slice)
DEV bf16x8 packrow8(const float* __restrict__ p) {
  float4 a = *(const float4*)p;
  float4 b = *(const float4*)(p + 4);
  uint4 u = make_uint4(pack2(a.x, a.y), pack2(a.z, a.w),
                       pack2(b.x, b.y), pack2(b.z, b.w));
  return __builtin_bit_cast(bf16x8, u);
}

// 16x16x32 GEMM over K=64: acc[nf] (n = nf*16 + q*4 + reg), A from wtb matrix wm
DEV void mm4(const unsigned short* __restrict__ wm, int er, int q,
             const bf16x8 (&bfr)[2], f32x4 (&acc)[4]) {
#pragma unroll
  for (int nf = 0; nf < 4; ++nf) {
    const unsigned short* ar = wm + (size_t)(nf * 16 + er) * 64 + q * 8;
    const bf16x8 a0 = *(const bf16x8*)ar;
    const bf16x8 a1 = *(const bf16x8*)(ar + 32);
    acc[nf] = __builtin_amdgcn_mfma_f32_16x16x32_bf16(a0, bfr[0], acc[nf], 0, 0, 0);
    acc[nf] = __builtin_amdgcn_mfma_f32_16x16x32_bf16(a1, bfr[1], acc[nf], 0, 0, 0);
  }
}

// ---------- CSR build over edges[0] (rows) ----------
__global__ void __launch_bounds__(256)
k_count(const int* __restrict__ edges, int* __restrict__ icnt) {
  int e = blockIdx.x * 256 + threadIdx.x;
  if (e < NE) atomicAdd(&icnt[edges[e]], 1);
}

__global__ void __launch_bounds__(256)
k_scan(const int* __restrict__ icnt, int* __restrict__ ioffs) {
  __shared__ int part[256];
  const int t = threadIdx.x;
  const int base = t * 40;
  int loc[40];
  int s = 0;
#pragma unroll
  for (int i = 0; i < 40; ++i) {
    int idx = base + i;
    int v = (idx < NN) ? icnt[idx] : 0;
    loc[i] = v; s += v;
  }
  part[t] = s;
  __syncthreads();
  for (int off = 1; off < 256; off <<= 1) {
    int v = (t >= off) ? part[t - off] : 0;
    __syncthreads();
    part[t] += v;
    __syncthreads();
  }
  int run = (t == 0) ? 0 : part[t - 1];
#pragma unroll
  for (int i = 0; i < 40; ++i) {
    int idx = base + i;
    if (idx < NN) { ioffs[idx] = run; run += loc[i]; }
  }
  if (t == 255) ioffs[NN] = NE;
}

__global__ void __launch_bounds__(256)
k_fill(const int* __restrict__ edges, const int* __restrict__ ioffs,
       int* __restrict__ icur, int* __restrict__ eidx) {
  int e = blockIdx.x * 256 + threadIdx.x;
  if (e >= NE) return;
  int r = edges[e];
  int p = atomicAdd(&icur[r], 1);
  eidx[ioffs[r] + p] = e;
}

// ---------- chem layer 1 via MFMA: 272 -> 64 silu; wave = 16 edges ----------
// 4 full K=64 slices (h[r],h[c],na[r],na[c]) + zero-padded K=16 edge-attr slice.
__global__ void __launch_bounds__(256)
k_chem1m(const float* __restrict__ h, const float* __restrict__ na,
         const float* __restrict__ ea, const int* __restrict__ edges,
         const unsigned short* __restrict__ wtb, const float* __restrict__ b1,
         float* __restrict__ act1c) {
  const int lane = threadIdx.x & 63;
  const int wid  = threadIdx.x >> 6;
  const int er   = lane & 15;
  const int q    = lane >> 4;
  const int e    = blockIdx.x * 64 + wid * 16 + er;
  const int r = edges[e], c = edges[NE + e];

  const f32x4 zero = {0.f, 0.f, 0.f, 0.f};
  f32x4 acc[4] = {zero, zero, zero, zero};
  bf16x8 f[2];
  const float* xr;
  xr = h  + (size_t)r * 64; f[0] = packrow8(xr + q * 8); f[1] = packrow8(xr + 32 + q * 8);
  mm4(wtb + (size_t)29 * 4096, er, q, f, acc);
  xr = h  + (size_t)c * 64; f[0] = packrow8(xr + q * 8); f[1] = packrow8(xr + 32 + q * 8);
  mm4(wtb + (size_t)30 * 4096, er, q, f, acc);
  xr = na + (size_t)r * 64; f[0] = packrow8(xr + q * 8); f[1] = packrow8(xr + 32 + q * 8);
  mm4(wtb + (size_t)31 * 4096, er, q, f, acc);
  xr = na + (size_t)c * 64; f[0] = packrow8(xr + q * 8); f[1] = packrow8(xr + 32 + q * 8);
  mm4(wtb + (size_t)32 * 4096, er, q, f, acc);
  // edge-attr slice: real B for k<16 (q=0,1), zero B elsewhere; half-2 skipped.
  {
    bf16x8 ef;
    if (q < 2) ef = packrow8(ea + (size_t)e * 16 + q * 8);
    else { uint4 z4 = make_uint4(0, 0, 0, 0); ef = __builtin_bit_cast(bf16x8, z4); }
    const unsigned short* wm = wtb + (size_t)33 * 4096;
#pragma unroll
    for (int nf = 0; nf < 4; ++nf) {
      const bf16x8 a0 = *(const bf16x8*)(wm + (size_t)(nf * 16 + er) * 64 + q * 8);
      acc[nf] = __builtin_amdgcn_mfma_f32_16x16x32_bf16(a0, ef, acc[nf], 0, 0, 0);
    }
  }
#pragma unroll
  for (int nf = 0; nf < 4; ++nf) {
    const float4 b4 = *(const float4*)(b1 + nf * 16 + q * 4);
    *(float4*)(act1c + (size_t)e * 64 + nf * 16 + q * 4) =
        make_float4(fsilu(acc[nf].x + b4.x), fsilu(acc[nf].y + b4.y),
                    fsilu(acc[nf].z + b4.z), fsilu(acc[nf].w + b4.w));
  }
}

// ---------- pos layer 1: 36 -> 64 silu ----------
__global__ void __launch_bounds__(256)
k_pos1(const float* __restrict__ coord, const float* __restrict__ nv,
       const float* __restrict__ ea, const int* __restrict__ edges,
       const float* __restrict__ w1, const float* __restrict__ b1,
       float* __restrict__ act1p) {
  const int e = blockIdx.x * 256 + threadIdx.x;
  const int co = blockIdx.y * 32;
  const int r = edges[e], c = edges[NE + e];

  float dx = coord[r * 3 + 0] - coord[c * 3 + 0];
  float dy = coord[r * 3 + 1] - coord[c * 3 + 1];
  float dz = coord[r * 3 + 2] - coord[c * 3 + 2];
  float nrm = sqrtf(dx * dx + dy * dy + dz * dz);
  float inv = 1.0f / (nrm + 1e-8f);
  dx *= inv; dy *= inv; dz *= inv;
  float ir = dx * dx + dy * dy + dz * dz;

  float in[36];
#pragma unroll
  for (int v = 0; v < 5; ++v) {
    float s = 0.f;
#pragma unroll
    for (int d = 0; d < 3; ++d)
      s += nv[(size_t)r * 15 + v * 3 + d] * nv[(size_t)c * 15 + v * 3 + d];
    in[v] = s;
  }
  {
    float cexp = -0.5f;
#pragma unroll
    for (int k = 0; k < 15; ++k) { in[5 + k] = __expf(ir * cexp); cexp *= (1.0f / 2.25f); }
  }
#pragma unroll
  for (int k = 0; k < 16; k += 4) {
    float4 e4 = *(const float4*)(ea + (size_t)e * 16 + k);
    in[20 + k] = e4.x; in[21 + k] = e4.y; in[22 + k] = e4.z; in[23 + k] = e4.w;
  }

  float acc[32];
#pragma unroll
  for (int j = 0; j < 32; ++j) acc[j] = b1[co + j];
#pragma unroll
  for (int k = 0; k < 36; ++k) {
    const float x = in[k];
    const float* wr = w1 + (size_t)k * 64 + co;
#pragma unroll
    for (int j = 0; j < 32; ++j) acc[j] = fmaf(x, wr[j], acc[j]);
  }
#pragma unroll
  for (int j = 0; j < 32; ++j) acc[j] = fsilu(acc[j]);
  store32(act1p + (size_t)e * 64 + co, acc);
}

// ---------- weight prep: wtb[m][n][k] = W_m[k][n] in bf16 (A-operand layout) ----------
// 0..15: hd*4+which (k,v,q,g); 16..18: wsh,wu1,wx1; 19..22: w_out/hd (chan-permuted k);
// 23..25: wh1 slices; 26: wh2; 27: w_chem2; 28: w_pos2; 29..32: w_chem1; 33: ea-slice
// chan(kk) maps fp8-record byte position -> original channel (record uint idx = q*4+nf).
__global__ void __launch_bounds__(256)
k_wprep(const float* __restrict__ wk, const float* __restrict__ wv,
        const float* __restrict__ wq, const float* __restrict__ wg,
        const float* __restrict__ wsh, const float* __restrict__ wu1,
        const float* __restrict__ wx1, const float* __restrict__ wout,
        const float* __restrict__ wh1, const float* __restrict__ wh2,
        const float* __restrict__ w2c, const float* __restrict__ w2p,
        const float* __restrict__ wc1,
        unsigned short* __restrict__ wtb) {
  const int m = blockIdx.x;          // 0..33
  const float* src;
  bool pad16 = false, permk = false;
  if (m < 16) {
    const int hd = m >> 2, which = m & 3;
    src = ((which == 0) ? wk : (which == 1) ? wv : (which == 2) ? wq : wg)
          + (size_t)hd * 4096;
  } else if (m < 19) {
    src = (m == 16) ? wsh : (m == 17) ? wu1 : wx1;
  } else if (m < 23) {
    src = wout + (size_t)(m - 19) * 4096;
    permk = true;                    // ho consumed in record-position order
  } else if (m < 26) {
    src = wh1 + (size_t)(m - 23) * 4096;
  } else if (m == 26) {
    src = wh2;
  } else if (m == 27) {
    src = w2c;
  } else if (m == 28) {
    src = w2p;
  } else if (m < 33) {
    src = wc1 + (size_t)(m - 29) * 4096;
  } else {
    src = wc1 + (size_t)4 * 4096;   // rows 256..271
    pad16 = true;
  }
  const int t = threadIdx.x;
#pragma unroll
  for (int i = 0; i < 16; ++i) {
    int idx = t * 16 + i;
    int n = idx >> 6, kk = idx & 63;
    int kr = permk ? (((kk >> 2) & 3) * 16 + (kk >> 4) * 4 + (kk & 3)) : kk;
    float v = (pad16 && kr >= 16) ? 0.f : src[kr * 64 + n];
    unsigned u = __float_as_uint(v);
    u += 0x7FFFu + ((u >> 16) & 1u);
    wtb[(size_t)m * 4096 + idx] = (unsigned short)(u >> 16);
  }
}

// ---------- fused layer-2 + scalars (MFMA): act1c/act1p -> zb/be/u/x ----------
// Wave = 16 edges. Layer-2 D-frags re-laid to k-slices via per-wave LDS tiles
// (same-wave ds ordering -> no barrier). posD is already in z's elementwise layout.
__global__ void __launch_bounds__(256)
k_l2s(const float* __restrict__ coord, const int* __restrict__ edges,
      const float* __restrict__ act1c, const float* __restrict__ act1p,
      const unsigned short* __restrict__ wtb,
      const float* __restrict__ b2c, const float* __restrict__ b2p,
      const float* __restrict__ bsh,
      const float* __restrict__ watt, const float* __restrict__ batt,
      const float* __restrict__ bu1, const float* __restrict__ wu2,
      const float* __restrict__ bu2,
      const float* __restrict__ bx1, const float* __restrict__ wx2,
      const float* __restrict__ bx2,
      const float* __restrict__ wb,
      unsigned* __restrict__ zb, float* __restrict__ be,
      float* __restrict__ x_sum, float* __restrict__ cntf) {
  __shared__ float ltc[4][16][68];   // +4 pad breaks er*64 bank alias
  __shared__ float ltp[4][16][68];
  const int lane = threadIdx.x & 63;
  const int wid  = threadIdx.x >> 6;
  const int er   = lane & 15;
  const int q    = lane >> 4;
  const int e    = blockIdx.x * 64 + wid * 16 + er;

  const f32x4 zero = {0.f, 0.f, 0.f, 0.f};
  bf16x8 f[2];

  // layer-2 chem: chemD = silu(act1c @ w2c + b2c)
  {
    const float* xr = act1c + (size_t)e * 64;
    f[0] = packrow8(xr + q * 8); f[1] = packrow8(xr + 32 + q * 8);
  }
  f32x4 cD[4] = {zero, zero, zero, zero};
  mm4(wtb + (size_t)27 * 4096, er, q, f, cD);
#pragma unroll
  for (int nf = 0; nf < 4; ++nf) {
    const float4 bc = *(const float4*)(b2c + nf * 16 + q * 4);
    *(float4*)&ltc[wid][er][nf * 16 + q * 4] =
        make_float4(fsilu(cD[nf].x + bc.x), fsilu(cD[nf].y + bc.y),
                    fsilu(cD[nf].z + bc.z), fsilu(cD[nf].w + bc.w));
  }
  // layer-2 pos: posD = silu(act1p @ w2p + b2p)  (kept in regs: z's elementwise layout)
  {
    const float* xr = act1p + (size_t)e * 64;
    f[0] = packrow8(xr + q * 8); f[1] = packrow8(xr + 32 + q * 8);
  }
  f32x4 pD[4] = {zero, zero, zero, zero};
  mm4(wtb + (size_t)28 * 4096, er, q, f, pD);
  float pv[16];
#pragma unroll
  for (int nf = 0; nf < 4; ++nf) {
    const float4 bp = *(const float4*)(b2p + nf * 16 + q * 4);
    pv[4*nf+0] = fsilu(pD[nf].x + bp.x); pv[4*nf+1] = fsilu(pD[nf].y + bp.y);
    pv[4*nf+2] = fsilu(pD[nf].z + bp.z); pv[4*nf+3] = fsilu(pD[nf].w + bp.w);
    *(float4*)&ltp[wid][er][nf * 16 + q * 4] =
        make_float4(pv[4*nf+0], pv[4*nf+1], pv[4*nf+2], pv[4*nf+3]);
  }
  // re-read as k-slice B-frags (per-wave-private tiles; same-wave ds order)
  bf16x8 cf[2], pf[2];
  cf[0] = packrow8(&ltc[wid][er][q * 8]); cf[1] = packrow8(&ltc[wid][er][32 + q * 8]);
  pf[0] = packrow8(&ltp[wid][er][q * 8]); pf[1] = packrow8(&ltp[wid][er][32 + q * 8]);

  // z = silu(chem @ wsh + bsh) * pos
  float z[16];
  {
    f32x4 acc[4] = {zero, zero, zero, zero};
    mm4(wtb + (size_t)16 * 4096, er, q, cf, acc);
#pragma unroll
    for (int nf = 0; nf < 4; ++nf) {
      const float4 b4 = *(const float4*)(bsh + nf * 16 + q * 4);
      z[4*nf+0] = fsilu(acc[nf].x + b4.x) * pv[4*nf+0];
      z[4*nf+1] = fsilu(acc[nf].y + b4.y) * pv[4*nf+1];
      z[4*nf+2] = fsilu(acc[nf].z + b4.z) * pv[4*nf+2];
      z[4*nf+3] = fsilu(acc[nf].w + b4.w) * pv[4*nf+3];
    }
  }
  // att gate
  {
    float ap = 0.f;
#pragma unroll
    for (int nf = 0; nf < 4; ++nf)
#pragma unroll
      for (int r = 0; r < 4; ++r)
        ap = fmaf(z[4*nf+r], watt[nf * 16 + q * 4 + r], ap);
    ap += __shfl_xor(ap, 16);
    ap += __shfl_xor(ap, 32);
    const float sg = fsig(ap + batt[0]);
#pragma unroll
    for (int j = 0; j < 16; ++j) z[j] *= sg;
  }
  // zb bf16 row (layout identical to original): uint idx = nf*8 + q*2
  {
    unsigned* zrow = zb + (size_t)e * 32 + q * 2;
#pragma unroll
    for (int nf = 0; nf < 4; ++nf) {
      uint2 w = make_uint2(pack2(z[4*nf+0], z[4*nf+1]), pack2(z[4*nf+2], z[4*nf+3]));
      *(uint2*)(zrow + nf * 8) = w;
    }
  }
  // per-head b scalars
  {
    float bb[4];
#pragma unroll
    for (int hd = 0; hd < 4; ++hd) {
      float b = 0.f;
#pragma unroll
      for (int nf = 0; nf < 4; ++nf)
#pragma unroll
        for (int r = 0; r < 4; ++r)
          b = fmaf(z[4*nf+r], wb[hd * 64 + nf * 16 + q * 4 + r], b);
      b += __shfl_xor(b, 16);
      b += __shfl_xor(b, 32);
      bb[hd] = b;
    }
    if (q == 0)
      *(float4*)(be + (size_t)e * 4) = make_float4(bb[0], bb[1], bb[2], bb[3]);
  }
  // u = silu(chem@wu1+bu1)@wu2 + bu2
  float u;
  {
    f32x4 acc[4] = {zero, zero, zero, zero};
    mm4(wtb + (size_t)17 * 4096, er, q, cf, acc);
    float up = 0.f;
#pragma unroll
    for (int nf = 0; nf < 4; ++nf) {
      const float4 b4 = *(const float4*)(bu1 + nf * 16 + q * 4);
      const float4 w4 = *(const float4*)(wu2 + nf * 16 + q * 4);
      up = fmaf(fsilu(acc[nf].x + b4.x), w4.x, up);
      up = fmaf(fsilu(acc[nf].y + b4.y), w4.y, up);
      up = fmaf(fsilu(acc[nf].z + b4.z), w4.z, up);
      up = fmaf(fsilu(acc[nf].w + b4.w), w4.w, up);
    }
    up += __shfl_xor(up, 16);
    up += __shfl_xor(up, 32);
    u = up + bu2[0];
  }
  // xs = silu(pos@wx1+bx1)@wx2 + bx2
  float xs;
  {
    f32x4 acc[4] = {zero, zero, zero, zero};
    mm4(wtb + (size_t)18 * 4096, er, q, pf, acc);
    float xp = 0.f;
#pragma unroll
    for (int nf = 0; nf < 4; ++nf) {
      const float4 b4 = *(const float4*)(bx1 + nf * 16 + q * 4);
      const float4 w4 = *(const float4*)(wx2 + nf * 16 + q * 4);
      xp = fmaf(fsilu(acc[nf].x + b4.x), w4.x, xp);
      xp = fmaf(fsilu(acc[nf].y + b4.y), w4.y, xp);
      xp = fmaf(fsilu(acc[nf].z + b4.z), w4.z, xp);
      xp = fmaf(fsilu(acc[nf].w + b4.w), w4.w, xp);
    }
    xp += __shfl_xor(xp, 16);
    xp += __shfl_xor(xp, 32);
    xs = xp + bx2[0];
  }

  if (q == 0) {
    const int r = edges[e], c = edges[NE + e];
    float dx = coord[r * 3 + 0] - coord[c * 3 + 0];
    float dy = coord[r * 3 + 1] - coord[c * 3 + 1];
    float dz = coord[r * 3 + 2] - coord[c * 3 + 2];
    float nrm = sqrtf(dx * dx + dy * dy + dz * dz);
    float inv = 1.0f / (nrm + 1e-8f);
    float t = u * xs;
    atomicAdd(&x_sum[r * 3 + 0], dx * inv * t);
    atomicAdd(&x_sum[r * 3 + 1], dy * inv * t);
    atomicAdd(&x_sum[r * 3 + 2], dz * inv * t);
    atomicAdd(&cntf[r], 1.0f);
  }
}

// ---------- MFMA projections -> ksep/vsep/qho/gf8 fp8, position-permuted records ----------
// Record uint idx = q*4+nf -> each lane stores one coalesced uint4 (1KB/wave-store).
// Permutation is shared by K/Q/V/gate/ho; only w_out (wtb 19..22) compensates (chan-perm).
// et=2 (32 edges/wave) doubles wave count for latency hiding.
__global__ void __launch_bounds__(256)
k_projm(const unsigned* __restrict__ zb, const unsigned short* __restrict__ wtb,
        const float* __restrict__ bg,
        unsigned* __restrict__ ksep, unsigned* __restrict__ vsep,
        unsigned* __restrict__ qho, unsigned* __restrict__ gf8) {
  const int lane = threadIdx.x & 63;
  const int wid  = threadIdx.x >> 6;        // wave 0..3
  const int er   = lane & 15;               // edge-in-tile (D col / B col / A row)
  const int q    = lane >> 4;               // k-block (A/B), row-quad (D)
  const int e0   = blockIdx.x * 128 + wid * 32 + er;

  // B frags: z^T, col=e, k=(lane>>4)*8 + i (+32 for half 1)
  bf16x8 zf[2][2];
#pragma unroll
  for (int et = 0; et < 2; ++et) {
    const unsigned* zrow = zb + (size_t)(e0 + et * 16) * 32;   // 64 bf16
    zf[et][0] = __builtin_bit_cast(bf16x8, *(const uint4*)(zrow + q * 4));
    zf[et][1] = __builtin_bit_cast(bf16x8, *(const uint4*)(zrow + 16 + q * 4));
  }

  const f32x4 zero = {0.f, 0.f, 0.f, 0.f};
#pragma unroll 1
  for (int m = 0; m < 16; ++m) {
    const unsigned short* wm = wtb + (size_t)m * 4096;
    f32x4 acc[2][4];
#pragma unroll
    for (int et = 0; et < 2; ++et)
#pragma unroll
      for (int nf = 0; nf < 4; ++nf) acc[et][nf] = zero;
#pragma unroll
    for (int nf = 0; nf < 4; ++nf) {
      const unsigned short* ar = wm + (size_t)(nf * 16 + er) * 64 + q * 8;
      const bf16x8 a0 = *(const bf16x8*)ar;
      const bf16x8 a1 = *(const bf16x8*)(ar + 32);
#pragma unroll
      for (int et = 0; et < 2; ++et) {
        acc[et][nf] = __builtin_amdgcn_mfma_f32_16x16x32_bf16(a0, zf[et][0], acc[et][nf], 0, 0, 0);
        acc[et][nf] = __builtin_amdgcn_mfma_f32_16x16x32_bf16(a1, zf[et][1], acc[et][nf], 0, 0, 0);
      }
    }
    const int hd = m >> 2, which = m & 3;    // wave-uniform
#pragma unroll
    for (int et = 0; et < 2; ++et) {
      const size_t rec = (size_t)(e0 + et * 16) * 4 + hd;
      unsigned* dst = (which == 0) ? (ksep + rec * 16)
                    : (which == 1) ? (vsep + rec * 16)
                    : (which == 2) ? (qho + rec * 16)
                                   : (gf8 + rec * 16);
      unsigned pk[4];
      if (which == 3) {
#pragma unroll
        for (int nf = 0; nf < 4; ++nf) {
          const float4 b4 = *(const float4*)(bg + hd * 64 + nf * 16 + q * 4);
          pk[nf] = packf8_4(fsig(acc[et][nf].x + b4.x), fsig(acc[et][nf].y + b4.y),
                            fsig(acc[et][nf].z + b4.z), fsig(acc[et][nf].w + b4.w));
        }
      } else {
#pragma unroll
        for (int nf = 0; nf < 4; ++nf)
          pk[nf] = packf8_4(acc[et][nf].x, acc[et][nf].y,
                            acc[et][nf].z, acc[et][nf].w);
      }
      *(uint4*)(dst + q * 4) = make_uint4(pk[0], pk[1], pk[2], pk[3]);
    }
  }
}

// ---------- attention: flat grid, lane quad = 4 heads of one edge ----------
// K/V deinterleaved: quad gather = 256B fully-used contiguous.
// ho stored BF16 split across qho (pos 0..31) + gf8 (pos 32..63) records (both dead).
__global__ void __launch_bounds__(256)
k_attn(unsigned* __restrict__ qho, unsigned* __restrict__ gf8,
       const unsigned* __restrict__ ksep, const unsigned* __restrict__ vsep,
       const float* __restrict__ be, const int* __restrict__ klist) {
  const int t = blockIdx.x * 256 + threadIdx.x;
  const int e = t >> 2, hd = t & 3;

  // q (fp8 -> fp32, position order; same permutation as K -> dot invariant)
  float q[64];
  {
    unsigned qp[16];
    ldrow16(qho + (size_t)t * 16, qp);
    unpackf8(qp, q);
  }

  int i2[8], j2[8];
#pragma unroll
  for (int kn = 0; kn < 8; ++kn) {
    i2[kn] = klist[(size_t)e * 16 + kn];
    j2[kn] = klist[(size_t)e * 16 + 8 + kn];
  }
  float bv[8];
#pragma unroll
  for (int kn = 0; kn < 8; ++kn)
    bv[kn] = be[(size_t)((i2[kn] < 0) ? 0 : j2[kn]) * 4 + hd];

  const uint4* k4 = (const uint4*)ksep;   // 4 uint4 per record
  float alpha[8];
#pragma unroll 2
  for (int kn = 0; kn < 8; ++kn) {
    if (i2[kn] < 0) { alpha[kn] = -10000.0f; continue; }
    const uint4* kr = k4 + ((size_t)i2[kn] * 4 + hd) * 4;
    uint4 u0 = kr[0], u1 = kr[1], u2 = kr[2], u3 = kr[3];
    float d = 0.f;
    d = dot16(u0, q,      d);
    d = dot16(u1, q + 16, d);
    d = dot16(u2, q + 32, d);
    d = dot16(u3, q + 48, d);
    alpha[kn] = d * 0.125f + bv[kn];
  }
  float mx = alpha[0];
#pragma unroll
  for (int kn = 1; kn < 8; ++kn) mx = fmaxf(mx, alpha[kn]);
  float p[8], s = 0.f;
#pragma unroll
  for (int kn = 0; kn < 8; ++kn) { p[kn] = __expf(alpha[kn] - mx); s += p[kn]; }
  float is = 1.0f / s;
#pragma unroll
  for (int kn = 0; kn < 8; ++kn) p[kn] *= is;

  float ov[64];
#pragma unroll
  for (int j = 0; j < 64; ++j) ov[j] = 0.f;
  const uint4* v4 = (const uint4*)vsep;
#pragma unroll 2
  for (int kn = 0; kn < 8; ++kn) {
    int vi = (i2[kn] < 0) ? (NE - 1) : i2[kn];   // jax v[-1] wraps
    const uint4* vr = v4 + ((size_t)vi * 4 + hd) * 4;
    uint4 u0 = vr[0], u1 = vr[1], u2 = vr[2], u3 = vr[3];
    const float pk = p[kn];
    acc16(u0, pk, ov +  0);
    acc16(u1, pk, ov + 16);
    acc16(u2, pk, ov + 32);
    acc16(u3, pk, ov + 48);
  }
  // gate (precomputed sigmoid, fp8; same position permutation)
  {
    unsigned gp[16];
    ldrow16(gf8 + (size_t)t * 16, gp);
    float g[64];
    unpackf8(gp, g);
#pragma unroll
    for (int j = 0; j < 64; ++j) ov[j] *= g[j];
  }
  // ho bf16 in position order: pos 0..31 -> qho rec, 32..63 -> gf8 rec
  {
    unsigned* qr = qho + (size_t)t * 16;
    unsigned* gr = gf8 + (size_t)t * 16;
#pragma unroll
    for (int t2 = 0; t2 < 2; ++t2) {
      ((uint4*)qr)[t2] = make_uint4(pack2(ov[8*t2+0],  ov[8*t2+1]),  pack2(ov[8*t2+2],  ov[8*t2+3]),
                                    pack2(ov[8*t2+4],  ov[8*t2+5]),  pack2(ov[8*t2+6],  ov[8*t2+7]));
      ((uint4*)qr)[2+t2] = make_uint4(pack2(ov[16+8*t2+0], ov[16+8*t2+1]), pack2(ov[16+8*t2+2], ov[16+8*t2+3]),
                                      pack2(ov[16+8*t2+4], ov[16+8*t2+5]), pack2(ov[16+8*t2+6], ov[16+8*t2+7]));
      ((uint4*)gr)[t2] = make_uint4(pack2(ov[32+8*t2+0], ov[32+8*t2+1]), pack2(ov[32+8*t2+2], ov[32+8*t2+3]),
                                    pack2(ov[32+8*t2+4], ov[32+8*t2+5]), pack2(ov[32+8*t2+6], ov[32+8*t2+7]));
      ((uint4*)gr)[2+t2] = make_uint4(pack2(ov[48+8*t2+0], ov[48+8*t2+1]), pack2(ov[48+8*t2+2], ov[48+8*t2+3]),
                                      pack2(ov[48+8*t2+4], ov[48+8*t2+5]), pack2(ov[48+8*t2+6], ov[48+8*t2+7]));
    }
  }
}

// ---------- output projection via MFMA: m[e] = sum_hd ho_hd @ Wout_hd ----------
// ho bf16 positions; Wout^T (chan-permuted k) at wtb[19+hd]. C chained over heads.
__global__ void __launch_bounds__(256)
k_mout(const unsigned* __restrict__ qho, const unsigned* __restrict__ gf8,
       const unsigned short* __restrict__ wtb, float* __restrict__ medge) {
  const int lane = threadIdx.x & 63;
  const int wid  = threadIdx.x >> 6;
  const int er   = lane & 15;
  const int q    = lane >> 4;
  const int e0   = blockIdx.x * 256 + wid * 64 + er;

  const f32x4 zero = {0.f, 0.f, 0.f, 0.f};
  f32x4 acc[4][4];
#pragma unroll
  for (int et = 0; et < 4; ++et)
#pragma unroll
    for (int nf = 0; nf < 4; ++nf) acc[et][nf] = zero;

#pragma unroll 1
  for (int hd = 0; hd < 4; ++hd) {
    const unsigned short* wm = wtb + (size_t)(19 + hd) * 4096;
    bf16x8 hf[4][2];
#pragma unroll
    for (int et = 0; et < 4; ++et) {
      const size_t rec = (size_t)(e0 + et * 16) * 4 + hd;
      hf[et][0] = __builtin_bit_cast(bf16x8, *(const uint4*)(qho + rec * 16 + q * 4));
      hf[et][1] = __builtin_bit_cast(bf16x8, *(const uint4*)(gf8 + rec * 16 + q * 4));
    }
#pragma unroll
    for (int nf = 0; nf < 4; ++nf) {
      const unsigned short* ar = wm + (size_t)(nf * 16 + er) * 64 + q * 8;
      const bf16x8 a0 = *(const bf16x8*)ar;
      const bf16x8 a1 = *(const bf16x8*)(ar + 32);
#pragma unroll
      for (int et = 0; et < 4; ++et) {
        acc[et][nf] = __builtin_amdgcn_mfma_f32_16x16x32_bf16(a0, hf[et][0], acc[et][nf], 0, 0, 0);
        acc[et][nf] = __builtin_amdgcn_mfma_f32_16x16x32_bf16(a1, hf[et][1], acc[et][nf], 0, 0, 0);
      }
    }
  }
#pragma unroll
  for (int et = 0; et < 4; ++et)
#pragma unroll
    for (int nf = 0; nf < 4; ++nf)
      *(float4*)(medge + (size_t)(e0 + et * 16) * 64 + nf * 16 + q * 4) =
          make_float4(acc[et][nf].x, acc[et][nf].y, acc[et][nf].z, acc[et][nf].w);
}

// ---------- CSR gather: per-node segment sum of medge ----------
__global__ void __launch_bounds__(256)
k_nodesum(const float* __restrict__ medge, const int* __restrict__ ioffs,
          const int* __restrict__ eidx, float* __restrict__ m_sum) {
  const int wid = threadIdx.x >> 6, lane = threadIdx.x & 63;
  const int n = blockIdx.x * 4 + wid;
  if (n >= NN) return;
  const int beg = ioffs[n], end = ioffs[n + 1];
  float acc = 0.f;
  for (int i = beg; i < end; ++i) {
    int e = eidx[i];
    acc += medge[(size_t)e * 64 + lane];
  }
  m_sum[(size_t)n * 64 + lane] = acc;
}

// ---------- final node update via MFMA: wave = 16 nodes ----------
__global__ void __launch_bounds__(256)
k_finm(const float* __restrict__ h, const float* __restrict__ na,
       const float* __restrict__ coord, const float* __restrict__ icoord,
       const float* __restrict__ m_sum, const float* __restrict__ x_sum,
       const float* __restrict__ cntf, const float* __restrict__ bout,
       const unsigned short* __restrict__ wtb,
       const float* __restrict__ bh1, const float* __restrict__ bh2,
       float* __restrict__ out) {
  __shared__ float lt[4][16][68];   // +4 pad breaks er*64 bank alias
  const int lane = threadIdx.x & 63;
  const int wid  = threadIdx.x >> 6;
  const int er   = lane & 15;
  const int q    = lane >> 4;
  const int e    = blockIdx.x * 64 + wid * 16 + er;
  const bool valid = e < NN;
  const int el = valid ? e : 0;

  const float* hr = h + (size_t)el * 64;
  const float* nr = na + (size_t)el * 64;
  const float* mr = m_sum + (size_t)el * 64;
  const float cn = cntf[el];
  const float invc = 1.0f / fmaxf(cn, 1.0f);
  const float bsc = (cn > 0.f) ? 1.0f : 0.0f;   // empty segment => m_agg = 0

  // B-frags: h, na, m_agg k-slices (bf16)
  bf16x8 hf[2], naf[2], mf[2];
  hf[0]  = packrow8(hr + q * 8); hf[1]  = packrow8(hr + 32 + q * 8);
  naf[0] = packrow8(nr + q * 8); naf[1] = packrow8(nr + 32 + q * 8);
#pragma unroll
  for (int half = 0; half < 2; ++half) {
    const int o = half * 32 + q * 8;
    const float4 m0 = *(const float4*)(mr + o);
    const float4 m1 = *(const float4*)(mr + o + 4);
    const float4 b0 = *(const float4*)(bout + o);
    const float4 b1 = *(const float4*)(bout + o + 4);
    float ma[8];
    ma[0] = fmaf(m0.x, invc, b0.x * bsc); ma[1] = fmaf(m0.y, invc, b0.y * bsc);
    ma[2] = fmaf(m0.z, invc, b0.z * bsc); ma[3] = fmaf(m0.w, invc, b0.w * bsc);
    ma[4] = fmaf(m1.x, invc, b1.x * bsc); ma[5] = fmaf(m1.y, invc, b1.y * bsc);
    ma[6] = fmaf(m1.z, invc, b1.z * bsc); ma[7] = fmaf(m1.w, invc, b1.w * bsc);
    uint4 u = make_uint4(pack2(ma[0], ma[1]), pack2(ma[2], ma[3]),
                         pack2(ma[4], ma[5]), pack2(ma[6], ma[7]));
    mf[half] = __builtin_bit_cast(bf16x8, u);
  }

  const f32x4 zero = {0.f, 0.f, 0.f, 0.f};
  f32x4 acc[4] = {zero, zero, zero, zero};
  mm4(wtb + (size_t)23 * 4096, er, q, hf,  acc);
  mm4(wtb + (size_t)24 * 4096, er, q, naf, acc);
  mm4(wtb + (size_t)25 * 4096, er, q, mf,  acc);
#pragma unroll
  for (int nf = 0; nf < 4; ++nf) {
    const float4 b4 = *(const float4*)(bh1 + nf * 16 + q * 4);
    float* d = &lt[wid][er][nf * 16 + q * 4];
    d[0] = fsilu(acc[nf].x + b4.x); d[1] = fsilu(acc[nf].y + b4.y);
    d[2] = fsilu(acc[nf].z + b4.z); d[3] = fsilu(acc[nf].w + b4.w);
  }
  __syncthreads();
  bf16x8 sf[2];
  sf[0] = packrow8(&lt[wid][er][q * 8]);
  sf[1] = packrow8(&lt[wid][er][32 + q * 8]);
  f32x4 a2[4] = {zero, zero, zero, zero};
  mm4(wtb + (size_t)26 * 4096, er, q, sf, a2);
  if (valid) {
#pragma unroll
    for (int nf = 0; nf < 4; ++nf) {
      const float4 b4 = *(const float4*)(bh2 + nf * 16 + q * 4);
      const float4 h4 = *(const float4*)(hr + nf * 16 + q * 4);
      *(float4*)(out + (size_t)e * 64 + nf * 16 + q * 4) =
          make_float4(a2[nf].x + b4.x + h4.x, a2[nf].y + b4.y + h4.y,
                      a2[nf].z + b4.z + h4.z, a2[nf].w + b4.w + h4.w);
    }
    if (q == 0) {
#pragma unroll
      for (int d = 0; d < 3; ++d)
        out[(size_t)NN * 64 + e * 3 + d] =
            0.2f * icoord[e * 3 + d] + 0.8f * coord[e * 3 + d] + x_sum[e * 3 + d] * invc;
    }
  }
}

extern "C" void kernel_launch(void* const* d_in, const int* in_sizes, int n_in,
                              void* d_out, int out_size, void* d_ws, size_t ws_size,
                              hipStream_t stream) {
  (void)in_sizes; (void)n_in; (void)out_size; (void)ws_size;
  const float* h      = (const float*)d_in[0];
  const float* coord  = (const float*)d_in[1];
  const int*   edges  = (const int*)  d_in[2];
  const float* nvecs  = (const float*)d_in[3];
  const float* ea     = (const float*)d_in[4];
  const float* na     = (const float*)d_in[5];
  const float* icoord = (const float*)d_in[6];
  const int*   klist  = (const int*)  d_in[7];
  const float* w_chem1 = (const float*)d_in[8];
  const float* b_chem1 = (const float*)d_in[9];
  const float* w_chem2 = (const float*)d_in[10];
  const float* b_chem2 = (const float*)d_in[11];
  const float* w_pos1  = (const float*)d_in[12];
  const float* b_pos1  = (const float*)d_in[13];
  const float* w_pos2  = (const float*)d_in[14];
  const float* b_pos2  = (const float*)d_in[15];
  const float* w_sh    = (const float*)d_in[16];
  const float* b_sh    = (const float*)d_in[17];
  const float* w_att   = (const float*)d_in[18];
  const float* b_att   = (const float*)d_in[19];
  const float* wq      = (const float*)d_in[20];
  const float* wk      = (const float*)d_in[21];
  const float* wv      = (const float*)d_in[22];
  const float* wb      = (const float*)d_in[23];
  const float* wg      = (const float*)d_in[24];
  const float* bg      = (const float*)d_in[25];
  const float* w_out   = (const float*)d_in[26];
  const float* b_out   = (const float*)d_in[27];
  const float* wu1     = (const float*)d_in[28];
  const float* bu1     = (const float*)d_in[29];
  const float* wu2     = (const float*)d_in[30];
  const float* bu2     = (const float*)d_in[31];
  const float* wx1     = (const float*)d_in[32];
  const float* bx1     = (const float*)d_in[33];
  const float* wx2     = (const float*)d_in[34];
  const float* bx2     = (const float*)d_in[35];
  const float* wh1     = (const float*)d_in[36];
  const float* bh1     = (const float*)d_in[37];
  const float* wh2     = (const float*)d_in[38];
  const float* bh2     = (const float*)d_in[39];

  float* out = (float*)d_out;
  float* ws  = (float*)d_ws;
  // Phase-reused regions (NE*64 floats each):
  //  R1: act1c -> ksep [NE*4][64B] fp8 K -> medge after attn
  //  R2: act1p -> vsep [NE*4][64B] fp8 V
  //  R3: qho  [NE*4][16u] fp8 q -> ho bf16 low-half after attn
  //  R4: gf8  [NE*4][16u] fp8 gate -> ho bf16 high-half after attn
  float* R1 = ws;
  float* R2 = R1 + (size_t)NE * 64;
  float* R3 = R2 + (size_t)NE * 64;
  float* R4 = R3 + (size_t)NE * 64;
  float* zbf   = R4 + (size_t)NE * 64;      // NE*32 floats (bf16 gated z)
  float* x_sum = zbf + (size_t)NE * 32;     // NN*3 (zeroed)
  float* cntf  = x_sum + (size_t)NN * 3;    // NN (zeroed)
  int*   icnt  = (int*)(cntf + NN);         // NN (zeroed)
  int*   icur  = icnt + NN;                 // NN (zeroed)
  float* m_sum = (float*)(icur + NN);       // NN*64
  float* be    = m_sum + (size_t)NN * 64;   // 4*NE  ([e*4+hd] layout)
  unsigned short* wtb = (unsigned short*)(be + (size_t)4 * NE);  // 34*64*64 bf16 (278KB)
  int*   ioffs = (int*)(wtb + 34 * 4096);   // NN+1
  int*   eidx  = ioffs + (NN + 1);          // NE

  unsigned* ksep = (unsigned*)R1;  // [NE*4][16u] fp8 K (deinterleaved, pos-permuted)
  unsigned* vsep = (unsigned*)R2;  // [NE*4][16u] fp8 V
  unsigned* qho  = (unsigned*)R3;  // [NE*4][16u] fp8 q -> bf16 ho lo
  unsigned* gf8  = (unsigned*)R4;  // [NE*4][16u] fp8 gate -> bf16 ho hi
  unsigned* zb   = (unsigned*)zbf;
  float* medge = R1;               // after attention (ksep dead)

  (void)hipMemsetAsync(x_sum, 0, ((size_t)NN * 3 + NN + NN + NN) * sizeof(float), stream);

  dim3 b256(256);
  dim3 gflat(NE / 256);

  // weight prep + CSR build (independent of the MLP pipeline)
  k_wprep<<<dim3(34), b256, 0, stream>>>(wk, wv, wq, wg, w_sh, wu1, wx1, w_out,
                                         wh1, wh2, w_chem2, w_pos2, w_chem1, wtb);
  k_count<<<gflat, b256, 0, stream>>>(edges, icnt);
  k_scan <<<dim3(1), b256, 0, stream>>>(icnt, ioffs);
  k_fill <<<gflat, b256, 0, stream>>>(edges, ioffs, icur, eidx);

  k_chem1m<<<dim3(NE / 64), b256, 0, stream>>>(h, na, ea, edges, wtb, b_chem1, R1);
  k_pos1  <<<dim3(NE / 256, 2), b256, 0, stream>>>(coord, nvecs, ea, edges, w_pos1, b_pos1, R2);
  k_l2s   <<<dim3(NE / 64), b256, 0, stream>>>(coord, edges, R1, R2, wtb,
                                               b_chem2, b_pos2, b_sh, w_att, b_att,
                                               bu1, wu2, bu2, bx1, wx2, bx2, wb,
                                               zb, be, x_sum, cntf);
  k_projm<<<dim3(NE / 128), b256, 0, stream>>>(zb, wtb, bg, ksep, vsep, qho, gf8);
  k_attn <<<dim3(NE * 4 / 256), b256, 0, stream>>>(qho, gf8, ksep, vsep, be, klist);
  k_mout <<<dim3(NE / 256), b256, 0, stream>>>(qho, gf8, wtb, medge);
  k_nodesum<<<dim3((NN + 3) / 4), b256, 0, stream>>>(medge, ioffs, eidx, m_sum);
  k_finm<<<dim3((NN + 63) / 64), b256, 0, stream>>>(h, na, coord, icoord, m_sum, x_sum,
                                                    cntf, b_out, wtb, bh1, bh2, out);
}

// Round 9
// 629.650 us; speedup vs baseline: 2.3003x; 1.0193x over previous
//
#include <hip/hip_runtime.h>
#include <math.h>

#define NE 160000
#define NN 10000

#define DEV __device__ __forceinline__

typedef float v2f __attribute__((ext_vector_type(2)));
typedef __attribute__((ext_vector_type(8))) short bf16x8;   // 8 bf16 (4 VGPRs)
typedef __attribute__((ext_vector_type(4))) float f32x4;

DEV float fsilu(float x) { return x / (1.0f + __expf(-x)); }
DEV float fsig(float x)  { return 1.0f / (1.0f + __expf(-x)); }

// ---- bf16 pack/unpack helpers (RNE) ----
DEV unsigned pack2(float a, float b) {
  unsigned ua = __float_as_uint(a); ua += 0x7FFFu + ((ua >> 16) & 1u);
  unsigned ub = __float_as_uint(b); ub += 0x7FFFu + ((ub >> 16) & 1u);
  return (ua >> 16) | (ub & 0xFFFF0000u);
}

// ---- fp8 e4m3 (OCP, HW-converted) ----
DEV unsigned packf8_4(float a, float b, float c, float d) {
  int r = __builtin_amdgcn_cvt_pk_fp8_f32(a, b, 0, false);
  r = __builtin_amdgcn_cvt_pk_fp8_f32(c, d, r, true);
  return (unsigned)r;
}
template<bool HI>
DEV v2f up2(unsigned u) { return __builtin_amdgcn_cvt_pk_f32_fp8((int)u, HI); }

// dot of 16 fp8 values (one uint4) against q[0..16)
DEV float dot16(uint4 u, const float* q, float d) {
  v2f f;
  f = up2<false>(u.x); d = fmaf(f.x, q[0],  d); d = fmaf(f.y, q[1],  d);
  f = up2<true >(u.x); d = fmaf(f.x, q[2],  d); d = fmaf(f.y, q[3],  d);
  f = up2<false>(u.y); d = fmaf(f.x, q[4],  d); d = fmaf(f.y, q[5],  d);
  f = up2<true >(u.y); d = fmaf(f.x, q[6],  d); d = fmaf(f.y, q[7],  d);
  f = up2<false>(u.z); d = fmaf(f.x, q[8],  d); d = fmaf(f.y, q[9],  d);
  f = up2<true >(u.z); d = fmaf(f.x, q[10], d); d = fmaf(f.y, q[11], d);
  f = up2<false>(u.w); d = fmaf(f.x, q[12], d); d = fmaf(f.y, q[13], d);
  f = up2<true >(u.w); d = fmaf(f.x, q[14], d); d = fmaf(f.y, q[15], d);
  return d;
}
// o[0..16) += pk * fp8x16(u)
DEV void acc16(uint4 u, float pk, float* o) {
  v2f f;
  f = up2<false>(u.x); o[0]  = fmaf(pk, f.x, o[0]);  o[1]  = fmaf(pk, f.y, o[1]);
  f = up2<true >(u.x); o[2]  = fmaf(pk, f.x, o[2]);  o[3]  = fmaf(pk, f.y, o[3]);
  f = up2<false>(u.y); o[4]  = fmaf(pk, f.x, o[4]);  o[5]  = fmaf(pk, f.y, o[5]);
  f = up2<true >(u.y); o[6]  = fmaf(pk, f.x, o[6]);  o[7]  = fmaf(pk, f.y, o[7]);
  f = up2<false>(u.z); o[8]  = fmaf(pk, f.x, o[8]);  o[9]  = fmaf(pk, f.y, o[9]);
  f = up2<true >(u.z); o[10] = fmaf(pk, f.x, o[10]); o[11] = fmaf(pk, f.y, o[11]);
  f = up2<false>(u.w); o[12] = fmaf(pk, f.x, o[12]); o[13] = fmaf(pk, f.y, o[13]);
  f = up2<true >(u.w); o[14] = fmaf(pk, f.x, o[14]); o[15] = fmaf(pk, f.y, o[15]);
}

DEV void ldrow16(const unsigned* __restrict__ p, unsigned (&r)[16]) {
#pragma unroll
  for (int t = 0; t < 4; ++t) {
    uint4 u = ((const uint4*)p)[t];
    r[4*t] = u.x; r[4*t+1] = u.y; r[4*t+2] = u.z; r[4*t+3] = u.w;
  }
}
DEV void unpackf8(const unsigned (&p)[16], float (&o)[64]) {
#pragma unroll
  for (int t = 0; t < 16; ++t) {
    v2f f0 = up2<false>(p[t]);
    v2f f1 = up2<true >(p[t]);
    o[4*t+0] = f0.x; o[4*t+1] = f0.y; o[4*t+2] = f1.x; o[4*t+3] = f1.y;
  }
}
DEV void store32(float* dst, const float (&a)[32]) {
#pragma unroll
  for (int j = 0; j < 32; j += 4)
    *(float4*)(dst + j) = make_float4(a[j], a[j+1], a[j+2], a[j+3]);
}

// pack 8 consecutive fp32 -> bf16x8 (B-fragment k-slice)
DEV bf16x8 packrow8(const float* __restrict__ p) {
  float4 a = *(const float4*)p;
  float4 b = *(const float4*)(p + 4);
  uint4 u = make_uint4(pack2(a.x, a.y), pack2(a.z, a.w),
                       pack2(b.x, b.y), pack2(b.z, b.w));
  return __builtin_bit_cast(bf16x8, u);
}

// 16x16x32 GEMM over K=64: acc[nf] (n = nf*16 + q*4 + reg), A from wtb matrix wm
DEV void mm4(const unsigned short* __restrict__ wm, int er, int q,
             const bf16x8 (&bfr)[2], f32x4 (&acc)[4]) {
#pragma unroll
  for (int nf = 0; nf < 4; ++nf) {
    const unsigned short* ar = wm + (size_t)(nf * 16 + er) * 64 + q * 8;
    const bf16x8 a0 = *(const bf16x8*)ar;
    const bf16x8 a1 = *(const bf16x8*)(ar + 32);
    acc[nf] = __builtin_amdgcn_mfma_f32_16x16x32_bf16(a0, bfr[0], acc[nf], 0, 0, 0);
    acc[nf] = __builtin_amdgcn_mfma_f32_16x16x32_bf16(a1, bfr[1], acc[nf], 0, 0, 0);
  }
}

// ---------- CSR build over edges[0] (rows) ----------
__global__ void __launch_bounds__(256)
k_count(const int* __restrict__ edges, int* __restrict__ icnt) {
  int e = blockIdx.x * 256 + threadIdx.x;
  if (e < NE) atomicAdd(&icnt[edges[e]], 1);
}

__global__ void __launch_bounds__(256)
k_scan(const int* __restrict__ icnt, int* __restrict__ ioffs) {
  __shared__ int part[256];
  const int t = threadIdx.x;
  const int base = t * 40;
  int loc[40];
  int s = 0;
#pragma unroll
  for (int i = 0; i < 40; ++i) {
    int idx = base + i;
    int v = (idx < NN) ? icnt[idx] : 0;
    loc[i] = v; s += v;
  }
  part[t] = s;
  __syncthreads();
  for (int off = 1; off < 256; off <<= 1) {
    int v = (t >= off) ? part[t - off] : 0;
    __syncthreads();
    part[t] += v;
    __syncthreads();
  }
  int run = (t == 0) ? 0 : part[t - 1];
#pragma unroll
  for (int i = 0; i < 40; ++i) {
    int idx = base + i;
    if (idx < NN) { ioffs[idx] = run; run += loc[i]; }
  }
  if (t == 255) ioffs[NN] = NE;
}

__global__ void __launch_bounds__(256)
k_fill(const int* __restrict__ edges, const int* __restrict__ ioffs,
       int* __restrict__ icur, int* __restrict__ eidx) {
  int e = blockIdx.x * 256 + threadIdx.x;
  if (e >= NE) return;
  int r = edges[e];
  int p = atomicAdd(&icur[r], 1);
  eidx[ioffs[r] + p] = e;
}

// ---------- chem layer 1 via MFMA: 272 -> 64 silu; wave = 16 edges ----------
// 4 full K=64 slices (h[r],h[c],na[r],na[c]) + zero-padded K=16 edge-attr slice.
__global__ void __launch_bounds__(256)
k_chem1m(const float* __restrict__ h, const float* __restrict__ na,
         const float* __restrict__ ea, const int* __restrict__ edges,
         const unsigned short* __restrict__ wtb, const float* __restrict__ b1,
         float* __restrict__ act1c) {
  const int lane = threadIdx.x & 63;
  const int wid  = threadIdx.x >> 6;
  const int er   = lane & 15;
  const int q    = lane >> 4;
  const int e    = blockIdx.x * 64 + wid * 16 + er;
  const int r = edges[e], c = edges[NE + e];

  const f32x4 zero = {0.f, 0.f, 0.f, 0.f};
  f32x4 acc[4] = {zero, zero, zero, zero};
  bf16x8 f[2];
  const float* xr;
  xr = h  + (size_t)r * 64; f[0] = packrow8(xr + q * 8); f[1] = packrow8(xr + 32 + q * 8);
  mm4(wtb + (size_t)29 * 4096, er, q, f, acc);
  xr = h  + (size_t)c * 64; f[0] = packrow8(xr + q * 8); f[1] = packrow8(xr + 32 + q * 8);
  mm4(wtb + (size_t)30 * 4096, er, q, f, acc);
  xr = na + (size_t)r * 64; f[0] = packrow8(xr + q * 8); f[1] = packrow8(xr + 32 + q * 8);
  mm4(wtb + (size_t)31 * 4096, er, q, f, acc);
  xr = na + (size_t)c * 64; f[0] = packrow8(xr + q * 8); f[1] = packrow8(xr + 32 + q * 8);
  mm4(wtb + (size_t)32 * 4096, er, q, f, acc);
  // edge-attr slice: real B for k<16 (q=0,1), zero B elsewhere; half-2 skipped.
  {
    bf16x8 ef;
    if (q < 2) ef = packrow8(ea + (size_t)e * 16 + q * 8);
    else { uint4 z4 = make_uint4(0, 0, 0, 0); ef = __builtin_bit_cast(bf16x8, z4); }
    const unsigned short* wm = wtb + (size_t)33 * 4096;
#pragma unroll
    for (int nf = 0; nf < 4; ++nf) {
      const bf16x8 a0 = *(const bf16x8*)(wm + (size_t)(nf * 16 + er) * 64 + q * 8);
      acc[nf] = __builtin_amdgcn_mfma_f32_16x16x32_bf16(a0, ef, acc[nf], 0, 0, 0);
    }
  }
#pragma unroll
  for (int nf = 0; nf < 4; ++nf) {
    const float4 b4 = *(const float4*)(b1 + nf * 16 + q * 4);
    *(float4*)(act1c + (size_t)e * 64 + nf * 16 + q * 4) =
        make_float4(fsilu(acc[nf].x + b4.x), fsilu(acc[nf].y + b4.y),
                    fsilu(acc[nf].z + b4.z), fsilu(acc[nf].w + b4.w));
  }
}

// ---------- pos layer 1: 36 -> 64 silu ----------
__global__ void __launch_bounds__(256)
k_pos1(const float* __restrict__ coord, const float* __restrict__ nv,
       const float* __restrict__ ea, const int* __restrict__ edges,
       const float* __restrict__ w1, const float* __restrict__ b1,
       float* __restrict__ act1p) {
  const int e = blockIdx.x * 256 + threadIdx.x;
  const int co = blockIdx.y * 32;
  const int r = edges[e], c = edges[NE + e];

  float dx = coord[r * 3 + 0] - coord[c * 3 + 0];
  float dy = coord[r * 3 + 1] - coord[c * 3 + 1];
  float dz = coord[r * 3 + 2] - coord[c * 3 + 2];
  float nrm = sqrtf(dx * dx + dy * dy + dz * dz);
  float inv = 1.0f / (nrm + 1e-8f);
  dx *= inv; dy *= inv; dz *= inv;
  float ir = dx * dx + dy * dy + dz * dz;

  float in[36];
#pragma unroll
  for (int v = 0; v < 5; ++v) {
    float s = 0.f;
#pragma unroll
    for (int d = 0; d < 3; ++d)
      s += nv[(size_t)r * 15 + v * 3 + d] * nv[(size_t)c * 15 + v * 3 + d];
    in[v] = s;
  }
  {
    float cexp = -0.5f;
#pragma unroll
    for (int k = 0; k < 15; ++k) { in[5 + k] = __expf(ir * cexp); cexp *= (1.0f / 2.25f); }
  }
#pragma unroll
  for (int k = 0; k < 16; k += 4) {
    float4 e4 = *(const float4*)(ea + (size_t)e * 16 + k);
    in[20 + k] = e4.x; in[21 + k] = e4.y; in[22 + k] = e4.z; in[23 + k] = e4.w;
  }

  float acc[32];
#pragma unroll
  for (int j = 0; j < 32; ++j) acc[j] = b1[co + j];
#pragma unroll
  for (int k = 0; k < 36; ++k) {
    const float x = in[k];
    const float* wr = w1 + (size_t)k * 64 + co;
#pragma unroll
    for (int j = 0; j < 32; ++j) acc[j] = fmaf(x, wr[j], acc[j]);
  }
#pragma unroll
  for (int j = 0; j < 32; ++j) acc[j] = fsilu(acc[j]);
  store32(act1p + (size_t)e * 64 + co, acc);
}

// ---------- weight prep: wtb[m][n][k] = W_m[k][n] in bf16 (A-operand layout) ----------
// 0..15: hd*4+which (k,v,q,g); 16..18: wsh,wu1,wx1; 19..22: w_out/hd (chan-permuted k);
// 23..25: wh1 slices; 26: wh2; 27: w_chem2; 28: w_pos2; 29..32: w_chem1; 33: ea-slice
// chan(kk) maps fp8-record byte position -> original channel (record uint idx = q*4+nf).
__global__ void __launch_bounds__(256)
k_wprep(const float* __restrict__ wk, const float* __restrict__ wv,
        const float* __restrict__ wq, const float* __restrict__ wg,
        const float* __restrict__ wsh, const float* __restrict__ wu1,
        const float* __restrict__ wx1, const float* __restrict__ wout,
        const float* __restrict__ wh1, const float* __restrict__ wh2,
        const float* __restrict__ w2c, const float* __restrict__ w2p,
        const float* __restrict__ wc1,
        unsigned short* __restrict__ wtb) {
  const int m = blockIdx.x;          // 0..33
  const float* src;
  bool pad16 = false, permk = false;
  if (m < 16) {
    const int hd = m >> 2, which = m & 3;
    src = ((which == 0) ? wk : (which == 1) ? wv : (which == 2) ? wq : wg)
          + (size_t)hd * 4096;
  } else if (m < 19) {
    src = (m == 16) ? wsh : (m == 17) ? wu1 : wx1;
  } else if (m < 23) {
    src = wout + (size_t)(m - 19) * 4096;
    permk = true;                    // ho consumed in record-position order
  } else if (m < 26) {
    src = wh1 + (size_t)(m - 23) * 4096;
  } else if (m == 26) {
    src = wh2;
  } else if (m == 27) {
    src = w2c;
  } else if (m == 28) {
    src = w2p;
  } else if (m < 33) {
    src = wc1 + (size_t)(m - 29) * 4096;
  } else {
    src = wc1 + (size_t)4 * 4096;   // rows 256..271
    pad16 = true;
  }
  const int t = threadIdx.x;
#pragma unroll
  for (int i = 0; i < 16; ++i) {
    int idx = t * 16 + i;
    int n = idx >> 6, kk = idx & 63;
    int kr = permk ? (((kk >> 2) & 3) * 16 + (kk >> 4) * 4 + (kk & 3)) : kk;
    float v = (pad16 && kr >= 16) ? 0.f : src[kr * 64 + n];
    unsigned u = __float_as_uint(v);
    u += 0x7FFFu + ((u >> 16) & 1u);
    wtb[(size_t)m * 4096 + idx] = (unsigned short)(u >> 16);
  }
}

// ---------- fused layer-2 + scalars (MFMA): act1c/act1p -> zb/be/u/x ----------
// Wave = 16 edges. Layer-2 D-frags re-laid to k-slices via per-wave LDS tiles
// (same-wave ds ordering -> no barrier). posD is already in z's elementwise layout.
__global__ void __launch_bounds__(256)
k_l2s(const float* __restrict__ coord, const int* __restrict__ edges,
      const float* __restrict__ act1c, const float* __restrict__ act1p,
      const unsigned short* __restrict__ wtb,
      const float* __restrict__ b2c, const float* __restrict__ b2p,
      const float* __restrict__ bsh,
      const float* __restrict__ watt, const float* __restrict__ batt,
      const float* __restrict__ bu1, const float* __restrict__ wu2,
      const float* __restrict__ bu2,
      const float* __restrict__ bx1, const float* __restrict__ wx2,
      const float* __restrict__ bx2,
      const float* __restrict__ wb,
      unsigned* __restrict__ zb, float* __restrict__ be,
      float* __restrict__ x_sum, float* __restrict__ cntf) {
  __shared__ float ltc[4][16][68];   // +4 pad breaks er*64 bank alias
  __shared__ float ltp[4][16][68];
  const int lane = threadIdx.x & 63;
  const int wid  = threadIdx.x >> 6;
  const int er   = lane & 15;
  const int q    = lane >> 4;
  const int e    = blockIdx.x * 64 + wid * 16 + er;

  const f32x4 zero = {0.f, 0.f, 0.f, 0.f};
  bf16x8 f[2];

  // layer-2 chem: chemD = silu(act1c @ w2c + b2c)
  {
    const float* xr = act1c + (size_t)e * 64;
    f[0] = packrow8(xr + q * 8); f[1] = packrow8(xr + 32 + q * 8);
  }
  f32x4 cD[4] = {zero, zero, zero, zero};
  mm4(wtb + (size_t)27 * 4096, er, q, f, cD);
#pragma unroll
  for (int nf = 0; nf < 4; ++nf) {
    const float4 bc = *(const float4*)(b2c + nf * 16 + q * 4);
    *(float4*)&ltc[wid][er][nf * 16 + q * 4] =
        make_float4(fsilu(cD[nf].x + bc.x), fsilu(cD[nf].y + bc.y),
                    fsilu(cD[nf].z + bc.z), fsilu(cD[nf].w + bc.w));
  }
  // layer-2 pos: posD = silu(act1p @ w2p + b2p)  (kept in regs: z's elementwise layout)
  {
    const float* xr = act1p + (size_t)e * 64;
    f[0] = packrow8(xr + q * 8); f[1] = packrow8(xr + 32 + q * 8);
  }
  f32x4 pD[4] = {zero, zero, zero, zero};
  mm4(wtb + (size_t)28 * 4096, er, q, f, pD);
  float pv[16];
#pragma unroll
  for (int nf = 0; nf < 4; ++nf) {
    const float4 bp = *(const float4*)(b2p + nf * 16 + q * 4);
    pv[4*nf+0] = fsilu(pD[nf].x + bp.x); pv[4*nf+1] = fsilu(pD[nf].y + bp.y);
    pv[4*nf+2] = fsilu(pD[nf].z + bp.z); pv[4*nf+3] = fsilu(pD[nf].w + bp.w);
    *(float4*)&ltp[wid][er][nf * 16 + q * 4] =
        make_float4(pv[4*nf+0], pv[4*nf+1], pv[4*nf+2], pv[4*nf+3]);
  }
  // re-read as k-slice B-frags (per-wave-private tiles; same-wave ds order)
  bf16x8 cf[2], pf[2];
  cf[0] = packrow8(&ltc[wid][er][q * 8]); cf[1] = packrow8(&ltc[wid][er][32 + q * 8]);
  pf[0] = packrow8(&ltp[wid][er][q * 8]); pf[1] = packrow8(&ltp[wid][er][32 + q * 8]);

  // z = silu(chem @ wsh + bsh) * pos
  float z[16];
  {
    f32x4 acc[4] = {zero, zero, zero, zero};
    mm4(wtb + (size_t)16 * 4096, er, q, cf, acc);
#pragma unroll
    for (int nf = 0; nf < 4; ++nf) {
      const float4 b4 = *(const float4*)(bsh + nf * 16 + q * 4);
      z[4*nf+0] = fsilu(acc[nf].x + b4.x) * pv[4*nf+0];
      z[4*nf+1] = fsilu(acc[nf].y + b4.y) * pv[4*nf+1];
      z[4*nf+2] = fsilu(acc[nf].z + b4.z) * pv[4*nf+2];
      z[4*nf+3] = fsilu(acc[nf].w + b4.w) * pv[4*nf+3];
    }
  }
  // att gate
  {
    float ap = 0.f;
#pragma unroll
    for (int nf = 0; nf < 4; ++nf)
#pragma unroll
      for (int r = 0; r < 4; ++r)
        ap = fmaf(z[4*nf+r], watt[nf * 16 + q * 4 + r], ap);
    ap += __shfl_xor(ap, 16);
    ap += __shfl_xor(ap, 32);
    const float sg = fsig(ap + batt[0]);
#pragma unroll
    for (int j = 0; j < 16; ++j) z[j] *= sg;
  }
  // zb bf16 row (layout identical to original): uint idx = nf*8 + q*2
  {
    unsigned* zrow = zb + (size_t)e * 32 + q * 2;
#pragma unroll
    for (int nf = 0; nf < 4; ++nf) {
      uint2 w = make_uint2(pack2(z[4*nf+0], z[4*nf+1]), pack2(z[4*nf+2], z[4*nf+3]));
      *(uint2*)(zrow + nf * 8) = w;
    }
  }
  // per-head b scalars
  {
    float bb[4];
#pragma unroll
    for (int hd = 0; hd < 4; ++hd) {
      float b = 0.f;
#pragma unroll
      for (int nf = 0; nf < 4; ++nf)
#pragma unroll
        for (int r = 0; r < 4; ++r)
          b = fmaf(z[4*nf+r], wb[hd * 64 + nf * 16 + q * 4 + r], b);
      b += __shfl_xor(b, 16);
      b += __shfl_xor(b, 32);
      bb[hd] = b;
    }
    if (q == 0)
      *(float4*)(be + (size_t)e * 4) = make_float4(bb[0], bb[1], bb[2], bb[3]);
  }
  // u = silu(chem@wu1+bu1)@wu2 + bu2
  float u;
  {
    f32x4 acc[4] = {zero, zero, zero, zero};
    mm4(wtb + (size_t)17 * 4096, er, q, cf, acc);
    float up = 0.f;
#pragma unroll
    for (int nf = 0; nf < 4; ++nf) {
      const float4 b4 = *(const float4*)(bu1 + nf * 16 + q * 4);
      const float4 w4 = *(const float4*)(wu2 + nf * 16 + q * 4);
      up = fmaf(fsilu(acc[nf].x + b4.x), w4.x, up);
      up = fmaf(fsilu(acc[nf].y + b4.y), w4.y, up);
      up = fmaf(fsilu(acc[nf].z + b4.z), w4.z, up);
      up = fmaf(fsilu(acc[nf].w + b4.w), w4.w, up);
    }
    up += __shfl_xor(up, 16);
    up += __shfl_xor(up, 32);
    u = up + bu2[0];
  }
  // xs = silu(pos@wx1+bx1)@wx2 + bx2
  float xs;
  {
    f32x4 acc[4] = {zero, zero, zero, zero};
    mm4(wtb + (size_t)18 * 4096, er, q, pf, acc);
    float xp = 0.f;
#pragma unroll
    for (int nf = 0; nf < 4; ++nf) {
      const float4 b4 = *(const float4*)(bx1 + nf * 16 + q * 4);
      const float4 w4 = *(const float4*)(wx2 + nf * 16 + q * 4);
      xp = fmaf(fsilu(acc[nf].x + b4.x), w4.x, xp);
      xp = fmaf(fsilu(acc[nf].y + b4.y), w4.y, xp);
      xp = fmaf(fsilu(acc[nf].z + b4.z), w4.z, xp);
      xp = fmaf(fsilu(acc[nf].w + b4.w), w4.w, xp);
    }
    xp += __shfl_xor(xp, 16);
    xp += __shfl_xor(xp, 32);
    xs = xp + bx2[0];
  }

  if (q == 0) {
    const int r = edges[e], c = edges[NE + e];
    float dx = coord[r * 3 + 0] - coord[c * 3 + 0];
    float dy = coord[r * 3 + 1] - coord[c * 3 + 1];
    float dz = coord[r * 3 + 2] - coord[c * 3 + 2];
    float nrm = sqrtf(dx * dx + dy * dy + dz * dz);
    float inv = 1.0f / (nrm + 1e-8f);
    float t = u * xs;
    atomicAdd(&x_sum[r * 3 + 0], dx * inv * t);
    atomicAdd(&x_sum[r * 3 + 1], dy * inv * t);
    atomicAdd(&x_sum[r * 3 + 2], dz * inv * t);
    atomicAdd(&cntf[r], 1.0f);
  }
}

// ---------- MFMA projections -> ksep/vsep/qho/gf8 fp8, position-permuted records ----------
// Record uint idx = q*4+nf -> each lane stores one coalesced uint4 (1KB/wave-store).
// Permutation is shared by K/Q/V/gate/ho; only w_out (wtb 19..22) compensates (chan-perm).
// et=2 (32 edges/wave) doubles wave count for latency hiding.
__global__ void __launch_bounds__(256)
k_projm(const unsigned* __restrict__ zb, const unsigned short* __restrict__ wtb,
        const float* __restrict__ bg,
        unsigned* __restrict__ ksep, unsigned* __restrict__ vsep,
        unsigned* __restrict__ qho, unsigned* __restrict__ gf8) {
  const int lane = threadIdx.x & 63;
  const int wid  = threadIdx.x >> 6;        // wave 0..3
  const int er   = lane & 15;               // edge-in-tile (D col / B col / A row)
  const int q    = lane >> 4;               // k-block (A/B), row-quad (D)
  const int e0   = blockIdx.x * 128 + wid * 32 + er;

  // B frags: z^T, col=e, k=(lane>>4)*8 + i (+32 for half 1)
  bf16x8 zf[2][2];
#pragma unroll
  for (int et = 0; et < 2; ++et) {
    const unsigned* zrow = zb + (size_t)(e0 + et * 16) * 32;   // 64 bf16
    zf[et][0] = __builtin_bit_cast(bf16x8, *(const uint4*)(zrow + q * 4));
    zf[et][1] = __builtin_bit_cast(bf16x8, *(const uint4*)(zrow + 16 + q * 4));
  }

  const f32x4 zero = {0.f, 0.f, 0.f, 0.f};
#pragma unroll 1
  for (int m = 0; m < 16; ++m) {
    const unsigned short* wm = wtb + (size_t)m * 4096;
    f32x4 acc[2][4];
#pragma unroll
    for (int et = 0; et < 2; ++et)
#pragma unroll
      for (int nf = 0; nf < 4; ++nf) acc[et][nf] = zero;
#pragma unroll
    for (int nf = 0; nf < 4; ++nf) {
      const unsigned short* ar = wm + (size_t)(nf * 16 + er) * 64 + q * 8;
      const bf16x8 a0 = *(const bf16x8*)ar;
      const bf16x8 a1 = *(const bf16x8*)(ar + 32);
#pragma unroll
      for (int et = 0; et < 2; ++et) {
        acc[et][nf] = __builtin_amdgcn_mfma_f32_16x16x32_bf16(a0, zf[et][0], acc[et][nf], 0, 0, 0);
        acc[et][nf] = __builtin_amdgcn_mfma_f32_16x16x32_bf16(a1, zf[et][1], acc[et][nf], 0, 0, 0);
      }
    }
    const int hd = m >> 2, which = m & 3;    // wave-uniform
#pragma unroll
    for (int et = 0; et < 2; ++et) {
      const size_t rec = (size_t)(e0 + et * 16) * 4 + hd;
      unsigned* dst = (which == 0) ? (ksep + rec * 16)
                    : (which == 1) ? (vsep + rec * 16)
                    : (which == 2) ? (qho + rec * 16)
                                   : (gf8 + rec * 16);
      unsigned pk[4];
      if (which == 3) {
#pragma unroll
        for (int nf = 0; nf < 4; ++nf) {
          const float4 b4 = *(const float4*)(bg + hd * 64 + nf * 16 + q * 4);
          pk[nf] = packf8_4(fsig(acc[et][nf].x + b4.x), fsig(acc[et][nf].y + b4.y),
                            fsig(acc[et][nf].z + b4.z), fsig(acc[et][nf].w + b4.w));
        }
      } else {
#pragma unroll
        for (int nf = 0; nf < 4; ++nf)
          pk[nf] = packf8_4(acc[et][nf].x, acc[et][nf].y,
                            acc[et][nf].z, acc[et][nf].w);
      }
      *(uint4*)(dst + q * 4) = make_uint4(pk[0], pk[1], pk[2], pk[3]);
    }
  }
}

// ---------- fused attention + output projection ----------
// Phase 1 (quad = 4 heads of one edge): gathers, softmax, PV, gate -> gated ho bf16
// into LDS (row = tid, stride 33 uints -> conflict-free b32 writes).
// Phase 2 (after barrier): k_mout fragment scheme from LDS, medge fp32 out.
// medge aliases qho (R3): q/gate reads complete before the barrier -> safe in-place.
__global__ void __launch_bounds__(256)
k_attnm(const unsigned* __restrict__ qho, const unsigned* __restrict__ gf8,
        const unsigned* __restrict__ ksep, const unsigned* __restrict__ vsep,
        const float* __restrict__ be, const int* __restrict__ klist,
        const unsigned short* __restrict__ wtb, float* __restrict__ medge) {
  __shared__ unsigned hlds[256][33];   // [e_local*4+hd][32 uints bf16 ho] +1 pad
  const int tid = threadIdx.x;
  const int t = blockIdx.x * 256 + tid;
  const int e = t >> 2, hd = t & 3;

  // q (fp8 -> fp32, position order; same permutation as K -> dot invariant)
  float q[64];
  {
    unsigned qp[16];
    ldrow16(qho + (size_t)t * 16, qp);
    unpackf8(qp, q);
  }

  int i2[8], j2[8];
#pragma unroll
  for (int kn = 0; kn < 8; ++kn) {
    i2[kn] = klist[(size_t)e * 16 + kn];
    j2[kn] = klist[(size_t)e * 16 + 8 + kn];
  }
  float bv[8];
#pragma unroll
  for (int kn = 0; kn < 8; ++kn)
    bv[kn] = be[(size_t)((i2[kn] < 0) ? 0 : j2[kn]) * 4 + hd];

  const uint4* k4 = (const uint4*)ksep;   // 4 uint4 per record
  float alpha[8];
#pragma unroll 2
  for (int kn = 0; kn < 8; ++kn) {
    if (i2[kn] < 0) { alpha[kn] = -10000.0f; continue; }
    const uint4* kr = k4 + ((size_t)i2[kn] * 4 + hd) * 4;
    uint4 u0 = kr[0], u1 = kr[1], u2 = kr[2], u3 = kr[3];
    float d = 0.f;
    d = dot16(u0, q,      d);
    d = dot16(u1, q + 16, d);
    d = dot16(u2, q + 32, d);
    d = dot16(u3, q + 48, d);
    alpha[kn] = d * 0.125f + bv[kn];
  }
  float mx = alpha[0];
#pragma unroll
  for (int kn = 1; kn < 8; ++kn) mx = fmaxf(mx, alpha[kn]);
  float p[8], s = 0.f;
#pragma unroll
  for (int kn = 0; kn < 8; ++kn) { p[kn] = __expf(alpha[kn] - mx); s += p[kn]; }
  float is = 1.0f / s;
#pragma unroll
  for (int kn = 0; kn < 8; ++kn) p[kn] *= is;

  float ov[64];
#pragma unroll
  for (int j = 0; j < 64; ++j) ov[j] = 0.f;
  const uint4* v4 = (const uint4*)vsep;
#pragma unroll 2
  for (int kn = 0; kn < 8; ++kn) {
    int vi = (i2[kn] < 0) ? (NE - 1) : i2[kn];   // jax v[-1] wraps
    const uint4* vr = v4 + ((size_t)vi * 4 + hd) * 4;
    uint4 u0 = vr[0], u1 = vr[1], u2 = vr[2], u3 = vr[3];
    const float pk = p[kn];
    acc16(u0, pk, ov +  0);
    acc16(u1, pk, ov + 16);
    acc16(u2, pk, ov + 32);
    acc16(u3, pk, ov + 48);
  }
  // gate (precomputed sigmoid, fp8; same position permutation) -> gated ho bf16 to LDS
  {
    unsigned gp[16];
    ldrow16(gf8 + (size_t)t * 16, gp);
    float g[64];
    unpackf8(gp, g);
#pragma unroll
    for (int j = 0; j < 64; ++j) ov[j] *= g[j];
#pragma unroll
    for (int j = 0; j < 32; ++j) hlds[tid][j] = pack2(ov[2*j], ov[2*j+1]);
  }
  __syncthreads();

  // ---- output projection: m[e] = sum_hd ho_hd @ Wout_hd (chan-permuted wtb 19..22)
  const int lane = tid & 63;
  const int w    = tid >> 6;
  const int er   = lane & 15;
  const int qq   = lane >> 4;
  const int eg   = blockIdx.x * 64 + w * 16 + er;

  const f32x4 zero = {0.f, 0.f, 0.f, 0.f};
  f32x4 acc[4] = {zero, zero, zero, zero};
#pragma unroll 1
  for (int hd2 = 0; hd2 < 4; ++hd2) {
    const unsigned* hr = hlds[(w * 16 + er) * 4 + hd2];
    uint4 u0 = make_uint4(hr[qq*4], hr[qq*4+1], hr[qq*4+2], hr[qq*4+3]);
    uint4 u1 = make_uint4(hr[16+qq*4], hr[16+qq*4+1], hr[16+qq*4+2], hr[16+qq*4+3]);
    const bf16x8 hf0 = __builtin_bit_cast(bf16x8, u0);
    const bf16x8 hf1 = __builtin_bit_cast(bf16x8, u1);
    const unsigned short* wm = wtb + (size_t)(19 + hd2) * 4096;
#pragma unroll
    for (int nf = 0; nf < 4; ++nf) {
      const unsigned short* ar = wm + (size_t)(nf * 16 + er) * 64 + qq * 8;
      const bf16x8 a0 = *(const bf16x8*)ar;
      const bf16x8 a1 = *(const bf16x8*)(ar + 32);
      acc[nf] = __builtin_amdgcn_mfma_f32_16x16x32_bf16(a0, hf0, acc[nf], 0, 0, 0);
      acc[nf] = __builtin_amdgcn_mfma_f32_16x16x32_bf16(a1, hf1, acc[nf], 0, 0, 0);
    }
  }
#pragma unroll
  for (int nf = 0; nf < 4; ++nf)
    *(float4*)(medge + (size_t)eg * 64 + nf * 16 + qq * 4) =
        make_float4(acc[nf].x, acc[nf].y, acc[nf].z, acc[nf].w);
}

// ---------- CSR gather: per-node segment sum of medge ----------
__global__ void __launch_bounds__(256)
k_nodesum(const float* __restrict__ medge, const int* __restrict__ ioffs,
          const int* __restrict__ eidx, float* __restrict__ m_sum) {
  const int wid = threadIdx.x >> 6, lane = threadIdx.x & 63;
  const int n = blockIdx.x * 4 + wid;
  if (n >= NN) return;
  const int beg = ioffs[n], end = ioffs[n + 1];
  float acc = 0.f;
  for (int i = beg; i < end; ++i) {
    int e = eidx[i];
    acc += medge[(size_t)e * 64 + lane];
  }
  m_sum[(size_t)n * 64 + lane] = acc;
}

// ---------- final node update via MFMA: wave = 16 nodes ----------
__global__ void __launch_bounds__(256)
k_finm(const float* __restrict__ h, const float* __restrict__ na,
       const float* __restrict__ coord, const float* __restrict__ icoord,
       const float* __restrict__ m_sum, const float* __restrict__ x_sum,
       const float* __restrict__ cntf, const float* __restrict__ bout,
       const unsigned short* __restrict__ wtb,
       const float* __restrict__ bh1, const float* __restrict__ bh2,
       float* __restrict__ out) {
  __shared__ float lt[4][16][68];   // +4 pad breaks er*64 bank alias
  const int lane = threadIdx.x & 63;
  const int wid  = threadIdx.x >> 6;
  const int er   = lane & 15;
  const int q    = lane >> 4;
  const int e    = blockIdx.x * 64 + wid * 16 + er;
  const bool valid = e < NN;
  const int el = valid ? e : 0;

  const float* hr = h + (size_t)el * 64;
  const float* nr = na + (size_t)el * 64;
  const float* mr = m_sum + (size_t)el * 64;
  const float cn = cntf[el];
  const float invc = 1.0f / fmaxf(cn, 1.0f);
  const float bsc = (cn > 0.f) ? 1.0f : 0.0f;   // empty segment => m_agg = 0

  // B-frags: h, na, m_agg k-slices (bf16)
  bf16x8 hf[2], naf[2], mf[2];
  hf[0]  = packrow8(hr + q * 8); hf[1]  = packrow8(hr + 32 + q * 8);
  naf[0] = packrow8(nr + q * 8); naf[1] = packrow8(nr + 32 + q * 8);
#pragma unroll
  for (int half = 0; half < 2; ++half) {
    const int o = half * 32 + q * 8;
    const float4 m0 = *(const float4*)(mr + o);
    const float4 m1 = *(const float4*)(mr + o + 4);
    const float4 b0 = *(const float4*)(bout + o);
    const float4 b1 = *(const float4*)(bout + o + 4);
    float ma[8];
    ma[0] = fmaf(m0.x, invc, b0.x * bsc); ma[1] = fmaf(m0.y, invc, b0.y * bsc);
    ma[2] = fmaf(m0.z, invc, b0.z * bsc); ma[3] = fmaf(m0.w, invc, b0.w * bsc);
    ma[4] = fmaf(m1.x, invc, b1.x * bsc); ma[5] = fmaf(m1.y, invc, b1.y * bsc);
    ma[6] = fmaf(m1.z, invc, b1.z * bsc); ma[7] = fmaf(m1.w, invc, b1.w * bsc);
    uint4 u = make_uint4(pack2(ma[0], ma[1]), pack2(ma[2], ma[3]),
                         pack2(ma[4], ma[5]), pack2(ma[6], ma[7]));
    mf[half] = __builtin_bit_cast(bf16x8, u);
  }

  const f32x4 zero = {0.f, 0.f, 0.f, 0.f};
  f32x4 acc[4] = {zero, zero, zero, zero};
  mm4(wtb + (size_t)23 * 4096, er, q, hf,  acc);
  mm4(wtb + (size_t)24 * 4096, er, q, naf, acc);
  mm4(wtb + (size_t)25 * 4096, er, q, mf,  acc);
#pragma unroll
  for (int nf = 0; nf < 4; ++nf) {
    const float4 b4 = *(const float4*)(bh1 + nf * 16 + q * 4);
    float* d = &lt[wid][er][nf * 16 + q * 4];
    d[0] = fsilu(acc[nf].x + b4.x); d[1] = fsilu(acc[nf].y + b4.y);
    d[2] = fsilu(acc[nf].z + b4.z); d[3] = fsilu(acc[nf].w + b4.w);
  }
  __syncthreads();
  bf16x8 sf[2];
  sf[0] = packrow8(&lt[wid][er][q * 8]);
  sf[1] = packrow8(&lt[wid][er][32 + q * 8]);
  f32x4 a2[4] = {zero, zero, zero, zero};
  mm4(wtb + (size_t)26 * 4096, er, q, sf, a2);
  if (valid) {
#pragma unroll
    for (int nf = 0; nf < 4; ++nf) {
      const float4 b4 = *(const float4*)(bh2 + nf * 16 + q * 4);
      const float4 h4 = *(const float4*)(hr + nf * 16 + q * 4);
      *(float4*)(out + (size_t)e * 64 + nf * 16 + q * 4) =
          make_float4(a2[nf].x + b4.x + h4.x, a2[nf].y + b4.y + h4.y,
                      a2[nf].z + b4.z + h4.z, a2[nf].w + b4.w + h4.w);
    }
    if (q == 0) {
#pragma unroll
      for (int d = 0; d < 3; ++d)
        out[(size_t)NN * 64 + e * 3 + d] =
            0.2f * icoord[e * 3 + d] + 0.8f * coord[e * 3 + d] + x_sum[e * 3 + d] * invc;
    }
  }
}

extern "C" void kernel_launch(void* const* d_in, const int* in_sizes, int n_in,
                              void* d_out, int out_size, void* d_ws, size_t ws_size,
                              hipStream_t stream) {
  (void)in_sizes; (void)n_in; (void)out_size; (void)ws_size;
  const float* h      = (const float*)d_in[0];
  const float* coord  = (const float*)d_in[1];
  const int*   edges  = (const int*)  d_in[2];
  const float* nvecs  = (const float*)d_in[3];
  const float* ea     = (const float*)d_in[4];
  const float* na     = (const float*)d_in[5];
  const float* icoord = (const float*)d_in[6];
  const int*   klist  = (const int*)  d_in[7];
  const float* w_chem1 = (const float*)d_in[8];
  const float* b_chem1 = (const float*)d_in[9];
  const float* w_chem2 = (const float*)d_in[10];
  const float* b_chem2 = (const float*)d_in[11];
  const float* w_pos1  = (const float*)d_in[12];
  const float* b_pos1  = (const float*)d_in[13];
  const float* w_pos2  = (const float*)d_in[14];
  const float* b_pos2  = (const float*)d_in[15];
  const float* w_sh    = (const float*)d_in[16];
  const float* b_sh    = (const float*)d_in[17];
  const float* w_att   = (const float*)d_in[18];
  const float* b_att   = (const float*)d_in[19];
  const float* wq      = (const float*)d_in[20];
  const float* wk      = (const float*)d_in[21];
  const float* wv      = (const float*)d_in[22];
  const float* wb      = (const float*)d_in[23];
  const float* wg      = (const float*)d_in[24];
  const float* bg      = (const float*)d_in[25];
  const float* w_out   = (const float*)d_in[26];
  const float* b_out   = (const float*)d_in[27];
  const float* wu1     = (const float*)d_in[28];
  const float* bu1     = (const float*)d_in[29];
  const float* wu2     = (const float*)d_in[30];
  const float* bu2     = (const float*)d_in[31];
  const float* wx1     = (const float*)d_in[32];
  const float* bx1     = (const float*)d_in[33];
  const float* wx2     = (const float*)d_in[34];
  const float* bx2     = (const float*)d_in[35];
  const float* wh1     = (const float*)d_in[36];
  const float* bh1     = (const float*)d_in[37];
  const float* wh2     = (const float*)d_in[38];
  const float* bh2     = (const float*)d_in[39];

  float* out = (float*)d_out;
  float* ws  = (float*)d_ws;
  // Phase-reused regions (NE*64 floats each):
  //  R1: act1c -> ksep [NE*4][64B] fp8 K
  //  R2: act1p -> vsep [NE*4][64B] fp8 V
  //  R3: qho  [NE*4][16u] fp8 q -> medge fp32 (in-place, barrier-separated)
  //  R4: gf8  [NE*4][16u] fp8 gate (dead after attn)
  float* R1 = ws;
  float* R2 = R1 + (size_t)NE * 64;
  float* R3 = R2 + (size_t)NE * 64;
  float* R4 = R3 + (size_t)NE * 64;
  float* zbf   = R4 + (size_t)NE * 64;      // NE*32 floats (bf16 gated z)
  float* x_sum = zbf + (size_t)NE * 32;     // NN*3 (zeroed)
  float* cntf  = x_sum + (size_t)NN * 3;    // NN (zeroed)
  int*   icnt  = (int*)(cntf + NN);         // NN (zeroed)
  int*   icur  = icnt + NN;                 // NN (zeroed)
  float* m_sum = (float*)(icur + NN);       // NN*64
  float* be    = m_sum + (size_t)NN * 64;   // 4*NE  ([e*4+hd] layout)
  unsigned short* wtb = (unsigned short*)(be + (size_t)4 * NE);  // 34*64*64 bf16 (278KB)
  int*   ioffs = (int*)(wtb + 34 * 4096);   // NN+1
  int*   eidx  = ioffs + (NN + 1);          // NE

  unsigned* ksep = (unsigned*)R1;  // [NE*4][16u] fp8 K (deinterleaved, pos-permuted)
  unsigned* vsep = (unsigned*)R2;  // [NE*4][16u] fp8 V
  unsigned* qho  = (unsigned*)R3;  // [NE*4][16u] fp8 q
  unsigned* gf8  = (unsigned*)R4;  // [NE*4][16u] fp8 gate
  unsigned* zb   = (unsigned*)zbf;
  float* medge = R3;               // fused attn writes in-place over qho

  (void)hipMemsetAsync(x_sum, 0, ((size_t)NN * 3 + NN + NN + NN) * sizeof(float), stream);

  dim3 b256(256);
  dim3 gflat(NE / 256);

  // weight prep + CSR build (independent of the MLP pipeline)
  k_wprep<<<dim3(34), b256, 0, stream>>>(wk, wv, wq, wg, w_sh, wu1, wx1, w_out,
                                         wh1, wh2, w_chem2, w_pos2, w_chem1, wtb);
  k_count<<<gflat, b256, 0, stream>>>(edges, icnt);
  k_scan <<<dim3(1), b256, 0, stream>>>(icnt, ioffs);
  k_fill <<<gflat, b256, 0, stream>>>(edges, ioffs, icur, eidx);

  k_chem1m<<<dim3(NE / 64), b256, 0, stream>>>(h, na, ea, edges, wtb, b_chem1, R1);
  k_pos1  <<<dim3(NE / 256, 2), b256, 0, stream>>>(coord, nvecs, ea, edges, w_pos1, b_pos1, R2);
  k_l2s   <<<dim3(NE / 64), b256, 0, stream>>>(coord, edges, R1, R2, wtb,
                                               b_chem2, b_pos2, b_sh, w_att, b_att,
                                               bu1, wu2, bu2, bx1, wx2, bx2, wb,
                                               zb, be, x_sum, cntf);
  k_projm<<<dim3(NE / 128), b256, 0, stream>>>(zb, wtb, bg, ksep, vsep, qho, gf8);
  k_attnm<<<dim3(NE * 4 / 256), b256, 0, stream>>>(qho, gf8, ksep, vsep, be, klist,
                                                   wtb, medge);
  k_nodesum<<<dim3((NN + 3) / 4), b256, 0, stream>>>(medge, ioffs, eidx, m_sum);
  k_finm<<<dim3((NN + 63) / 64), b256, 0, stream>>>(h, na, coord, icoord, m_sum, x_sum,
                                                    cntf, b_out, wtb, bh1, bh2, out);
}

// Round 10
// 626.301 us; speedup vs baseline: 2.3126x; 1.0053x over previous
//
#include <hip/hip_runtime.h>
#include <math.h>

#define NE 160000
#define NN 10000

#define DEV __device__ __forceinline__

typedef float v2f __attribute__((ext_vector_type(2)));
typedef __attribute__((ext_vector_type(8))) short bf16x8;   // 8 bf16 (4 VGPRs)
typedef __attribute__((ext_vector_type(4))) float f32x4;

DEV float fsilu(float x) { return x / (1.0f + __expf(-x)); }
DEV float fsig(float x)  { return 1.0f / (1.0f + __expf(-x)); }

// ---- bf16 pack/unpack helpers (RNE) ----
DEV unsigned pack2(float a, float b) {
  unsigned ua = __float_as_uint(a); ua += 0x7FFFu + ((ua >> 16) & 1u);
  unsigned ub = __float_as_uint(b); ub += 0x7FFFu + ((ub >> 16) & 1u);
  return (ua >> 16) | (ub & 0xFFFF0000u);
}

// ---- fp8 e4m3 (OCP, HW-converted) ----
DEV unsigned packf8_4(float a, float b, float c, float d) {
  int r = __builtin_amdgcn_cvt_pk_fp8_f32(a, b, 0, false);
  r = __builtin_amdgcn_cvt_pk_fp8_f32(c, d, r, true);
  return (unsigned)r;
}
template<bool HI>
DEV v2f up2(unsigned u) { return __builtin_amdgcn_cvt_pk_f32_fp8((int)u, HI); }

// partial dot of 16 fp8 values (one uint4) against q[0..16) — 2 internal chains
DEV float dot16p(uint4 u, const float* q) {
  v2f f; float a = 0.f, b = 0.f;
  f = up2<false>(u.x); a = fmaf(f.x, q[0],  a); b = fmaf(f.y, q[1],  b);
  f = up2<true >(u.x); a = fmaf(f.x, q[2],  a); b = fmaf(f.y, q[3],  b);
  f = up2<false>(u.y); a = fmaf(f.x, q[4],  a); b = fmaf(f.y, q[5],  b);
  f = up2<true >(u.y); a = fmaf(f.x, q[6],  a); b = fmaf(f.y, q[7],  b);
  f = up2<false>(u.z); a = fmaf(f.x, q[8],  a); b = fmaf(f.y, q[9],  b);
  f = up2<true >(u.z); a = fmaf(f.x, q[10], a); b = fmaf(f.y, q[11], b);
  f = up2<false>(u.w); a = fmaf(f.x, q[12], a); b = fmaf(f.y, q[13], b);
  f = up2<true >(u.w); a = fmaf(f.x, q[14], a); b = fmaf(f.y, q[15], b);
  return a + b;
}
// o[0..16) += pk * fp8x16(u)
DEV void acc16(uint4 u, float pk, float* o) {
  v2f f;
  f = up2<false>(u.x); o[0]  = fmaf(pk, f.x, o[0]);  o[1]  = fmaf(pk, f.y, o[1]);
  f = up2<true >(u.x); o[2]  = fmaf(pk, f.x, o[2]);  o[3]  = fmaf(pk, f.y, o[3]);
  f = up2<false>(u.y); o[4]  = fmaf(pk, f.x, o[4]);  o[5]  = fmaf(pk, f.y, o[5]);
  f = up2<true >(u.y); o[6]  = fmaf(pk, f.x, o[6]);  o[7]  = fmaf(pk, f.y, o[7]);
  f = up2<false>(u.z); o[8]  = fmaf(pk, f.x, o[8]);  o[9]  = fmaf(pk, f.y, o[9]);
  f = up2<true >(u.z); o[10] = fmaf(pk, f.x, o[10]); o[11] = fmaf(pk, f.y, o[11]);
  f = up2<false>(u.w); o[12] = fmaf(pk, f.x, o[12]); o[13] = fmaf(pk, f.y, o[13]);
  f = up2<true >(u.w); o[14] = fmaf(pk, f.x, o[14]); o[15] = fmaf(pk, f.y, o[15]);
}

DEV void ldrow16(const unsigned* __restrict__ p, unsigned (&r)[16]) {
#pragma unroll
  for (int t = 0; t < 4; ++t) {
    uint4 u = ((const uint4*)p)[t];
    r[4*t] = u.x; r[4*t+1] = u.y; r[4*t+2] = u.z; r[4*t+3] = u.w;
  }
}
DEV void unpackf8(const unsigned (&p)[16], float (&o)[64]) {
#pragma unroll
  for (int t = 0; t < 16; ++t) {
    v2f f0 = up2<false>(p[t]);
    v2f f1 = up2<true >(p[t]);
    o[4*t+0] = f0.x; o[4*t+1] = f0.y; o[4*t+2] = f1.x; o[4*t+3] = f1.y;
  }
}
DEV void store32(float* dst, const float (&a)[32]) {
#pragma unroll
  for (int j = 0; j < 32; j += 4)
    *(float4*)(dst + j) = make_float4(a[j], a[j+1], a[j+2], a[j+3]);
}

// pack 8 consecutive fp32 -> bf16x8 (B-fragment k-slice)
DEV bf16x8 packrow8(const float* __restrict__ p) {
  float4 a = *(const float4*)p;
  float4 b = *(const float4*)(p + 4);
  uint4 u = make_uint4(pack2(a.x, a.y), pack2(a.z, a.w),
                       pack2(b.x, b.y), pack2(b.z, b.w));
  return __builtin_bit_cast(bf16x8, u);
}

// 16x16x32 GEMM over K=64: acc[nf] (n = nf*16 + q*4 + reg), A from wtb matrix wm
DEV void mm4(const unsigned short* __restrict__ wm, int er, int q,
             const bf16x8 (&bfr)[2], f32x4 (&acc)[4]) {
#pragma unroll
  for (int nf = 0; nf < 4; ++nf) {
    const unsigned short* ar = wm + (size_t)(nf * 16 + er) * 64 + q * 8;
    const bf16x8 a0 = *(const bf16x8*)ar;
    const bf16x8 a1 = *(const bf16x8*)(ar + 32);
    acc[nf] = __builtin_amdgcn_mfma_f32_16x16x32_bf16(a0, bfr[0], acc[nf], 0, 0, 0);
    acc[nf] = __builtin_amdgcn_mfma_f32_16x16x32_bf16(a1, bfr[1], acc[nf], 0, 0, 0);
  }
}

// ---------- CSR build over edges[0] (rows) ----------
__global__ void __launch_bounds__(256)
k_count(const int* __restrict__ edges, int* __restrict__ icnt) {
  int e = blockIdx.x * 256 + threadIdx.x;
  if (e < NE) atomicAdd(&icnt[edges[e]], 1);
}

__global__ void __launch_bounds__(256)
k_scan(const int* __restrict__ icnt, int* __restrict__ ioffs) {
  __shared__ int part[256];
  const int t = threadIdx.x;
  const int base = t * 40;
  int loc[40];
  int s = 0;
#pragma unroll
  for (int i = 0; i < 40; ++i) {
    int idx = base + i;
    int v = (idx < NN) ? icnt[idx] : 0;
    loc[i] = v; s += v;
  }
  part[t] = s;
  __syncthreads();
  for (int off = 1; off < 256; off <<= 1) {
    int v = (t >= off) ? part[t - off] : 0;
    __syncthreads();
    part[t] += v;
    __syncthreads();
  }
  int run = (t == 0) ? 0 : part[t - 1];
#pragma unroll
  for (int i = 0; i < 40; ++i) {
    int idx = base + i;
    if (idx < NN) { ioffs[idx] = run; run += loc[i]; }
  }
  if (t == 255) ioffs[NN] = NE;
}

__global__ void __launch_bounds__(256)
k_fill(const int* __restrict__ edges, const int* __restrict__ ioffs,
       int* __restrict__ icur, int* __restrict__ eidx) {
  int e = blockIdx.x * 256 + threadIdx.x;
  if (e >= NE) return;
  int r = edges[e];
  int p = atomicAdd(&icur[r], 1);
  eidx[ioffs[r] + p] = e;
}

// ---------- chem layer 1 via MFMA: 272 -> 64 silu; wave = 16 edges ----------
// 4 full K=64 slices (h[r],h[c],na[r],na[c]) + zero-padded K=16 edge-attr slice.
__global__ void __launch_bounds__(256)
k_chem1m(const float* __restrict__ h, const float* __restrict__ na,
         const float* __restrict__ ea, const int* __restrict__ edges,
         const unsigned short* __restrict__ wtb, const float* __restrict__ b1,
         float* __restrict__ act1c) {
  const int lane = threadIdx.x & 63;
  const int wid  = threadIdx.x >> 6;
  const int er   = lane & 15;
  const int q    = lane >> 4;
  const int e    = blockIdx.x * 64 + wid * 16 + er;
  const int r = edges[e], c = edges[NE + e];

  const f32x4 zero = {0.f, 0.f, 0.f, 0.f};
  f32x4 acc[4] = {zero, zero, zero, zero};
  bf16x8 f[2];
  const float* xr;
  xr = h  + (size_t)r * 64; f[0] = packrow8(xr + q * 8); f[1] = packrow8(xr + 32 + q * 8);
  mm4(wtb + (size_t)29 * 4096, er, q, f, acc);
  xr = h  + (size_t)c * 64; f[0] = packrow8(xr + q * 8); f[1] = packrow8(xr + 32 + q * 8);
  mm4(wtb + (size_t)30 * 4096, er, q, f, acc);
  xr = na + (size_t)r * 64; f[0] = packrow8(xr + q * 8); f[1] = packrow8(xr + 32 + q * 8);
  mm4(wtb + (size_t)31 * 4096, er, q, f, acc);
  xr = na + (size_t)c * 64; f[0] = packrow8(xr + q * 8); f[1] = packrow8(xr + 32 + q * 8);
  mm4(wtb + (size_t)32 * 4096, er, q, f, acc);
  // edge-attr slice: real B for k<16 (q=0,1), zero B elsewhere; half-2 skipped.
  {
    bf16x8 ef;
    if (q < 2) ef = packrow8(ea + (size_t)e * 16 + q * 8);
    else { uint4 z4 = make_uint4(0, 0, 0, 0); ef = __builtin_bit_cast(bf16x8, z4); }
    const unsigned short* wm = wtb + (size_t)33 * 4096;
#pragma unroll
    for (int nf = 0; nf < 4; ++nf) {
      const bf16x8 a0 = *(const bf16x8*)(wm + (size_t)(nf * 16 + er) * 64 + q * 8);
      acc[nf] = __builtin_amdgcn_mfma_f32_16x16x32_bf16(a0, ef, acc[nf], 0, 0, 0);
    }
  }
#pragma unroll
  for (int nf = 0; nf < 4; ++nf) {
    const float4 b4 = *(const float4*)(b1 + nf * 16 + q * 4);
    *(float4*)(act1c + (size_t)e * 64 + nf * 16 + q * 4) =
        make_float4(fsilu(acc[nf].x + b4.x), fsilu(acc[nf].y + b4.y),
                    fsilu(acc[nf].z + b4.z), fsilu(acc[nf].w + b4.w));
  }
}

// ---------- pos layer 1: 36 -> 64 silu ----------
__global__ void __launch_bounds__(256)
k_pos1(const float* __restrict__ coord, const float* __restrict__ nv,
       const float* __restrict__ ea, const int* __restrict__ edges,
       const float* __restrict__ w1, const float* __restrict__ b1,
       float* __restrict__ act1p) {
  const int e = blockIdx.x * 256 + threadIdx.x;
  const int co = blockIdx.y * 32;
  const int r = edges[e], c = edges[NE + e];

  float dx = coord[r * 3 + 0] - coord[c * 3 + 0];
  float dy = coord[r * 3 + 1] - coord[c * 3 + 1];
  float dz = coord[r * 3 + 2] - coord[c * 3 + 2];
  float nrm = sqrtf(dx * dx + dy * dy + dz * dz);
  float inv = 1.0f / (nrm + 1e-8f);
  dx *= inv; dy *= inv; dz *= inv;
  float ir = dx * dx + dy * dy + dz * dz;

  float in[36];
#pragma unroll
  for (int v = 0; v < 5; ++v) {
    float s = 0.f;
#pragma unroll
    for (int d = 0; d < 3; ++d)
      s += nv[(size_t)r * 15 + v * 3 + d] * nv[(size_t)c * 15 + v * 3 + d];
    in[v] = s;
  }
  {
    float cexp = -0.5f;
#pragma unroll
    for (int k = 0; k < 15; ++k) { in[5 + k] = __expf(ir * cexp); cexp *= (1.0f / 2.25f); }
  }
#pragma unroll
  for (int k = 0; k < 16; k += 4) {
    float4 e4 = *(const float4*)(ea + (size_t)e * 16 + k);
    in[20 + k] = e4.x; in[21 + k] = e4.y; in[22 + k] = e4.z; in[23 + k] = e4.w;
  }

  float acc[32];
#pragma unroll
  for (int j = 0; j < 32; ++j) acc[j] = b1[co + j];
#pragma unroll
  for (int k = 0; k < 36; ++k) {
    const float x = in[k];
    const float* wr = w1 + (size_t)k * 64 + co;
#pragma unroll
    for (int j = 0; j < 32; ++j) acc[j] = fmaf(x, wr[j], acc[j]);
  }
#pragma unroll
  for (int j = 0; j < 32; ++j) acc[j] = fsilu(acc[j]);
  store32(act1p + (size_t)e * 64 + co, acc);
}

// ---------- weight prep: wtb[m][n][k] = W_m[k][n] in bf16 (A-operand layout) ----------
// 0..15: hd*4+which (k,v,q,g); 16..18: wsh,wu1,wx1; 19..22: w_out/hd (chan-permuted k);
// 23..25: wh1 slices; 26: wh2; 27: w_chem2; 28: w_pos2; 29..32: w_chem1; 33: ea-slice
// chan(kk) maps fp8-record byte position -> original channel (record uint idx = q*4+nf).
__global__ void __launch_bounds__(256)
k_wprep(const float* __restrict__ wk, const float* __restrict__ wv,
        const float* __restrict__ wq, const float* __restrict__ wg,
        const float* __restrict__ wsh, const float* __restrict__ wu1,
        const float* __restrict__ wx1, const float* __restrict__ wout,
        const float* __restrict__ wh1, const float* __restrict__ wh2,
        const float* __restrict__ w2c, const float* __restrict__ w2p,
        const float* __restrict__ wc1,
        unsigned short* __restrict__ wtb) {
  const int m = blockIdx.x;          // 0..33
  const float* src;
  bool pad16 = false, permk = false;
  if (m < 16) {
    const int hd = m >> 2, which = m & 3;
    src = ((which == 0) ? wk : (which == 1) ? wv : (which == 2) ? wq : wg)
          + (size_t)hd * 4096;
  } else if (m < 19) {
    src = (m == 16) ? wsh : (m == 17) ? wu1 : wx1;
  } else if (m < 23) {
    src = wout + (size_t)(m - 19) * 4096;
    permk = true;                    // ho consumed in record-position order
  } else if (m < 26) {
    src = wh1 + (size_t)(m - 23) * 4096;
  } else if (m == 26) {
    src = wh2;
  } else if (m == 27) {
    src = w2c;
  } else if (m == 28) {
    src = w2p;
  } else if (m < 33) {
    src = wc1 + (size_t)(m - 29) * 4096;
  } else {
    src = wc1 + (size_t)4 * 4096;   // rows 256..271
    pad16 = true;
  }
  const int t = threadIdx.x;
#pragma unroll
  for (int i = 0; i < 16; ++i) {
    int idx = t * 16 + i;
    int n = idx >> 6, kk = idx & 63;
    int kr = permk ? (((kk >> 2) & 3) * 16 + (kk >> 4) * 4 + (kk & 3)) : kk;
    float v = (pad16 && kr >= 16) ? 0.f : src[kr * 64 + n];
    unsigned u = __float_as_uint(v);
    u += 0x7FFFu + ((u >> 16) & 1u);
    wtb[(size_t)m * 4096 + idx] = (unsigned short)(u >> 16);
  }
}

// ---------- fused layer-2 + scalars (MFMA): act1c/act1p -> zb/be/u/x ----------
// Wave = 16 edges. Layer-2 D-frags re-laid to k-slices via per-wave LDS tiles
// (same-wave ds ordering -> no barrier). posD is already in z's elementwise layout.
__global__ void __launch_bounds__(256)
k_l2s(const float* __restrict__ coord, const int* __restrict__ edges,
      const float* __restrict__ act1c, const float* __restrict__ act1p,
      const unsigned short* __restrict__ wtb,
      const float* __restrict__ b2c, const float* __restrict__ b2p,
      const float* __restrict__ bsh,
      const float* __restrict__ watt, const float* __restrict__ batt,
      const float* __restrict__ bu1, const float* __restrict__ wu2,
      const float* __restrict__ bu2,
      const float* __restrict__ bx1, const float* __restrict__ wx2,
      const float* __restrict__ bx2,
      const float* __restrict__ wb,
      unsigned* __restrict__ zb, float* __restrict__ be,
      float* __restrict__ x_sum, float* __restrict__ cntf) {
  __shared__ float ltc[4][16][68];   // +4 pad breaks er*64 bank alias
  __shared__ float ltp[4][16][68];
  const int lane = threadIdx.x & 63;
  const int wid  = threadIdx.x >> 6;
  const int er   = lane & 15;
  const int q    = lane >> 4;
  const int e    = blockIdx.x * 64 + wid * 16 + er;

  const f32x4 zero = {0.f, 0.f, 0.f, 0.f};
  bf16x8 f[2];

  // layer-2 chem: chemD = silu(act1c @ w2c + b2c)
  {
    const float* xr = act1c + (size_t)e * 64;
    f[0] = packrow8(xr + q * 8); f[1] = packrow8(xr + 32 + q * 8);
  }
  f32x4 cD[4] = {zero, zero, zero, zero};
  mm4(wtb + (size_t)27 * 4096, er, q, f, cD);
#pragma unroll
  for (int nf = 0; nf < 4; ++nf) {
    const float4 bc = *(const float4*)(b2c + nf * 16 + q * 4);
    *(float4*)&ltc[wid][er][nf * 16 + q * 4] =
        make_float4(fsilu(cD[nf].x + bc.x), fsilu(cD[nf].y + bc.y),
                    fsilu(cD[nf].z + bc.z), fsilu(cD[nf].w + bc.w));
  }
  // layer-2 pos: posD = silu(act1p @ w2p + b2p)  (kept in regs: z's elementwise layout)
  {
    const float* xr = act1p + (size_t)e * 64;
    f[0] = packrow8(xr + q * 8); f[1] = packrow8(xr + 32 + q * 8);
  }
  f32x4 pD[4] = {zero, zero, zero, zero};
  mm4(wtb + (size_t)28 * 4096, er, q, f, pD);
  float pv[16];
#pragma unroll
  for (int nf = 0; nf < 4; ++nf) {
    const float4 bp = *(const float4*)(b2p + nf * 16 + q * 4);
    pv[4*nf+0] = fsilu(pD[nf].x + bp.x); pv[4*nf+1] = fsilu(pD[nf].y + bp.y);
    pv[4*nf+2] = fsilu(pD[nf].z + bp.z); pv[4*nf+3] = fsilu(pD[nf].w + bp.w);
    *(float4*)&ltp[wid][er][nf * 16 + q * 4] =
        make_float4(pv[4*nf+0], pv[4*nf+1], pv[4*nf+2], pv[4*nf+3]);
  }
  // re-read as k-slice B-frags (per-wave-private tiles; same-wave ds order)
  bf16x8 cf[2], pf[2];
  cf[0] = packrow8(&ltc[wid][er][q * 8]); cf[1] = packrow8(&ltc[wid][er][32 + q * 8]);
  pf[0] = packrow8(&ltp[wid][er][q * 8]); pf[1] = packrow8(&ltp[wid][er][32 + q * 8]);

  // z = silu(chem @ wsh + bsh) * pos
  float z[16];
  {
    f32x4 acc[4] = {zero, zero, zero, zero};
    mm4(wtb + (size_t)16 * 4096, er, q, cf, acc);
#pragma unroll
    for (int nf = 0; nf < 4; ++nf) {
      const float4 b4 = *(const float4*)(bsh + nf * 16 + q * 4);
      z[4*nf+0] = fsilu(acc[nf].x + b4.x) * pv[4*nf+0];
      z[4*nf+1] = fsilu(acc[nf].y + b4.y) * pv[4*nf+1];
      z[4*nf+2] = fsilu(acc[nf].z + b4.z) * pv[4*nf+2];
      z[4*nf+3] = fsilu(acc[nf].w + b4.w) * pv[4*nf+3];
    }
  }
  // att gate
  {
    float ap = 0.f;
#pragma unroll
    for (int nf = 0; nf < 4; ++nf)
#pragma unroll
      for (int r = 0; r < 4; ++r)
        ap = fmaf(z[4*nf+r], watt[nf * 16 + q * 4 + r], ap);
    ap += __shfl_xor(ap, 16);
    ap += __shfl_xor(ap, 32);
    const float sg = fsig(ap + batt[0]);
#pragma unroll
    for (int j = 0; j < 16; ++j) z[j] *= sg;
  }
  // zb bf16 row (layout identical to original): uint idx = nf*8 + q*2
  {
    unsigned* zrow = zb + (size_t)e * 32 + q * 2;
#pragma unroll
    for (int nf = 0; nf < 4; ++nf) {
      uint2 w = make_uint2(pack2(z[4*nf+0], z[4*nf+1]), pack2(z[4*nf+2], z[4*nf+3]));
      *(uint2*)(zrow + nf * 8) = w;
    }
  }
  // per-head b scalars
  {
    float bb[4];
#pragma unroll
    for (int hd = 0; hd < 4; ++hd) {
      float b = 0.f;
#pragma unroll
      for (int nf = 0; nf < 4; ++nf)
#pragma unroll
        for (int r = 0; r < 4; ++r)
          b = fmaf(z[4*nf+r], wb[hd * 64 + nf * 16 + q * 4 + r], b);
      b += __shfl_xor(b, 16);
      b += __shfl_xor(b, 32);
      bb[hd] = b;
    }
    if (q == 0)
      *(float4*)(be + (size_t)e * 4) = make_float4(bb[0], bb[1], bb[2], bb[3]);
  }
  // u = silu(chem@wu1+bu1)@wu2 + bu2
  float u;
  {
    f32x4 acc[4] = {zero, zero, zero, zero};
    mm4(wtb + (size_t)17 * 4096, er, q, cf, acc);
    float up = 0.f;
#pragma unroll
    for (int nf = 0; nf < 4; ++nf) {
      const float4 b4 = *(const float4*)(bu1 + nf * 16 + q * 4);
      const float4 w4 = *(const float4*)(wu2 + nf * 16 + q * 4);
      up = fmaf(fsilu(acc[nf].x + b4.x), w4.x, up);
      up = fmaf(fsilu(acc[nf].y + b4.y), w4.y, up);
      up = fmaf(fsilu(acc[nf].z + b4.z), w4.z, up);
      up = fmaf(fsilu(acc[nf].w + b4.w), w4.w, up);
    }
    up += __shfl_xor(up, 16);
    up += __shfl_xor(up, 32);
    u = up + bu2[0];
  }
  // xs = silu(pos@wx1+bx1)@wx2 + bx2
  float xs;
  {
    f32x4 acc[4] = {zero, zero, zero, zero};
    mm4(wtb + (size_t)18 * 4096, er, q, pf, acc);
    float xp = 0.f;
#pragma unroll
    for (int nf = 0; nf < 4; ++nf) {
      const float4 b4 = *(const float4*)(bx1 + nf * 16 + q * 4);
      const float4 w4 = *(const float4*)(wx2 + nf * 16 + q * 4);
      xp = fmaf(fsilu(acc[nf].x + b4.x), w4.x, xp);
      xp = fmaf(fsilu(acc[nf].y + b4.y), w4.y, xp);
      xp = fmaf(fsilu(acc[nf].z + b4.z), w4.z, xp);
      xp = fmaf(fsilu(acc[nf].w + b4.w), w4.w, xp);
    }
    xp += __shfl_xor(xp, 16);
    xp += __shfl_xor(xp, 32);
    xs = xp + bx2[0];
  }

  if (q == 0) {
    const int r = edges[e], c = edges[NE + e];
    float dx = coord[r * 3 + 0] - coord[c * 3 + 0];
    float dy = coord[r * 3 + 1] - coord[c * 3 + 1];
    float dz = coord[r * 3 + 2] - coord[c * 3 + 2];
    float nrm = sqrtf(dx * dx + dy * dy + dz * dz);
    float inv = 1.0f / (nrm + 1e-8f);
    float t = u * xs;
    atomicAdd(&x_sum[r * 3 + 0], dx * inv * t);
    atomicAdd(&x_sum[r * 3 + 1], dy * inv * t);
    atomicAdd(&x_sum[r * 3 + 2], dz * inv * t);
    atomicAdd(&cntf[r], 1.0f);
  }
}

// ---------- MFMA projections -> ksep/vsep/qho/gf8 fp8, position-permuted records ----------
// Record uint idx = q*4+nf -> each lane stores one coalesced uint4 (1KB/wave-store).
// Permutation is shared by K/Q/V/gate/ho; only w_out (wtb 19..22) compensates (chan-perm).
// et=2 (32 edges/wave) doubles wave count for latency hiding.
__global__ void __launch_bounds__(256)
k_projm(const unsigned* __restrict__ zb, const unsigned short* __restrict__ wtb,
        const float* __restrict__ bg,
        unsigned* __restrict__ ksep, unsigned* __restrict__ vsep,
        unsigned* __restrict__ qho, unsigned* __restrict__ gf8) {
  const int lane = threadIdx.x & 63;
  const int wid  = threadIdx.x >> 6;        // wave 0..3
  const int er   = lane & 15;               // edge-in-tile (D col / B col / A row)
  const int q    = lane >> 4;               // k-block (A/B), row-quad (D)
  const int e0   = blockIdx.x * 128 + wid * 32 + er;

  // B frags: z^T, col=e, k=(lane>>4)*8 + i (+32 for half 1)
  bf16x8 zf[2][2];
#pragma unroll
  for (int et = 0; et < 2; ++et) {
    const unsigned* zrow = zb + (size_t)(e0 + et * 16) * 32;   // 64 bf16
    zf[et][0] = __builtin_bit_cast(bf16x8, *(const uint4*)(zrow + q * 4));
    zf[et][1] = __builtin_bit_cast(bf16x8, *(const uint4*)(zrow + 16 + q * 4));
  }

  const f32x4 zero = {0.f, 0.f, 0.f, 0.f};
#pragma unroll 1
  for (int m = 0; m < 16; ++m) {
    const unsigned short* wm = wtb + (size_t)m * 4096;
    f32x4 acc[2][4];
#pragma unroll
    for (int et = 0; et < 2; ++et)
#pragma unroll
      for (int nf = 0; nf < 4; ++nf) acc[et][nf] = zero;
#pragma unroll
    for (int nf = 0; nf < 4; ++nf) {
      const unsigned short* ar = wm + (size_t)(nf * 16 + er) * 64 + q * 8;
      const bf16x8 a0 = *(const bf16x8*)ar;
      const bf16x8 a1 = *(const bf16x8*)(ar + 32);
#pragma unroll
      for (int et = 0; et < 2; ++et) {
        acc[et][nf] = __builtin_amdgcn_mfma_f32_16x16x32_bf16(a0, zf[et][0], acc[et][nf], 0, 0, 0);
        acc[et][nf] = __builtin_amdgcn_mfma_f32_16x16x32_bf16(a1, zf[et][1], acc[et][nf], 0, 0, 0);
      }
    }
    const int hd = m >> 2, which = m & 3;    // wave-uniform
#pragma unroll
    for (int et = 0; et < 2; ++et) {
      const size_t rec = (size_t)(e0 + et * 16) * 4 + hd;
      unsigned* dst = (which == 0) ? (ksep + rec * 16)
                    : (which == 1) ? (vsep + rec * 16)
                    : (which == 2) ? (qho + rec * 16)
                                   : (gf8 + rec * 16);
      unsigned pk[4];
      if (which == 3) {
#pragma unroll
        for (int nf = 0; nf < 4; ++nf) {
          const float4 b4 = *(const float4*)(bg + hd * 64 + nf * 16 + q * 4);
          pk[nf] = packf8_4(fsig(acc[et][nf].x + b4.x), fsig(acc[et][nf].y + b4.y),
                            fsig(acc[et][nf].z + b4.z), fsig(acc[et][nf].w + b4.w));
        }
      } else {
#pragma unroll
        for (int nf = 0; nf < 4; ++nf)
          pk[nf] = packf8_4(acc[et][nf].x, acc[et][nf].y,
                            acc[et][nf].z, acc[et][nf].w);
      }
      *(uint4*)(dst + q * 4) = make_uint4(pk[0], pk[1], pk[2], pk[3]);
    }
  }
}

// ---------- fused attention + output projection (128-thread blocks) ----------
// Phase 1 (quad = 4 heads of one edge): gathers, softmax (split-chain dots), PV,
// gate -> gated ho bf16 into ragged LDS: base(r) = r*33 + ((r>>2)&3) ->
// phase-2 read banks (4er + (er&3) + 4qq) mod 32 hit all 32 banks 2-way (free).
// Phase 2 (after barrier): k_mout fragment scheme from LDS, medge fp32 out.
// medge aliases qho (R3): q/gate reads complete before the barrier -> safe in-place.
__global__ void __launch_bounds__(128)
k_attnm(const unsigned* __restrict__ qho, const unsigned* __restrict__ gf8,
        const unsigned* __restrict__ ksep, const unsigned* __restrict__ vsep,
        const float* __restrict__ be, const int* __restrict__ klist,
        const unsigned short* __restrict__ wtb, float* __restrict__ medge) {
  __shared__ unsigned hl[128 * 33 + 4];   // ragged rows: base(r) = r*33 + ((r>>2)&3)
  const int tid = threadIdx.x;
  const int t = blockIdx.x * 128 + tid;
  const int e = t >> 2, hd = t & 3;

  // q (fp8 -> fp32, position order; same permutation as K -> dot invariant)
  float q[64];
  {
    unsigned qp[16];
    ldrow16(qho + (size_t)t * 16, qp);
    unpackf8(qp, q);
  }

  int i2[8], j2[8];
#pragma unroll
  for (int kn = 0; kn < 8; ++kn) {
    i2[kn] = klist[(size_t)e * 16 + kn];
    j2[kn] = klist[(size_t)e * 16 + 8 + kn];
  }
  float bv[8];
#pragma unroll
  for (int kn = 0; kn < 8; ++kn)
    bv[kn] = be[(size_t)((i2[kn] < 0) ? 0 : j2[kn]) * 4 + hd];

  const uint4* k4 = (const uint4*)ksep;   // 4 uint4 per record
  float alpha[8];
#pragma unroll 2
  for (int kn = 0; kn < 8; ++kn) {
    if (i2[kn] < 0) { alpha[kn] = -10000.0f; continue; }
    const uint4* kr = k4 + ((size_t)i2[kn] * 4 + hd) * 4;
    uint4 u0 = kr[0], u1 = kr[1], u2 = kr[2], u3 = kr[3];
    float d = (dot16p(u0, q) + dot16p(u1, q + 16)) +
              (dot16p(u2, q + 32) + dot16p(u3, q + 48));
    alpha[kn] = d * 0.125f + bv[kn];
  }
  float mx = alpha[0];
#pragma unroll
  for (int kn = 1; kn < 8; ++kn) mx = fmaxf(mx, alpha[kn]);
  float p[8], s = 0.f;
#pragma unroll
  for (int kn = 0; kn < 8; ++kn) { p[kn] = __expf(alpha[kn] - mx); s += p[kn]; }
  float is = 1.0f / s;
#pragma unroll
  for (int kn = 0; kn < 8; ++kn) p[kn] *= is;

  float ov[64];
#pragma unroll
  for (int j = 0; j < 64; ++j) ov[j] = 0.f;
  const uint4* v4 = (const uint4*)vsep;
#pragma unroll 2
  for (int kn = 0; kn < 8; ++kn) {
    int vi = (i2[kn] < 0) ? (NE - 1) : i2[kn];   // jax v[-1] wraps
    const uint4* vr = v4 + ((size_t)vi * 4 + hd) * 4;
    uint4 u0 = vr[0], u1 = vr[1], u2 = vr[2], u3 = vr[3];
    const float pk = p[kn];
    acc16(u0, pk, ov +  0);
    acc16(u1, pk, ov + 16);
    acc16(u2, pk, ov + 32);
    acc16(u3, pk, ov + 48);
  }
  // gate (precomputed sigmoid, fp8; same position permutation) -> gated ho bf16 to LDS
  {
    unsigned gp[16];
    ldrow16(gf8 + (size_t)t * 16, gp);
    float g[64];
    unpackf8(gp, g);
#pragma unroll
    for (int j = 0; j < 64; ++j) ov[j] *= g[j];
    unsigned* hw = hl + tid * 33 + ((tid >> 2) & 3);
#pragma unroll
    for (int j = 0; j < 32; ++j) hw[j] = pack2(ov[2*j], ov[2*j+1]);
  }
  __syncthreads();

  // ---- output projection: m[e] = sum_hd ho_hd @ Wout_hd (chan-permuted wtb 19..22)
  const int lane = tid & 63;
  const int w    = tid >> 6;           // 0..1
  const int er   = lane & 15;
  const int qq   = lane >> 4;
  const int eg   = blockIdx.x * 32 + w * 16 + er;

  const f32x4 zero = {0.f, 0.f, 0.f, 0.f};
  f32x4 acc[4] = {zero, zero, zero, zero};
#pragma unroll 1
  for (int hd2 = 0; hd2 < 4; ++hd2) {
    const int r = (w * 16 + er) * 4 + hd2;
    const unsigned* hr = hl + r * 33 + ((r >> 2) & 3);
    uint4 u0 = make_uint4(hr[qq*4], hr[qq*4+1], hr[qq*4+2], hr[qq*4+3]);
    uint4 u1 = make_uint4(hr[16+qq*4], hr[16+qq*4+1], hr[16+qq*4+2], hr[16+qq*4+3]);
    const bf16x8 hf0 = __builtin_bit_cast(bf16x8, u0);
    const bf16x8 hf1 = __builtin_bit_cast(bf16x8, u1);
    const unsigned short* wm = wtb + (size_t)(19 + hd2) * 4096;
#pragma unroll
    for (int nf = 0; nf < 4; ++nf) {
      const unsigned short* ar = wm + (size_t)(nf * 16 + er) * 64 + qq * 8;
      const bf16x8 a0 = *(const bf16x8*)ar;
      const bf16x8 a1 = *(const bf16x8*)(ar + 32);
      acc[nf] = __builtin_amdgcn_mfma_f32_16x16x32_bf16(a0, hf0, acc[nf], 0, 0, 0);
      acc[nf] = __builtin_amdgcn_mfma_f32_16x16x32_bf16(a1, hf1, acc[nf], 0, 0, 0);
    }
  }
#pragma unroll
  for (int nf = 0; nf < 4; ++nf)
    *(float4*)(medge + (size_t)eg * 64 + nf * 16 + qq * 4) =
        make_float4(acc[nf].x, acc[nf].y, acc[nf].z, acc[nf].w);
}

// ---------- CSR gather: per-node segment sum of medge ----------
__global__ void __launch_bounds__(256)
k_nodesum(const float* __restrict__ medge, const int* __restrict__ ioffs,
          const int* __restrict__ eidx, float* __restrict__ m_sum) {
  const int wid = threadIdx.x >> 6, lane = threadIdx.x & 63;
  const int n = blockIdx.x * 4 + wid;
  if (n >= NN) return;
  const int beg = ioffs[n], end = ioffs[n + 1];
  float acc = 0.f;
  for (int i = beg; i < end; ++i) {
    int e = eidx[i];
    acc += medge[(size_t)e * 64 + lane];
  }
  m_sum[(size_t)n * 64 + lane] = acc;
}

// ---------- final node update via MFMA: wave = 16 nodes ----------
__global__ void __launch_bounds__(256)
k_finm(const float* __restrict__ h, const float* __restrict__ na,
       const float* __restrict__ coord, const float* __restrict__ icoord,
       const float* __restrict__ m_sum, const float* __restrict__ x_sum,
       const float* __restrict__ cntf, const float* __restrict__ bout,
       const unsigned short* __restrict__ wtb,
       const float* __restrict__ bh1, const float* __restrict__ bh2,
       float* __restrict__ out) {
  __shared__ float lt[4][16][68];   // +4 pad breaks er*64 bank alias
  const int lane = threadIdx.x & 63;
  const int wid  = threadIdx.x >> 6;
  const int er   = lane & 15;
  const int q    = lane >> 4;
  const int e    = blockIdx.x * 64 + wid * 16 + er;
  const bool valid = e < NN;
  const int el = valid ? e : 0;

  const float* hr = h + (size_t)el * 64;
  const float* nr = na + (size_t)el * 64;
  const float* mr = m_sum + (size_t)el * 64;
  const float cn = cntf[el];
  const float invc = 1.0f / fmaxf(cn, 1.0f);
  const float bsc = (cn > 0.f) ? 1.0f : 0.0f;   // empty segment => m_agg = 0

  // B-frags: h, na, m_agg k-slices (bf16)
  bf16x8 hf[2], naf[2], mf[2];
  hf[0]  = packrow8(hr + q * 8); hf[1]  = packrow8(hr + 32 + q * 8);
  naf[0] = packrow8(nr + q * 8); naf[1] = packrow8(nr + 32 + q * 8);
#pragma unroll
  for (int half = 0; half < 2; ++half) {
    const int o = half * 32 + q * 8;
    const float4 m0 = *(const float4*)(mr + o);
    const float4 m1 = *(const float4*)(mr + o + 4);
    const float4 b0 = *(const float4*)(bout + o);
    const float4 b1 = *(const float4*)(bout + o + 4);
    float ma[8];
    ma[0] = fmaf(m0.x, invc, b0.x * bsc); ma[1] = fmaf(m0.y, invc, b0.y * bsc);
    ma[2] = fmaf(m0.z, invc, b0.z * bsc); ma[3] = fmaf(m0.w, invc, b0.w * bsc);
    ma[4] = fmaf(m1.x, invc, b1.x * bsc); ma[5] = fmaf(m1.y, invc, b1.y * bsc);
    ma[6] = fmaf(m1.z, invc, b1.z * bsc); ma[7] = fmaf(m1.w, invc, b1.w * bsc);
    uint4 u = make_uint4(pack2(ma[0], ma[1]), pack2(ma[2], ma[3]),
                         pack2(ma[4], ma[5]), pack2(ma[6], ma[7]));
    mf[half] = __builtin_bit_cast(bf16x8, u);
  }

  const f32x4 zero = {0.f, 0.f, 0.f, 0.f};
  f32x4 acc[4] = {zero, zero, zero, zero};
  mm4(wtb + (size_t)23 * 4096, er, q, hf,  acc);
  mm4(wtb + (size_t)24 * 4096, er, q, naf, acc);
  mm4(wtb + (size_t)25 * 4096, er, q, mf,  acc);
#pragma unroll
  for (int nf = 0; nf < 4; ++nf) {
    const float4 b4 = *(const float4*)(bh1 + nf * 16 + q * 4);
    float* d = &lt[wid][er][nf * 16 + q * 4];
    d[0] = fsilu(acc[nf].x + b4.x); d[1] = fsilu(acc[nf].y + b4.y);
    d[2] = fsilu(acc[nf].z + b4.z); d[3] = fsilu(acc[nf].w + b4.w);
  }
  __syncthreads();
  bf16x8 sf[2];
  sf[0] = packrow8(&lt[wid][er][q * 8]);
  sf[1] = packrow8(&lt[wid][er][32 + q * 8]);
  f32x4 a2[4] = {zero, zero, zero, zero};
  mm4(wtb + (size_t)26 * 4096, er, q, sf, a2);
  if (valid) {
#pragma unroll
    for (int nf = 0; nf < 4; ++nf) {
      const float4 b4 = *(const float4*)(bh2 + nf * 16 + q * 4);
      const float4 h4 = *(const float4*)(hr + nf * 16 + q * 4);
      *(float4*)(out + (size_t)e * 64 + nf * 16 + q * 4) =
          make_float4(a2[nf].x + b4.x + h4.x, a2[nf].y + b4.y + h4.y,
                      a2[nf].z + b4.z + h4.z, a2[nf].w + b4.w + h4.w);
    }
    if (q == 0) {
#pragma unroll
      for (int d = 0; d < 3; ++d)
        out[(size_t)NN * 64 + e * 3 + d] =
            0.2f * icoord[e * 3 + d] + 0.8f * coord[e * 3 + d] + x_sum[e * 3 + d] * invc;
    }
  }
}

extern "C" void kernel_launch(void* const* d_in, const int* in_sizes, int n_in,
                              void* d_out, int out_size, void* d_ws, size_t ws_size,
                              hipStream_t stream) {
  (void)in_sizes; (void)n_in; (void)out_size; (void)ws_size;
  const float* h      = (const float*)d_in[0];
  const float* coord  = (const float*)d_in[1];
  const int*   edges  = (const int*)  d_in[2];
  const float* nvecs  = (const float*)d_in[3];
  const float* ea     = (const float*)d_in[4];
  const float* na     = (const float*)d_in[5];
  const float* icoord = (const float*)d_in[6];
  const int*   klist  = (const int*)  d_in[7];
  const float* w_chem1 = (const float*)d_in[8];
  const float* b_chem1 = (const float*)d_in[9];
  const float* w_chem2 = (const float*)d_in[10];
  const float* b_chem2 = (const float*)d_in[11];
  const float* w_pos1  = (const float*)d_in[12];
  const float* b_pos1  = (const float*)d_in[13];
  const float* w_pos2  = (const float*)d_in[14];
  const float* b_pos2  = (const float*)d_in[15];
  const float* w_sh    = (const float*)d_in[16];
  const float* b_sh    = (const float*)d_in[17];
  const float* w_att   = (const float*)d_in[18];
  const float* b_att   = (const float*)d_in[19];
  const float* wq      = (const float*)d_in[20];
  const float* wk      = (const float*)d_in[21];
  const float* wv      = (const float*)d_in[22];
  const float* wb      = (const float*)d_in[23];
  const float* wg      = (const float*)d_in[24];
  const float* bg      = (const float*)d_in[25];
  const float* w_out   = (const float*)d_in[26];
  const float* b_out   = (const float*)d_in[27];
  const float* wu1     = (const float*)d_in[28];
  const float* bu1     = (const float*)d_in[29];
  const float* wu2     = (const float*)d_in[30];
  const float* bu2     = (const float*)d_in[31];
  const float* wx1     = (const float*)d_in[32];
  const float* bx1     = (const float*)d_in[33];
  const float* wx2     = (const float*)d_in[34];
  const float* bx2     = (const float*)d_in[35];
  const float* wh1     = (const float*)d_in[36];
  const float* bh1     = (const float*)d_in[37];
  const float* wh2     = (const float*)d_in[38];
  const float* bh2     = (const float*)d_in[39];

  float* out = (float*)d_out;
  float* ws  = (float*)d_ws;
  // Phase-reused regions (NE*64 floats each):
  //  R1: act1c -> ksep [NE*4][64B] fp8 K
  //  R2: act1p -> vsep [NE*4][64B] fp8 V
  //  R3: qho  [NE*4][16u] fp8 q -> medge fp32 (in-place, barrier-separated)
  //  R4: gf8  [NE*4][16u] fp8 gate (dead after attn)
  float* R1 = ws;
  float* R2 = R1 + (size_t)NE * 64;
  float* R3 = R2 + (size_t)NE * 64;
  float* R4 = R3 + (size_t)NE * 64;
  float* zbf   = R4 + (size_t)NE * 64;      // NE*32 floats (bf16 gated z)
  float* x_sum = zbf + (size_t)NE * 32;     // NN*3 (zeroed)
  float* cntf  = x_sum + (size_t)NN * 3;    // NN (zeroed)
  int*   icnt  = (int*)(cntf + NN);         // NN (zeroed)
  int*   icur  = icnt + NN;                 // NN (zeroed)
  float* m_sum = (float*)(icur + NN);       // NN*64
  float* be    = m_sum + (size_t)NN * 64;   // 4*NE  ([e*4+hd] layout)
  unsigned short* wtb = (unsigned short*)(be + (size_t)4 * NE);  // 34*64*64 bf16 (278KB)
  int*   ioffs = (int*)(wtb + 34 * 4096);   // NN+1
  int*   eidx  = ioffs + (NN + 1);          // NE

  unsigned* ksep = (unsigned*)R1;  // [NE*4][16u] fp8 K (deinterleaved, pos-permuted)
  unsigned* vsep = (unsigned*)R2;  // [NE*4][16u] fp8 V
  unsigned* qho  = (unsigned*)R3;  // [NE*4][16u] fp8 q
  unsigned* gf8  = (unsigned*)R4;  // [NE*4][16u] fp8 gate
  unsigned* zb   = (unsigned*)zbf;
  float* medge = R3;               // fused attn writes in-place over qho

  (void)hipMemsetAsync(x_sum, 0, ((size_t)NN * 3 + NN + NN + NN) * sizeof(float), stream);

  dim3 b256(256);
  dim3 gflat(NE / 256);

  // weight prep + CSR build (independent of the MLP pipeline)
  k_wprep<<<dim3(34), b256, 0, stream>>>(wk, wv, wq, wg, w_sh, wu1, wx1, w_out,
                                         wh1, wh2, w_chem2, w_pos2, w_chem1, wtb);
  k_count<<<gflat, b256, 0, stream>>>(edges, icnt);
  k_scan <<<dim3(1), b256, 0, stream>>>(icnt, ioffs);
  k_fill <<<gflat, b256, 0, stream>>>(edges, ioffs, icur, eidx);

  k_chem1m<<<dim3(NE / 64), b256, 0, stream>>>(h, na, ea, edges, wtb, b_chem1, R1);
  k_pos1  <<<dim3(NE / 256, 2), b256, 0, stream>>>(coord, nvecs, ea, edges, w_pos1, b_pos1, R2);
  k_l2s   <<<dim3(NE / 64), b256, 0, stream>>>(coord, edges, R1, R2, wtb,
                                               b_chem2, b_pos2, b_sh, w_att, b_att,
                                               bu1, wu2, bu2, bx1, wx2, bx2, wb,
                                               zb, be, x_sum, cntf);
  k_projm<<<dim3(NE / 128), b256, 0, stream>>>(zb, wtb, bg, ksep, vsep, qho, gf8);
  k_attnm<<<dim3(NE * 4 / 128), dim3(128), 0, stream>>>(qho, gf8, ksep, vsep, be, klist,
                                                        wtb, medge);
  k_nodesum<<<dim3((NN + 3) / 4), b256, 0, stream>>>(medge, ioffs, eidx, m_sum);
  k_finm<<<dim3((NN + 63) / 64), b256, 0, stream>>>(h, na, coord, icoord, m_sum, x_sum,
                                                    cntf, b_out, wtb, bh1, bh2, out);
}

// Round 11
// 601.015 us; speedup vs baseline: 2.4099x; 1.0421x over previous
//
#include <hip/hip_runtime.h>
#include <math.h>

#define NE 160000
#define NN 10000

#define DEV __device__ __forceinline__

typedef float v2f __attribute__((ext_vector_type(2)));
typedef __attribute__((ext_vector_type(8))) short bf16x8;   // 8 bf16 (4 VGPRs)
typedef __attribute__((ext_vector_type(4))) float f32x4;

DEV float fsilu(float x) { return x / (1.0f + __expf(-x)); }
DEV float fsig(float x)  { return 1.0f / (1.0f + __expf(-x)); }

// ---- bf16 pack/unpack helpers (RNE) ----
DEV unsigned pack2(float a, float b) {
  unsigned ua = __float_as_uint(a); ua += 0x7FFFu + ((ua >> 16) & 1u);
  unsigned ub = __float_as_uint(b); ub += 0x7FFFu + ((ub >> 16) & 1u);
  return (ua >> 16) | (ub & 0xFFFF0000u);
}

// ---- fp8 e4m3 (OCP, HW-converted) ----
DEV unsigned packf8_4(float a, float b, float c, float d) {
  int r = __builtin_amdgcn_cvt_pk_fp8_f32(a, b, 0, false);
  r = __builtin_amdgcn_cvt_pk_fp8_f32(c, d, r, true);
  return (unsigned)r;
}
template<bool HI>
DEV v2f up2(unsigned u) { return __builtin_amdgcn_cvt_pk_f32_fp8((int)u, HI); }

// partial dot of 16 fp8 values (one uint4) against q[0..16) — 2 internal chains
DEV float dot16p(uint4 u, const float* q) {
  v2f f; float a = 0.f, b = 0.f;
  f = up2<false>(u.x); a = fmaf(f.x, q[0],  a); b = fmaf(f.y, q[1],  b);
  f = up2<true >(u.x); a = fmaf(f.x, q[2],  a); b = fmaf(f.y, q[3],  b);
  f = up2<false>(u.y); a = fmaf(f.x, q[4],  a); b = fmaf(f.y, q[5],  b);
  f = up2<true >(u.y); a = fmaf(f.x, q[6],  a); b = fmaf(f.y, q[7],  b);
  f = up2<false>(u.z); a = fmaf(f.x, q[8],  a); b = fmaf(f.y, q[9],  b);
  f = up2<true >(u.z); a = fmaf(f.x, q[10], a); b = fmaf(f.y, q[11], b);
  f = up2<false>(u.w); a = fmaf(f.x, q[12], a); b = fmaf(f.y, q[13], b);
  f = up2<true >(u.w); a = fmaf(f.x, q[14], a); b = fmaf(f.y, q[15], b);
  return a + b;
}
// o[0..16) += pk * fp8x16(u)
DEV void acc16(uint4 u, float pk, float* o) {
  v2f f;
  f = up2<false>(u.x); o[0]  = fmaf(pk, f.x, o[0]);  o[1]  = fmaf(pk, f.y, o[1]);
  f = up2<true >(u.x); o[2]  = fmaf(pk, f.x, o[2]);  o[3]  = fmaf(pk, f.y, o[3]);
  f = up2<false>(u.y); o[4]  = fmaf(pk, f.x, o[4]);  o[5]  = fmaf(pk, f.y, o[5]);
  f = up2<true >(u.y); o[6]  = fmaf(pk, f.x, o[6]);  o[7]  = fmaf(pk, f.y, o[7]);
  f = up2<false>(u.z); o[8]  = fmaf(pk, f.x, o[8]);  o[9]  = fmaf(pk, f.y, o[9]);
  f = up2<true >(u.z); o[10] = fmaf(pk, f.x, o[10]); o[11] = fmaf(pk, f.y, o[11]);
  f = up2<false>(u.w); o[12] = fmaf(pk, f.x, o[12]); o[13] = fmaf(pk, f.y, o[13]);
  f = up2<true >(u.w); o[14] = fmaf(pk, f.x, o[14]); o[15] = fmaf(pk, f.y, o[15]);
}

DEV void ldrow16(const unsigned* __restrict__ p, unsigned (&r)[16]) {
#pragma unroll
  for (int t = 0; t < 4; ++t) {
    uint4 u = ((const uint4*)p)[t];
    r[4*t] = u.x; r[4*t+1] = u.y; r[4*t+2] = u.z; r[4*t+3] = u.w;
  }
}
DEV void unpackf8_32(const unsigned (&p)[8], float (&o)[32]) {
#pragma unroll
  for (int t = 0; t < 8; ++t) {
    v2f f0 = up2<false>(p[t]);
    v2f f1 = up2<true >(p[t]);
    o[4*t+0] = f0.x; o[4*t+1] = f0.y; o[4*t+2] = f1.x; o[4*t+3] = f1.y;
  }
}
DEV void store32(float* dst, const float (&a)[32]) {
#pragma unroll
  for (int j = 0; j < 32; j += 4)
    *(float4*)(dst + j) = make_float4(a[j], a[j+1], a[j+2], a[j+3]);
}

// pack 8 consecutive fp32 -> bf16x8 (B-fragment k-slice)
DEV bf16x8 packrow8(const float* __restrict__ p) {
  float4 a = *(const float4*)p;
  float4 b = *(const float4*)(p + 4);
  uint4 u = make_uint4(pack2(a.x, a.y), pack2(a.z, a.w),
                       pack2(b.x, b.y), pack2(b.z, b.w));
  return __builtin_bit_cast(bf16x8, u);
}

// 16x16x32 GEMM over K=64: acc[nf] (n = nf*16 + q*4 + reg), A from wtb matrix wm
DEV void mm4(const unsigned short* __restrict__ wm, int er, int q,
             const bf16x8 (&bfr)[2], f32x4 (&acc)[4]) {
#pragma unroll
  for (int nf = 0; nf < 4; ++nf) {
    const unsigned short* ar = wm + (size_t)(nf * 16 + er) * 64 + q * 8;
    const bf16x8 a0 = *(const bf16x8*)ar;
    const bf16x8 a1 = *(const bf16x8*)(ar + 32);
    acc[nf] = __builtin_amdgcn_mfma_f32_16x16x32_bf16(a0, bfr[0], acc[nf], 0, 0, 0);
    acc[nf] = __builtin_amdgcn_mfma_f32_16x16x32_bf16(a1, bfr[1], acc[nf], 0, 0, 0);
  }
}

// ---------- CSR build over edges[0] (rows) ----------
__global__ void __launch_bounds__(256)
k_count(const int* __restrict__ edges, int* __restrict__ icnt) {
  int e = blockIdx.x * 256 + threadIdx.x;
  if (e < NE) atomicAdd(&icnt[edges[e]], 1);
}

__global__ void __launch_bounds__(256)
k_scan(const int* __restrict__ icnt, int* __restrict__ ioffs) {
  __shared__ int part[256];
  const int t = threadIdx.x;
  const int base = t * 40;
  int loc[40];
  int s = 0;
#pragma unroll
  for (int i = 0; i < 40; ++i) {
    int idx = base + i;
    int v = (idx < NN) ? icnt[idx] : 0;
    loc[i] = v; s += v;
  }
  part[t] = s;
  __syncthreads();
  for (int off = 1; off < 256; off <<= 1) {
    int v = (t >= off) ? part[t - off] : 0;
    __syncthreads();
    part[t] += v;
    __syncthreads();
  }
  int run = (t == 0) ? 0 : part[t - 1];
#pragma unroll
  for (int i = 0; i < 40; ++i) {
    int idx = base + i;
    if (idx < NN) { ioffs[idx] = run; run += loc[i]; }
  }
  if (t == 255) ioffs[NN] = NE;
}

__global__ void __launch_bounds__(256)
k_fill(const int* __restrict__ edges, const int* __restrict__ ioffs,
       int* __restrict__ icur, int* __restrict__ eidx) {
  int e = blockIdx.x * 256 + threadIdx.x;
  if (e >= NE) return;
  int r = edges[e];
  int p = atomicAdd(&icur[r], 1);
  eidx[ioffs[r] + p] = e;
}

// ---------- chem layer 1 via MFMA: 272 -> 64 silu; wave = 16 edges ----------
// 4 full K=64 slices (h[r],h[c],na[r],na[c]) + zero-padded K=16 edge-attr slice.
__global__ void __launch_bounds__(256)
k_chem1m(const float* __restrict__ h, const float* __restrict__ na,
         const float* __restrict__ ea, const int* __restrict__ edges,
         const unsigned short* __restrict__ wtb, const float* __restrict__ b1,
         float* __restrict__ act1c) {
  const int lane = threadIdx.x & 63;
  const int wid  = threadIdx.x >> 6;
  const int er   = lane & 15;
  const int q    = lane >> 4;
  const int e    = blockIdx.x * 64 + wid * 16 + er;
  const int r = edges[e], c = edges[NE + e];

  const f32x4 zero = {0.f, 0.f, 0.f, 0.f};
  f32x4 acc[4] = {zero, zero, zero, zero};
  bf16x8 f[2];
  const float* xr;
  xr = h  + (size_t)r * 64; f[0] = packrow8(xr + q * 8); f[1] = packrow8(xr + 32 + q * 8);
  mm4(wtb + (size_t)29 * 4096, er, q, f, acc);
  xr = h  + (size_t)c * 64; f[0] = packrow8(xr + q * 8); f[1] = packrow8(xr + 32 + q * 8);
  mm4(wtb + (size_t)30 * 4096, er, q, f, acc);
  xr = na + (size_t)r * 64; f[0] = packrow8(xr + q * 8); f[1] = packrow8(xr + 32 + q * 8);
  mm4(wtb + (size_t)31 * 4096, er, q, f, acc);
  xr = na + (size_t)c * 64; f[0] = packrow8(xr + q * 8); f[1] = packrow8(xr + 32 + q * 8);
  mm4(wtb + (size_t)32 * 4096, er, q, f, acc);
  // edge-attr slice: real B for k<16 (q=0,1), zero B elsewhere; half-2 skipped.
  {
    bf16x8 ef;
    if (q < 2) ef = packrow8(ea + (size_t)e * 16 + q * 8);
    else { uint4 z4 = make_uint4(0, 0, 0, 0); ef = __builtin_bit_cast(bf16x8, z4); }
    const unsigned short* wm = wtb + (size_t)33 * 4096;
#pragma unroll
    for (int nf = 0; nf < 4; ++nf) {
      const bf16x8 a0 = *(const bf16x8*)(wm + (size_t)(nf * 16 + er) * 64 + q * 8);
      acc[nf] = __builtin_amdgcn_mfma_f32_16x16x32_bf16(a0, ef, acc[nf], 0, 0, 0);
    }
  }
#pragma unroll
  for (int nf = 0; nf < 4; ++nf) {
    const float4 b4 = *(const float4*)(b1 + nf * 16 + q * 4);
    *(float4*)(act1c + (size_t)e * 64 + nf * 16 + q * 4) =
        make_float4(fsilu(acc[nf].x + b4.x), fsilu(acc[nf].y + b4.y),
                    fsilu(acc[nf].z + b4.z), fsilu(acc[nf].w + b4.w));
  }
}

// ---------- pos layer 1: 36 -> 64 silu ----------
__global__ void __launch_bounds__(256)
k_pos1(const float* __restrict__ coord, const float* __restrict__ nv,
       const float* __restrict__ ea, const int* __restrict__ edges,
       const float* __restrict__ w1, const float* __restrict__ b1,
       float* __restrict__ act1p) {
  const int e = blockIdx.x * 256 + threadIdx.x;
  const int co = blockIdx.y * 32;
  const int r = edges[e], c = edges[NE + e];

  float dx = coord[r * 3 + 0] - coord[c * 3 + 0];
  float dy = coord[r * 3 + 1] - coord[c * 3 + 1];
  float dz = coord[r * 3 + 2] - coord[c * 3 + 2];
  float nrm = sqrtf(dx * dx + dy * dy + dz * dz);
  float inv = 1.0f / (nrm + 1e-8f);
  dx *= inv; dy *= inv; dz *= inv;
  float ir = dx * dx + dy * dy + dz * dz;

  float in[36];
#pragma unroll
  for (int v = 0; v < 5; ++v) {
    float s = 0.f;
#pragma unroll
    for (int d = 0; d < 3; ++d)
      s += nv[(size_t)r * 15 + v * 3 + d] * nv[(size_t)c * 15 + v * 3 + d];
    in[v] = s;
  }
  {
    float cexp = -0.5f;
#pragma unroll
    for (int k = 0; k < 15; ++k) { in[5 + k] = __expf(ir * cexp); cexp *= (1.0f / 2.25f); }
  }
#pragma unroll
  for (int k = 0; k < 16; k += 4) {
    float4 e4 = *(const float4*)(ea + (size_t)e * 16 + k);
    in[20 + k] = e4.x; in[21 + k] = e4.y; in[22 + k] = e4.z; in[23 + k] = e4.w;
  }

  float acc[32];
#pragma unroll
  for (int j = 0; j < 32; ++j) acc[j] = b1[co + j];
#pragma unroll
  for (int k = 0; k < 36; ++k) {
    const float x = in[k];
    const float* wr = w1 + (size_t)k * 64 + co;
#pragma unroll
    for (int j = 0; j < 32; ++j) acc[j] = fmaf(x, wr[j], acc[j]);
  }
#pragma unroll
  for (int j = 0; j < 32; ++j) acc[j] = fsilu(acc[j]);
  store32(act1p + (size_t)e * 64 + co, acc);
}

// ---------- weight prep: wtb[m][n][k] = W_m[k][n] in bf16 (A-operand layout) ----------
// 0..15: hd*4+which (k,v,q,g); 16..18: wsh,wu1,wx1; 19..22: w_out/hd (chan-permuted k);
// 23..25: wh1 slices; 26: wh2; 27: w_chem2; 28: w_pos2; 29..32: w_chem1; 33: ea-slice
// chan(kk) maps fp8-record byte position -> original channel (record uint idx = q*4+nf).
__global__ void __launch_bounds__(256)
k_wprep(const float* __restrict__ wk, const float* __restrict__ wv,
        const float* __restrict__ wq, const float* __restrict__ wg,
        const float* __restrict__ wsh, const float* __restrict__ wu1,
        const float* __restrict__ wx1, const float* __restrict__ wout,
        const float* __restrict__ wh1, const float* __restrict__ wh2,
        const float* __restrict__ w2c, const float* __restrict__ w2p,
        const float* __restrict__ wc1,
        unsigned short* __restrict__ wtb) {
  const int m = blockIdx.x;          // 0..33
  const float* src;
  bool pad16 = false, permk = false;
  if (m < 16) {
    const int hd = m >> 2, which = m & 3;
    src = ((which == 0) ? wk : (which == 1) ? wv : (which == 2) ? wq : wg)
          + (size_t)hd * 4096;
  } else if (m < 19) {
    src = (m == 16) ? wsh : (m == 17) ? wu1 : wx1;
  } else if (m < 23) {
    src = wout + (size_t)(m - 19) * 4096;
    permk = true;                    // ho consumed in record-position order
  } else if (m < 26) {
    src = wh1 + (size_t)(m - 23) * 4096;
  } else if (m == 26) {
    src = wh2;
  } else if (m == 27) {
    src = w2c;
  } else if (m == 28) {
    src = w2p;
  } else if (m < 33) {
    src = wc1 + (size_t)(m - 29) * 4096;
  } else {
    src = wc1 + (size_t)4 * 4096;   // rows 256..271
    pad16 = true;
  }
  const int t = threadIdx.x;
#pragma unroll
  for (int i = 0; i < 16; ++i) {
    int idx = t * 16 + i;
    int n = idx >> 6, kk = idx & 63;
    int kr = permk ? (((kk >> 2) & 3) * 16 + (kk >> 4) * 4 + (kk & 3)) : kk;
    float v = (pad16 && kr >= 16) ? 0.f : src[kr * 64 + n];
    unsigned u = __float_as_uint(v);
    u += 0x7FFFu + ((u >> 16) & 1u);
    wtb[(size_t)m * 4096 + idx] = (unsigned short)(u >> 16);
  }
}

// ---------- fused layer-2 + scalars (MFMA): act1c/act1p -> zb/be/u/x ----------
// Wave = 16 edges. Layer-2 D-frags re-laid to k-slices via per-wave LDS tiles
// (same-wave ds ordering -> no barrier). posD is already in z's elementwise layout.
__global__ void __launch_bounds__(256)
k_l2s(const float* __restrict__ coord, const int* __restrict__ edges,
      const float* __restrict__ act1c, const float* __restrict__ act1p,
      const unsigned short* __restrict__ wtb,
      const float* __restrict__ b2c, const float* __restrict__ b2p,
      const float* __restrict__ bsh,
      const float* __restrict__ watt, const float* __restrict__ batt,
      const float* __restrict__ bu1, const float* __restrict__ wu2,
      const float* __restrict__ bu2,
      const float* __restrict__ bx1, const float* __restrict__ wx2,
      const float* __restrict__ bx2,
      const float* __restrict__ wb,
      unsigned* __restrict__ zb, float* __restrict__ be,
      float* __restrict__ x_sum, float* __restrict__ cntf) {
  __shared__ float ltc[4][16][68];   // +4 pad breaks er*64 bank alias
  __shared__ float ltp[4][16][68];
  const int lane = threadIdx.x & 63;
  const int wid  = threadIdx.x >> 6;
  const int er   = lane & 15;
  const int q    = lane >> 4;
  const int e    = blockIdx.x * 64 + wid * 16 + er;

  const f32x4 zero = {0.f, 0.f, 0.f, 0.f};
  bf16x8 f[2];

  // layer-2 chem: chemD = silu(act1c @ w2c + b2c)
  {
    const float* xr = act1c + (size_t)e * 64;
    f[0] = packrow8(xr + q * 8); f[1] = packrow8(xr + 32 + q * 8);
  }
  f32x4 cD[4] = {zero, zero, zero, zero};
  mm4(wtb + (size_t)27 * 4096, er, q, f, cD);
#pragma unroll
  for (int nf = 0; nf < 4; ++nf) {
    const float4 bc = *(const float4*)(b2c + nf * 16 + q * 4);
    *(float4*)&ltc[wid][er][nf * 16 + q * 4] =
        make_float4(fsilu(cD[nf].x + bc.x), fsilu(cD[nf].y + bc.y),
                    fsilu(cD[nf].z + bc.z), fsilu(cD[nf].w + bc.w));
  }
  // layer-2 pos: posD = silu(act1p @ w2p + b2p)  (kept in regs: z's elementwise layout)
  {
    const float* xr = act1p + (size_t)e * 64;
    f[0] = packrow8(xr + q * 8); f[1] = packrow8(xr + 32 + q * 8);
  }
  f32x4 pD[4] = {zero, zero, zero, zero};
  mm4(wtb + (size_t)28 * 4096, er, q, f, pD);
  float pv[16];
#pragma unroll
  for (int nf = 0; nf < 4; ++nf) {
    const float4 bp = *(const float4*)(b2p + nf * 16 + q * 4);
    pv[4*nf+0] = fsilu(pD[nf].x + bp.x); pv[4*nf+1] = fsilu(pD[nf].y + bp.y);
    pv[4*nf+2] = fsilu(pD[nf].z + bp.z); pv[4*nf+3] = fsilu(pD[nf].w + bp.w);
    *(float4*)&ltp[wid][er][nf * 16 + q * 4] =
        make_float4(pv[4*nf+0], pv[4*nf+1], pv[4*nf+2], pv[4*nf+3]);
  }
  // re-read as k-slice B-frags (per-wave-private tiles; same-wave ds order)
  bf16x8 cf[2], pf[2];
  cf[0] = packrow8(&ltc[wid][er][q * 8]); cf[1] = packrow8(&ltc[wid][er][32 + q * 8]);
  pf[0] = packrow8(&ltp[wid][er][q * 8]); pf[1] = packrow8(&ltp[wid][er][32 + q * 8]);

  // z = silu(chem @ wsh + bsh) * pos
  float z[16];
  {
    f32x4 acc[4] = {zero, zero, zero, zero};
    mm4(wtb + (size_t)16 * 4096, er, q, cf, acc);
#pragma unroll
    for (int nf = 0; nf < 4; ++nf) {
      const float4 b4 = *(const float4*)(bsh + nf * 16 + q * 4);
      z[4*nf+0] = fsilu(acc[nf].x + b4.x) * pv[4*nf+0];
      z[4*nf+1] = fsilu(acc[nf].y + b4.y) * pv[4*nf+1];
      z[4*nf+2] = fsilu(acc[nf].z + b4.z) * pv[4*nf+2];
      z[4*nf+3] = fsilu(acc[nf].w + b4.w) * pv[4*nf+3];
    }
  }
  // att gate
  {
    float ap = 0.f;
#pragma unroll
    for (int nf = 0; nf < 4; ++nf)
#pragma unroll
      for (int r = 0; r < 4; ++r)
        ap = fmaf(z[4*nf+r], watt[nf * 16 + q * 4 + r], ap);
    ap += __shfl_xor(ap, 16);
    ap += __shfl_xor(ap, 32);
    const float sg = fsig(ap + batt[0]);
#pragma unroll
    for (int j = 0; j < 16; ++j) z[j] *= sg;
  }
  // zb bf16 row (layout identical to original): uint idx = nf*8 + q*2
  {
    unsigned* zrow = zb + (size_t)e * 32 + q * 2;
#pragma unroll
    for (int nf = 0; nf < 4; ++nf) {
      uint2 w = make_uint2(pack2(z[4*nf+0], z[4*nf+1]), pack2(z[4*nf+2], z[4*nf+3]));
      *(uint2*)(zrow + nf * 8) = w;
    }
  }
  // per-head b scalars
  {
    float bb[4];
#pragma unroll
    for (int hd = 0; hd < 4; ++hd) {
      float b = 0.f;
#pragma unroll
      for (int nf = 0; nf < 4; ++nf)
#pragma unroll
        for (int r = 0; r < 4; ++r)
          b = fmaf(z[4*nf+r], wb[hd * 64 + nf * 16 + q * 4 + r], b);
      b += __shfl_xor(b, 16);
      b += __shfl_xor(b, 32);
      bb[hd] = b;
    }
    if (q == 0)
      *(float4*)(be + (size_t)e * 4) = make_float4(bb[0], bb[1], bb[2], bb[3]);
  }
  // u = silu(chem@wu1+bu1)@wu2 + bu2
  float u;
  {
    f32x4 acc[4] = {zero, zero, zero, zero};
    mm4(wtb + (size_t)17 * 4096, er, q, cf, acc);
    float up = 0.f;
#pragma unroll
    for (int nf = 0; nf < 4; ++nf) {
      const float4 b4 = *(const float4*)(bu1 + nf * 16 + q * 4);
      const float4 w4 = *(const float4*)(wu2 + nf * 16 + q * 4);
      up = fmaf(fsilu(acc[nf].x + b4.x), w4.x, up);
      up = fmaf(fsilu(acc[nf].y + b4.y), w4.y, up);
      up = fmaf(fsilu(acc[nf].z + b4.z), w4.z, up);
      up = fmaf(fsilu(acc[nf].w + b4.w), w4.w, up);
    }
    up += __shfl_xor(up, 16);
    up += __shfl_xor(up, 32);
    u = up + bu2[0];
  }
  // xs = silu(pos@wx1+bx1)@wx2 + bx2
  float xs;
  {
    f32x4 acc[4] = {zero, zero, zero, zero};
    mm4(wtb + (size_t)18 * 4096, er, q, pf, acc);
    float xp = 0.f;
#pragma unroll
    for (int nf = 0; nf < 4; ++nf) {
      const float4 b4 = *(const float4*)(bx1 + nf * 16 + q * 4);
      const float4 w4 = *(const float4*)(wx2 + nf * 16 + q * 4);
      xp = fmaf(fsilu(acc[nf].x + b4.x), w4.x, xp);
      xp = fmaf(fsilu(acc[nf].y + b4.y), w4.y, xp);
      xp = fmaf(fsilu(acc[nf].z + b4.z), w4.z, xp);
      xp = fmaf(fsilu(acc[nf].w + b4.w), w4.w, xp);
    }
    xp += __shfl_xor(xp, 16);
    xp += __shfl_xor(xp, 32);
    xs = xp + bx2[0];
  }

  if (q == 0) {
    const int r = edges[e], c = edges[NE + e];
    float dx = coord[r * 3 + 0] - coord[c * 3 + 0];
    float dy = coord[r * 3 + 1] - coord[c * 3 + 1];
    float dz = coord[r * 3 + 2] - coord[c * 3 + 2];
    float nrm = sqrtf(dx * dx + dy * dy + dz * dz);
    float inv = 1.0f / (nrm + 1e-8f);
    float t = u * xs;
    atomicAdd(&x_sum[r * 3 + 0], dx * inv * t);
    atomicAdd(&x_sum[r * 3 + 1], dy * inv * t);
    atomicAdd(&x_sum[r * 3 + 2], dz * inv * t);
    atomicAdd(&cntf[r], 1.0f);
  }
}

// ---------- MFMA projections -> ksep/vsep/qho/gf8 fp8, position-permuted records ----------
// Record uint idx = q*4+nf -> each lane stores one coalesced uint4 (1KB/wave-store).
// Permutation is shared by K/Q/V/gate/ho; only w_out (wtb 19..22) compensates (chan-perm).
// et=2 (32 edges/wave) doubles wave count for latency hiding.
__global__ void __launch_bounds__(256)
k_projm(const unsigned* __restrict__ zb, const unsigned short* __restrict__ wtb,
        const float* __restrict__ bg,
        unsigned* __restrict__ ksep, unsigned* __restrict__ vsep,
        unsigned* __restrict__ qho, unsigned* __restrict__ gf8) {
  const int lane = threadIdx.x & 63;
  const int wid  = threadIdx.x >> 6;        // wave 0..3
  const int er   = lane & 15;               // edge-in-tile (D col / B col / A row)
  const int q    = lane >> 4;               // k-block (A/B), row-quad (D)
  const int e0   = blockIdx.x * 128 + wid * 32 + er;

  // B frags: z^T, col=e, k=(lane>>4)*8 + i (+32 for half 1)
  bf16x8 zf[2][2];
#pragma unroll
  for (int et = 0; et < 2; ++et) {
    const unsigned* zrow = zb + (size_t)(e0 + et * 16) * 32;   // 64 bf16
    zf[et][0] = __builtin_bit_cast(bf16x8, *(const uint4*)(zrow + q * 4));
    zf[et][1] = __builtin_bit_cast(bf16x8, *(const uint4*)(zrow + 16 + q * 4));
  }

  const f32x4 zero = {0.f, 0.f, 0.f, 0.f};
#pragma unroll 1
  for (int m = 0; m < 16; ++m) {
    const unsigned short* wm = wtb + (size_t)m * 4096;
    f32x4 acc[2][4];
#pragma unroll
    for (int et = 0; et < 2; ++et)
#pragma unroll
      for (int nf = 0; nf < 4; ++nf) acc[et][nf] = zero;
#pragma unroll
    for (int nf = 0; nf < 4; ++nf) {
      const unsigned short* ar = wm + (size_t)(nf * 16 + er) * 64 + q * 8;
      const bf16x8 a0 = *(const bf16x8*)ar;
      const bf16x8 a1 = *(const bf16x8*)(ar + 32);
#pragma unroll
      for (int et = 0; et < 2; ++et) {
        acc[et][nf] = __builtin_amdgcn_mfma_f32_16x16x32_bf16(a0, zf[et][0], acc[et][nf], 0, 0, 0);
        acc[et][nf] = __builtin_amdgcn_mfma_f32_16x16x32_bf16(a1, zf[et][1], acc[et][nf], 0, 0, 0);
      }
    }
    const int hd = m >> 2, which = m & 3;    // wave-uniform
#pragma unroll
    for (int et = 0; et < 2; ++et) {
      const size_t rec = (size_t)(e0 + et * 16) * 4 + hd;
      unsigned* dst = (which == 0) ? (ksep + rec * 16)
                    : (which == 1) ? (vsep + rec * 16)
                    : (which == 2) ? (qho + rec * 16)
                                   : (gf8 + rec * 16);
      unsigned pk[4];
      if (which == 3) {
#pragma unroll
        for (int nf = 0; nf < 4; ++nf) {
          const float4 b4 = *(const float4*)(bg + hd * 64 + nf * 16 + q * 4);
          pk[nf] = packf8_4(fsig(acc[et][nf].x + b4.x), fsig(acc[et][nf].y + b4.y),
                            fsig(acc[et][nf].z + b4.z), fsig(acc[et][nf].w + b4.w));
        }
      } else {
#pragma unroll
        for (int nf = 0; nf < 4; ++nf)
          pk[nf] = packf8_4(acc[et][nf].x, acc[et][nf].y,
                            acc[et][nf].z, acc[et][nf].w);
      }
      *(uint4*)(dst + q * 4) = make_uint4(pk[0], pk[1], pk[2], pk[3]);
    }
  }
}

// ---------- fused attention + output projection (8 threads/edge, d-split halves) ----------
// Lane pair (half=0/1) owns d in [half*32, half*32+32): q/ov are 32 f32 each ->
// VGPR ~70, per-thread gather chain halved, 2x waves for latency hiding.
// Half dots combine via __shfl_xor(d,1) (pair-uniform mask branch). Softmax duplicated.
// LDS row (e_local*4+hd) ragged base r*33+((r>>2)&3); each half writes 16 uints.
// Phase 2 (after barrier): waves 0-1 run the verified k_mout MFMA epilogue (32 edges).
// medge aliases qho (R3): q/gate reads complete before the barrier -> safe in-place.
__global__ void __launch_bounds__(256)
k_attnm(const unsigned* __restrict__ qho, const unsigned* __restrict__ gf8,
        const unsigned* __restrict__ ksep, const unsigned* __restrict__ vsep,
        const float* __restrict__ be, const int* __restrict__ klist,
        const unsigned short* __restrict__ wtb, float* __restrict__ medge) {
  __shared__ unsigned hl[128 * 33 + 4];   // ragged rows: base(r) = r*33 + ((r>>2)&3)
  const int tid = threadIdx.x;
  const int gt = blockIdx.x * 256 + tid;
  const int e = gt >> 3;
  const int hd = (gt >> 1) & 3, half = gt & 1;
  const int t = e * 4 + hd;               // record index

  // q half (fp8 -> fp32, position order; same permutation as K -> dot invariant)
  float q[32];
  {
    unsigned qp[8];
    const uint4* qr = (const uint4*)(qho + (size_t)t * 16 + half * 8);
    uint4 a = qr[0], b = qr[1];
    qp[0] = a.x; qp[1] = a.y; qp[2] = a.z; qp[3] = a.w;
    qp[4] = b.x; qp[5] = b.y; qp[6] = b.z; qp[7] = b.w;
    unpackf8_32(qp, q);
  }

  int i2[8], j2[8];
#pragma unroll
  for (int kn = 0; kn < 8; ++kn) {
    i2[kn] = klist[(size_t)e * 16 + kn];
    j2[kn] = klist[(size_t)e * 16 + 8 + kn];
  }
  float bv[8];
#pragma unroll
  for (int kn = 0; kn < 8; ++kn)
    bv[kn] = be[(size_t)((i2[kn] < 0) ? 0 : j2[kn]) * 4 + hd];

  const uint4* k4 = (const uint4*)ksep;   // 4 uint4 per record; half owns 2
  float alpha[8];
#pragma unroll 2
  for (int kn = 0; kn < 8; ++kn) {
    float d = 0.f;
    if (i2[kn] >= 0) {
      const uint4* kr = k4 + ((size_t)i2[kn] * 4 + hd) * 4 + half * 2;
      uint4 u0 = kr[0], u1 = kr[1];
      d = dot16p(u0, q) + dot16p(u1, q + 16);
    }
    d += __shfl_xor(d, 1);               // combine halves (pair-uniform path)
    alpha[kn] = (i2[kn] < 0) ? -10000.0f : fmaf(d, 0.125f, bv[kn]);
  }
  float mx = alpha[0];
#pragma unroll
  for (int kn = 1; kn < 8; ++kn) mx = fmaxf(mx, alpha[kn]);
  float p[8], s = 0.f;
#pragma unroll
  for (int kn = 0; kn < 8; ++kn) { p[kn] = __expf(alpha[kn] - mx); s += p[kn]; }
  float is = 1.0f / s;
#pragma unroll
  for (int kn = 0; kn < 8; ++kn) p[kn] *= is;

  float ov[32];
#pragma unroll
  for (int j = 0; j < 32; ++j) ov[j] = 0.f;
  const uint4* v4 = (const uint4*)vsep;
#pragma unroll 2
  for (int kn = 0; kn < 8; ++kn) {
    int vi = (i2[kn] < 0) ? (NE - 1) : i2[kn];   // jax v[-1] wraps
    const uint4* vr = v4 + ((size_t)vi * 4 + hd) * 4 + half * 2;
    uint4 u0 = vr[0], u1 = vr[1];
    const float pk = p[kn];
    acc16(u0, pk, ov);
    acc16(u1, pk, ov + 16);
  }
  // gate half (precomputed sigmoid, fp8) -> gated ho bf16 half into LDS
  {
    unsigned gp[8];
    const uint4* gr = (const uint4*)(gf8 + (size_t)t * 16 + half * 8);
    uint4 a = gr[0], b = gr[1];
    gp[0] = a.x; gp[1] = a.y; gp[2] = a.z; gp[3] = a.w;
    gp[4] = b.x; gp[5] = b.y; gp[6] = b.z; gp[7] = b.w;
    float g[32];
    unpackf8_32(gp, g);
#pragma unroll
    for (int j = 0; j < 32; ++j) ov[j] *= g[j];
    const int r = (tid >> 3) * 4 + hd;
    unsigned* hw = hl + r * 33 + ((r >> 2) & 3) + half * 16;
#pragma unroll
    for (int j = 0; j < 16; ++j) hw[j] = pack2(ov[2*j], ov[2*j+1]);
  }
  __syncthreads();

  // ---- output projection: m[e] = sum_hd ho_hd @ Wout_hd (chan-permuted wtb 19..22)
  const int lane = tid & 63;
  const int w    = tid >> 6;           // 0..3; waves 0-1 active
  if (w < 2) {
    const int er   = lane & 15;
    const int qq   = lane >> 4;
    const int eg   = blockIdx.x * 32 + w * 16 + er;

    const f32x4 zero = {0.f, 0.f, 0.f, 0.f};
    f32x4 acc[4] = {zero, zero, zero, zero};
#pragma unroll 1
    for (int hd2 = 0; hd2 < 4; ++hd2) {
      const int r = (w * 16 + er) * 4 + hd2;
      const unsigned* hr = hl + r * 33 + ((r >> 2) & 3);
      uint4 u0 = make_uint4(hr[qq*4], hr[qq*4+1], hr[qq*4+2], hr[qq*4+3]);
      uint4 u1 = make_uint4(hr[16+qq*4], hr[16+qq*4+1], hr[16+qq*4+2], hr[16+qq*4+3]);
      const bf16x8 hf0 = __builtin_bit_cast(bf16x8, u0);
      const bf16x8 hf1 = __builtin_bit_cast(bf16x8, u1);
      const unsigned short* wm = wtb + (size_t)(19 + hd2) * 4096;
#pragma unroll
      for (int nf = 0; nf < 4; ++nf) {
        const unsigned short* ar = wm + (size_t)(nf * 16 + er) * 64 + qq * 8;
        const bf16x8 a0 = *(const bf16x8*)ar;
        const bf16x8 a1 = *(const bf16x8*)(ar + 32);
        acc[nf] = __builtin_amdgcn_mfma_f32_16x16x32_bf16(a0, hf0, acc[nf], 0, 0, 0);
        acc[nf] = __builtin_amdgcn_mfma_f32_16x16x32_bf16(a1, hf1, acc[nf], 0, 0, 0);
      }
    }
#pragma unroll
    for (int nf = 0; nf < 4; ++nf)
      *(float4*)(medge + (size_t)eg * 64 + nf * 16 + qq * 4) =
          make_float4(acc[nf].x, acc[nf].y, acc[nf].z, acc[nf].w);
  }
}

// ---------- CSR gather: per-node segment sum of medge ----------
__global__ void __launch_bounds__(256)
k_nodesum(const float* __restrict__ medge, const int* __restrict__ ioffs,
          const int* __restrict__ eidx, float* __restrict__ m_sum) {
  const int wid = threadIdx.x >> 6, lane = threadIdx.x & 63;
  const int n = blockIdx.x * 4 + wid;
  if (n >= NN) return;
  const int beg = ioffs[n], end = ioffs[n + 1];
  float acc = 0.f;
  for (int i = beg; i < end; ++i) {
    int e = eidx[i];
    acc += medge[(size_t)e * 64 + lane];
  }
  m_sum[(size_t)n * 64 + lane] = acc;
}

// ---------- final node update via MFMA: wave = 16 nodes ----------
__global__ void __launch_bounds__(256)
k_finm(const float* __restrict__ h, const float* __restrict__ na,
       const float* __restrict__ coord, const float* __restrict__ icoord,
       const float* __restrict__ m_sum, const float* __restrict__ x_sum,
       const float* __restrict__ cntf, const float* __restrict__ bout,
       const unsigned short* __restrict__ wtb,
       const float* __restrict__ bh1, const float* __restrict__ bh2,
       float* __restrict__ out) {
  __shared__ float lt[4][16][68];   // +4 pad breaks er*64 bank alias
  const int lane = threadIdx.x & 63;
  const int wid  = threadIdx.x >> 6;
  const int er   = lane & 15;
  const int q    = lane >> 4;
  const int e    = blockIdx.x * 64 + wid * 16 + er;
  const bool valid = e < NN;
  const int el = valid ? e : 0;

  const float* hr = h + (size_t)el * 64;
  const float* nr = na + (size_t)el * 64;
  const float* mr = m_sum + (size_t)el * 64;
  const float cn = cntf[el];
  const float invc = 1.0f / fmaxf(cn, 1.0f);
  const float bsc = (cn > 0.f) ? 1.0f : 0.0f;   // empty segment => m_agg = 0

  // B-frags: h, na, m_agg k-slices (bf16)
  bf16x8 hf[2], naf[2], mf[2];
  hf[0]  = packrow8(hr + q * 8); hf[1]  = packrow8(hr + 32 + q * 8);
  naf[0] = packrow8(nr + q * 8); naf[1] = packrow8(nr + 32 + q * 8);
#pragma unroll
  for (int half = 0; half < 2; ++half) {
    const int o = half * 32 + q * 8;
    const float4 m0 = *(const float4*)(mr + o);
    const float4 m1 = *(const float4*)(mr + o + 4);
    const float4 b0 = *(const float4*)(bout + o);
    const float4 b1 = *(const float4*)(bout + o + 4);
    float ma[8];
    ma[0] = fmaf(m0.x, invc, b0.x * bsc); ma[1] = fmaf(m0.y, invc, b0.y * bsc);
    ma[2] = fmaf(m0.z, invc, b0.z * bsc); ma[3] = fmaf(m0.w, invc, b0.w * bsc);
    ma[4] = fmaf(m1.x, invc, b1.x * bsc); ma[5] = fmaf(m1.y, invc, b1.y * bsc);
    ma[6] = fmaf(m1.z, invc, b1.z * bsc); ma[7] = fmaf(m1.w, invc, b1.w * bsc);
    uint4 u = make_uint4(pack2(ma[0], ma[1]), pack2(ma[2], ma[3]),
                         pack2(ma[4], ma[5]), pack2(ma[6], ma[7]));
    mf[half] = __builtin_bit_cast(bf16x8, u);
  }

  const f32x4 zero = {0.f, 0.f, 0.f, 0.f};
  f32x4 acc[4] = {zero, zero, zero, zero};
  mm4(wtb + (size_t)23 * 4096, er, q, hf,  acc);
  mm4(wtb + (size_t)24 * 4096, er, q, naf, acc);
  mm4(wtb + (size_t)25 * 4096, er, q, mf,  acc);
#pragma unroll
  for (int nf = 0; nf < 4; ++nf) {
    const float4 b4 = *(const float4*)(bh1 + nf * 16 + q * 4);
    float* d = &lt[wid][er][nf * 16 + q * 4];
    d[0] = fsilu(acc[nf].x + b4.x); d[1] = fsilu(acc[nf].y + b4.y);
    d[2] = fsilu(acc[nf].z + b4.z); d[3] = fsilu(acc[nf].w + b4.w);
  }
  __syncthreads();
  bf16x8 sf[2];
  sf[0] = packrow8(&lt[wid][er][q * 8]);
  sf[1] = packrow8(&lt[wid][er][32 + q * 8]);
  f32x4 a2[4] = {zero, zero, zero, zero};
  mm4(wtb + (size_t)26 * 4096, er, q, sf, a2);
  if (valid) {
#pragma unroll
    for (int nf = 0; nf < 4; ++nf) {
      const float4 b4 = *(const float4*)(bh2 + nf * 16 + q * 4);
      const float4 h4 = *(const float4*)(hr + nf * 16 + q * 4);
      *(float4*)(out + (size_t)e * 64 + nf * 16 + q * 4) =
          make_float4(a2[nf].x + b4.x + h4.x, a2[nf].y + b4.y + h4.y,
                      a2[nf].z + b4.z + h4.z, a2[nf].w + b4.w + h4.w);
    }
    if (q == 0) {
#pragma unroll
      for (int d = 0; d < 3; ++d)
        out[(size_t)NN * 64 + e * 3 + d] =
            0.2f * icoord[e * 3 + d] + 0.8f * coord[e * 3 + d] + x_sum[e * 3 + d] * invc;
    }
  }
}

extern "C" void kernel_launch(void* const* d_in, const int* in_sizes, int n_in,
                              void* d_out, int out_size, void* d_ws, size_t ws_size,
                              hipStream_t stream) {
  (void)in_sizes; (void)n_in; (void)out_size; (void)ws_size;
  const float* h      = (const float*)d_in[0];
  const float* coord  = (const float*)d_in[1];
  const int*   edges  = (const int*)  d_in[2];
  const float* nvecs  = (const float*)d_in[3];
  const float* ea     = (const float*)d_in[4];
  const float* na     = (const float*)d_in[5];
  const float* icoord = (const float*)d_in[6];
  const int*   klist  = (const int*)  d_in[7];
  const float* w_chem1 = (const float*)d_in[8];
  const float* b_chem1 = (const float*)d_in[9];
  const float* w_chem2 = (const float*)d_in[10];
  const float* b_chem2 = (const float*)d_in[11];
  const float* w_pos1  = (const float*)d_in[12];
  const float* b_pos1  = (const float*)d_in[13];
  const float* w_pos2  = (const float*)d_in[14];
  const float* b_pos2  = (const float*)d_in[15];
  const float* w_sh    = (const float*)d_in[16];
  const float* b_sh    = (const float*)d_in[17];
  const float* w_att   = (const float*)d_in[18];
  const float* b_att   = (const float*)d_in[19];
  const float* wq      = (const float*)d_in[20];
  const float* wk      = (const float*)d_in[21];
  const float* wv      = (const float*)d_in[22];
  const float* wb      = (const float*)d_in[23];
  const float* wg      = (const float*)d_in[24];
  const float* bg      = (const float*)d_in[25];
  const float* w_out   = (const float*)d_in[26];
  const float* b_out   = (const float*)d_in[27];
  const float* wu1     = (const float*)d_in[28];
  const float* bu1     = (const float*)d_in[29];
  const float* wu2     = (const float*)d_in[30];
  const float* bu2     = (const float*)d_in[31];
  const float* wx1     = (const float*)d_in[32];
  const float* bx1     = (const float*)d_in[33];
  const float* wx2     = (const float*)d_in[34];
  const float* bx2     = (const float*)d_in[35];
  const float* wh1     = (const float*)d_in[36];
  const float* bh1     = (const float*)d_in[37];
  const float* wh2     = (const float*)d_in[38];
  const float* bh2     = (const float*)d_in[39];

  float* out = (float*)d_out;
  float* ws  = (float*)d_ws;
  // Phase-reused regions (NE*64 floats each):
  //  R1: act1c -> ksep [NE*4][64B] fp8 K
  //  R2: act1p -> vsep [NE*4][64B] fp8 V
  //  R3: qho  [NE*4][16u] fp8 q -> medge fp32 (in-place, barrier-separated)
  //  R4: gf8  [NE*4][16u] fp8 gate (dead after attn)
  float* R1 = ws;
  float* R2 = R1 + (size_t)NE * 64;
  float* R3 = R2 + (size_t)NE * 64;
  float* R4 = R3 + (size_t)NE * 64;
  float* zbf   = R4 + (size_t)NE * 64;      // NE*32 floats (bf16 gated z)
  float* x_sum = zbf + (size_t)NE * 32;     // NN*3 (zeroed)
  float* cntf  = x_sum + (size_t)NN * 3;    // NN (zeroed)
  int*   icnt  = (int*)(cntf + NN);         // NN (zeroed)
  int*   icur  = icnt + NN;                 // NN (zeroed)
  float* m_sum = (float*)(icur + NN);       // NN*64
  float* be    = m_sum + (size_t)NN * 64;   // 4*NE  ([e*4+hd] layout)
  unsigned short* wtb = (unsigned short*)(be + (size_t)4 * NE);  // 34*64*64 bf16 (278KB)
  int*   ioffs = (int*)(wtb + 34 * 4096);   // NN+1
  int*   eidx  = ioffs + (NN + 1);          // NE

  unsigned* ksep = (unsigned*)R1;  // [NE*4][16u] fp8 K (deinterleaved, pos-permuted)
  unsigned* vsep = (unsigned*)R2;  // [NE*4][16u] fp8 V
  unsigned* qho  = (unsigned*)R3;  // [NE*4][16u] fp8 q
  unsigned* gf8  = (unsigned*)R4;  // [NE*4][16u] fp8 gate
  unsigned* zb   = (unsigned*)zbf;
  float* medge = R3;               // fused attn writes in-place over qho

  (void)hipMemsetAsync(x_sum, 0, ((size_t)NN * 3 + NN + NN + NN) * sizeof(float), stream);

  dim3 b256(256);
  dim3 gflat(NE / 256);

  // weight prep + CSR build (independent of the MLP pipeline)
  k_wprep<<<dim3(34), b256, 0, stream>>>(wk, wv, wq, wg, w_sh, wu1, wx1, w_out,
                                         wh1, wh2, w_chem2, w_pos2, w_chem1, wtb);
  k_count<<<gflat, b256, 0, stream>>>(edges, icnt);
  k_scan <<<dim3(1), b256, 0, stream>>>(icnt, ioffs);
  k_fill <<<gflat, b256, 0, stream>>>(edges, ioffs, icur, eidx);

  k_chem1m<<<dim3(NE / 64), b256, 0, stream>>>(h, na, ea, edges, wtb, b_chem1, R1);
  k_pos1  <<<dim3(NE / 256, 2), b256, 0, stream>>>(coord, nvecs, ea, edges, w_pos1, b_pos1, R2);
  k_l2s   <<<dim3(NE / 64), b256, 0, stream>>>(coord, edges, R1, R2, wtb,
                                               b_chem2, b_pos2, b_sh, w_att, b_att,
                                               bu1, wu2, bu2, bx1, wx2, bx2, wb,
                                               zb, be, x_sum, cntf);
  k_projm<<<dim3(NE / 128), b256, 0, stream>>>(zb, wtb, bg, ksep, vsep, qho, gf8);
  k_attnm<<<dim3(NE * 8 / 256), b256, 0, stream>>>(qho, gf8, ksep, vsep, be, klist,
                                                   wtb, medge);
  k_nodesum<<<dim3((NN + 3) / 4), b256, 0, stream>>>(medge, ioffs, eidx, m_sum);
  k_finm<<<dim3((NN + 63) / 64), b256, 0, stream>>>(h, na, coord, icoord, m_sum, x_sum,
                                                    cntf, b_out, wtb, bh1, bh2, out);
}